// Round 7
// baseline (268.581 us; speedup 1.0000x reference)
//
#include <hip/hip_runtime.h>
#include <cmath>
#include <complex>

#define T_TAB 4096
#define G_TAB 8
#define NN 16384
#define CH 16

// ---------------- CG tables (exact host-side port of the reference) ----------------
struct CGPack {
  float c000[1];
  float c110[9];
  float c220[25];
  float c330[49];
  float c011[9];
  float c101[9];
  float c111[27];
  float c121[45];
  float c211[45];
  float c221[75];
  float c231[105];
  float c321[105];
  float c331[147];
};

static double factd(int n){ double r=1.0; for(int i=2;i<=n;++i) r*=(double)i; return r; }

static double cg_coef(int j1,int m1,int j2,int m2,int j3,int m3){
  double pref = sqrt((2.0*j3+1.0)*factd(j3+j1-j2)*factd(j3-j1+j2)*factd(j1+j2-j3)/factd(j1+j2+j3+1));
  pref *= sqrt(factd(j3+m3)*factd(j3-m3)*factd(j1-m1)*factd(j1+m1)*factd(j2-m2)*factd(j2+m2));
  double s=0.0;
  for(int k=0;k<=j1+j2-j3;++k){
    int a0=k,a1=j1+j2-j3-k,a2=j1-m1-k,a3=j2+m2-k,a4=j3-j2+m1+k,a5=j3-j1-m2+k;
    if(a0<0||a1<0||a2<0||a3<0||a4<0||a5<0) continue;
    double d=factd(a0)*factd(a1)*factd(a2)*factd(a3)*factd(a4)*factd(a5);
    s += ((k&1)?-1.0:1.0)/d;
  }
  return pref*s;
}

static void u_fill(int l, std::complex<double> U[7][7]){
  for(int i=0;i<7;++i) for(int j=0;j<7;++j) U[i][j]=std::complex<double>(0.0,0.0);
  const double is2 = 1.0/sqrt(2.0);
  U[l][l]=1.0;
  for(int m=1;m<=l;++m){
    double sgn = (m&1)?-1.0:1.0;
    U[l+m][l+m] = sgn*is2;
    U[l+m][l-m] = is2;
    U[l-m][l-m] = std::complex<double>(0.0, is2);
    U[l-m][l+m] = std::complex<double>(0.0, -sgn*is2);
  }
}

static void cg_fill(int l1,int l2,int l3, float* out){
  int n1=2*l1+1,n2=2*l2+1,n3=2*l3+1;
  double Cc[7][7][7];
  for(int a=0;a<7;++a)for(int b=0;b<7;++b)for(int c=0;c<7;++c) Cc[a][b][c]=0.0;
  for(int m1=-l1;m1<=l1;++m1)
    for(int m2=-l2;m2<=l2;++m2){
      int m3=m1+m2;
      if(m3>=-l3&&m3<=l3) Cc[m1+l1][m2+l2][m3+l3]=cg_coef(l1,m1,l2,m2,l3,m3);
    }
  std::complex<double> U1[7][7],U2[7][7],U3[7][7];
  u_fill(l1,U1); u_fill(l2,U2); u_fill(l3,U3);
  std::complex<double> Cr[343];
  double sre=0.0,sim=0.0;
  for(int a=0;a<n1;++a)for(int b=0;b<n2;++b)for(int c=0;c<n3;++c){
    std::complex<double> acc(0.0,0.0);
    for(int u=0;u<n1;++u)for(int v=0;v<n2;++v)for(int w=0;w<n3;++w){
      double cc=Cc[u][v][w];
      if(cc==0.0) continue;
      acc += U1[a][u]*U2[b][v]*std::conj(U3[c][w])*cc;
    }
    Cr[(a*n2+b)*n3+c]=acc;
    sre+=fabs(acc.real()); sim+=fabs(acc.imag());
  }
  bool useim = sim>sre;
  for(int idx=0;idx<n1*n2*n3;++idx) out[idx]=(float)(useim?Cr[idx].imag():Cr[idx].real());
}

static void build_cg(CGPack& P){
  cg_fill(0,0,0,P.c000);
  cg_fill(1,1,0,P.c110);
  cg_fill(2,2,0,P.c220);
  cg_fill(3,3,0,P.c330);
  cg_fill(0,1,1,P.c011);
  cg_fill(1,0,1,P.c101);
  cg_fill(1,1,1,P.c111);
  cg_fill(1,2,1,P.c121);
  cg_fill(2,1,1,P.c211);
  cg_fill(2,2,1,P.c221);
  cg_fill(2,3,1,P.c231);
  cg_fill(3,2,1,P.c321);
  cg_fill(3,3,1,P.c331);
}

// ---------------- device helpers ----------------
__device__ __forceinline__ float soh(float r, float c){
  float d = (r - c) * 2.0f;
  float d2 = d*d;
  return (d2 < 1.0f) ? 1.14136f * expf(2.0f + 1.0f/(d2-1.0f)) : 0.0f;
}

// Per-lane weight schedule: lane ℓ, sub-index q (0..7) -> (column in [0,272) or -1, LDS slot).
// Slot 31 is a guaranteed-zero slot.
__device__ __forceinline__ void lane_sched(int lane, int q, int& col, int& slot){
  col = -1; slot = 31;
  if (lane < 16){
    int s = q >> 2, qq = q & 3;
    int a = 2*lane + s;                 // scalar output index 0..31
    const int base0[4] = {0, 64, 144, 224};
    col = base0[qq] + a; slot = qq;
  } else if (lane < 40){
    int idx = lane-16, u = idx/3, k = idx-3*u;
    const int wb[6] = {32,48,112,128,192,208};
    const int sb[6] = {4,7,10,13,16,19};
    if (q < 6){ col = wb[q]+u; slot = sb[q]+k; }
  } else if (lane < 52){
    int m = lane-40;
    int c0 = (q < 4) ? 2*m : 2*m+1;
    int u = c0/3, k = c0-3*u;
    int qq = (q < 4) ? q : q-4;
    if (qq < 3){
      const int wb[3] = {96,176,256};
      const int sb[3] = {22,25,28};
      col = wb[qq]+u; slot = sb[qq]+k;
    }
  }
}

// ---------------- radial MLP lookup table: tab[T_TAB][336] ----------------
__global__ __launch_bounds__(256) void k_table(
    const float* __restrict__ W1, const float* __restrict__ W2,
    const float* __restrict__ W1f, const float* __restrict__ W2f,
    float* __restrict__ tab)
{
  __shared__ float h[G_TAB][256];
  __shared__ float hf[G_TAB][256];
  const int c = threadIdx.x;
  const int t0 = blockIdx.x * G_TAB;
  const float dr = 2.5f / (float)(T_TAB-1);
  const float w1a = W1[c], w1b = W1[256+c], w1c = W1[512+c];
  const float f1a = W1f[c], f1b = W1f[256+c], f1c = W1f[512+c];
#pragma unroll
  for (int g=0; g<G_TAB; ++g){
    float r = (float)(t0+g) * dr;
    float e0 = soh(r,1.0f), e1 = soh(r,1.5f), e2 = soh(r,2.0f);
    h[g][c]  = fmaxf(e0*w1a + e1*w1b + e2*w1c, 0.0f);
    hf[g][c] = fmaxf(e0*f1a + e1*f1b + e2*f1c, 0.0f);
  }
  __syncthreads();
  for (int j = c; j < 336; j += 256){
    float acc[G_TAB];
#pragma unroll
    for (int g=0; g<G_TAB; ++g) acc[g]=0.0f;
    if (j < 272){
      for (int cc=0; cc<256; ++cc){
        float wv = W2[cc*272 + j];
#pragma unroll
        for (int g=0; g<G_TAB; ++g) acc[g] = fmaf(h[g][cc], wv, acc[g]);
      }
    } else {
      int jj = j - 272;
      for (int cc=0; cc<256; ++cc){
        float wv = W2f[cc*64 + jj];
#pragma unroll
        for (int g=0; g<G_TAB; ++g) acc[g] = fmaf(hf[g][cc], wv, acc[g]);
      }
    }
#pragma unroll
    for (int g=0; g<G_TAB; ++g) tab[(size_t)(t0+g)*336 + j] = acc[g] * 0.0625f;
  }
}

// ---------------- rowptr: dst is globally non-decreasing -> CSR via binary search ----
__global__ __launch_bounds__(256) void k_rowptr(
    const int* __restrict__ dst, int E, int* __restrict__ rowptr)
{
  const int n = blockIdx.x*256 + threadIdx.x;
  if (n > NN) return;
  int lo=0, hi=E;
  while (lo < hi){ int mid=(lo+hi)>>1; if (dst[mid] < n) lo=mid+1; else hi=mid; }
  rowptr[n]=lo;
}

// ---------------- x = segsum(sph_harm): 4 lanes/node, each edge touched once -------
__global__ __launch_bounds__(256) void k_x(
    const float* __restrict__ pos, const int* __restrict__ src,
    const int* __restrict__ rowptr, float* __restrict__ xacc)
{
  const int t = blockIdx.x*256 + threadIdx.x;
  const int n = t>>2, q = t&3;
  if (n>=NN) return;
  const int r0=rowptr[n], r1=rowptr[n+1];
  const float pdx=pos[3*n], pdy=pos[3*n+1], pdz=pos[3*n+2];
  const float s3=1.73205081f, s5=2.23606798f, s15=3.87298335f;
  const float c33=2.09165007f, c32=10.2469508f, c31=1.62018517f, c30=1.32287566f, cp2=5.12347538f;
  float a0=0,a1=0,a2=0,a3=0,a4=0,a5=0,a6=0,a7=0,a8=0,a9=0,a10=0,a11=0,a12=0,a13=0,a14=0,a15=0;
  for (int e=r0+q; e<r1; e+=4){
    const int s=src[e];
    float ax=pos[3*s]-pdx, ay=pos[3*s+1]-pdy, az=pos[3*s+2]-pdz;
    float ir = 1.0f/sqrtf(ax*ax+ay*ay+az*az);
    float x=ax*ir, y=ay*ir, z=az*ir;
    a0+=1.0f; a1+=s3*y; a2+=s3*z; a3+=s3*x;
    a4+=s15*x*y; a5+=s15*y*z; a6+=0.5f*s5*(3.0f*z*z-1.0f); a7+=s15*x*z;
    a8+=0.5f*s15*(x*x-y*y); a9+=c33*y*(3.0f*x*x-y*y); a10+=c32*x*y*z; a11+=c31*y*(5.0f*z*z-1.0f);
    a12+=c30*(5.0f*z*z*z-3.0f*z); a13+=c31*x*(5.0f*z*z-1.0f); a14+=cp2*z*(x*x-y*y);
    a15+=c33*x*(x*x-3.0f*y*y);
  }
#define RED(v) v += __shfl_xor(v,1); v += __shfl_xor(v,2);
  RED(a0) RED(a1) RED(a2) RED(a3) RED(a4) RED(a5) RED(a6) RED(a7)
  RED(a8) RED(a9) RED(a10) RED(a11) RED(a12) RED(a13) RED(a14) RED(a15)
#undef RED
  float o0,o1,o2,o3;
  if (q==0){ o0=a0; o1=a1; o2=a2; o3=a3; }
  else if (q==1){ o0=a4; o1=a5; o2=a6; o3=a7; }
  else if (q==2){ o0=a8; o1=a9; o2=a10; o3=a11; }
  else { o0=a12; o1=a13; o2=a14; o3=a15; }
  *(float4*)(xacc + (size_t)n*16 + q*4) = make_float4(o0,o1,o2,o3);
}

// ---------------- fctp1 + gate fused: 4 independent waves per block, 1 node/wave ----
// Phase 1: 4 lanes/edge -> 31 CG intermediates, stored as I*(1-al), I*al in LDS
//          (rows padded to 33 floats: bank = (je+slot)%32, conflict-free).
// Phase 2: per-lane scattered loads from the SHARED 336-float table row (L2-friendly:
//          all lanes + nearby-r edges hit the same lines; R6's per-lane permuted
//          layout quadrupled HBM fetch and regressed).
// Intra-wave fences only (LDS ops of one wave complete in order).
__global__ __launch_bounds__(256) void k_tp1(
    const float* __restrict__ pos, const int* __restrict__ src,
    const int* __restrict__ rowptr, const float* __restrict__ xacc,
    const float* __restrict__ tab, float* __restrict__ xg, CGPack cg)
{
  const int wid  = threadIdx.x >> 6;
  const int lane = threadIdx.x & 63;
  const int node = blockIdx.x*4 + wid;
  __shared__ float SIA[4][CH][33];
  __shared__ float SIB[4][CH][33];
  __shared__ int   SiT[4][CH];
  __shared__ float SG[4][32];
  const int r0 = rowptr[node], r1 = rowptr[node+1];
  const int nch = (r1 - r0 + CH - 1) / CH;

#define WAVE_FENCE() { asm volatile("s_waitcnt lgkmcnt(0)" ::: "memory"); __builtin_amdgcn_sched_barrier(0); }

  // ---- static (weight-col, LDS-slot) schedule + gate indices ----
  int wo[8], ioS[8];
#pragma unroll
  for (int p=0;p<8;++p){
    int c_, s_; lane_sched(lane, p, c_, s_);
    wo[p] = (c_>=0) ? c_ : 0; ioS[p] = s_;
  }
  int gu0=16, gu1=16;
  if (lane >= 16 && lane < 40){ gu0 = 16 + (lane-16)/3; }
  else if (lane >= 40 && lane < 52){
    int m=lane-40; gu0 = 24 + (2*m)/3; gu1 = 24 + (2*m+1)/3;
  }

  const float pdx=pos[3*node], pdy=pos[3*node+1], pdz=pos[3*node+2];
  const int je = lane & 15, part = lane >> 4;
  float acc0 = 0.f, acc1 = 0.f;

  for (int t=0; t<nch; ++t){
    const int e0 = r0 + t*CH;
    const int cnt = min(CH, r1-e0);
    WAVE_FENCE();                    // WAR: phase-2 reads of prev chunk done
    if (je < cnt){
      const int e = e0 + je;
      const int s = src[e];
      float ax=pos[3*s]-pdx, ay=pos[3*s+1]-pdy, az=pos[3*s+2]-pdz;
      float r = sqrtf(ax*ax+ay*ay+az*az);
      float ir = 1.0f/r;
      float x=ax*ir, y=ay*ir, z=az*ir;
      float f = r * 1638.0f;                    // (T_TAB-1)/2.5
      int i0 = (int)f; if (i0 > T_TAB-2) i0 = T_TAB-2;
      float bl = f - (float)i0;
      float aw = 1.0f - bl;

      const float s3=1.73205081f, s5=2.23606798f, s15=3.87298335f;
      const float c33=2.09165007f, c32=10.2469508f, c31=1.62018517f, c30=1.32287566f, cp2=5.12347538f;
      float Y[16];
      Y[0]=1.0f;
      Y[1]=s3*y; Y[2]=s3*z; Y[3]=s3*x;
      Y[4]=s15*x*y; Y[5]=s15*y*z; Y[6]=0.5f*s5*(3.0f*z*z-1.0f); Y[7]=s15*x*z; Y[8]=0.5f*s15*(x*x-y*y);
      Y[9]=c33*y*(3.0f*x*x-y*y); Y[10]=c32*x*y*z; Y[11]=c31*y*(5.0f*z*z-1.0f);
      Y[12]=c30*(5.0f*z*z*z-3.0f*z); Y[13]=c31*x*(5.0f*z*z-1.0f); Y[14]=cp2*z*(x*x-y*y);
      Y[15]=c33*x*(x*x-3.0f*y*y);
      float X[16];
      {
        const float inv = 0.5129891760f;           // 1/sqrt(3.8)
        const float4* q4 = (const float4*)(xacc + (size_t)s*16);
        float4 a=q4[0],b=q4[1],cc4=q4[2],d4=q4[3];
        X[0]=a.x*inv;X[1]=a.y*inv;X[2]=a.z*inv;X[3]=a.w*inv;
        X[4]=b.x*inv;X[5]=b.y*inv;X[6]=b.z*inv;X[7]=b.w*inv;
        X[8]=cc4.x*inv;X[9]=cc4.y*inv;X[10]=cc4.z*inv;X[11]=cc4.w*inv;
        X[12]=d4.x*inv;X[13]=d4.y*inv;X[14]=d4.z*inv;X[15]=d4.w*inv;
      }
      float* A_ = SIA[wid][je];
      float* B_ = SIB[wid][je];
#define PUT(slot, val) { float vv_=(val); A_[slot]=vv_*aw; B_[slot]=vv_*bl; }
      if (part == 0){
        float t0v = cg.c000[0]*X[0]*Y[0];
        float t1v=0.f, t2v=0.f, t3v=0.f;
#pragma unroll
        for (int i=0;i<3;++i)
#pragma unroll
          for (int j=0;j<3;++j) t1v = fmaf(X[1+i]*Y[1+j], cg.c110[i*3+j], t1v);
#pragma unroll
        for (int i=0;i<5;++i)
#pragma unroll
          for (int j=0;j<5;++j) t2v = fmaf(X[4+i]*Y[4+j], cg.c220[i*5+j], t2v);
#pragma unroll
        for (int i=0;i<7;++i)
#pragma unroll
          for (int j=0;j<7;++j) t3v = fmaf(X[9+i]*Y[9+j], cg.c330[i*7+j], t3v);
        float v12[3]={0,0,0};
#pragma unroll
        for (int i=0;i<3;++i)
#pragma unroll
          for (int j=0;j<5;++j){ float tt=X[1+i]*Y[4+j];
#pragma unroll
            for (int k=0;k<3;++k) v12[k]=fmaf(tt, cg.c121[(i*5+j)*3+k], v12[k]); }
        PUT(0,t0v) PUT(1,t1v) PUT(2,t2v) PUT(3,t3v)
        PUT(10,v12[0]) PUT(11,v12[1]) PUT(12,v12[2])
        A_[31]=0.0f; B_[31]=0.0f;
        SiT[wid][je]=i0;
      } else if (part == 1){
        float v01[3]={0,0,0}, v10[3]={0,0,0}, v33[3]={0,0,0};
#pragma unroll
        for (int j=0;j<3;++j){ float tt=X[0]*Y[1+j];
#pragma unroll
          for (int k=0;k<3;++k) v01[k]=fmaf(tt, cg.c011[j*3+k], v01[k]); }
#pragma unroll
        for (int i=0;i<3;++i){ float tt=X[1+i]*Y[0];
#pragma unroll
          for (int k=0;k<3;++k) v10[k]=fmaf(tt, cg.c101[i*3+k], v10[k]); }
#pragma unroll
        for (int i=0;i<7;++i)
#pragma unroll
          for (int j=0;j<7;++j){ float tt=X[9+i]*Y[9+j];
#pragma unroll
            for (int k=0;k<3;++k) v33[k]=fmaf(tt, cg.c331[(i*7+j)*3+k], v33[k]); }
        PUT(4,v01[0]) PUT(5,v01[1]) PUT(6,v01[2])
        PUT(7,v10[0]) PUT(8,v10[1]) PUT(9,v10[2])
        PUT(28,v33[0]) PUT(29,v33[1]) PUT(30,v33[2])
      } else if (part == 2){
        float v11[3]={0,0,0}, v21[3]={0,0,0}, v23[3]={0,0,0};
#pragma unroll
        for (int i=0;i<3;++i)
#pragma unroll
          for (int j=0;j<3;++j){ float tt=X[1+i]*Y[1+j];
#pragma unroll
            for (int k=0;k<3;++k) v11[k]=fmaf(tt, cg.c111[(i*3+j)*3+k], v11[k]); }
#pragma unroll
        for (int i=0;i<5;++i)
#pragma unroll
          for (int j=0;j<3;++j){ float tt=X[4+i]*Y[1+j];
#pragma unroll
            for (int k=0;k<3;++k) v21[k]=fmaf(tt, cg.c211[(i*3+j)*3+k], v21[k]); }
#pragma unroll
        for (int i=0;i<5;++i)
#pragma unroll
          for (int j=0;j<7;++j){ float tt=X[4+i]*Y[9+j];
#pragma unroll
            for (int k=0;k<3;++k) v23[k]=fmaf(tt, cg.c231[(i*7+j)*3+k], v23[k]); }
        PUT(22,v11[0]) PUT(23,v11[1]) PUT(24,v11[2])
        PUT(13,v21[0]) PUT(14,v21[1]) PUT(15,v21[2])
        PUT(16,v23[0]) PUT(17,v23[1]) PUT(18,v23[2])
      } else {
        float v22[3]={0,0,0}, v32[3]={0,0,0};
#pragma unroll
        for (int i=0;i<5;++i)
#pragma unroll
          for (int j=0;j<5;++j){ float tt=X[4+i]*Y[4+j];
#pragma unroll
            for (int k=0;k<3;++k) v22[k]=fmaf(tt, cg.c221[(i*5+j)*3+k], v22[k]); }
#pragma unroll
        for (int i=0;i<7;++i)
#pragma unroll
          for (int j=0;j<5;++j){ float tt=X[9+i]*Y[4+j];
#pragma unroll
            for (int k=0;k<3;++k) v32[k]=fmaf(tt, cg.c321[(i*5+j)*3+k], v32[k]); }
        PUT(25,v22[0]) PUT(26,v22[1]) PUT(27,v22[2])
        PUT(19,v32[0]) PUT(20,v32[1]) PUT(21,v32[2])
      }
#undef PUT
    }
    WAVE_FENCE();                    // RAW: phase-1 writes visible
    // ---- phase 2: shared-row table loads, fully static schedule ----
#pragma unroll 4
    for (int j=0; j<CH; ++j){
      if (j < cnt){
        const float* __restrict__ wr0 = tab + (size_t)SiT[wid][j]*336;
        const float* __restrict__ wr1 = wr0 + 336;
        const float* __restrict__ IA = SIA[wid][j];
        const float* __restrict__ IB = SIB[wid][j];
        acc0 = fmaf(wr0[wo[0]], IA[ioS[0]], acc0); acc0 = fmaf(wr1[wo[0]], IB[ioS[0]], acc0);
        acc0 = fmaf(wr0[wo[1]], IA[ioS[1]], acc0); acc0 = fmaf(wr1[wo[1]], IB[ioS[1]], acc0);
        acc0 = fmaf(wr0[wo[2]], IA[ioS[2]], acc0); acc0 = fmaf(wr1[wo[2]], IB[ioS[2]], acc0);
        acc0 = fmaf(wr0[wo[3]], IA[ioS[3]], acc0); acc0 = fmaf(wr1[wo[3]], IB[ioS[3]], acc0);
        acc1 = fmaf(wr0[wo[4]], IA[ioS[4]], acc1); acc1 = fmaf(wr1[wo[4]], IB[ioS[4]], acc1);
        acc1 = fmaf(wr0[wo[5]], IA[ioS[5]], acc1); acc1 = fmaf(wr1[wo[5]], IB[ioS[5]], acc1);
        acc1 = fmaf(wr0[wo[6]], IA[ioS[6]], acc1); acc1 = fmaf(wr1[wo[6]], IB[ioS[6]], acc1);
        acc1 = fmaf(wr0[wo[7]], IA[ioS[7]], acc1); acc1 = fmaf(wr1[wo[7]], IB[ioS[7]], acc1);
      }
    }
  }

  // ---- fused gate epilogue ----
  const float inv = 0.5129891760f;
  if (lane < 16){
    SG[wid][2*lane]   = acc0*0.5f*inv;
    SG[wid][2*lane+1] = acc1*0.5f*inv;
  }
  WAVE_FENCE();
  float* __restrict__ o = xg + (size_t)node*64;
  if (lane < 16){
    o[lane] = fmaxf(SG[wid][lane], 0.0f);                  // se
  } else if (lane < 40){
    int idx = lane-16;
    float vv = (acc0+acc1)*0.4082482905f*inv;
    o[16+idx] = vv * fmaxf(SG[wid][gu0], 0.0f);            // v1o (u<8)
  } else if (lane < 52){
    int m = lane-40;
    float vv0 = acc0*0.5773502692f*inv;
    float vv1 = acc1*0.5773502692f*inv;
    o[40+2*m]   = vv0 * fmaxf(SG[wid][gu0], 0.0f);         // v1e (u<8)
    o[40+2*m+1] = vv1 * fmaxf(SG[wid][gu1], 0.0f);
  }
#undef WAVE_FENCE
}

// ---------------- fctp2 per edge -> e2buf[E][4] (pruned) ----------------
__global__ __launch_bounds__(256) void k_tp2(
    const float* __restrict__ pos, const int* __restrict__ src, const int* __restrict__ dst, int E,
    const float* __restrict__ xg, const float* __restrict__ tab,
    float* __restrict__ e2buf, CGPack cg)
{
  const int e = blockIdx.x*256 + threadIdx.x;
  if (e>=E) return;
  const int s = src[e], d = dst[e];
  float ax=pos[3*s]-pos[3*d], ay=pos[3*s+1]-pos[3*d+1], az=pos[3*s+2]-pos[3*d+2];
  float r = sqrtf(ax*ax+ay*ay+az*az);
  float ir = 1.0f/r;
  float x=ax*ir, y=ay*ir, z=az*ir;
  float f = r * 1638.0f;
  int i0 = (int)f; if (i0 > T_TAB-2) i0 = T_TAB-2;
  const float al = f - (float)i0;
  const float* __restrict__ w0 = tab + (size_t)i0*336 + 272;
  const float* __restrict__ w1 = w0 + 336;
  float wse[16], wA[8], wB[8], wC[8];
#pragma unroll
  for (int j=0;j<16;j+=4){
    float4 p = *(const float4*)(w0+j);
    float4 q = *(const float4*)(w1+j);
    wse[j+0]=fmaf(al,q.x-p.x,p.x); wse[j+1]=fmaf(al,q.y-p.y,p.y);
    wse[j+2]=fmaf(al,q.z-p.z,p.z); wse[j+3]=fmaf(al,q.w-p.w,p.w);
  }
#pragma unroll
  for (int j=0;j<8;j+=4){
    float4 p = *(const float4*)(w0+16+j); float4 q = *(const float4*)(w1+16+j);
    wA[j+0]=fmaf(al,q.x-p.x,p.x); wA[j+1]=fmaf(al,q.y-p.y,p.y);
    wA[j+2]=fmaf(al,q.z-p.z,p.z); wA[j+3]=fmaf(al,q.w-p.w,p.w);
    p = *(const float4*)(w0+32+j); q = *(const float4*)(w1+32+j);
    wB[j+0]=fmaf(al,q.x-p.x,p.x); wB[j+1]=fmaf(al,q.y-p.y,p.y);
    wB[j+2]=fmaf(al,q.z-p.z,p.z); wB[j+3]=fmaf(al,q.w-p.w,p.w);
    p = *(const float4*)(w0+48+j); q = *(const float4*)(w1+48+j);
    wC[j+0]=fmaf(al,q.x-p.x,p.x); wC[j+1]=fmaf(al,q.y-p.y,p.y);
    wC[j+2]=fmaf(al,q.z-p.z,p.z); wC[j+3]=fmaf(al,q.w-p.w,p.w);
  }
  const float s3=1.73205081f, s5=2.23606798f, s15=3.87298335f;
  float Y[9];
  Y[0]=1.0f;
  Y[1]=s3*y; Y[2]=s3*z; Y[3]=s3*x;
  Y[4]=s15*x*y; Y[5]=s15*y*z; Y[6]=0.5f*s5*(3.0f*z*z-1.0f); Y[7]=s15*x*z; Y[8]=0.5f*s15*(x*x-y*y);
  const float* __restrict__ g = xg + (size_t)s*64;
  float se[16], vo[24], ve[24];
#pragma unroll
  for (int jj=0;jj<4;++jj){ float4 t=((const float4*)g)[jj];
    se[4*jj]=t.x; se[4*jj+1]=t.y; se[4*jj+2]=t.z; se[4*jj+3]=t.w; }
#pragma unroll
  for (int jj=0;jj<6;++jj){ float4 t=((const float4*)(g+16))[jj];
    vo[4*jj]=t.x; vo[4*jj+1]=t.y; vo[4*jj+2]=t.z; vo[4*jj+3]=t.w; }
#pragma unroll
  for (int jj=0;jj<6;++jj){ float4 t=((const float4*)(g+40))[jj];
    ve[4*jj]=t.x; ve[4*jj+1]=t.y; ve[4*jj+2]=t.z; ve[4*jj+3]=t.w; }

  float SA=0.0f;
#pragma unroll
  for (int u=0;u<16;++u) SA = fmaf(wse[u], se[u], SA);
  float AB[3]={0,0,0}, AC[3]={0,0,0}, AD[3]={0,0,0};
#pragma unroll
  for (int u=0;u<8;++u)
#pragma unroll
    for (int i=0;i<3;++i){
      AB[i]=fmaf(wA[u], vo[u*3+i], AB[i]);
      AC[i]=fmaf(wB[u], vo[u*3+i], AC[i]);
      AD[i]=fmaf(wC[u], ve[u*3+i], AD[i]);
    }
  float e2[3]={0,0,0};
#pragma unroll
  for (int j=0;j<3;++j){ float t=SA*Y[1+j];
#pragma unroll
    for (int k=0;k<3;++k) e2[k]=fmaf(t, cg.c011[j*3+k], e2[k]); }
#pragma unroll
  for (int i=0;i<3;++i){ float t=AB[i]*Y[0];
#pragma unroll
    for (int k=0;k<3;++k) e2[k]=fmaf(t, cg.c101[i*3+k], e2[k]); }
#pragma unroll
  for (int i=0;i<3;++i)
#pragma unroll
    for (int j=0;j<5;++j){ float t=AC[i]*Y[4+j];
#pragma unroll
      for (int k=0;k<3;++k) e2[k]=fmaf(t, cg.c121[(i*5+j)*3+k], e2[k]); }
#pragma unroll
  for (int i=0;i<3;++i)
#pragma unroll
    for (int j=0;j<3;++j){ float t=AD[i]*Y[1+j];
#pragma unroll
      for (int k=0;k<3;++k) e2[k]=fmaf(t, cg.c111[(i*3+j)*3+k], e2[k]); }

  *(float4*)(e2buf + (size_t)e*4) = make_float4(e2[0], e2[1], e2[2], 0.0f);
}

// ---------------- final gather ----------------
__global__ __launch_bounds__(256) void k_out(
    const float* __restrict__ e2buf, const int* __restrict__ rowptr,
    float* __restrict__ out)
{
  const int t = blockIdx.x*256 + threadIdx.x;
  const int n = t>>2, k = t&3;
  if (n>=NN) return;
  const int r0=rowptr[n], r1=rowptr[n+1];
  float a=0.f;
  for (int e=r0;e<r1;++e) a += e2buf[(size_t)e*4 + k];
  const float sc = 0.0641236437f;  // (1/sqrt(64)) * 1/sqrt(3.8)
  if (k<3) out[(size_t)n*3 + k] = a*sc;
}

// ---------------- host launcher ----------------
extern "C" void kernel_launch(void* const* d_in, const int* in_sizes, int n_in,
                              void* d_out, int out_size, void* d_ws, size_t ws_size,
                              hipStream_t stream)
{
  (void)n_in; (void)ws_size; (void)out_size;
  const float* pos = (const float*)d_in[0];
  const int*   src = (const int*)d_in[1];
  const int*   dst = (const int*)d_in[2];
  const float* W1  = (const float*)d_in[3];
  const float* W2  = (const float*)d_in[4];
  const float* W1f = (const float*)d_in[5];
  const float* W2f = (const float*)d_in[6];
  const int E = in_sizes[1];

  char* ws = (char*)d_ws;
  float* xacc  = (float*)ws;                     // NN*16
  float* xg    = xacc + (size_t)NN*16;           // NN*64
  float* tab   = xg + (size_t)NN*64;             // T_TAB*336
  float* e2buf = tab + (size_t)T_TAB*336;        // E*4
  int*   rowptr= (int*)(e2buf + (size_t)E*4);    // NN+1

  CGPack cg;
  build_cg(cg);

  k_table<<<T_TAB/G_TAB, 256, 0, stream>>>(W1, W2, W1f, W2f, tab);
  k_rowptr<<<(NN+1+255)/256, 256, 0, stream>>>(dst, E, rowptr);
  k_x<<<(NN*4)/256, 256, 0, stream>>>(pos, src, rowptr, xacc);
  k_tp1<<<NN/4, 256, 0, stream>>>(pos, src, rowptr, xacc, tab, xg, cg);
  k_tp2<<<(E + 255) / 256, 256, 0, stream>>>(pos, src, dst, E, xg, tab, e2buf, cg);
  k_out<<<(NN*4)/256, 256, 0, stream>>>(e2buf, rowptr, (float*)d_out);
}

// Round 8
// 247.418 us; speedup vs baseline: 1.0855x; 1.0855x over previous
//
#include <hip/hip_runtime.h>
#include <cmath>
#include <complex>

#define T_TAB 4096
#define G_TAB 8
#define NN 16384
#define CH 16

// ---------------- CG tables (exact host-side port of the reference) ----------------
struct CGPack {
  float c000[1];
  float c110[9];
  float c220[25];
  float c330[49];
  float c011[9];
  float c101[9];
  float c111[27];
  float c121[45];
  float c211[45];
  float c221[75];
  float c231[105];
  float c321[105];
  float c331[147];
};

static double factd(int n){ double r=1.0; for(int i=2;i<=n;++i) r*=(double)i; return r; }

static double cg_coef(int j1,int m1,int j2,int m2,int j3,int m3){
  double pref = sqrt((2.0*j3+1.0)*factd(j3+j1-j2)*factd(j3-j1+j2)*factd(j1+j2-j3)/factd(j1+j2+j3+1));
  pref *= sqrt(factd(j3+m3)*factd(j3-m3)*factd(j1-m1)*factd(j1+m1)*factd(j2-m2)*factd(j2+m2));
  double s=0.0;
  for(int k=0;k<=j1+j2-j3;++k){
    int a0=k,a1=j1+j2-j3-k,a2=j1-m1-k,a3=j2+m2-k,a4=j3-j2+m1+k,a5=j3-j1-m2+k;
    if(a0<0||a1<0||a2<0||a3<0||a4<0||a5<0) continue;
    double d=factd(a0)*factd(a1)*factd(a2)*factd(a3)*factd(a4)*factd(a5);
    s += ((k&1)?-1.0:1.0)/d;
  }
  return pref*s;
}

static void u_fill(int l, std::complex<double> U[7][7]){
  for(int i=0;i<7;++i) for(int j=0;j<7;++j) U[i][j]=std::complex<double>(0.0,0.0);
  const double is2 = 1.0/sqrt(2.0);
  U[l][l]=1.0;
  for(int m=1;m<=l;++m){
    double sgn = (m&1)?-1.0:1.0;
    U[l+m][l+m] = sgn*is2;
    U[l+m][l-m] = is2;
    U[l-m][l-m] = std::complex<double>(0.0, is2);
    U[l-m][l+m] = std::complex<double>(0.0, -sgn*is2);
  }
}

static void cg_fill(int l1,int l2,int l3, float* out){
  int n1=2*l1+1,n2=2*l2+1,n3=2*l3+1;
  double Cc[7][7][7];
  for(int a=0;a<7;++a)for(int b=0;b<7;++b)for(int c=0;c<7;++c) Cc[a][b][c]=0.0;
  for(int m1=-l1;m1<=l1;++m1)
    for(int m2=-l2;m2<=l2;++m2){
      int m3=m1+m2;
      if(m3>=-l3&&m3<=l3) Cc[m1+l1][m2+l2][m3+l3]=cg_coef(l1,m1,l2,m2,l3,m3);
    }
  std::complex<double> U1[7][7],U2[7][7],U3[7][7];
  u_fill(l1,U1); u_fill(l2,U2); u_fill(l3,U3);
  std::complex<double> Cr[343];
  double sre=0.0,sim=0.0;
  for(int a=0;a<n1;++a)for(int b=0;b<n2;++b)for(int c=0;c<n3;++c){
    std::complex<double> acc(0.0,0.0);
    for(int u=0;u<n1;++u)for(int v=0;v<n2;++v)for(int w=0;w<n3;++w){
      double cc=Cc[u][v][w];
      if(cc==0.0) continue;
      acc += U1[a][u]*U2[b][v]*std::conj(U3[c][w])*cc;
    }
    Cr[(a*n2+b)*n3+c]=acc;
    sre+=fabs(acc.real()); sim+=fabs(acc.imag());
  }
  bool useim = sim>sre;
  for(int idx=0;idx<n1*n2*n3;++idx) out[idx]=(float)(useim?Cr[idx].imag():Cr[idx].real());
}

static void build_cg(CGPack& P){
  cg_fill(0,0,0,P.c000);
  cg_fill(1,1,0,P.c110);
  cg_fill(2,2,0,P.c220);
  cg_fill(3,3,0,P.c330);
  cg_fill(0,1,1,P.c011);
  cg_fill(1,0,1,P.c101);
  cg_fill(1,1,1,P.c111);
  cg_fill(1,2,1,P.c121);
  cg_fill(2,1,1,P.c211);
  cg_fill(2,2,1,P.c221);
  cg_fill(2,3,1,P.c231);
  cg_fill(3,2,1,P.c321);
  cg_fill(3,3,1,P.c331);
}

// ---------------- device helpers ----------------
__device__ __forceinline__ float soh(float r, float c){
  float d = (r - c) * 2.0f;
  float d2 = d*d;
  return (d2 < 1.0f) ? 1.14136f * expf(2.0f + 1.0f/(d2-1.0f)) : 0.0f;
}

// Per-lane weight schedule: lane ℓ, sub-index q (0..7) -> (column in [0,272) or -1, LDS slot).
// Slot 31 is a guaranteed-zero slot.
__device__ __forceinline__ void lane_sched(int lane, int q, int& col, int& slot){
  col = -1; slot = 31;
  if (lane < 16){
    int s = q >> 2, qq = q & 3;
    int a = 2*lane + s;                 // scalar output index 0..31
    const int base0[4] = {0, 64, 144, 224};
    col = base0[qq] + a; slot = qq;
  } else if (lane < 40){
    int idx = lane-16, u = idx/3, k = idx-3*u;
    const int wb[6] = {32,48,112,128,192,208};
    const int sb[6] = {4,7,10,13,16,19};
    if (q < 6){ col = wb[q]+u; slot = sb[q]+k; }
  } else if (lane < 52){
    int m = lane-40;
    int c0 = (q < 4) ? 2*m : 2*m+1;
    int u = c0/3, k = c0-3*u;
    int qq = (q < 4) ? q : q-4;
    if (qq < 3){
      const int wb[3] = {96,176,256};
      const int sb[3] = {22,25,28};
      col = wb[qq]+u; slot = sb[qq]+k;
    }
  }
}

// ---------------- radial MLP lookup table: tab[T_TAB][336] ----------------
// float4 h-reads: 1 LDS b128 per 4 FMAs (the scalar version was LDS-issue-bound).
__global__ __launch_bounds__(256) void k_table(
    const float* __restrict__ W1, const float* __restrict__ W2,
    const float* __restrict__ W1f, const float* __restrict__ W2f,
    float* __restrict__ tab)
{
  __shared__ float h[G_TAB][256];
  __shared__ float hf[G_TAB][256];
  const int c = threadIdx.x;
  const int t0 = blockIdx.x * G_TAB;
  const float dr = 2.5f / (float)(T_TAB-1);
  const float w1a = W1[c], w1b = W1[256+c], w1c = W1[512+c];
  const float f1a = W1f[c], f1b = W1f[256+c], f1c = W1f[512+c];
#pragma unroll
  for (int g=0; g<G_TAB; ++g){
    float r = (float)(t0+g) * dr;
    float e0 = soh(r,1.0f), e1 = soh(r,1.5f), e2 = soh(r,2.0f);
    h[g][c]  = fmaxf(e0*w1a + e1*w1b + e2*w1c, 0.0f);
    hf[g][c] = fmaxf(e0*f1a + e1*f1b + e2*f1c, 0.0f);
  }
  __syncthreads();
  for (int j = c; j < 336; j += 256){
    float acc[G_TAB];
#pragma unroll
    for (int g=0; g<G_TAB; ++g) acc[g]=0.0f;
    if (j < 272){
      for (int cc=0; cc<256; cc+=4){
        float w0=W2[(cc+0)*272+j], w1=W2[(cc+1)*272+j], w2=W2[(cc+2)*272+j], w3=W2[(cc+3)*272+j];
#pragma unroll
        for (int g=0; g<G_TAB; ++g){
          float4 h4 = *(const float4*)&h[g][cc];
          acc[g] = fmaf(h4.x,w0, fmaf(h4.y,w1, fmaf(h4.z,w2, fmaf(h4.w,w3, acc[g]))));
        }
      }
    } else {
      int jj = j - 272;
      for (int cc=0; cc<256; cc+=4){
        float w0=W2f[(cc+0)*64+jj], w1=W2f[(cc+1)*64+jj], w2=W2f[(cc+2)*64+jj], w3=W2f[(cc+3)*64+jj];
#pragma unroll
        for (int g=0; g<G_TAB; ++g){
          float4 h4 = *(const float4*)&hf[g][cc];
          acc[g] = fmaf(h4.x,w0, fmaf(h4.y,w1, fmaf(h4.z,w2, fmaf(h4.w,w3, acc[g]))));
        }
      }
    }
#pragma unroll
    for (int g=0; g<G_TAB; ++g) tab[(size_t)(t0+g)*336 + j] = acc[g] * 0.0625f;
  }
}

// ---------------- rowptr: dst is globally non-decreasing -> CSR via binary search ----
__global__ __launch_bounds__(256) void k_rowptr(
    const int* __restrict__ dst, int E, int* __restrict__ rowptr)
{
  const int n = blockIdx.x*256 + threadIdx.x;
  if (n > NN) return;
  int lo=0, hi=E;
  while (lo < hi){ int mid=(lo+hi)>>1; if (dst[mid] < n) lo=mid+1; else hi=mid; }
  rowptr[n]=lo;
}

// ---------------- x = segsum(sph_harm): 4 lanes/node, each edge touched once -------
__global__ __launch_bounds__(256) void k_x(
    const float* __restrict__ pos, const int* __restrict__ src,
    const int* __restrict__ rowptr, float* __restrict__ xacc)
{
  const int t = blockIdx.x*256 + threadIdx.x;
  const int n = t>>2, q = t&3;
  if (n>=NN) return;
  const int r0=rowptr[n], r1=rowptr[n+1];
  const float pdx=pos[3*n], pdy=pos[3*n+1], pdz=pos[3*n+2];
  const float s3=1.73205081f, s5=2.23606798f, s15=3.87298335f;
  const float c33=2.09165007f, c32=10.2469508f, c31=1.62018517f, c30=1.32287566f, cp2=5.12347538f;
  float a0=0,a1=0,a2=0,a3=0,a4=0,a5=0,a6=0,a7=0,a8=0,a9=0,a10=0,a11=0,a12=0,a13=0,a14=0,a15=0;
  for (int e=r0+q; e<r1; e+=4){
    const int s=src[e];
    float ax=pos[3*s]-pdx, ay=pos[3*s+1]-pdy, az=pos[3*s+2]-pdz;
    float ir = 1.0f/sqrtf(ax*ax+ay*ay+az*az);
    float x=ax*ir, y=ay*ir, z=az*ir;
    a0+=1.0f; a1+=s3*y; a2+=s3*z; a3+=s3*x;
    a4+=s15*x*y; a5+=s15*y*z; a6+=0.5f*s5*(3.0f*z*z-1.0f); a7+=s15*x*z;
    a8+=0.5f*s15*(x*x-y*y); a9+=c33*y*(3.0f*x*x-y*y); a10+=c32*x*y*z; a11+=c31*y*(5.0f*z*z-1.0f);
    a12+=c30*(5.0f*z*z*z-3.0f*z); a13+=c31*x*(5.0f*z*z-1.0f); a14+=cp2*z*(x*x-y*y);
    a15+=c33*x*(x*x-3.0f*y*y);
  }
#define RED(v) v += __shfl_xor(v,1); v += __shfl_xor(v,2);
  RED(a0) RED(a1) RED(a2) RED(a3) RED(a4) RED(a5) RED(a6) RED(a7)
  RED(a8) RED(a9) RED(a10) RED(a11) RED(a12) RED(a13) RED(a14) RED(a15)
#undef RED
  float o0,o1,o2,o3;
  if (q==0){ o0=a0; o1=a1; o2=a2; o3=a3; }
  else if (q==1){ o0=a4; o1=a5; o2=a6; o3=a7; }
  else if (q==2){ o0=a8; o1=a9; o2=a10; o3=a11; }
  else { o0=a12; o1=a13; o2=a14; o3=a15; }
  *(float4*)(xacc + (size_t)n*16 + q*4) = make_float4(o0,o1,o2,o3);
}

// ---------------- fctp1 + gate fused: ONE WAVE PER NODE (R5 base) ----------------
// Phase 1: 4 lanes/edge -> 31 raw CG intermediates in SI[16][33] (+ al, i0).
// Stage:   4 lanes/edge cooperatively load both table rows (float4, 64B/edge-group),
//          lerp ONCE, write blended weights to SW[16][273] in LDS.
//          Converts 256 scattered VMEM/chunk -> 34 fully-utilized ones (L1-BW fix).
// Phase 2: pure LDS: 8 W-reads + 8 I-reads + 8 FMA per edge per lane.
// Epilogue: gate via 32-float LDS exchange; writes compact xg[NN][64].
__global__ __launch_bounds__(64) void k_tp1(
    const float* __restrict__ pos, const int* __restrict__ src,
    const int* __restrict__ rowptr, const float* __restrict__ xacc,
    const float* __restrict__ tab, float* __restrict__ xg, CGPack cg)
{
  const int lane = threadIdx.x;
  const int node = blockIdx.x;
  __shared__ float SI[CH][33];    // 0..30: intermediates, 31: zero, 32: al
  __shared__ float SW[CH][273];   // blended weights, cols 0..271
  __shared__ int   SiT[CH];
  __shared__ float SG[32];
  const int r0 = rowptr[node], r1 = rowptr[node+1];
  const int nch = (r1 - r0 + CH - 1) / CH;

  // ---- static (weight-col, LDS-slot) schedule + gate indices ----
  int wo[8], ioS[8];
#pragma unroll
  for (int p=0;p<8;++p){
    int c_, s_; lane_sched(lane, p, c_, s_);
    wo[p] = (c_>=0) ? c_ : 0; ioS[p] = s_;
  }
  int gu0=16, gu1=16;
  if (lane >= 16 && lane < 40){ gu0 = 16 + (lane-16)/3; }
  else if (lane >= 40 && lane < 52){
    int m=lane-40; gu0 = 24 + (2*m)/3; gu1 = 24 + (2*m+1)/3;
  }

  const float pdx=pos[3*node], pdy=pos[3*node+1], pdz=pos[3*node+2];
  const int je = lane & 15, part = lane >> 4;
  const int sj = lane >> 2, ss = lane & 3;
  float acc0 = 0.f, acc1 = 0.f;

  for (int t=0; t<nch; ++t){
    const int e0 = r0 + t*CH;
    const int cnt = min(CH, r1-e0);
    __syncthreads();                 // WAR: prev chunk phase-2 reads done
    if (je < cnt){
      const int e = e0 + je;
      const int s = src[e];
      float ax=pos[3*s]-pdx, ay=pos[3*s+1]-pdy, az=pos[3*s+2]-pdz;
      float r = sqrtf(ax*ax+ay*ay+az*az);
      float ir = 1.0f/r;
      float x=ax*ir, y=ay*ir, z=az*ir;

      const float s3=1.73205081f, s5=2.23606798f, s15=3.87298335f;
      const float c33=2.09165007f, c32=10.2469508f, c31=1.62018517f, c30=1.32287566f, cp2=5.12347538f;
      float Y[16];
      Y[0]=1.0f;
      Y[1]=s3*y; Y[2]=s3*z; Y[3]=s3*x;
      Y[4]=s15*x*y; Y[5]=s15*y*z; Y[6]=0.5f*s5*(3.0f*z*z-1.0f); Y[7]=s15*x*z; Y[8]=0.5f*s15*(x*x-y*y);
      Y[9]=c33*y*(3.0f*x*x-y*y); Y[10]=c32*x*y*z; Y[11]=c31*y*(5.0f*z*z-1.0f);
      Y[12]=c30*(5.0f*z*z*z-3.0f*z); Y[13]=c31*x*(5.0f*z*z-1.0f); Y[14]=cp2*z*(x*x-y*y);
      Y[15]=c33*x*(x*x-3.0f*y*y);
      float X[16];
      {
        const float inv = 0.5129891760f;           // 1/sqrt(3.8)
        const float4* q4 = (const float4*)(xacc + (size_t)s*16);
        float4 a=q4[0],b=q4[1],cc4=q4[2],d4=q4[3];
        X[0]=a.x*inv;X[1]=a.y*inv;X[2]=a.z*inv;X[3]=a.w*inv;
        X[4]=b.x*inv;X[5]=b.y*inv;X[6]=b.z*inv;X[7]=b.w*inv;
        X[8]=cc4.x*inv;X[9]=cc4.y*inv;X[10]=cc4.z*inv;X[11]=cc4.w*inv;
        X[12]=d4.x*inv;X[13]=d4.y*inv;X[14]=d4.z*inv;X[15]=d4.w*inv;
      }
      float* SS = SI[je];
#define PUT(slot, val) SS[slot] = (val);
      if (part == 0){
        float f = r * 1638.0f;                    // (T_TAB-1)/2.5
        int i0 = (int)f; if (i0 > T_TAB-2) i0 = T_TAB-2;
        float al = f - (float)i0;
        float t0v = cg.c000[0]*X[0]*Y[0];
        float t1v=0.f, t2v=0.f, t3v=0.f;
#pragma unroll
        for (int i=0;i<3;++i)
#pragma unroll
          for (int j=0;j<3;++j) t1v = fmaf(X[1+i]*Y[1+j], cg.c110[i*3+j], t1v);
#pragma unroll
        for (int i=0;i<5;++i)
#pragma unroll
          for (int j=0;j<5;++j) t2v = fmaf(X[4+i]*Y[4+j], cg.c220[i*5+j], t2v);
#pragma unroll
        for (int i=0;i<7;++i)
#pragma unroll
          for (int j=0;j<7;++j) t3v = fmaf(X[9+i]*Y[9+j], cg.c330[i*7+j], t3v);
        float v12[3]={0,0,0};
#pragma unroll
        for (int i=0;i<3;++i)
#pragma unroll
          for (int j=0;j<5;++j){ float tt=X[1+i]*Y[4+j];
#pragma unroll
            for (int k=0;k<3;++k) v12[k]=fmaf(tt, cg.c121[(i*5+j)*3+k], v12[k]); }
        PUT(0,t0v) PUT(1,t1v) PUT(2,t2v) PUT(3,t3v)
        PUT(10,v12[0]) PUT(11,v12[1]) PUT(12,v12[2])
        SS[31]=0.0f; SS[32]=al;
        SiT[je]=i0;
      } else if (part == 1){
        float v01[3]={0,0,0}, v10[3]={0,0,0}, v33[3]={0,0,0};
#pragma unroll
        for (int j=0;j<3;++j){ float tt=X[0]*Y[1+j];
#pragma unroll
          for (int k=0;k<3;++k) v01[k]=fmaf(tt, cg.c011[j*3+k], v01[k]); }
#pragma unroll
        for (int i=0;i<3;++i){ float tt=X[1+i]*Y[0];
#pragma unroll
          for (int k=0;k<3;++k) v10[k]=fmaf(tt, cg.c101[i*3+k], v10[k]); }
#pragma unroll
        for (int i=0;i<7;++i)
#pragma unroll
          for (int j=0;j<7;++j){ float tt=X[9+i]*Y[9+j];
#pragma unroll
            for (int k=0;k<3;++k) v33[k]=fmaf(tt, cg.c331[(i*7+j)*3+k], v33[k]); }
        PUT(4,v01[0]) PUT(5,v01[1]) PUT(6,v01[2])
        PUT(7,v10[0]) PUT(8,v10[1]) PUT(9,v10[2])
        PUT(28,v33[0]) PUT(29,v33[1]) PUT(30,v33[2])
      } else if (part == 2){
        float v11[3]={0,0,0}, v21[3]={0,0,0}, v23[3]={0,0,0};
#pragma unroll
        for (int i=0;i<3;++i)
#pragma unroll
          for (int j=0;j<3;++j){ float tt=X[1+i]*Y[1+j];
#pragma unroll
            for (int k=0;k<3;++k) v11[k]=fmaf(tt, cg.c111[(i*3+j)*3+k], v11[k]); }
#pragma unroll
        for (int i=0;i<5;++i)
#pragma unroll
          for (int j=0;j<3;++j){ float tt=X[4+i]*Y[1+j];
#pragma unroll
            for (int k=0;k<3;++k) v21[k]=fmaf(tt, cg.c211[(i*3+j)*3+k], v21[k]); }
#pragma unroll
        for (int i=0;i<5;++i)
#pragma unroll
          for (int j=0;j<7;++j){ float tt=X[4+i]*Y[9+j];
#pragma unroll
            for (int k=0;k<3;++k) v23[k]=fmaf(tt, cg.c231[(i*7+j)*3+k], v23[k]); }
        PUT(22,v11[0]) PUT(23,v11[1]) PUT(24,v11[2])
        PUT(13,v21[0]) PUT(14,v21[1]) PUT(15,v21[2])
        PUT(16,v23[0]) PUT(17,v23[1]) PUT(18,v23[2])
      } else {
        float v22[3]={0,0,0}, v32[3]={0,0,0};
#pragma unroll
        for (int i=0;i<5;++i)
#pragma unroll
          for (int j=0;j<5;++j){ float tt=X[4+i]*Y[4+j];
#pragma unroll
            for (int k=0;k<3;++k) v22[k]=fmaf(tt, cg.c221[(i*5+j)*3+k], v22[k]); }
#pragma unroll
        for (int i=0;i<7;++i)
#pragma unroll
          for (int j=0;j<5;++j){ float tt=X[9+i]*Y[4+j];
#pragma unroll
            for (int k=0;k<3;++k) v32[k]=fmaf(tt, cg.c321[(i*5+j)*3+k], v32[k]); }
        PUT(25,v22[0]) PUT(26,v22[1]) PUT(27,v22[2])
        PUT(19,v32[0]) PUT(20,v32[1]) PUT(21,v32[2])
      }
#undef PUT
    }
    __syncthreads();                 // RAW: phase-1 SI/SiT visible
    // ---- stage blended weights: 4 lanes per edge, coalesced float4, lerp once ----
    if (sj < cnt){
      const float al = SI[sj][32];
      const float* __restrict__ w0 = tab + (size_t)SiT[sj]*336;
      const float* __restrict__ w1 = w0 + 336;
      float* __restrict__ dw = SW[sj];
#pragma unroll
      for (int k=0; k<17; ++k){
        const int cidx = ss*4 + k*16;
        float4 p = *(const float4*)(w0+cidx);
        float4 q = *(const float4*)(w1+cidx);
        float4 b;
        b.x = fmaf(al, q.x-p.x, p.x);
        b.y = fmaf(al, q.y-p.y, p.y);
        b.z = fmaf(al, q.z-p.z, p.z);
        b.w = fmaf(al, q.w-p.w, p.w);
        *(float4*)(dw+cidx) = b;
      }
    }
    __syncthreads();                 // RAW: SW visible
    // ---- phase 2: pure LDS, fully static schedule ----
#pragma unroll 4
    for (int j=0; j<CH; ++j){
      if (j < cnt){
        const float* __restrict__ W = SW[j];
        const float* __restrict__ I = SI[j];
        acc0 = fmaf(W[wo[0]], I[ioS[0]], acc0);
        acc0 = fmaf(W[wo[1]], I[ioS[1]], acc0);
        acc0 = fmaf(W[wo[2]], I[ioS[2]], acc0);
        acc0 = fmaf(W[wo[3]], I[ioS[3]], acc0);
        acc1 = fmaf(W[wo[4]], I[ioS[4]], acc1);
        acc1 = fmaf(W[wo[5]], I[ioS[5]], acc1);
        acc1 = fmaf(W[wo[6]], I[ioS[6]], acc1);
        acc1 = fmaf(W[wo[7]], I[ioS[7]], acc1);
      }
    }
  }

  // ---- fused gate epilogue ----
  const float inv = 0.5129891760f;
  if (lane < 16){
    SG[2*lane]   = acc0*0.5f*inv;
    SG[2*lane+1] = acc1*0.5f*inv;
  }
  __syncthreads();
  float* __restrict__ o = xg + (size_t)node*64;
  if (lane < 16){
    o[lane] = fmaxf(SG[lane], 0.0f);                       // se
  } else if (lane < 40){
    int idx = lane-16;
    float vv = (acc0+acc1)*0.4082482905f*inv;
    o[16+idx] = vv * fmaxf(SG[gu0], 0.0f);                 // v1o (u<8)
  } else if (lane < 52){
    int m = lane-40;
    float vv0 = acc0*0.5773502692f*inv;
    float vv1 = acc1*0.5773502692f*inv;
    o[40+2*m]   = vv0 * fmaxf(SG[gu0], 0.0f);              // v1e (u<8)
    o[40+2*m+1] = vv1 * fmaxf(SG[gu1], 0.0f);
  }
}

// ---------------- fctp2 per edge -> e2buf[E][4] (pruned) ----------------
__global__ __launch_bounds__(256) void k_tp2(
    const float* __restrict__ pos, const int* __restrict__ src, const int* __restrict__ dst, int E,
    const float* __restrict__ xg, const float* __restrict__ tab,
    float* __restrict__ e2buf, CGPack cg)
{
  const int e = blockIdx.x*256 + threadIdx.x;
  if (e>=E) return;
  const int s = src[e], d = dst[e];
  float ax=pos[3*s]-pos[3*d], ay=pos[3*s+1]-pos[3*d+1], az=pos[3*s+2]-pos[3*d+2];
  float r = sqrtf(ax*ax+ay*ay+az*az);
  float ir = 1.0f/r;
  float x=ax*ir, y=ay*ir, z=az*ir;
  float f = r * 1638.0f;
  int i0 = (int)f; if (i0 > T_TAB-2) i0 = T_TAB-2;
  const float al = f - (float)i0;
  const float* __restrict__ w0 = tab + (size_t)i0*336 + 272;
  const float* __restrict__ w1 = w0 + 336;
  float wse[16], wA[8], wB[8], wC[8];
#pragma unroll
  for (int j=0;j<16;j+=4){
    float4 p = *(const float4*)(w0+j);
    float4 q = *(const float4*)(w1+j);
    wse[j+0]=fmaf(al,q.x-p.x,p.x); wse[j+1]=fmaf(al,q.y-p.y,p.y);
    wse[j+2]=fmaf(al,q.z-p.z,p.z); wse[j+3]=fmaf(al,q.w-p.w,p.w);
  }
#pragma unroll
  for (int j=0;j<8;j+=4){
    float4 p = *(const float4*)(w0+16+j); float4 q = *(const float4*)(w1+16+j);
    wA[j+0]=fmaf(al,q.x-p.x,p.x); wA[j+1]=fmaf(al,q.y-p.y,p.y);
    wA[j+2]=fmaf(al,q.z-p.z,p.z); wA[j+3]=fmaf(al,q.w-p.w,p.w);
    p = *(const float4*)(w0+32+j); q = *(const float4*)(w1+32+j);
    wB[j+0]=fmaf(al,q.x-p.x,p.x); wB[j+1]=fmaf(al,q.y-p.y,p.y);
    wB[j+2]=fmaf(al,q.z-p.z,p.z); wB[j+3]=fmaf(al,q.w-p.w,p.w);
    p = *(const float4*)(w0+48+j); q = *(const float4*)(w1+48+j);
    wC[j+0]=fmaf(al,q.x-p.x,p.x); wC[j+1]=fmaf(al,q.y-p.y,p.y);
    wC[j+2]=fmaf(al,q.z-p.z,p.z); wC[j+3]=fmaf(al,q.w-p.w,p.w);
  }
  const float s3=1.73205081f, s5=2.23606798f, s15=3.87298335f;
  float Y[9];
  Y[0]=1.0f;
  Y[1]=s3*y; Y[2]=s3*z; Y[3]=s3*x;
  Y[4]=s15*x*y; Y[5]=s15*y*z; Y[6]=0.5f*s5*(3.0f*z*z-1.0f); Y[7]=s15*x*z; Y[8]=0.5f*s15*(x*x-y*y);
  const float* __restrict__ g = xg + (size_t)s*64;
  float se[16], vo[24], ve[24];
#pragma unroll
  for (int jj=0;jj<4;++jj){ float4 t=((const float4*)g)[jj];
    se[4*jj]=t.x; se[4*jj+1]=t.y; se[4*jj+2]=t.z; se[4*jj+3]=t.w; }
#pragma unroll
  for (int jj=0;jj<6;++jj){ float4 t=((const float4*)(g+16))[jj];
    vo[4*jj]=t.x; vo[4*jj+1]=t.y; vo[4*jj+2]=t.z; vo[4*jj+3]=t.w; }
#pragma unroll
  for (int jj=0;jj<6;++jj){ float4 t=((const float4*)(g+40))[jj];
    ve[4*jj]=t.x; ve[4*jj+1]=t.y; ve[4*jj+2]=t.z; ve[4*jj+3]=t.w; }

  float SA=0.0f;
#pragma unroll
  for (int u=0;u<16;++u) SA = fmaf(wse[u], se[u], SA);
  float AB[3]={0,0,0}, AC[3]={0,0,0}, AD[3]={0,0,0};
#pragma unroll
  for (int u=0;u<8;++u)
#pragma unroll
    for (int i=0;i<3;++i){
      AB[i]=fmaf(wA[u], vo[u*3+i], AB[i]);
      AC[i]=fmaf(wB[u], vo[u*3+i], AC[i]);
      AD[i]=fmaf(wC[u], ve[u*3+i], AD[i]);
    }
  float e2[3]={0,0,0};
#pragma unroll
  for (int j=0;j<3;++j){ float t=SA*Y[1+j];
#pragma unroll
    for (int k=0;k<3;++k) e2[k]=fmaf(t, cg.c011[j*3+k], e2[k]); }
#pragma unroll
  for (int i=0;i<3;++i){ float t=AB[i]*Y[0];
#pragma unroll
    for (int k=0;k<3;++k) e2[k]=fmaf(t, cg.c101[i*3+k], e2[k]); }
#pragma unroll
  for (int i=0;i<3;++i)
#pragma unroll
    for (int j=0;j<5;++j){ float t=AC[i]*Y[4+j];
#pragma unroll
      for (int k=0;k<3;++k) e2[k]=fmaf(t, cg.c121[(i*5+j)*3+k], e2[k]); }
#pragma unroll
  for (int i=0;i<3;++i)
#pragma unroll
    for (int j=0;j<3;++j){ float t=AD[i]*Y[1+j];
#pragma unroll
      for (int k=0;k<3;++k) e2[k]=fmaf(t, cg.c111[(i*3+j)*3+k], e2[k]); }

  *(float4*)(e2buf + (size_t)e*4) = make_float4(e2[0], e2[1], e2[2], 0.0f);
}

// ---------------- final gather ----------------
__global__ __launch_bounds__(256) void k_out(
    const float* __restrict__ e2buf, const int* __restrict__ rowptr,
    float* __restrict__ out)
{
  const int t = blockIdx.x*256 + threadIdx.x;
  const int n = t>>2, k = t&3;
  if (n>=NN) return;
  const int r0=rowptr[n], r1=rowptr[n+1];
  float a=0.f;
  for (int e=r0;e<r1;++e) a += e2buf[(size_t)e*4 + k];
  const float sc = 0.0641236437f;  // (1/sqrt(64)) * 1/sqrt(3.8)
  if (k<3) out[(size_t)n*3 + k] = a*sc;
}

// ---------------- host launcher ----------------
extern "C" void kernel_launch(void* const* d_in, const int* in_sizes, int n_in,
                              void* d_out, int out_size, void* d_ws, size_t ws_size,
                              hipStream_t stream)
{
  (void)n_in; (void)ws_size; (void)out_size;
  const float* pos = (const float*)d_in[0];
  const int*   src = (const int*)d_in[1];
  const int*   dst = (const int*)d_in[2];
  const float* W1  = (const float*)d_in[3];
  const float* W2  = (const float*)d_in[4];
  const float* W1f = (const float*)d_in[5];
  const float* W2f = (const float*)d_in[6];
  const int E = in_sizes[1];

  char* ws = (char*)d_ws;
  float* xacc  = (float*)ws;                     // NN*16
  float* xg    = xacc + (size_t)NN*16;           // NN*64
  float* tab   = xg + (size_t)NN*64;             // T_TAB*336
  float* e2buf = tab + (size_t)T_TAB*336;        // E*4
  int*   rowptr= (int*)(e2buf + (size_t)E*4);    // NN+1

  CGPack cg;
  build_cg(cg);

  k_table<<<T_TAB/G_TAB, 256, 0, stream>>>(W1, W2, W1f, W2f, tab);
  k_rowptr<<<(NN+1+255)/256, 256, 0, stream>>>(dst, E, rowptr);
  k_x<<<(NN*4)/256, 256, 0, stream>>>(pos, src, rowptr, xacc);
  k_tp1<<<NN, 64, 0, stream>>>(pos, src, rowptr, xacc, tab, xg, cg);
  k_tp2<<<(E + 255) / 256, 256, 0, stream>>>(pos, src, dst, E, xg, tab, e2buf, cg);
  k_out<<<(NN*4)/256, 256, 0, stream>>>(e2buf, rowptr, (float*)d_out);
}

// Round 9
// 164.421 us; speedup vs baseline: 1.6335x; 1.5048x over previous
//
#include <hip/hip_runtime.h>
#include <cmath>

#define T_TAB 4096
#define G_TAB 8
#define NN 16384
#define CH 32

// ================= compile-time CG tables (constexpr port of the reference) ========
struct CD { double re, im; };
constexpr CD cmul(CD a, CD b){ return {a.re*b.re - a.im*b.im, a.re*b.im + a.im*b.re}; }
constexpr CD cadd(CD a, CD b){ return {a.re+b.re, a.im+b.im}; }
constexpr CD conj_(CD a){ return {a.re, -a.im}; }
constexpr CD cscale(CD a, double s){ return {a.re*s, a.im*s}; }
constexpr double cfabs_(double x){ return x<0.0 ? -x : x; }
constexpr double csqrt_(double x){
  double g = x > 1.0 ? x : 1.0;
  for (int i=0;i<80;++i) g = 0.5*(g + x/g);
  return g;
}
constexpr double factd(int n){ double r=1.0; for(int i=2;i<=n;++i) r*=(double)i; return r; }

constexpr double cg_coef(int j1,int m1,int j2,int m2,int j3,int m3){
  double pref = csqrt_((2.0*j3+1.0)*factd(j3+j1-j2)*factd(j3-j1+j2)*factd(j1+j2-j3)/factd(j1+j2+j3+1));
  pref *= csqrt_(factd(j3+m3)*factd(j3-m3)*factd(j1-m1)*factd(j1+m1)*factd(j2-m2)*factd(j2+m2));
  double s=0.0;
  for(int k=0;k<=j1+j2-j3;++k){
    int a0=k,a1=j1+j2-j3-k,a2=j1-m1-k,a3=j2+m2-k,a4=j3-j2+m1+k,a5=j3-j1-m2+k;
    if(a0<0||a1<0||a2<0||a3<0||a4<0||a5<0) continue;
    double d=factd(a0)*factd(a1)*factd(a2)*factd(a3)*factd(a4)*factd(a5);
    s += ((k&1)?-1.0:1.0)/d;
  }
  return pref*s;
}

struct UMat { CD u[7][7]; };
constexpr UMat u_fill(int l){
  UMat M{};
  const double is2 = csqrt_(0.5);
  M.u[l][l] = CD{1.0, 0.0};
  for(int m=1;m<=l;++m){
    double sgn = (m&1)?-1.0:1.0;
    M.u[l+m][l+m] = CD{sgn*is2, 0.0};
    M.u[l+m][l-m] = CD{is2, 0.0};
    M.u[l-m][l-m] = CD{0.0, is2};
    M.u[l-m][l+m] = CD{0.0, -sgn*is2};
  }
  return M;
}

template<int L1,int L2,int L3>
struct FT { float v[(2*L1+1)*(2*L2+1)*(2*L3+1)]; };

template<int L1,int L2,int L3>
constexpr FT<L1,L2,L3> cg_real_ct(){
  constexpr int n1=2*L1+1, n2=2*L2+1, n3=2*L3+1;
  double Cc[7][7][7] = {};
  for(int m1=-L1;m1<=L1;++m1)
    for(int m2=-L2;m2<=L2;++m2){
      int m3=m1+m2;
      if(m3>=-L3&&m3<=L3) Cc[m1+L1][m2+L2][m3+L3]=cg_coef(L1,m1,L2,m2,L3,m3);
    }
  UMat U1 = u_fill(L1), U2 = u_fill(L2), U3 = u_fill(L3);
  CD Cr[7][7][7] = {};
  double sre=0.0, sim=0.0;
  for(int a=0;a<n1;++a)for(int b=0;b<n2;++b)for(int c=0;c<n3;++c){
    CD acc{0.0,0.0};
    for(int u=0;u<n1;++u)for(int v=0;v<n2;++v){
      int w = (u-L1)+(v-L2)+L3;           // only m3=m1+m2 can be nonzero in Cc
      if (w < 0 || w >= n3) continue;
      double cc = Cc[u][v][w];
      if (cc == 0.0) continue;
      acc = cadd(acc, cscale(cmul(cmul(U1.u[a][u],U2.u[b][v]),conj_(U3.u[c][w])), cc));
    }
    Cr[a][b][c] = acc;
    sre += cfabs_(acc.re); sim += cfabs_(acc.im);
  }
  FT<L1,L2,L3> out{};
  bool useim = sim > sre;
  for(int a=0;a<n1;++a)for(int b=0;b<n2;++b)for(int c=0;c<n3;++c)
    out.v[(a*n2+b)*n3+c] = (float)(useim ? Cr[a][b][c].im : Cr[a][b][c].re);
  return out;
}

constexpr auto CG000 = cg_real_ct<0,0,0>();
constexpr auto CG110 = cg_real_ct<1,1,0>();
constexpr auto CG220 = cg_real_ct<2,2,0>();
constexpr auto CG330 = cg_real_ct<3,3,0>();
constexpr auto CG011 = cg_real_ct<0,1,1>();
constexpr auto CG101 = cg_real_ct<1,0,1>();
constexpr auto CG111 = cg_real_ct<1,1,1>();
constexpr auto CG121 = cg_real_ct<1,2,1>();
constexpr auto CG211 = cg_real_ct<2,1,1>();
constexpr auto CG221 = cg_real_ct<2,2,1>();
constexpr auto CG231 = cg_real_ct<2,3,1>();
constexpr auto CG321 = cg_real_ct<3,2,1>();
constexpr auto CG331 = cg_real_ct<3,3,1>();

// zero-pruned FMA term: coefficient folds to a literal; zero terms are deleted.
#define TERM(TBL, IDX, PROD, ACC) { float c_ = TBL.v[IDX]; if (c_ != 0.0f) ACC = fmaf((PROD), c_, ACC); }

// ---------------- device helpers ----------------
__device__ __forceinline__ float soh(float r, float c){
  float d = (r - c) * 2.0f;
  float d2 = d*d;
  return (d2 < 1.0f) ? 1.14136f * expf(2.0f + 1.0f/(d2-1.0f)) : 0.0f;
}

// Per-lane weight schedule: lane ℓ, sub-index q (0..7) -> (column in [0,272) or -1, LDS slot).
// Slot 31 is a guaranteed-zero slot.
__device__ __forceinline__ void lane_sched(int lane, int q, int& col, int& slot){
  col = -1; slot = 31;
  if (lane < 16){
    int s = q >> 2, qq = q & 3;
    int a = 2*lane + s;                 // scalar output index 0..31
    const int base0[4] = {0, 64, 144, 224};
    col = base0[qq] + a; slot = qq;
  } else if (lane < 40){
    int idx = lane-16, u = idx/3, k = idx-3*u;
    const int wb[6] = {32,48,112,128,192,208};
    const int sb[6] = {4,7,10,13,16,19};
    if (q < 6){ col = wb[q]+u; slot = sb[q]+k; }
  } else if (lane < 52){
    int m = lane-40;
    int c0 = (q < 4) ? 2*m : 2*m+1;
    int u = c0/3, k = c0-3*u;
    int qq = (q < 4) ? q : q-4;
    if (qq < 3){
      const int wb[3] = {96,176,256};
      const int sb[3] = {22,25,28};
      col = wb[qq]+u; slot = sb[qq]+k;
    }
  }
}

// ---------------- radial MLP lookup table: tab[T_TAB][336] ----------------
__global__ __launch_bounds__(256) void k_table(
    const float* __restrict__ W1, const float* __restrict__ W2,
    const float* __restrict__ W1f, const float* __restrict__ W2f,
    float* __restrict__ tab)
{
  __shared__ float h[G_TAB][256];
  __shared__ float hf[G_TAB][256];
  const int c = threadIdx.x;
  const int t0 = blockIdx.x * G_TAB;
  const float dr = 2.5f / (float)(T_TAB-1);
  const float w1a = W1[c], w1b = W1[256+c], w1c = W1[512+c];
  const float f1a = W1f[c], f1b = W1f[256+c], f1c = W1f[512+c];
#pragma unroll
  for (int g=0; g<G_TAB; ++g){
    float r = (float)(t0+g) * dr;
    float e0 = soh(r,1.0f), e1 = soh(r,1.5f), e2 = soh(r,2.0f);
    h[g][c]  = fmaxf(e0*w1a + e1*w1b + e2*w1c, 0.0f);
    hf[g][c] = fmaxf(e0*f1a + e1*f1b + e2*f1c, 0.0f);
  }
  __syncthreads();
  for (int j = c; j < 336; j += 256){
    float acc[G_TAB];
#pragma unroll
    for (int g=0; g<G_TAB; ++g) acc[g]=0.0f;
    if (j < 272){
      for (int cc=0; cc<256; cc+=4){
        float w0=W2[(cc+0)*272+j], w1=W2[(cc+1)*272+j], w2=W2[(cc+2)*272+j], w3=W2[(cc+3)*272+j];
#pragma unroll
        for (int g=0; g<G_TAB; ++g){
          float4 h4 = *(const float4*)&h[g][cc];
          acc[g] = fmaf(h4.x,w0, fmaf(h4.y,w1, fmaf(h4.z,w2, fmaf(h4.w,w3, acc[g]))));
        }
      }
    } else {
      int jj = j - 272;
      for (int cc=0; cc<256; cc+=4){
        float w0=W2f[(cc+0)*64+jj], w1=W2f[(cc+1)*64+jj], w2=W2f[(cc+2)*64+jj], w3=W2f[(cc+3)*64+jj];
#pragma unroll
        for (int g=0; g<G_TAB; ++g){
          float4 h4 = *(const float4*)&hf[g][cc];
          acc[g] = fmaf(h4.x,w0, fmaf(h4.y,w1, fmaf(h4.z,w2, fmaf(h4.w,w3, acc[g]))));
        }
      }
    }
#pragma unroll
    for (int g=0; g<G_TAB; ++g) tab[(size_t)(t0+g)*336 + j] = acc[g] * 0.0625f;
  }
}

// ---------------- rowptr: dst is globally non-decreasing -> CSR via binary search ----
__global__ __launch_bounds__(256) void k_rowptr(
    const int* __restrict__ dst, int E, int* __restrict__ rowptr)
{
  const int n = blockIdx.x*256 + threadIdx.x;
  if (n > NN) return;
  int lo=0, hi=E;
  while (lo < hi){ int mid=(lo+hi)>>1; if (dst[mid] < n) lo=mid+1; else hi=mid; }
  rowptr[n]=lo;
}

// ---------------- x = segsum(sph_harm): 4 lanes/node, each edge touched once -------
__global__ __launch_bounds__(256) void k_x(
    const float* __restrict__ pos, const int* __restrict__ src,
    const int* __restrict__ rowptr, float* __restrict__ xacc)
{
  const int t = blockIdx.x*256 + threadIdx.x;
  const int n = t>>2, q = t&3;
  if (n>=NN) return;
  const int r0=rowptr[n], r1=rowptr[n+1];
  const float pdx=pos[3*n], pdy=pos[3*n+1], pdz=pos[3*n+2];
  const float s3=1.73205081f, s5=2.23606798f, s15=3.87298335f;
  const float c33=2.09165007f, c32=10.2469508f, c31=1.62018517f, c30=1.32287566f, cp2=5.12347538f;
  float a0=0,a1=0,a2=0,a3=0,a4=0,a5=0,a6=0,a7=0,a8=0,a9=0,a10=0,a11=0,a12=0,a13=0,a14=0,a15=0;
  for (int e=r0+q; e<r1; e+=4){
    const int s=src[e];
    float ax=pos[3*s]-pdx, ay=pos[3*s+1]-pdy, az=pos[3*s+2]-pdz;
    float ir = 1.0f/sqrtf(ax*ax+ay*ay+az*az);
    float x=ax*ir, y=ay*ir, z=az*ir;
    a0+=1.0f; a1+=s3*y; a2+=s3*z; a3+=s3*x;
    a4+=s15*x*y; a5+=s15*y*z; a6+=0.5f*s5*(3.0f*z*z-1.0f); a7+=s15*x*z;
    a8+=0.5f*s15*(x*x-y*y); a9+=c33*y*(3.0f*x*x-y*y); a10+=c32*x*y*z; a11+=c31*y*(5.0f*z*z-1.0f);
    a12+=c30*(5.0f*z*z*z-3.0f*z); a13+=c31*x*(5.0f*z*z-1.0f); a14+=cp2*z*(x*x-y*y);
    a15+=c33*x*(x*x-3.0f*y*y);
  }
#define RED(v) v += __shfl_xor(v,1); v += __shfl_xor(v,2);
  RED(a0) RED(a1) RED(a2) RED(a3) RED(a4) RED(a5) RED(a6) RED(a7)
  RED(a8) RED(a9) RED(a10) RED(a11) RED(a12) RED(a13) RED(a14) RED(a15)
#undef RED
  float o0,o1,o2,o3;
  if (q==0){ o0=a0; o1=a1; o2=a2; o3=a3; }
  else if (q==1){ o0=a4; o1=a5; o2=a6; o3=a7; }
  else if (q==2){ o0=a8; o1=a9; o2=a10; o3=a11; }
  else { o0=a12; o1=a13; o2=a14; o3=a15; }
  *(float4*)(xacc + (size_t)n*16 + q*4) = make_float4(o0,o1,o2,o3);
}

// ---------------- fctp1 + gate fused: ONE WAVE PER NODE, lane = edge ----------------
// Phase 1: lane e computes ALL 31 CG intermediates for its edge with zero-pruned
//          compile-time CG coefficients -- single code path, no wave divergence
//          (the old 4-way part split executed all 4 bodies serially under exec masks).
// Phase 2: R5-style shared-row scattered table loads + inline lerp, static schedule.
// Epilogue: gate via 32-float LDS exchange; writes compact xg[NN][64].
__global__ __launch_bounds__(64) void k_tp1(
    const float* __restrict__ pos, const int* __restrict__ src,
    const int* __restrict__ rowptr, const float* __restrict__ xacc,
    const float* __restrict__ tab, float* __restrict__ xg)
{
  const int lane = threadIdx.x;
  const int node = blockIdx.x;
  __shared__ float SI[CH][33];   // 0..30 intermediates, 31 zero, 32 al
  __shared__ int   SiT[CH];
  __shared__ float SG[32];
  const int r0 = rowptr[node], r1 = rowptr[node+1];
  const int nch = (r1 - r0 + CH - 1) / CH;

  // ---- static (weight-col, LDS-slot) schedule + gate indices ----
  int wo[8], ioS[8];
#pragma unroll
  for (int p=0;p<8;++p){
    int c_, s_; lane_sched(lane, p, c_, s_);
    wo[p] = (c_>=0) ? c_ : 0; ioS[p] = s_;
  }
  int gu0=16, gu1=16;
  if (lane >= 16 && lane < 40){ gu0 = 16 + (lane-16)/3; }
  else if (lane >= 40 && lane < 52){
    int m=lane-40; gu0 = 24 + (2*m)/3; gu1 = 24 + (2*m+1)/3;
  }

  const float pdx=pos[3*node], pdy=pos[3*node+1], pdz=pos[3*node+2];
  float acc0 = 0.f, acc1 = 0.f;

  for (int t=0; t<nch; ++t){
    const int e0 = r0 + t*CH;
    const int cnt = min(CH, r1-e0);
    __syncthreads();                 // WAR: prev chunk phase-2 reads done
    if (lane < cnt){
      const int e = e0 + lane;
      const int s = src[e];
      float ax=pos[3*s]-pdx, ay=pos[3*s+1]-pdy, az=pos[3*s+2]-pdz;
      float r = sqrtf(ax*ax+ay*ay+az*az);
      float ir = 1.0f/r;
      float x=ax*ir, y=ay*ir, z=az*ir;
      float f = r * 1638.0f;                    // (T_TAB-1)/2.5
      int i0 = (int)f; if (i0 > T_TAB-2) i0 = T_TAB-2;
      float al = f - (float)i0;

      const float s3=1.73205081f, s5=2.23606798f, s15=3.87298335f;
      const float c33=2.09165007f, c32=10.2469508f, c31=1.62018517f, c30=1.32287566f, cp2=5.12347538f;
      float Y[16];
      Y[0]=1.0f;
      Y[1]=s3*y; Y[2]=s3*z; Y[3]=s3*x;
      Y[4]=s15*x*y; Y[5]=s15*y*z; Y[6]=0.5f*s5*(3.0f*z*z-1.0f); Y[7]=s15*x*z; Y[8]=0.5f*s15*(x*x-y*y);
      Y[9]=c33*y*(3.0f*x*x-y*y); Y[10]=c32*x*y*z; Y[11]=c31*y*(5.0f*z*z-1.0f);
      Y[12]=c30*(5.0f*z*z*z-3.0f*z); Y[13]=c31*x*(5.0f*z*z-1.0f); Y[14]=cp2*z*(x*x-y*y);
      Y[15]=c33*x*(x*x-3.0f*y*y);
      float X[16];
      {
        const float inv = 0.5129891760f;           // 1/sqrt(3.8)
        const float4* q4 = (const float4*)(xacc + (size_t)s*16);
        float4 a=q4[0],b=q4[1],cc4=q4[2],d4=q4[3];
        X[0]=a.x*inv;X[1]=a.y*inv;X[2]=a.z*inv;X[3]=a.w*inv;
        X[4]=b.x*inv;X[5]=b.y*inv;X[6]=b.z*inv;X[7]=b.w*inv;
        X[8]=cc4.x*inv;X[9]=cc4.y*inv;X[10]=cc4.z*inv;X[11]=cc4.w*inv;
        X[12]=d4.x*inv;X[13]=d4.y*inv;X[14]=d4.z*inv;X[15]=d4.w*inv;
      }
      float* SS = SI[lane];

      // t-block (scalar outputs)
      {
        float t0v = CG000.v[0]*X[0]*Y[0];
        float t1v=0.f, t2v=0.f, t3v=0.f;
#pragma unroll
        for (int i=0;i<3;++i)
#pragma unroll
          for (int j=0;j<3;++j) TERM(CG110, i*3+j, X[1+i]*Y[1+j], t1v)
#pragma unroll
        for (int i=0;i<5;++i)
#pragma unroll
          for (int j=0;j<5;++j) TERM(CG220, i*5+j, X[4+i]*Y[4+j], t2v)
#pragma unroll
        for (int i=0;i<7;++i)
#pragma unroll
          for (int j=0;j<7;++j) TERM(CG330, i*7+j, X[9+i]*Y[9+j], t3v)
        SS[0]=t0v; SS[1]=t1v; SS[2]=t2v; SS[3]=t3v;
      }
      // vector outputs
      {
        float v01[3]={0,0,0}, v10[3]={0,0,0}, v11[3]={0,0,0}, v12[3]={0,0,0},
              v21[3]={0,0,0}, v22[3]={0,0,0}, v23[3]={0,0,0}, v32[3]={0,0,0}, v33[3]={0,0,0};
#pragma unroll
        for (int j=0;j<3;++j){ float tt=X[0]*Y[1+j];
#pragma unroll
          for (int k=0;k<3;++k) TERM(CG011, j*3+k, tt, v01[k]) }
#pragma unroll
        for (int i=0;i<3;++i){ float tt=X[1+i]*Y[0];
#pragma unroll
          for (int k=0;k<3;++k) TERM(CG101, i*3+k, tt, v10[k]) }
#pragma unroll
        for (int i=0;i<3;++i)
#pragma unroll
          for (int j=0;j<3;++j){ float tt=X[1+i]*Y[1+j];
#pragma unroll
            for (int k=0;k<3;++k) TERM(CG111, (i*3+j)*3+k, tt, v11[k]) }
#pragma unroll
        for (int i=0;i<3;++i)
#pragma unroll
          for (int j=0;j<5;++j){ float tt=X[1+i]*Y[4+j];
#pragma unroll
            for (int k=0;k<3;++k) TERM(CG121, (i*5+j)*3+k, tt, v12[k]) }
#pragma unroll
        for (int i=0;i<5;++i)
#pragma unroll
          for (int j=0;j<3;++j){ float tt=X[4+i]*Y[1+j];
#pragma unroll
            for (int k=0;k<3;++k) TERM(CG211, (i*3+j)*3+k, tt, v21[k]) }
#pragma unroll
        for (int i=0;i<5;++i)
#pragma unroll
          for (int j=0;j<5;++j){ float tt=X[4+i]*Y[4+j];
#pragma unroll
            for (int k=0;k<3;++k) TERM(CG221, (i*5+j)*3+k, tt, v22[k]) }
#pragma unroll
        for (int i=0;i<5;++i)
#pragma unroll
          for (int j=0;j<7;++j){ float tt=X[4+i]*Y[9+j];
#pragma unroll
            for (int k=0;k<3;++k) TERM(CG231, (i*7+j)*3+k, tt, v23[k]) }
#pragma unroll
        for (int i=0;i<7;++i)
#pragma unroll
          for (int j=0;j<5;++j){ float tt=X[9+i]*Y[4+j];
#pragma unroll
            for (int k=0;k<3;++k) TERM(CG321, (i*5+j)*3+k, tt, v32[k]) }
#pragma unroll
        for (int i=0;i<7;++i)
#pragma unroll
          for (int j=0;j<7;++j){ float tt=X[9+i]*Y[9+j];
#pragma unroll
            for (int k=0;k<3;++k) TERM(CG331, (i*7+j)*3+k, tt, v33[k]) }
#pragma unroll
        for (int k=0;k<3;++k){
          SS[4+k]=v01[k]; SS[7+k]=v10[k]; SS[10+k]=v12[k]; SS[13+k]=v21[k];
          SS[16+k]=v23[k]; SS[19+k]=v32[k]; SS[22+k]=v11[k]; SS[25+k]=v22[k]; SS[28+k]=v33[k];
        }
      }
      SS[31]=0.0f; SS[32]=al;
      SiT[lane]=i0;
    }
    __syncthreads();                 // RAW: phase-1 SI/SiT visible
    // ---- phase 2: shared-row scattered loads + inline lerp, static schedule ----
#pragma unroll 4
    for (int j=0; j<CH; ++j){
      if (j < cnt){
        const float* __restrict__ wr0 = tab + (size_t)SiT[j]*336;
        const float* __restrict__ wr1 = wr0 + 336;
        const float* __restrict__ I = SI[j];
        const float alj = I[32];
#pragma unroll
        for (int p=0;p<4;++p){
          float wa = wr0[wo[p]], wb = wr1[wo[p]];
          acc0 = fmaf(fmaf(alj, wb-wa, wa), I[ioS[p]], acc0);
        }
#pragma unroll
        for (int p=4;p<8;++p){
          float wa = wr0[wo[p]], wb = wr1[wo[p]];
          acc1 = fmaf(fmaf(alj, wb-wa, wa), I[ioS[p]], acc1);
        }
      }
    }
  }

  // ---- fused gate epilogue ----
  const float inv = 0.5129891760f;
  if (lane < 16){
    SG[2*lane]   = acc0*0.5f*inv;
    SG[2*lane+1] = acc1*0.5f*inv;
  }
  __syncthreads();
  float* __restrict__ o = xg + (size_t)node*64;
  if (lane < 16){
    o[lane] = fmaxf(SG[lane], 0.0f);                       // se
  } else if (lane < 40){
    int idx = lane-16;
    float vv = (acc0+acc1)*0.4082482905f*inv;
    o[16+idx] = vv * fmaxf(SG[gu0], 0.0f);                 // v1o (u<8)
  } else if (lane < 52){
    int m = lane-40;
    float vv0 = acc0*0.5773502692f*inv;
    float vv1 = acc1*0.5773502692f*inv;
    o[40+2*m]   = vv0 * fmaxf(SG[gu0], 0.0f);              // v1e (u<8)
    o[40+2*m+1] = vv1 * fmaxf(SG[gu1], 0.0f);
  }
}

// ---------------- fctp2 per edge -> e2buf[E][4] (pruned, compile-time CG) ----------
__global__ __launch_bounds__(256) void k_tp2(
    const float* __restrict__ pos, const int* __restrict__ src, const int* __restrict__ dst, int E,
    const float* __restrict__ xg, const float* __restrict__ tab,
    float* __restrict__ e2buf)
{
  const int e = blockIdx.x*256 + threadIdx.x;
  if (e>=E) return;
  const int s = src[e], d = dst[e];
  float ax=pos[3*s]-pos[3*d], ay=pos[3*s+1]-pos[3*d+1], az=pos[3*s+2]-pos[3*d+2];
  float r = sqrtf(ax*ax+ay*ay+az*az);
  float ir = 1.0f/r;
  float x=ax*ir, y=ay*ir, z=az*ir;
  float f = r * 1638.0f;
  int i0 = (int)f; if (i0 > T_TAB-2) i0 = T_TAB-2;
  const float al = f - (float)i0;
  const float* __restrict__ w0 = tab + (size_t)i0*336 + 272;
  const float* __restrict__ w1 = w0 + 336;
  float wse[16], wA[8], wB[8], wC[8];
#pragma unroll
  for (int j=0;j<16;j+=4){
    float4 p = *(const float4*)(w0+j);
    float4 q = *(const float4*)(w1+j);
    wse[j+0]=fmaf(al,q.x-p.x,p.x); wse[j+1]=fmaf(al,q.y-p.y,p.y);
    wse[j+2]=fmaf(al,q.z-p.z,p.z); wse[j+3]=fmaf(al,q.w-p.w,p.w);
  }
#pragma unroll
  for (int j=0;j<8;j+=4){
    float4 p = *(const float4*)(w0+16+j); float4 q = *(const float4*)(w1+16+j);
    wA[j+0]=fmaf(al,q.x-p.x,p.x); wA[j+1]=fmaf(al,q.y-p.y,p.y);
    wA[j+2]=fmaf(al,q.z-p.z,p.z); wA[j+3]=fmaf(al,q.w-p.w,p.w);
    p = *(const float4*)(w0+32+j); q = *(const float4*)(w1+32+j);
    wB[j+0]=fmaf(al,q.x-p.x,p.x); wB[j+1]=fmaf(al,q.y-p.y,p.y);
    wB[j+2]=fmaf(al,q.z-p.z,p.z); wB[j+3]=fmaf(al,q.w-p.w,p.w);
    p = *(const float4*)(w0+48+j); q = *(const float4*)(w1+48+j);
    wC[j+0]=fmaf(al,q.x-p.x,p.x); wC[j+1]=fmaf(al,q.y-p.y,p.y);
    wC[j+2]=fmaf(al,q.z-p.z,p.z); wC[j+3]=fmaf(al,q.w-p.w,p.w);
  }
  const float s3=1.73205081f, s5=2.23606798f, s15=3.87298335f;
  float Y[9];
  Y[0]=1.0f;
  Y[1]=s3*y; Y[2]=s3*z; Y[3]=s3*x;
  Y[4]=s15*x*y; Y[5]=s15*y*z; Y[6]=0.5f*s5*(3.0f*z*z-1.0f); Y[7]=s15*x*z; Y[8]=0.5f*s15*(x*x-y*y);
  const float* __restrict__ g = xg + (size_t)s*64;
  float se[16], vo[24], ve[24];
#pragma unroll
  for (int jj=0;jj<4;++jj){ float4 t=((const float4*)g)[jj];
    se[4*jj]=t.x; se[4*jj+1]=t.y; se[4*jj+2]=t.z; se[4*jj+3]=t.w; }
#pragma unroll
  for (int jj=0;jj<6;++jj){ float4 t=((const float4*)(g+16))[jj];
    vo[4*jj]=t.x; vo[4*jj+1]=t.y; vo[4*jj+2]=t.z; vo[4*jj+3]=t.w; }
#pragma unroll
  for (int jj=0;jj<6;++jj){ float4 t=((const float4*)(g+40))[jj];
    ve[4*jj]=t.x; ve[4*jj+1]=t.y; ve[4*jj+2]=t.z; ve[4*jj+3]=t.w; }

  float SA=0.0f;
#pragma unroll
  for (int u=0;u<16;++u) SA = fmaf(wse[u], se[u], SA);
  float AB[3]={0,0,0}, AC[3]={0,0,0}, AD[3]={0,0,0};
#pragma unroll
  for (int u=0;u<8;++u)
#pragma unroll
    for (int i=0;i<3;++i){
      AB[i]=fmaf(wA[u], vo[u*3+i], AB[i]);
      AC[i]=fmaf(wB[u], vo[u*3+i], AC[i]);
      AD[i]=fmaf(wC[u], ve[u*3+i], AD[i]);
    }
  float e2[3]={0,0,0};
#pragma unroll
  for (int j=0;j<3;++j){ float t=SA*Y[1+j];
#pragma unroll
    for (int k=0;k<3;++k) TERM(CG011, j*3+k, t, e2[k]) }
#pragma unroll
  for (int i=0;i<3;++i){ float t=AB[i]*Y[0];
#pragma unroll
    for (int k=0;k<3;++k) TERM(CG101, i*3+k, t, e2[k]) }
#pragma unroll
  for (int i=0;i<3;++i)
#pragma unroll
    for (int j=0;j<5;++j){ float t=AC[i]*Y[4+j];
#pragma unroll
      for (int k=0;k<3;++k) TERM(CG121, (i*5+j)*3+k, t, e2[k]) }
#pragma unroll
  for (int i=0;i<3;++i)
#pragma unroll
    for (int j=0;j<3;++j){ float t=AD[i]*Y[1+j];
#pragma unroll
      for (int k=0;k<3;++k) TERM(CG111, (i*3+j)*3+k, t, e2[k]) }

  *(float4*)(e2buf + (size_t)e*4) = make_float4(e2[0], e2[1], e2[2], 0.0f);
}

// ---------------- final gather ----------------
__global__ __launch_bounds__(256) void k_out(
    const float* __restrict__ e2buf, const int* __restrict__ rowptr,
    float* __restrict__ out)
{
  const int t = blockIdx.x*256 + threadIdx.x;
  const int n = t>>2, k = t&3;
  if (n>=NN) return;
  const int r0=rowptr[n], r1=rowptr[n+1];
  float a=0.f;
  for (int e=r0;e<r1;++e) a += e2buf[(size_t)e*4 + k];
  const float sc = 0.0641236437f;  // (1/sqrt(64)) * 1/sqrt(3.8)
  if (k<3) out[(size_t)n*3 + k] = a*sc;
}

// ---------------- host launcher ----------------
extern "C" void kernel_launch(void* const* d_in, const int* in_sizes, int n_in,
                              void* d_out, int out_size, void* d_ws, size_t ws_size,
                              hipStream_t stream)
{
  (void)n_in; (void)ws_size; (void)out_size;
  const float* pos = (const float*)d_in[0];
  const int*   src = (const int*)d_in[1];
  const int*   dst = (const int*)d_in[2];
  const float* W1  = (const float*)d_in[3];
  const float* W2  = (const float*)d_in[4];
  const float* W1f = (const float*)d_in[5];
  const float* W2f = (const float*)d_in[6];
  const int E = in_sizes[1];

  char* ws = (char*)d_ws;
  float* xacc  = (float*)ws;                     // NN*16
  float* xg    = xacc + (size_t)NN*16;           // NN*64
  float* tab   = xg + (size_t)NN*64;             // T_TAB*336
  float* e2buf = tab + (size_t)T_TAB*336;        // E*4
  int*   rowptr= (int*)(e2buf + (size_t)E*4);    // NN+1

  k_table<<<T_TAB/G_TAB, 256, 0, stream>>>(W1, W2, W1f, W2f, tab);
  k_rowptr<<<(NN+1+255)/256, 256, 0, stream>>>(dst, E, rowptr);
  k_x<<<(NN*4)/256, 256, 0, stream>>>(pos, src, rowptr, xacc);
  k_tp1<<<NN, 64, 0, stream>>>(pos, src, rowptr, xacc, tab, xg);
  k_tp2<<<(E + 255) / 256, 256, 0, stream>>>(pos, src, dst, E, xg, tab, e2buf);
  k_out<<<(NN*4)/256, 256, 0, stream>>>(e2buf, rowptr, (float*)d_out);
}

// Round 10
// 148.677 us; speedup vs baseline: 1.8065x; 1.1059x over previous
//
#include <hip/hip_runtime.h>
#include <cmath>

#define T_TAB 4096
#define NN 16384
#define CH 32

// ================= compile-time CG tables (constexpr port of the reference) ========
struct CD { double re, im; };
constexpr CD cmul(CD a, CD b){ return {a.re*b.re - a.im*b.im, a.re*b.im + a.im*b.re}; }
constexpr CD cadd(CD a, CD b){ return {a.re+b.re, a.im+b.im}; }
constexpr CD conj_(CD a){ return {a.re, -a.im}; }
constexpr CD cscale(CD a, double s){ return {a.re*s, a.im*s}; }
constexpr double cfabs_(double x){ return x<0.0 ? -x : x; }
constexpr double csqrt_(double x){
  double g = x > 1.0 ? x : 1.0;
  for (int i=0;i<80;++i) g = 0.5*(g + x/g);
  return g;
}
constexpr double factd(int n){ double r=1.0; for(int i=2;i<=n;++i) r*=(double)i; return r; }

constexpr double cg_coef(int j1,int m1,int j2,int m2,int j3,int m3){
  double pref = csqrt_((2.0*j3+1.0)*factd(j3+j1-j2)*factd(j3-j1+j2)*factd(j1+j2-j3)/factd(j1+j2+j3+1));
  pref *= csqrt_(factd(j3+m3)*factd(j3-m3)*factd(j1-m1)*factd(j1+m1)*factd(j2-m2)*factd(j2+m2));
  double s=0.0;
  for(int k=0;k<=j1+j2-j3;++k){
    int a0=k,a1=j1+j2-j3-k,a2=j1-m1-k,a3=j2+m2-k,a4=j3-j2+m1+k,a5=j3-j1-m2+k;
    if(a0<0||a1<0||a2<0||a3<0||a4<0||a5<0) continue;
    double d=factd(a0)*factd(a1)*factd(a2)*factd(a3)*factd(a4)*factd(a5);
    s += ((k&1)?-1.0:1.0)/d;
  }
  return pref*s;
}

struct UMat { CD u[7][7]; };
constexpr UMat u_fill(int l){
  UMat M{};
  const double is2 = csqrt_(0.5);
  M.u[l][l] = CD{1.0, 0.0};
  for(int m=1;m<=l;++m){
    double sgn = (m&1)?-1.0:1.0;
    M.u[l+m][l+m] = CD{sgn*is2, 0.0};
    M.u[l+m][l-m] = CD{is2, 0.0};
    M.u[l-m][l-m] = CD{0.0, is2};
    M.u[l-m][l+m] = CD{0.0, -sgn*is2};
  }
  return M;
}

template<int L1,int L2,int L3>
struct FT { float v[(2*L1+1)*(2*L2+1)*(2*L3+1)]; };

template<int L1,int L2,int L3>
constexpr FT<L1,L2,L3> cg_real_ct(){
  constexpr int n1=2*L1+1, n2=2*L2+1, n3=2*L3+1;
  double Cc[7][7][7] = {};
  for(int m1=-L1;m1<=L1;++m1)
    for(int m2=-L2;m2<=L2;++m2){
      int m3=m1+m2;
      if(m3>=-L3&&m3<=L3) Cc[m1+L1][m2+L2][m3+L3]=cg_coef(L1,m1,L2,m2,L3,m3);
    }
  UMat U1 = u_fill(L1), U2 = u_fill(L2), U3 = u_fill(L3);
  CD Cr[7][7][7] = {};
  double sre=0.0, sim=0.0;
  for(int a=0;a<n1;++a)for(int b=0;b<n2;++b)for(int c=0;c<n3;++c){
    CD acc{0.0,0.0};
    for(int u=0;u<n1;++u)for(int v=0;v<n2;++v){
      int w = (u-L1)+(v-L2)+L3;           // only m3=m1+m2 can be nonzero in Cc
      if (w < 0 || w >= n3) continue;
      double cc = Cc[u][v][w];
      if (cc == 0.0) continue;
      acc = cadd(acc, cscale(cmul(cmul(U1.u[a][u],U2.u[b][v]),conj_(U3.u[c][w])), cc));
    }
    Cr[a][b][c] = acc;
    sre += cfabs_(acc.re); sim += cfabs_(acc.im);
  }
  FT<L1,L2,L3> out{};
  bool useim = sim > sre;
  for(int a=0;a<n1;++a)for(int b=0;b<n2;++b)for(int c=0;c<n3;++c)
    out.v[(a*n2+b)*n3+c] = (float)(useim ? Cr[a][b][c].im : Cr[a][b][c].re);
  return out;
}

constexpr auto CG000 = cg_real_ct<0,0,0>();
constexpr auto CG110 = cg_real_ct<1,1,0>();
constexpr auto CG220 = cg_real_ct<2,2,0>();
constexpr auto CG330 = cg_real_ct<3,3,0>();
constexpr auto CG011 = cg_real_ct<0,1,1>();
constexpr auto CG101 = cg_real_ct<1,0,1>();
constexpr auto CG111 = cg_real_ct<1,1,1>();
constexpr auto CG121 = cg_real_ct<1,2,1>();
constexpr auto CG211 = cg_real_ct<2,1,1>();
constexpr auto CG221 = cg_real_ct<2,2,1>();
constexpr auto CG231 = cg_real_ct<2,3,1>();
constexpr auto CG321 = cg_real_ct<3,2,1>();
constexpr auto CG331 = cg_real_ct<3,3,1>();

// zero-pruned FMA term: coefficient folds to a literal; zero terms are deleted.
#define TERM(TBL, IDX, PROD, ACC) { float c_ = TBL.v[IDX]; if (c_ != 0.0f) ACC = fmaf((PROD), c_, ACC); }

// ---------------- device helpers ----------------
__device__ __forceinline__ float soh(float r, float c){
  float d = (r - c) * 2.0f;
  float d2 = d*d;
  return (d2 < 1.0f) ? 1.14136f * expf(2.0f + 1.0f/(d2-1.0f)) : 0.0f;
}

// Per-lane weight schedule: lane ℓ, sub-index q (0..7) -> (column in [0,272) or -1, LDS slot).
// Slot 31 is a guaranteed-zero slot.
__device__ __forceinline__ void lane_sched(int lane, int q, int& col, int& slot){
  col = -1; slot = 31;
  if (lane < 16){
    int s = q >> 2, qq = q & 3;
    int a = 2*lane + s;                 // scalar output index 0..31
    const int base0[4] = {0, 64, 144, 224};
    col = base0[qq] + a; slot = qq;
  } else if (lane < 40){
    int idx = lane-16, u = idx/3, k = idx-3*u;
    const int wb[6] = {32,48,112,128,192,208};
    const int sb[6] = {4,7,10,13,16,19};
    if (q < 6){ col = wb[q]+u; slot = sb[q]+k; }
  } else if (lane < 52){
    int m = lane-40;
    int c0 = (q < 4) ? 2*m : 2*m+1;
    int u = c0/3, k = c0-3*u;
    int qq = (q < 4) ? q : q-4;
    if (qq < 3){
      const int wb[3] = {96,176,256};
      const int sb[3] = {22,25,28};
      col = wb[qq]+u; slot = sb[qq]+k;
    }
  }
}

// ---------------- radial MLP lookup table: tab[T_TAB][336] ----------------
// jq-major grid: block bid covers j-quad jq=bid>>4, t-range (bid&15)*256 + lane.
// All weight addresses are wave-uniform -> scalar (s_load) traffic; no LDS, no sync.
__global__ __launch_bounds__(256) void k_table(
    const float* __restrict__ W1, const float* __restrict__ W2,
    const float* __restrict__ W1f, const float* __restrict__ W2f,
    float* __restrict__ tab)
{
  const int bid = blockIdx.x;                 // 84*16 = 1344
  const int jq  = bid >> 4;                   // 0..83
  const int t   = (bid & 15)*256 + threadIdx.x;
  const int j0  = jq*4;
  const float dr = 2.5f / (float)(T_TAB-1);
  const float r = (float)t * dr;
  const float e0 = soh(r,1.0f), e1 = soh(r,1.5f), e2 = soh(r,2.0f);
  float ax=0.f, ay=0.f, az=0.f, aw=0.f;
  if (j0 < 272){
    for (int cc=0; cc<256; ++cc){
      float h = fmaxf(fmaf(e0,W1[cc], fmaf(e1,W1[256+cc], e2*W1[512+cc])), 0.0f);
      float4 w = *(const float4*)(W2 + cc*272 + j0);
      ax = fmaf(h,w.x,ax); ay = fmaf(h,w.y,ay);
      az = fmaf(h,w.z,az); aw = fmaf(h,w.w,aw);
    }
  } else {
    const int jj = j0 - 272;
    for (int cc=0; cc<256; ++cc){
      float h = fmaxf(fmaf(e0,W1f[cc], fmaf(e1,W1f[256+cc], e2*W1f[512+cc])), 0.0f);
      float4 w = *(const float4*)(W2f + cc*64 + jj);
      ax = fmaf(h,w.x,ax); ay = fmaf(h,w.y,ay);
      az = fmaf(h,w.z,az); aw = fmaf(h,w.w,aw);
    }
  }
  *(float4*)(tab + (size_t)t*336 + j0) = make_float4(ax*0.0625f, ay*0.0625f, az*0.0625f, aw*0.0625f);
}

// ---------------- rowptr: dst is globally non-decreasing -> CSR via binary search ----
__global__ __launch_bounds__(256) void k_rowptr(
    const int* __restrict__ dst, int E, int* __restrict__ rowptr)
{
  const int n = blockIdx.x*256 + threadIdx.x;
  if (n > NN) return;
  int lo=0, hi=E;
  while (lo < hi){ int mid=(lo+hi)>>1; if (dst[mid] < n) lo=mid+1; else hi=mid; }
  rowptr[n]=lo;
}

// ---------------- x = segsum(sph_harm): 4 lanes/node, each edge touched once -------
__global__ __launch_bounds__(256) void k_x(
    const float* __restrict__ pos, const int* __restrict__ src,
    const int* __restrict__ rowptr, float* __restrict__ xacc)
{
  const int t = blockIdx.x*256 + threadIdx.x;
  const int n = t>>2, q = t&3;
  if (n>=NN) return;
  const int r0=rowptr[n], r1=rowptr[n+1];
  const float pdx=pos[3*n], pdy=pos[3*n+1], pdz=pos[3*n+2];
  const float s3=1.73205081f, s5=2.23606798f, s15=3.87298335f;
  const float c33=2.09165007f, c32=10.2469508f, c31=1.62018517f, c30=1.32287566f, cp2=5.12347538f;
  float a0=0,a1=0,a2=0,a3=0,a4=0,a5=0,a6=0,a7=0,a8=0,a9=0,a10=0,a11=0,a12=0,a13=0,a14=0,a15=0;
  for (int e=r0+q; e<r1; e+=4){
    const int s=src[e];
    float ax=pos[3*s]-pdx, ay=pos[3*s+1]-pdy, az=pos[3*s+2]-pdz;
    float ir = 1.0f/sqrtf(ax*ax+ay*ay+az*az);
    float x=ax*ir, y=ay*ir, z=az*ir;
    a0+=1.0f; a1+=s3*y; a2+=s3*z; a3+=s3*x;
    a4+=s15*x*y; a5+=s15*y*z; a6+=0.5f*s5*(3.0f*z*z-1.0f); a7+=s15*x*z;
    a8+=0.5f*s15*(x*x-y*y); a9+=c33*y*(3.0f*x*x-y*y); a10+=c32*x*y*z; a11+=c31*y*(5.0f*z*z-1.0f);
    a12+=c30*(5.0f*z*z*z-3.0f*z); a13+=c31*x*(5.0f*z*z-1.0f); a14+=cp2*z*(x*x-y*y);
    a15+=c33*x*(x*x-3.0f*y*y);
  }
#define RED(v) v += __shfl_xor(v,1); v += __shfl_xor(v,2);
  RED(a0) RED(a1) RED(a2) RED(a3) RED(a4) RED(a5) RED(a6) RED(a7)
  RED(a8) RED(a9) RED(a10) RED(a11) RED(a12) RED(a13) RED(a14) RED(a15)
#undef RED
  float o0,o1,o2,o3;
  if (q==0){ o0=a0; o1=a1; o2=a2; o3=a3; }
  else if (q==1){ o0=a4; o1=a5; o2=a6; o3=a7; }
  else if (q==2){ o0=a8; o1=a9; o2=a10; o3=a11; }
  else { o0=a12; o1=a13; o2=a14; o3=a15; }
  *(float4*)(xacc + (size_t)n*16 + q*4) = make_float4(o0,o1,o2,o3);
}

// ---------------- fctp1 + gate fused: 4 waves per block, ONE NODE PER WAVE ----------
// With CH=32 and avg degree ~12, nch==1 for nearly all nodes -> barrier coupling is
// free, and 256-thread blocks lift the workgroup-per-CU occupancy cap (R9: 33%).
// Phase 1: lane = edge, zero-pruned compile-time CG, single code path.
// Phase 2: shared-row scattered table loads + inline lerp, static schedule.
__global__ __launch_bounds__(256) void k_tp1(
    const float* __restrict__ pos, const int* __restrict__ src,
    const int* __restrict__ rowptr, const float* __restrict__ xacc,
    const float* __restrict__ tab, float* __restrict__ xg)
{
  const int wid  = threadIdx.x >> 6;
  const int lane = threadIdx.x & 63;
  const int node = blockIdx.x*4 + wid;
  __shared__ float SI[4][CH][33];   // 0..30 intermediates, 31 zero, 32 al
  __shared__ int   SiT[4][CH];
  __shared__ float SG[4][32];
  __shared__ int   sdeg[4];
  const int r0 = rowptr[node], r1 = rowptr[node+1];
  if (lane==0) sdeg[wid] = r1 - r0;
  __syncthreads();
  const int dmax = max(max(sdeg[0],sdeg[1]), max(sdeg[2],sdeg[3]));
  const int nch = (dmax + CH - 1) / CH;

  // ---- static (weight-col, LDS-slot) schedule + gate indices ----
  int wo[8], ioS[8];
#pragma unroll
  for (int p=0;p<8;++p){
    int c_, s_; lane_sched(lane, p, c_, s_);
    wo[p] = (c_>=0) ? c_ : 0; ioS[p] = s_;
  }
  int gu0=16, gu1=16;
  if (lane >= 16 && lane < 40){ gu0 = 16 + (lane-16)/3; }
  else if (lane >= 40 && lane < 52){
    int m=lane-40; gu0 = 24 + (2*m)/3; gu1 = 24 + (2*m+1)/3;
  }

  const float pdx=pos[3*node], pdy=pos[3*node+1], pdz=pos[3*node+2];
  float acc0 = 0.f, acc1 = 0.f;

  for (int t=0; t<nch; ++t){
    const int e0 = r0 + t*CH;
    const int cnt = min(CH, r1-e0);        // may be <= 0 for this wave
    __syncthreads();                       // WAR: prev chunk phase-2 reads done
    if (lane < cnt){
      const int e = e0 + lane;
      const int s = src[e];
      float ax=pos[3*s]-pdx, ay=pos[3*s+1]-pdy, az=pos[3*s+2]-pdz;
      float r = sqrtf(ax*ax+ay*ay+az*az);
      float ir = 1.0f/r;
      float x=ax*ir, y=ay*ir, z=az*ir;
      float f = r * 1638.0f;                    // (T_TAB-1)/2.5
      int i0 = (int)f; if (i0 > T_TAB-2) i0 = T_TAB-2;
      float al = f - (float)i0;

      const float s3=1.73205081f, s5=2.23606798f, s15=3.87298335f;
      const float c33=2.09165007f, c32=10.2469508f, c31=1.62018517f, c30=1.32287566f, cp2=5.12347538f;
      float Y[16];
      Y[0]=1.0f;
      Y[1]=s3*y; Y[2]=s3*z; Y[3]=s3*x;
      Y[4]=s15*x*y; Y[5]=s15*y*z; Y[6]=0.5f*s5*(3.0f*z*z-1.0f); Y[7]=s15*x*z; Y[8]=0.5f*s15*(x*x-y*y);
      Y[9]=c33*y*(3.0f*x*x-y*y); Y[10]=c32*x*y*z; Y[11]=c31*y*(5.0f*z*z-1.0f);
      Y[12]=c30*(5.0f*z*z*z-3.0f*z); Y[13]=c31*x*(5.0f*z*z-1.0f); Y[14]=cp2*z*(x*x-y*y);
      Y[15]=c33*x*(x*x-3.0f*y*y);
      float X[16];
      {
        const float inv = 0.5129891760f;           // 1/sqrt(3.8)
        const float4* q4 = (const float4*)(xacc + (size_t)s*16);
        float4 a=q4[0],b=q4[1],cc4=q4[2],d4=q4[3];
        X[0]=a.x*inv;X[1]=a.y*inv;X[2]=a.z*inv;X[3]=a.w*inv;
        X[4]=b.x*inv;X[5]=b.y*inv;X[6]=b.z*inv;X[7]=b.w*inv;
        X[8]=cc4.x*inv;X[9]=cc4.y*inv;X[10]=cc4.z*inv;X[11]=cc4.w*inv;
        X[12]=d4.x*inv;X[13]=d4.y*inv;X[14]=d4.z*inv;X[15]=d4.w*inv;
      }
      float* SS = SI[wid][lane];

      // t-block (scalar outputs)
      {
        float t0v = CG000.v[0]*X[0]*Y[0];
        float t1v=0.f, t2v=0.f, t3v=0.f;
#pragma unroll
        for (int i=0;i<3;++i)
#pragma unroll
          for (int j=0;j<3;++j) TERM(CG110, i*3+j, X[1+i]*Y[1+j], t1v)
#pragma unroll
        for (int i=0;i<5;++i)
#pragma unroll
          for (int j=0;j<5;++j) TERM(CG220, i*5+j, X[4+i]*Y[4+j], t2v)
#pragma unroll
        for (int i=0;i<7;++i)
#pragma unroll
          for (int j=0;j<7;++j) TERM(CG330, i*7+j, X[9+i]*Y[9+j], t3v)
        SS[0]=t0v; SS[1]=t1v; SS[2]=t2v; SS[3]=t3v;
      }
      // vector outputs
      {
        float v01[3]={0,0,0}, v10[3]={0,0,0}, v11[3]={0,0,0}, v12[3]={0,0,0},
              v21[3]={0,0,0}, v22[3]={0,0,0}, v23[3]={0,0,0}, v32[3]={0,0,0}, v33[3]={0,0,0};
#pragma unroll
        for (int j=0;j<3;++j){ float tt=X[0]*Y[1+j];
#pragma unroll
          for (int k=0;k<3;++k) TERM(CG011, j*3+k, tt, v01[k]) }
#pragma unroll
        for (int i=0;i<3;++i){ float tt=X[1+i]*Y[0];
#pragma unroll
          for (int k=0;k<3;++k) TERM(CG101, i*3+k, tt, v10[k]) }
#pragma unroll
        for (int i=0;i<3;++i)
#pragma unroll
          for (int j=0;j<3;++j){ float tt=X[1+i]*Y[1+j];
#pragma unroll
            for (int k=0;k<3;++k) TERM(CG111, (i*3+j)*3+k, tt, v11[k]) }
#pragma unroll
        for (int i=0;i<3;++i)
#pragma unroll
          for (int j=0;j<5;++j){ float tt=X[1+i]*Y[4+j];
#pragma unroll
            for (int k=0;k<3;++k) TERM(CG121, (i*5+j)*3+k, tt, v12[k]) }
#pragma unroll
        for (int i=0;i<5;++i)
#pragma unroll
          for (int j=0;j<3;++j){ float tt=X[4+i]*Y[1+j];
#pragma unroll
            for (int k=0;k<3;++k) TERM(CG211, (i*3+j)*3+k, tt, v21[k]) }
#pragma unroll
        for (int i=0;i<5;++i)
#pragma unroll
          for (int j=0;j<5;++j){ float tt=X[4+i]*Y[4+j];
#pragma unroll
            for (int k=0;k<3;++k) TERM(CG221, (i*5+j)*3+k, tt, v22[k]) }
#pragma unroll
        for (int i=0;i<5;++i)
#pragma unroll
          for (int j=0;j<7;++j){ float tt=X[4+i]*Y[9+j];
#pragma unroll
            for (int k=0;k<3;++k) TERM(CG231, (i*7+j)*3+k, tt, v23[k]) }
#pragma unroll
        for (int i=0;i<7;++i)
#pragma unroll
          for (int j=0;j<5;++j){ float tt=X[9+i]*Y[4+j];
#pragma unroll
            for (int k=0;k<3;++k) TERM(CG321, (i*5+j)*3+k, tt, v32[k]) }
#pragma unroll
        for (int i=0;i<7;++i)
#pragma unroll
          for (int j=0;j<7;++j){ float tt=X[9+i]*Y[9+j];
#pragma unroll
            for (int k=0;k<3;++k) TERM(CG331, (i*7+j)*3+k, tt, v33[k]) }
#pragma unroll
        for (int k=0;k<3;++k){
          SS[4+k]=v01[k]; SS[7+k]=v10[k]; SS[10+k]=v12[k]; SS[13+k]=v21[k];
          SS[16+k]=v23[k]; SS[19+k]=v32[k]; SS[22+k]=v11[k]; SS[25+k]=v22[k]; SS[28+k]=v33[k];
        }
      }
      SS[31]=0.0f; SS[32]=al;
      SiT[wid][lane]=i0;
    }
    __syncthreads();                 // RAW: phase-1 SI/SiT visible
    // ---- phase 2: shared-row scattered loads + inline lerp, static schedule ----
#pragma unroll 4
    for (int j=0; j<CH; ++j){
      if (j < cnt){
        const float* __restrict__ wr0 = tab + (size_t)SiT[wid][j]*336;
        const float* __restrict__ wr1 = wr0 + 336;
        const float* __restrict__ I = SI[wid][j];
        const float alj = I[32];
#pragma unroll
        for (int p=0;p<4;++p){
          float wa = wr0[wo[p]], wb = wr1[wo[p]];
          acc0 = fmaf(fmaf(alj, wb-wa, wa), I[ioS[p]], acc0);
        }
#pragma unroll
        for (int p=4;p<8;++p){
          float wa = wr0[wo[p]], wb = wr1[wo[p]];
          acc1 = fmaf(fmaf(alj, wb-wa, wa), I[ioS[p]], acc1);
        }
      }
    }
  }

  // ---- fused gate epilogue ----
  const float inv = 0.5129891760f;
  if (lane < 16){
    SG[wid][2*lane]   = acc0*0.5f*inv;
    SG[wid][2*lane+1] = acc1*0.5f*inv;
  }
  __syncthreads();
  float* __restrict__ o = xg + (size_t)node*64;
  if (lane < 16){
    o[lane] = fmaxf(SG[wid][lane], 0.0f);                  // se
  } else if (lane < 40){
    int idx = lane-16;
    float vv = (acc0+acc1)*0.4082482905f*inv;
    o[16+idx] = vv * fmaxf(SG[wid][gu0], 0.0f);            // v1o (u<8)
  } else if (lane < 52){
    int m = lane-40;
    float vv0 = acc0*0.5773502692f*inv;
    float vv1 = acc1*0.5773502692f*inv;
    o[40+2*m]   = vv0 * fmaxf(SG[wid][gu0], 0.0f);         // v1e (u<8)
    o[40+2*m+1] = vv1 * fmaxf(SG[wid][gu1], 0.0f);
  }
}

// ---------------- fctp2 per edge -> e2buf[E][4] (pruned, compile-time CG) ----------
__global__ __launch_bounds__(256) void k_tp2(
    const float* __restrict__ pos, const int* __restrict__ src, const int* __restrict__ dst, int E,
    const float* __restrict__ xg, const float* __restrict__ tab,
    float* __restrict__ e2buf)
{
  const int e = blockIdx.x*256 + threadIdx.x;
  if (e>=E) return;
  const int s = src[e], d = dst[e];
  float ax=pos[3*s]-pos[3*d], ay=pos[3*s+1]-pos[3*d+1], az=pos[3*s+2]-pos[3*d+2];
  float r = sqrtf(ax*ax+ay*ay+az*az);
  float ir = 1.0f/r;
  float x=ax*ir, y=ay*ir, z=az*ir;
  float f = r * 1638.0f;
  int i0 = (int)f; if (i0 > T_TAB-2) i0 = T_TAB-2;
  const float al = f - (float)i0;
  const float* __restrict__ w0 = tab + (size_t)i0*336 + 272;
  const float* __restrict__ w1 = w0 + 336;
  float wse[16], wA[8], wB[8], wC[8];
#pragma unroll
  for (int j=0;j<16;j+=4){
    float4 p = *(const float4*)(w0+j);
    float4 q = *(const float4*)(w1+j);
    wse[j+0]=fmaf(al,q.x-p.x,p.x); wse[j+1]=fmaf(al,q.y-p.y,p.y);
    wse[j+2]=fmaf(al,q.z-p.z,p.z); wse[j+3]=fmaf(al,q.w-p.w,p.w);
  }
#pragma unroll
  for (int j=0;j<8;j+=4){
    float4 p = *(const float4*)(w0+16+j); float4 q = *(const float4*)(w1+16+j);
    wA[j+0]=fmaf(al,q.x-p.x,p.x); wA[j+1]=fmaf(al,q.y-p.y,p.y);
    wA[j+2]=fmaf(al,q.z-p.z,p.z); wA[j+3]=fmaf(al,q.w-p.w,p.w);
    p = *(const float4*)(w0+32+j); q = *(const float4*)(w1+32+j);
    wB[j+0]=fmaf(al,q.x-p.x,p.x); wB[j+1]=fmaf(al,q.y-p.y,p.y);
    wB[j+2]=fmaf(al,q.z-p.z,p.z); wB[j+3]=fmaf(al,q.w-p.w,p.w);
    p = *(const float4*)(w0+48+j); q = *(const float4*)(w1+48+j);
    wC[j+0]=fmaf(al,q.x-p.x,p.x); wC[j+1]=fmaf(al,q.y-p.y,p.y);
    wC[j+2]=fmaf(al,q.z-p.z,p.z); wC[j+3]=fmaf(al,q.w-p.w,p.w);
  }
  const float s3=1.73205081f, s5=2.23606798f, s15=3.87298335f;
  float Y[9];
  Y[0]=1.0f;
  Y[1]=s3*y; Y[2]=s3*z; Y[3]=s3*x;
  Y[4]=s15*x*y; Y[5]=s15*y*z; Y[6]=0.5f*s5*(3.0f*z*z-1.0f); Y[7]=s15*x*z; Y[8]=0.5f*s15*(x*x-y*y);
  const float* __restrict__ g = xg + (size_t)s*64;
  float se[16], vo[24], ve[24];
#pragma unroll
  for (int jj=0;jj<4;++jj){ float4 t=((const float4*)g)[jj];
    se[4*jj]=t.x; se[4*jj+1]=t.y; se[4*jj+2]=t.z; se[4*jj+3]=t.w; }
#pragma unroll
  for (int jj=0;jj<6;++jj){ float4 t=((const float4*)(g+16))[jj];
    vo[4*jj]=t.x; vo[4*jj+1]=t.y; vo[4*jj+2]=t.z; vo[4*jj+3]=t.w; }
#pragma unroll
  for (int jj=0;jj<6;++jj){ float4 t=((const float4*)(g+40))[jj];
    ve[4*jj]=t.x; ve[4*jj+1]=t.y; ve[4*jj+2]=t.z; ve[4*jj+3]=t.w; }

  float SA=0.0f;
#pragma unroll
  for (int u=0;u<16;++u) SA = fmaf(wse[u], se[u], SA);
  float AB[3]={0,0,0}, AC[3]={0,0,0}, AD[3]={0,0,0};
#pragma unroll
  for (int u=0;u<8;++u)
#pragma unroll
    for (int i=0;i<3;++i){
      AB[i]=fmaf(wA[u], vo[u*3+i], AB[i]);
      AC[i]=fmaf(wB[u], vo[u*3+i], AC[i]);
      AD[i]=fmaf(wC[u], ve[u*3+i], AD[i]);
    }
  float e2[3]={0,0,0};
#pragma unroll
  for (int j=0;j<3;++j){ float t=SA*Y[1+j];
#pragma unroll
    for (int k=0;k<3;++k) TERM(CG011, j*3+k, t, e2[k]) }
#pragma unroll
  for (int i=0;i<3;++i){ float t=AB[i]*Y[0];
#pragma unroll
    for (int k=0;k<3;++k) TERM(CG101, i*3+k, t, e2[k]) }
#pragma unroll
  for (int i=0;i<3;++i)
#pragma unroll
    for (int j=0;j<5;++j){ float t=AC[i]*Y[4+j];
#pragma unroll
      for (int k=0;k<3;++k) TERM(CG121, (i*5+j)*3+k, t, e2[k]) }
#pragma unroll
  for (int i=0;i<3;++i)
#pragma unroll
    for (int j=0;j<3;++j){ float t=AD[i]*Y[1+j];
#pragma unroll
      for (int k=0;k<3;++k) TERM(CG111, (i*3+j)*3+k, t, e2[k]) }

  *(float4*)(e2buf + (size_t)e*4) = make_float4(e2[0], e2[1], e2[2], 0.0f);
}

// ---------------- final gather ----------------
__global__ __launch_bounds__(256) void k_out(
    const float* __restrict__ e2buf, const int* __restrict__ rowptr,
    float* __restrict__ out)
{
  const int t = blockIdx.x*256 + threadIdx.x;
  const int n = t>>2, k = t&3;
  if (n>=NN) return;
  const int r0=rowptr[n], r1=rowptr[n+1];
  float a=0.f;
  for (int e=r0;e<r1;++e) a += e2buf[(size_t)e*4 + k];
  const float sc = 0.0641236437f;  // (1/sqrt(64)) * 1/sqrt(3.8)
  if (k<3) out[(size_t)n*3 + k] = a*sc;
}

// ---------------- host launcher ----------------
extern "C" void kernel_launch(void* const* d_in, const int* in_sizes, int n_in,
                              void* d_out, int out_size, void* d_ws, size_t ws_size,
                              hipStream_t stream)
{
  (void)n_in; (void)ws_size; (void)out_size;
  const float* pos = (const float*)d_in[0];
  const int*   src = (const int*)d_in[1];
  const int*   dst = (const int*)d_in[2];
  const float* W1  = (const float*)d_in[3];
  const float* W2  = (const float*)d_in[4];
  const float* W1f = (const float*)d_in[5];
  const float* W2f = (const float*)d_in[6];
  const int E = in_sizes[1];

  char* ws = (char*)d_ws;
  float* xacc  = (float*)ws;                     // NN*16
  float* xg    = xacc + (size_t)NN*16;           // NN*64
  float* tab   = xg + (size_t)NN*64;             // T_TAB*336
  float* e2buf = tab + (size_t)T_TAB*336;        // E*4
  int*   rowptr= (int*)(e2buf + (size_t)E*4);    // NN+1

  k_table<<<84*16, 256, 0, stream>>>(W1, W2, W1f, W2f, tab);
  k_rowptr<<<(NN+1+255)/256, 256, 0, stream>>>(dst, E, rowptr);
  k_x<<<(NN*4)/256, 256, 0, stream>>>(pos, src, rowptr, xacc);
  k_tp1<<<NN/4, 256, 0, stream>>>(pos, src, rowptr, xacc, tab, xg);
  k_tp2<<<(E + 255) / 256, 256, 0, stream>>>(pos, src, dst, E, xg, tab, e2buf);
  k_out<<<(NN*4)/256, 256, 0, stream>>>(e2buf, rowptr, (float*)d_out);
}

// Round 11
// 141.835 us; speedup vs baseline: 1.8936x; 1.0482x over previous
//
#include <hip/hip_runtime.h>
#include <cmath>

#define T_TAB 3072
#define NN 16384
#define CH 32

// ================= compile-time CG tables (constexpr port of the reference) ========
struct CD { double re, im; };
constexpr CD cmul(CD a, CD b){ return {a.re*b.re - a.im*b.im, a.re*b.im + a.im*b.re}; }
constexpr CD cadd(CD a, CD b){ return {a.re+b.re, a.im+b.im}; }
constexpr CD conj_(CD a){ return {a.re, -a.im}; }
constexpr CD cscale(CD a, double s){ return {a.re*s, a.im*s}; }
constexpr double cfabs_(double x){ return x<0.0 ? -x : x; }
constexpr double csqrt_(double x){
  double g = x > 1.0 ? x : 1.0;
  for (int i=0;i<80;++i) g = 0.5*(g + x/g);
  return g;
}
constexpr double factd(int n){ double r=1.0; for(int i=2;i<=n;++i) r*=(double)i; return r; }

constexpr double cg_coef(int j1,int m1,int j2,int m2,int j3,int m3){
  double pref = csqrt_((2.0*j3+1.0)*factd(j3+j1-j2)*factd(j3-j1+j2)*factd(j1+j2-j3)/factd(j1+j2+j3+1));
  pref *= csqrt_(factd(j3+m3)*factd(j3-m3)*factd(j1-m1)*factd(j1+m1)*factd(j2-m2)*factd(j2+m2));
  double s=0.0;
  for(int k=0;k<=j1+j2-j3;++k){
    int a0=k,a1=j1+j2-j3-k,a2=j1-m1-k,a3=j2+m2-k,a4=j3-j2+m1+k,a5=j3-j1-m2+k;
    if(a0<0||a1<0||a2<0||a3<0||a4<0||a5<0) continue;
    double d=factd(a0)*factd(a1)*factd(a2)*factd(a3)*factd(a4)*factd(a5);
    s += ((k&1)?-1.0:1.0)/d;
  }
  return pref*s;
}

struct UMat { CD u[7][7]; };
constexpr UMat u_fill(int l){
  UMat M{};
  const double is2 = csqrt_(0.5);
  M.u[l][l] = CD{1.0, 0.0};
  for(int m=1;m<=l;++m){
    double sgn = (m&1)?-1.0:1.0;
    M.u[l+m][l+m] = CD{sgn*is2, 0.0};
    M.u[l+m][l-m] = CD{is2, 0.0};
    M.u[l-m][l-m] = CD{0.0, is2};
    M.u[l-m][l+m] = CD{0.0, -sgn*is2};
  }
  return M;
}

template<int L1,int L2,int L3>
struct FT { float v[(2*L1+1)*(2*L2+1)*(2*L3+1)]; };

template<int L1,int L2,int L3>
constexpr FT<L1,L2,L3> cg_real_ct(){
  constexpr int n1=2*L1+1, n2=2*L2+1, n3=2*L3+1;
  double Cc[7][7][7] = {};
  for(int m1=-L1;m1<=L1;++m1)
    for(int m2=-L2;m2<=L2;++m2){
      int m3=m1+m2;
      if(m3>=-L3&&m3<=L3) Cc[m1+L1][m2+L2][m3+L3]=cg_coef(L1,m1,L2,m2,L3,m3);
    }
  UMat U1 = u_fill(L1), U2 = u_fill(L2), U3 = u_fill(L3);
  CD Cr[7][7][7] = {};
  double sre=0.0, sim=0.0;
  for(int a=0;a<n1;++a)for(int b=0;b<n2;++b)for(int c=0;c<n3;++c){
    CD acc{0.0,0.0};
    for(int u=0;u<n1;++u)for(int v=0;v<n2;++v){
      int w = (u-L1)+(v-L2)+L3;           // only m3=m1+m2 can be nonzero in Cc
      if (w < 0 || w >= n3) continue;
      double cc = Cc[u][v][w];
      if (cc == 0.0) continue;
      acc = cadd(acc, cscale(cmul(cmul(U1.u[a][u],U2.u[b][v]),conj_(U3.u[c][w])), cc));
    }
    Cr[a][b][c] = acc;
    sre += cfabs_(acc.re); sim += cfabs_(acc.im);
  }
  FT<L1,L2,L3> out{};
  bool useim = sim > sre;
  for(int a=0;a<n1;++a)for(int b=0;b<n2;++b)for(int c=0;c<n3;++c)
    out.v[(a*n2+b)*n3+c] = (float)(useim ? Cr[a][b][c].im : Cr[a][b][c].re);
  return out;
}

constexpr auto CG000 = cg_real_ct<0,0,0>();
constexpr auto CG110 = cg_real_ct<1,1,0>();
constexpr auto CG220 = cg_real_ct<2,2,0>();
constexpr auto CG330 = cg_real_ct<3,3,0>();
constexpr auto CG011 = cg_real_ct<0,1,1>();
constexpr auto CG101 = cg_real_ct<1,0,1>();
constexpr auto CG111 = cg_real_ct<1,1,1>();
constexpr auto CG121 = cg_real_ct<1,2,1>();
constexpr auto CG211 = cg_real_ct<2,1,1>();
constexpr auto CG221 = cg_real_ct<2,2,1>();
constexpr auto CG231 = cg_real_ct<2,3,1>();
constexpr auto CG321 = cg_real_ct<3,2,1>();
constexpr auto CG331 = cg_real_ct<3,3,1>();

// zero-pruned FMA term: coefficient folds to a literal; zero terms are deleted.
#define TERM(TBL, IDX, PROD, ACC) { float c_ = TBL.v[IDX]; if (c_ != 0.0f) ACC = fmaf((PROD), c_, ACC); }

// ---------------- device helpers ----------------
__device__ __forceinline__ float soh(float r, float c){
  float d = (r - c) * 2.0f;
  float d2 = d*d;
  return (d2 < 1.0f) ? 1.14136f * expf(2.0f + 1.0f/(d2-1.0f)) : 0.0f;
}

// Per-lane weight schedule: lane ℓ, sub-index q (0..7) -> (column in [0,272) or -1, LDS slot).
// Slot 31 is a guaranteed-zero slot.
__device__ __forceinline__ void lane_sched(int lane, int q, int& col, int& slot){
  col = -1; slot = 31;
  if (lane < 16){
    int s = q >> 2, qq = q & 3;
    int a = 2*lane + s;                 // scalar output index 0..31
    const int base0[4] = {0, 64, 144, 224};
    col = base0[qq] + a; slot = qq;
  } else if (lane < 40){
    int idx = lane-16, u = idx/3, k = idx-3*u;
    const int wb[6] = {32,48,112,128,192,208};
    const int sb[6] = {4,7,10,13,16,19};
    if (q < 6){ col = wb[q]+u; slot = sb[q]+k; }
  } else if (lane < 52){
    int m = lane-40;
    int c0 = (q < 4) ? 2*m : 2*m+1;
    int u = c0/3, k = c0-3*u;
    int qq = (q < 4) ? q : q-4;
    if (qq < 3){
      const int wb[3] = {96,176,256};
      const int sb[3] = {22,25,28};
      col = wb[qq]+u; slot = sb[qq]+k;
    }
  }
}

// ---------------- radial MLP tables: tab1[T_TAB][272] (fctp1), tab2[T_TAB][64] (fctp2)
// jq-major grid: jq = bid/12 (0..83), t = (bid%12)*256 + lane. Weight addresses are
// wave-uniform (scalar loads); split tables keep each consumer's footprint L2-resident.
__global__ __launch_bounds__(256) void k_table(
    const float* __restrict__ W1, const float* __restrict__ W2,
    const float* __restrict__ W1f, const float* __restrict__ W2f,
    float* __restrict__ tab1, float* __restrict__ tab2)
{
  const int bid = blockIdx.x;                 // 84*12 = 1008
  const int jq  = bid / 12;                   // 0..83
  const int t   = (bid % 12)*256 + threadIdx.x;
  const int j0  = jq*4;
  const float dr = 2.5f / (float)(T_TAB-1);
  const float r = (float)t * dr;
  const float e0 = soh(r,1.0f), e1 = soh(r,1.5f), e2 = soh(r,2.0f);
  float ax=0.f, ay=0.f, az=0.f, aw=0.f;
  if (j0 < 272){
    for (int cc=0; cc<256; ++cc){
      float h = fmaxf(fmaf(e0,W1[cc], fmaf(e1,W1[256+cc], e2*W1[512+cc])), 0.0f);
      float4 w = *(const float4*)(W2 + cc*272 + j0);
      ax = fmaf(h,w.x,ax); ay = fmaf(h,w.y,ay);
      az = fmaf(h,w.z,az); aw = fmaf(h,w.w,aw);
    }
    *(float4*)(tab1 + (size_t)t*272 + j0) = make_float4(ax*0.0625f, ay*0.0625f, az*0.0625f, aw*0.0625f);
  } else {
    const int jj = j0 - 272;
    for (int cc=0; cc<256; ++cc){
      float h = fmaxf(fmaf(e0,W1f[cc], fmaf(e1,W1f[256+cc], e2*W1f[512+cc])), 0.0f);
      float4 w = *(const float4*)(W2f + cc*64 + jj);
      ax = fmaf(h,w.x,ax); ay = fmaf(h,w.y,ay);
      az = fmaf(h,w.z,az); aw = fmaf(h,w.w,aw);
    }
    *(float4*)(tab2 + (size_t)t*64 + jj) = make_float4(ax*0.0625f, ay*0.0625f, az*0.0625f, aw*0.0625f);
  }
}

// ---------------- rowptr: dst is globally non-decreasing -> CSR via binary search ----
__global__ __launch_bounds__(256) void k_rowptr(
    const int* __restrict__ dst, int E, int* __restrict__ rowptr)
{
  const int n = blockIdx.x*256 + threadIdx.x;
  if (n > NN) return;
  int lo=0, hi=E;
  while (lo < hi){ int mid=(lo+hi)>>1; if (dst[mid] < n) lo=mid+1; else hi=mid; }
  rowptr[n]=lo;
}

// ---------------- x = segsum(sph_harm): 4 lanes/node, each edge touched once -------
__global__ __launch_bounds__(256) void k_x(
    const float* __restrict__ pos, const int* __restrict__ src,
    const int* __restrict__ rowptr, float* __restrict__ xacc)
{
  const int t = blockIdx.x*256 + threadIdx.x;
  const int n = t>>2, q = t&3;
  if (n>=NN) return;
  const int r0=rowptr[n], r1=rowptr[n+1];
  const float pdx=pos[3*n], pdy=pos[3*n+1], pdz=pos[3*n+2];
  const float s3=1.73205081f, s5=2.23606798f, s15=3.87298335f;
  const float c33=2.09165007f, c32=10.2469508f, c31=1.62018517f, c30=1.32287566f, cp2=5.12347538f;
  float a0=0,a1=0,a2=0,a3=0,a4=0,a5=0,a6=0,a7=0,a8=0,a9=0,a10=0,a11=0,a12=0,a13=0,a14=0,a15=0;
  for (int e=r0+q; e<r1; e+=4){
    const int s=src[e];
    float ax=pos[3*s]-pdx, ay=pos[3*s+1]-pdy, az=pos[3*s+2]-pdz;
    float ir = 1.0f/sqrtf(ax*ax+ay*ay+az*az);
    float x=ax*ir, y=ay*ir, z=az*ir;
    a0+=1.0f; a1+=s3*y; a2+=s3*z; a3+=s3*x;
    a4+=s15*x*y; a5+=s15*y*z; a6+=0.5f*s5*(3.0f*z*z-1.0f); a7+=s15*x*z;
    a8+=0.5f*s15*(x*x-y*y); a9+=c33*y*(3.0f*x*x-y*y); a10+=c32*x*y*z; a11+=c31*y*(5.0f*z*z-1.0f);
    a12+=c30*(5.0f*z*z*z-3.0f*z); a13+=c31*x*(5.0f*z*z-1.0f); a14+=cp2*z*(x*x-y*y);
    a15+=c33*x*(x*x-3.0f*y*y);
  }
#define RED(v) v += __shfl_xor(v,1); v += __shfl_xor(v,2);
  RED(a0) RED(a1) RED(a2) RED(a3) RED(a4) RED(a5) RED(a6) RED(a7)
  RED(a8) RED(a9) RED(a10) RED(a11) RED(a12) RED(a13) RED(a14) RED(a15)
#undef RED
  float o0,o1,o2,o3;
  if (q==0){ o0=a0; o1=a1; o2=a2; o3=a3; }
  else if (q==1){ o0=a4; o1=a5; o2=a6; o3=a7; }
  else if (q==2){ o0=a8; o1=a9; o2=a10; o3=a11; }
  else { o0=a12; o1=a13; o2=a14; o3=a15; }
  *(float4*)(xacc + (size_t)n*16 + q*4) = make_float4(o0,o1,o2,o3);
}

// ---------------- fctp1 + gate fused: ONE WAVE PER NODE (R9 structure) --------------
// Phase 1: lane = edge, zero-pruned compile-time CG, single code path.
// Phase 2: shared-row scattered tab1 loads + inline lerp, static schedule,
//          alternating accumulator pairs to break the FMA dependency chain.
__global__ __launch_bounds__(64) void k_tp1(
    const float* __restrict__ pos, const int* __restrict__ src,
    const int* __restrict__ rowptr, const float* __restrict__ xacc,
    const float* __restrict__ tab1, float* __restrict__ xg)
{
  const int lane = threadIdx.x;
  const int node = blockIdx.x;
  __shared__ float SI[CH][33];   // 0..30 intermediates, 31 zero, 32 al
  __shared__ int   SiT[CH];
  __shared__ float SG[32];
  const int r0 = rowptr[node], r1 = rowptr[node+1];
  const int nch = (r1 - r0 + CH - 1) / CH;

  // ---- static (weight-col, LDS-slot) schedule + gate indices ----
  int wo[8], ioS[8];
#pragma unroll
  for (int p=0;p<8;++p){
    int c_, s_; lane_sched(lane, p, c_, s_);
    wo[p] = (c_>=0) ? c_ : 0; ioS[p] = s_;
  }
  int gu0=16, gu1=16;
  if (lane >= 16 && lane < 40){ gu0 = 16 + (lane-16)/3; }
  else if (lane >= 40 && lane < 52){
    int m=lane-40; gu0 = 24 + (2*m)/3; gu1 = 24 + (2*m+1)/3;
  }

  const float pdx=pos[3*node], pdy=pos[3*node+1], pdz=pos[3*node+2];
  float acc0a=0.f, acc0b=0.f, acc1a=0.f, acc1b=0.f;

  for (int t=0; t<nch; ++t){
    const int e0 = r0 + t*CH;
    const int cnt = min(CH, r1-e0);
    __syncthreads();                 // WAR: prev chunk phase-2 reads done
    if (lane < cnt){
      const int e = e0 + lane;
      const int s = src[e];
      float ax=pos[3*s]-pdx, ay=pos[3*s+1]-pdy, az=pos[3*s+2]-pdz;
      float r = sqrtf(ax*ax+ay*ay+az*az);
      float ir = 1.0f/r;
      float x=ax*ir, y=ay*ir, z=az*ir;
      float f = r * 1228.4f;                    // (T_TAB-1)/2.5
      int i0 = (int)f; if (i0 > T_TAB-2) i0 = T_TAB-2;
      float al = f - (float)i0;

      const float s3=1.73205081f, s5=2.23606798f, s15=3.87298335f;
      const float c33=2.09165007f, c32=10.2469508f, c31=1.62018517f, c30=1.32287566f, cp2=5.12347538f;
      float Y[16];
      Y[0]=1.0f;
      Y[1]=s3*y; Y[2]=s3*z; Y[3]=s3*x;
      Y[4]=s15*x*y; Y[5]=s15*y*z; Y[6]=0.5f*s5*(3.0f*z*z-1.0f); Y[7]=s15*x*z; Y[8]=0.5f*s15*(x*x-y*y);
      Y[9]=c33*y*(3.0f*x*x-y*y); Y[10]=c32*x*y*z; Y[11]=c31*y*(5.0f*z*z-1.0f);
      Y[12]=c30*(5.0f*z*z*z-3.0f*z); Y[13]=c31*x*(5.0f*z*z-1.0f); Y[14]=cp2*z*(x*x-y*y);
      Y[15]=c33*x*(x*x-3.0f*y*y);
      float X[16];
      {
        const float inv = 0.5129891760f;           // 1/sqrt(3.8)
        const float4* q4 = (const float4*)(xacc + (size_t)s*16);
        float4 a=q4[0],b=q4[1],cc4=q4[2],d4=q4[3];
        X[0]=a.x*inv;X[1]=a.y*inv;X[2]=a.z*inv;X[3]=a.w*inv;
        X[4]=b.x*inv;X[5]=b.y*inv;X[6]=b.z*inv;X[7]=b.w*inv;
        X[8]=cc4.x*inv;X[9]=cc4.y*inv;X[10]=cc4.z*inv;X[11]=cc4.w*inv;
        X[12]=d4.x*inv;X[13]=d4.y*inv;X[14]=d4.z*inv;X[15]=d4.w*inv;
      }
      float* SS = SI[lane];

      // t-block (scalar outputs)
      {
        float t0v = CG000.v[0]*X[0]*Y[0];
        float t1v=0.f, t2v=0.f, t3v=0.f;
#pragma unroll
        for (int i=0;i<3;++i)
#pragma unroll
          for (int j=0;j<3;++j) TERM(CG110, i*3+j, X[1+i]*Y[1+j], t1v)
#pragma unroll
        for (int i=0;i<5;++i)
#pragma unroll
          for (int j=0;j<5;++j) TERM(CG220, i*5+j, X[4+i]*Y[4+j], t2v)
#pragma unroll
        for (int i=0;i<7;++i)
#pragma unroll
          for (int j=0;j<7;++j) TERM(CG330, i*7+j, X[9+i]*Y[9+j], t3v)
        SS[0]=t0v; SS[1]=t1v; SS[2]=t2v; SS[3]=t3v;
      }
      // vector outputs
      {
        float v01[3]={0,0,0}, v10[3]={0,0,0}, v11[3]={0,0,0}, v12[3]={0,0,0},
              v21[3]={0,0,0}, v22[3]={0,0,0}, v23[3]={0,0,0}, v32[3]={0,0,0}, v33[3]={0,0,0};
#pragma unroll
        for (int j=0;j<3;++j){ float tt=X[0]*Y[1+j];
#pragma unroll
          for (int k=0;k<3;++k) TERM(CG011, j*3+k, tt, v01[k]) }
#pragma unroll
        for (int i=0;i<3;++i){ float tt=X[1+i]*Y[0];
#pragma unroll
          for (int k=0;k<3;++k) TERM(CG101, i*3+k, tt, v10[k]) }
#pragma unroll
        for (int i=0;i<3;++i)
#pragma unroll
          for (int j=0;j<3;++j){ float tt=X[1+i]*Y[1+j];
#pragma unroll
            for (int k=0;k<3;++k) TERM(CG111, (i*3+j)*3+k, tt, v11[k]) }
#pragma unroll
        for (int i=0;i<3;++i)
#pragma unroll
          for (int j=0;j<5;++j){ float tt=X[1+i]*Y[4+j];
#pragma unroll
            for (int k=0;k<3;++k) TERM(CG121, (i*5+j)*3+k, tt, v12[k]) }
#pragma unroll
        for (int i=0;i<5;++i)
#pragma unroll
          for (int j=0;j<3;++j){ float tt=X[4+i]*Y[1+j];
#pragma unroll
            for (int k=0;k<3;++k) TERM(CG211, (i*3+j)*3+k, tt, v21[k]) }
#pragma unroll
        for (int i=0;i<5;++i)
#pragma unroll
          for (int j=0;j<5;++j){ float tt=X[4+i]*Y[4+j];
#pragma unroll
            for (int k=0;k<3;++k) TERM(CG221, (i*5+j)*3+k, tt, v22[k]) }
#pragma unroll
        for (int i=0;i<5;++i)
#pragma unroll
          for (int j=0;j<7;++j){ float tt=X[4+i]*Y[9+j];
#pragma unroll
            for (int k=0;k<3;++k) TERM(CG231, (i*7+j)*3+k, tt, v23[k]) }
#pragma unroll
        for (int i=0;i<7;++i)
#pragma unroll
          for (int j=0;j<5;++j){ float tt=X[9+i]*Y[4+j];
#pragma unroll
            for (int k=0;k<3;++k) TERM(CG321, (i*5+j)*3+k, tt, v32[k]) }
#pragma unroll
        for (int i=0;i<7;++i)
#pragma unroll
          for (int j=0;j<7;++j){ float tt=X[9+i]*Y[9+j];
#pragma unroll
            for (int k=0;k<3;++k) TERM(CG331, (i*7+j)*3+k, tt, v33[k]) }
#pragma unroll
        for (int k=0;k<3;++k){
          SS[4+k]=v01[k]; SS[7+k]=v10[k]; SS[10+k]=v12[k]; SS[13+k]=v21[k];
          SS[16+k]=v23[k]; SS[19+k]=v32[k]; SS[22+k]=v11[k]; SS[25+k]=v22[k]; SS[28+k]=v33[k];
        }
      }
      SS[31]=0.0f; SS[32]=al;
      SiT[lane]=i0;
    }
    __syncthreads();                 // RAW: phase-1 SI/SiT visible
    // ---- phase 2: shared-row scattered loads + inline lerp, static schedule ----
#pragma unroll 4
    for (int j=0; j<CH; ++j){
      if (j < cnt){
        const float* __restrict__ wr0 = tab1 + (size_t)SiT[j]*272;
        const float* __restrict__ wr1 = wr0 + 272;
        const float* __restrict__ I = SI[j];
        const float alj = I[32];
        if (j & 1){
#pragma unroll
          for (int p=0;p<4;++p){
            float wa = wr0[wo[p]], wb = wr1[wo[p]];
            acc0b = fmaf(fmaf(alj, wb-wa, wa), I[ioS[p]], acc0b);
          }
#pragma unroll
          for (int p=4;p<8;++p){
            float wa = wr0[wo[p]], wb = wr1[wo[p]];
            acc1b = fmaf(fmaf(alj, wb-wa, wa), I[ioS[p]], acc1b);
          }
        } else {
#pragma unroll
          for (int p=0;p<4;++p){
            float wa = wr0[wo[p]], wb = wr1[wo[p]];
            acc0a = fmaf(fmaf(alj, wb-wa, wa), I[ioS[p]], acc0a);
          }
#pragma unroll
          for (int p=4;p<8;++p){
            float wa = wr0[wo[p]], wb = wr1[wo[p]];
            acc1a = fmaf(fmaf(alj, wb-wa, wa), I[ioS[p]], acc1a);
          }
        }
      }
    }
  }
  const float acc0 = acc0a + acc0b;
  const float acc1 = acc1a + acc1b;

  // ---- fused gate epilogue ----
  const float inv = 0.5129891760f;
  if (lane < 16){
    SG[2*lane]   = acc0*0.5f*inv;
    SG[2*lane+1] = acc1*0.5f*inv;
  }
  __syncthreads();
  float* __restrict__ o = xg + (size_t)node*64;
  if (lane < 16){
    o[lane] = fmaxf(SG[lane], 0.0f);                       // se
  } else if (lane < 40){
    int idx = lane-16;
    float vv = (acc0+acc1)*0.4082482905f*inv;
    o[16+idx] = vv * fmaxf(SG[gu0], 0.0f);                 // v1o (u<8)
  } else if (lane < 52){
    int m = lane-40;
    float vv0 = acc0*0.5773502692f*inv;
    float vv1 = acc1*0.5773502692f*inv;
    o[40+2*m]   = vv0 * fmaxf(SG[gu0], 0.0f);              // v1e (u<8)
    o[40+2*m+1] = vv1 * fmaxf(SG[gu1], 0.0f);
  }
}

// ---------------- fctp2 per edge -> e2buf[E][4] (pruned, compile-time CG) ----------
__global__ __launch_bounds__(256) void k_tp2(
    const float* __restrict__ pos, const int* __restrict__ src, const int* __restrict__ dst, int E,
    const float* __restrict__ xg, const float* __restrict__ tab2,
    float* __restrict__ e2buf)
{
  const int e = blockIdx.x*256 + threadIdx.x;
  if (e>=E) return;
  const int s = src[e], d = dst[e];
  float ax=pos[3*s]-pos[3*d], ay=pos[3*s+1]-pos[3*d+1], az=pos[3*s+2]-pos[3*d+2];
  float r = sqrtf(ax*ax+ay*ay+az*az);
  float ir = 1.0f/r;
  float x=ax*ir, y=ay*ir, z=az*ir;
  float f = r * 1228.4f;                       // (T_TAB-1)/2.5
  int i0 = (int)f; if (i0 > T_TAB-2) i0 = T_TAB-2;
  const float al = f - (float)i0;
  const float* __restrict__ w0 = tab2 + (size_t)i0*64;
  const float* __restrict__ w1 = w0 + 64;
  float wse[16], wA[8], wB[8], wC[8];
#pragma unroll
  for (int j=0;j<16;j+=4){
    float4 p = *(const float4*)(w0+j);
    float4 q = *(const float4*)(w1+j);
    wse[j+0]=fmaf(al,q.x-p.x,p.x); wse[j+1]=fmaf(al,q.y-p.y,p.y);
    wse[j+2]=fmaf(al,q.z-p.z,p.z); wse[j+3]=fmaf(al,q.w-p.w,p.w);
  }
#pragma unroll
  for (int j=0;j<8;j+=4){
    float4 p = *(const float4*)(w0+16+j); float4 q = *(const float4*)(w1+16+j);
    wA[j+0]=fmaf(al,q.x-p.x,p.x); wA[j+1]=fmaf(al,q.y-p.y,p.y);
    wA[j+2]=fmaf(al,q.z-p.z,p.z); wA[j+3]=fmaf(al,q.w-p.w,p.w);
    p = *(const float4*)(w0+32+j); q = *(const float4*)(w1+32+j);
    wB[j+0]=fmaf(al,q.x-p.x,p.x); wB[j+1]=fmaf(al,q.y-p.y,p.y);
    wB[j+2]=fmaf(al,q.z-p.z,p.z); wB[j+3]=fmaf(al,q.w-p.w,p.w);
    p = *(const float4*)(w0+48+j); q = *(const float4*)(w1+48+j);
    wC[j+0]=fmaf(al,q.x-p.x,p.x); wC[j+1]=fmaf(al,q.y-p.y,p.y);
    wC[j+2]=fmaf(al,q.z-p.z,p.z); wC[j+3]=fmaf(al,q.w-p.w,p.w);
  }
  const float s3=1.73205081f, s5=2.23606798f, s15=3.87298335f;
  float Y[9];
  Y[0]=1.0f;
  Y[1]=s3*y; Y[2]=s3*z; Y[3]=s3*x;
  Y[4]=s15*x*y; Y[5]=s15*y*z; Y[6]=0.5f*s5*(3.0f*z*z-1.0f); Y[7]=s15*x*z; Y[8]=0.5f*s15*(x*x-y*y);
  const float* __restrict__ g = xg + (size_t)s*64;
  float se[16], vo[24], ve[24];
#pragma unroll
  for (int jj=0;jj<4;++jj){ float4 t=((const float4*)g)[jj];
    se[4*jj]=t.x; se[4*jj+1]=t.y; se[4*jj+2]=t.z; se[4*jj+3]=t.w; }
#pragma unroll
  for (int jj=0;jj<6;++jj){ float4 t=((const float4*)(g+16))[jj];
    vo[4*jj]=t.x; vo[4*jj+1]=t.y; vo[4*jj+2]=t.z; vo[4*jj+3]=t.w; }
#pragma unroll
  for (int jj=0;jj<6;++jj){ float4 t=((const float4*)(g+40))[jj];
    ve[4*jj]=t.x; ve[4*jj+1]=t.y; ve[4*jj+2]=t.z; ve[4*jj+3]=t.w; }

  float SA=0.0f;
#pragma unroll
  for (int u=0;u<16;++u) SA = fmaf(wse[u], se[u], SA);
  float AB[3]={0,0,0}, AC[3]={0,0,0}, AD[3]={0,0,0};
#pragma unroll
  for (int u=0;u<8;++u)
#pragma unroll
    for (int i=0;i<3;++i){
      AB[i]=fmaf(wA[u], vo[u*3+i], AB[i]);
      AC[i]=fmaf(wB[u], vo[u*3+i], AC[i]);
      AD[i]=fmaf(wC[u], ve[u*3+i], AD[i]);
    }
  float e2[3]={0,0,0};
#pragma unroll
  for (int j=0;j<3;++j){ float t=SA*Y[1+j];
#pragma unroll
    for (int k=0;k<3;++k) TERM(CG011, j*3+k, t, e2[k]) }
#pragma unroll
  for (int i=0;i<3;++i){ float t=AB[i]*Y[0];
#pragma unroll
    for (int k=0;k<3;++k) TERM(CG101, i*3+k, t, e2[k]) }
#pragma unroll
  for (int i=0;i<3;++i)
#pragma unroll
    for (int j=0;j<5;++j){ float t=AC[i]*Y[4+j];
#pragma unroll
      for (int k=0;k<3;++k) TERM(CG121, (i*5+j)*3+k, t, e2[k]) }
#pragma unroll
  for (int i=0;i<3;++i)
#pragma unroll
    for (int j=0;j<3;++j){ float t=AD[i]*Y[1+j];
#pragma unroll
      for (int k=0;k<3;++k) TERM(CG111, (i*3+j)*3+k, t, e2[k]) }

  *(float4*)(e2buf + (size_t)e*4) = make_float4(e2[0], e2[1], e2[2], 0.0f);
}

// ---------------- final gather ----------------
__global__ __launch_bounds__(256) void k_out(
    const float* __restrict__ e2buf, const int* __restrict__ rowptr,
    float* __restrict__ out)
{
  const int t = blockIdx.x*256 + threadIdx.x;
  const int n = t>>2, k = t&3;
  if (n>=NN) return;
  const int r0=rowptr[n], r1=rowptr[n+1];
  float a=0.f;
  for (int e=r0;e<r1;++e) a += e2buf[(size_t)e*4 + k];
  const float sc = 0.0641236437f;  // (1/sqrt(64)) * 1/sqrt(3.8)
  if (k<3) out[(size_t)n*3 + k] = a*sc;
}

// ---------------- host launcher ----------------
extern "C" void kernel_launch(void* const* d_in, const int* in_sizes, int n_in,
                              void* d_out, int out_size, void* d_ws, size_t ws_size,
                              hipStream_t stream)
{
  (void)n_in; (void)ws_size; (void)out_size;
  const float* pos = (const float*)d_in[0];
  const int*   src = (const int*)d_in[1];
  const int*   dst = (const int*)d_in[2];
  const float* W1  = (const float*)d_in[3];
  const float* W2  = (const float*)d_in[4];
  const float* W1f = (const float*)d_in[5];
  const float* W2f = (const float*)d_in[6];
  const int E = in_sizes[1];

  char* ws = (char*)d_ws;
  float* xacc  = (float*)ws;                     // NN*16
  float* xg    = xacc + (size_t)NN*16;           // NN*64
  float* tab1  = xg + (size_t)NN*64;             // T_TAB*272
  float* tab2  = tab1 + (size_t)T_TAB*272;       // T_TAB*64
  float* e2buf = tab2 + (size_t)T_TAB*64;        // E*4
  int*   rowptr= (int*)(e2buf + (size_t)E*4);    // NN+1

  k_table<<<84*12, 256, 0, stream>>>(W1, W2, W1f, W2f, tab1, tab2);
  k_rowptr<<<(NN+1+255)/256, 256, 0, stream>>>(dst, E, rowptr);
  k_x<<<(NN*4)/256, 256, 0, stream>>>(pos, src, rowptr, xacc);
  k_tp1<<<NN, 64, 0, stream>>>(pos, src, rowptr, xacc, tab1, xg);
  k_tp2<<<(E + 255) / 256, 256, 0, stream>>>(pos, src, dst, E, xg, tab2, e2buf);
  k_out<<<(NN*4)/256, 256, 0, stream>>>(e2buf, rowptr, (float*)d_out);
}

// Round 12
// 123.712 us; speedup vs baseline: 2.1710x; 1.1465x over previous
//
#include <hip/hip_runtime.h>
#include <cmath>

#define T_TAB 1536
#define NN 16384
#define CH 32

// ================= compile-time CG tables (constexpr port of the reference) ========
struct CD { double re, im; };
constexpr CD cmul(CD a, CD b){ return {a.re*b.re - a.im*b.im, a.re*b.im + a.im*b.re}; }
constexpr CD cadd(CD a, CD b){ return {a.re+b.re, a.im+b.im}; }
constexpr CD conj_(CD a){ return {a.re, -a.im}; }
constexpr CD cscale(CD a, double s){ return {a.re*s, a.im*s}; }
constexpr double cfabs_(double x){ return x<0.0 ? -x : x; }
constexpr double csqrt_(double x){
  double g = x > 1.0 ? x : 1.0;
  for (int i=0;i<80;++i) g = 0.5*(g + x/g);
  return g;
}
constexpr double factd(int n){ double r=1.0; for(int i=2;i<=n;++i) r*=(double)i; return r; }

constexpr double cg_coef(int j1,int m1,int j2,int m2,int j3,int m3){
  double pref = csqrt_((2.0*j3+1.0)*factd(j3+j1-j2)*factd(j3-j1+j2)*factd(j1+j2-j3)/factd(j1+j2+j3+1));
  pref *= csqrt_(factd(j3+m3)*factd(j3-m3)*factd(j1-m1)*factd(j1+m1)*factd(j2-m2)*factd(j2+m2));
  double s=0.0;
  for(int k=0;k<=j1+j2-j3;++k){
    int a0=k,a1=j1+j2-j3-k,a2=j1-m1-k,a3=j2+m2-k,a4=j3-j2+m1+k,a5=j3-j1-m2+k;
    if(a0<0||a1<0||a2<0||a3<0||a4<0||a5<0) continue;
    double d=factd(a0)*factd(a1)*factd(a2)*factd(a3)*factd(a4)*factd(a5);
    s += ((k&1)?-1.0:1.0)/d;
  }
  return pref*s;
}

struct UMat { CD u[7][7]; };
constexpr UMat u_fill(int l){
  UMat M{};
  const double is2 = csqrt_(0.5);
  M.u[l][l] = CD{1.0, 0.0};
  for(int m=1;m<=l;++m){
    double sgn = (m&1)?-1.0:1.0;
    M.u[l+m][l+m] = CD{sgn*is2, 0.0};
    M.u[l+m][l-m] = CD{is2, 0.0};
    M.u[l-m][l-m] = CD{0.0, is2};
    M.u[l-m][l+m] = CD{0.0, -sgn*is2};
  }
  return M;
}

template<int L1,int L2,int L3>
struct FT { float v[(2*L1+1)*(2*L2+1)*(2*L3+1)]; };

template<int L1,int L2,int L3>
constexpr FT<L1,L2,L3> cg_real_ct(){
  constexpr int n1=2*L1+1, n2=2*L2+1, n3=2*L3+1;
  double Cc[7][7][7] = {};
  for(int m1=-L1;m1<=L1;++m1)
    for(int m2=-L2;m2<=L2;++m2){
      int m3=m1+m2;
      if(m3>=-L3&&m3<=L3) Cc[m1+L1][m2+L2][m3+L3]=cg_coef(L1,m1,L2,m2,L3,m3);
    }
  UMat U1 = u_fill(L1), U2 = u_fill(L2), U3 = u_fill(L3);
  CD Cr[7][7][7] = {};
  double sre=0.0, sim=0.0;
  for(int a=0;a<n1;++a)for(int b=0;b<n2;++b)for(int c=0;c<n3;++c){
    CD acc{0.0,0.0};
    for(int u=0;u<n1;++u)for(int v=0;v<n2;++v){
      int w = (u-L1)+(v-L2)+L3;           // only m3=m1+m2 can be nonzero in Cc
      if (w < 0 || w >= n3) continue;
      double cc = Cc[u][v][w];
      if (cc == 0.0) continue;
      acc = cadd(acc, cscale(cmul(cmul(U1.u[a][u],U2.u[b][v]),conj_(U3.u[c][w])), cc));
    }
    Cr[a][b][c] = acc;
    sre += cfabs_(acc.re); sim += cfabs_(acc.im);
  }
  FT<L1,L2,L3> out{};
  bool useim = sim > sre;
  for(int a=0;a<n1;++a)for(int b=0;b<n2;++b)for(int c=0;c<n3;++c)
    out.v[(a*n2+b)*n3+c] = (float)(useim ? Cr[a][b][c].im : Cr[a][b][c].re);
  return out;
}

constexpr auto CG000 = cg_real_ct<0,0,0>();
constexpr auto CG110 = cg_real_ct<1,1,0>();
constexpr auto CG220 = cg_real_ct<2,2,0>();
constexpr auto CG330 = cg_real_ct<3,3,0>();
constexpr auto CG011 = cg_real_ct<0,1,1>();
constexpr auto CG101 = cg_real_ct<1,0,1>();
constexpr auto CG111 = cg_real_ct<1,1,1>();
constexpr auto CG121 = cg_real_ct<1,2,1>();
constexpr auto CG211 = cg_real_ct<2,1,1>();
constexpr auto CG221 = cg_real_ct<2,2,1>();
constexpr auto CG231 = cg_real_ct<2,3,1>();
constexpr auto CG321 = cg_real_ct<3,2,1>();
constexpr auto CG331 = cg_real_ct<3,3,1>();

// zero-pruned FMA term: coefficient folds to a literal; zero terms are deleted.
#define TERM(TBL, IDX, PROD, ACC) { float c_ = TBL.v[IDX]; if (c_ != 0.0f) ACC = fmaf((PROD), c_, ACC); }

// ---------------- device helpers ----------------
__device__ __forceinline__ float soh(float r, float c){
  float d = (r - c) * 2.0f;
  float d2 = d*d;
  return (d2 < 1.0f) ? 1.14136f * expf(2.0f + 1.0f/(d2-1.0f)) : 0.0f;
}

// Per-lane weight schedule: lane ℓ, sub-index q (0..7) -> (column in [0,272) or -1, LDS slot).
// Slot 31 is a guaranteed-zero slot.
__device__ __forceinline__ void lane_sched(int lane, int q, int& col, int& slot){
  col = -1; slot = 31;
  if (lane < 16){
    int s = q >> 2, qq = q & 3;
    int a = 2*lane + s;                 // scalar output index 0..31
    const int base0[4] = {0, 64, 144, 224};
    col = base0[qq] + a; slot = qq;
  } else if (lane < 40){
    int idx = lane-16, u = idx/3, k = idx-3*u;
    const int wb[6] = {32,48,112,128,192,208};
    const int sb[6] = {4,7,10,13,16,19};
    if (q < 6){ col = wb[q]+u; slot = sb[q]+k; }
  } else if (lane < 52){
    int m = lane-40;
    int c0 = (q < 4) ? 2*m : 2*m+1;
    int u = c0/3, k = c0-3*u;
    int qq = (q < 4) ? q : q-4;
    if (qq < 3){
      const int wb[3] = {96,176,256};
      const int sb[3] = {22,25,28};
      col = wb[qq]+u; slot = sb[qq]+k;
    }
  }
}

// ---------------- radial MLP tables: tab1[T_TAB][272] (fctp1), tab2[T_TAB][64] (fctp2)
// jq-major grid: jq = bid/6 (0..83), t = (bid%6)*256 + lane. Weight addresses are
// wave-uniform (scalar loads); split tables keep each consumer's footprint L2-resident.
__global__ __launch_bounds__(256) void k_table(
    const float* __restrict__ W1, const float* __restrict__ W2,
    const float* __restrict__ W1f, const float* __restrict__ W2f,
    float* __restrict__ tab1, float* __restrict__ tab2)
{
  const int bid = blockIdx.x;                 // 84*6 = 504
  const int jq  = bid / 6;                    // 0..83
  const int t   = (bid % 6)*256 + threadIdx.x;
  const int j0  = jq*4;
  const float dr = 2.5f / (float)(T_TAB-1);
  const float r = (float)t * dr;
  const float e0 = soh(r,1.0f), e1 = soh(r,1.5f), e2 = soh(r,2.0f);
  float ax=0.f, ay=0.f, az=0.f, aw=0.f;
  if (j0 < 272){
    for (int cc=0; cc<256; ++cc){
      float h = fmaxf(fmaf(e0,W1[cc], fmaf(e1,W1[256+cc], e2*W1[512+cc])), 0.0f);
      float4 w = *(const float4*)(W2 + cc*272 + j0);
      ax = fmaf(h,w.x,ax); ay = fmaf(h,w.y,ay);
      az = fmaf(h,w.z,az); aw = fmaf(h,w.w,aw);
    }
    *(float4*)(tab1 + (size_t)t*272 + j0) = make_float4(ax*0.0625f, ay*0.0625f, az*0.0625f, aw*0.0625f);
  } else {
    const int jj = j0 - 272;
    for (int cc=0; cc<256; ++cc){
      float h = fmaxf(fmaf(e0,W1f[cc], fmaf(e1,W1f[256+cc], e2*W1f[512+cc])), 0.0f);
      float4 w = *(const float4*)(W2f + cc*64 + jj);
      ax = fmaf(h,w.x,ax); ay = fmaf(h,w.y,ay);
      az = fmaf(h,w.z,az); aw = fmaf(h,w.w,aw);
    }
    *(float4*)(tab2 + (size_t)t*64 + jj) = make_float4(ax*0.0625f, ay*0.0625f, az*0.0625f, aw*0.0625f);
  }
}

// ---------------- per-lane packed table: tabP[T_TAB][512], lane l's 8 weights at 8l --
// Footprint 1536*512*4B = 3.15 MB < 4 MB per-XCD L2 (R6's version was 8.4 MB -> thrash).
__global__ __launch_bounds__(256) void k_perm(
    const float* __restrict__ tab1, float* __restrict__ tabP)
{
  const int gid = blockIdx.x*256 + threadIdx.x;     // [0, T_TAB*512)
  const int t = gid >> 9, p = gid & 511;
  int col, slot;
  lane_sched(p>>3, p&7, col, slot);
  tabP[gid] = (col >= 0) ? tab1[(size_t)t*272 + col] : 0.0f;
}

// ---------------- rowptr: dst is globally non-decreasing -> CSR via binary search ----
__global__ __launch_bounds__(256) void k_rowptr(
    const int* __restrict__ dst, int E, int* __restrict__ rowptr)
{
  const int n = blockIdx.x*256 + threadIdx.x;
  if (n > NN) return;
  int lo=0, hi=E;
  while (lo < hi){ int mid=(lo+hi)>>1; if (dst[mid] < n) lo=mid+1; else hi=mid; }
  rowptr[n]=lo;
}

// ---------------- x = segsum(sph_harm): 4 lanes/node, each edge touched once -------
__global__ __launch_bounds__(256) void k_x(
    const float* __restrict__ pos, const int* __restrict__ src,
    const int* __restrict__ rowptr, float* __restrict__ xacc)
{
  const int t = blockIdx.x*256 + threadIdx.x;
  const int n = t>>2, q = t&3;
  if (n>=NN) return;
  const int r0=rowptr[n], r1=rowptr[n+1];
  const float pdx=pos[3*n], pdy=pos[3*n+1], pdz=pos[3*n+2];
  const float s3=1.73205081f, s5=2.23606798f, s15=3.87298335f;
  const float c33=2.09165007f, c32=10.2469508f, c31=1.62018517f, c30=1.32287566f, cp2=5.12347538f;
  float a0=0,a1=0,a2=0,a3=0,a4=0,a5=0,a6=0,a7=0,a8=0,a9=0,a10=0,a11=0,a12=0,a13=0,a14=0,a15=0;
  for (int e=r0+q; e<r1; e+=4){
    const int s=src[e];
    float ax=pos[3*s]-pdx, ay=pos[3*s+1]-pdy, az=pos[3*s+2]-pdz;
    float ir = 1.0f/sqrtf(ax*ax+ay*ay+az*az);
    float x=ax*ir, y=ay*ir, z=az*ir;
    a0+=1.0f; a1+=s3*y; a2+=s3*z; a3+=s3*x;
    a4+=s15*x*y; a5+=s15*y*z; a6+=0.5f*s5*(3.0f*z*z-1.0f); a7+=s15*x*z;
    a8+=0.5f*s15*(x*x-y*y); a9+=c33*y*(3.0f*x*x-y*y); a10+=c32*x*y*z; a11+=c31*y*(5.0f*z*z-1.0f);
    a12+=c30*(5.0f*z*z*z-3.0f*z); a13+=c31*x*(5.0f*z*z-1.0f); a14+=cp2*z*(x*x-y*y);
    a15+=c33*x*(x*x-3.0f*y*y);
  }
#define RED(v) v += __shfl_xor(v,1); v += __shfl_xor(v,2);
  RED(a0) RED(a1) RED(a2) RED(a3) RED(a4) RED(a5) RED(a6) RED(a7)
  RED(a8) RED(a9) RED(a10) RED(a11) RED(a12) RED(a13) RED(a14) RED(a15)
#undef RED
  float o0,o1,o2,o3;
  if (q==0){ o0=a0; o1=a1; o2=a2; o3=a3; }
  else if (q==1){ o0=a4; o1=a5; o2=a6; o3=a7; }
  else if (q==2){ o0=a8; o1=a9; o2=a10; o3=a11; }
  else { o0=a12; o1=a13; o2=a14; o3=a15; }
  *(float4*)(xacc + (size_t)n*16 + q*4) = make_float4(o0,o1,o2,o3);
}

// ---------------- fctp1 + gate fused: ONE WAVE PER NODE (R9 structure) --------------
// Phase 1: lane = edge, zero-pruned compile-time CG, single code path.
// Phase 2: 4 coalesced float4 loads/edge from the per-lane packed tabP (L2-resident),
//          8 LDS reads + lerp + 8 FMA; alternating accumulator pairs.
__global__ __launch_bounds__(64) void k_tp1(
    const float* __restrict__ pos, const int* __restrict__ src,
    const int* __restrict__ rowptr, const float* __restrict__ xacc,
    const float* __restrict__ tabP, float* __restrict__ xg)
{
  const int lane = threadIdx.x;
  const int node = blockIdx.x;
  __shared__ float SI[CH][33];   // 0..30 intermediates, 31 zero, 32 al
  __shared__ int   SiT[CH];
  __shared__ float SG[32];
  const int r0 = rowptr[node], r1 = rowptr[node+1];
  const int nch = (r1 - r0 + CH - 1) / CH;

  // ---- static LDS-slot schedule + gate indices ----
  int ioS[8];
#pragma unroll
  for (int p=0;p<8;++p){ int c_, s_; lane_sched(lane, p, c_, s_); ioS[p] = s_; }
  int gu0=16, gu1=16;
  if (lane >= 16 && lane < 40){ gu0 = 16 + (lane-16)/3; }
  else if (lane >= 40 && lane < 52){
    int m=lane-40; gu0 = 24 + (2*m)/3; gu1 = 24 + (2*m+1)/3;
  }

  const float pdx=pos[3*node], pdy=pos[3*node+1], pdz=pos[3*node+2];
  float acc0a=0.f, acc0b=0.f, acc1a=0.f, acc1b=0.f;

  for (int t=0; t<nch; ++t){
    const int e0 = r0 + t*CH;
    const int cnt = min(CH, r1-e0);
    __syncthreads();                 // WAR: prev chunk phase-2 reads done
    if (lane < cnt){
      const int e = e0 + lane;
      const int s = src[e];
      float ax=pos[3*s]-pdx, ay=pos[3*s+1]-pdy, az=pos[3*s+2]-pdz;
      float r = sqrtf(ax*ax+ay*ay+az*az);
      float ir = 1.0f/r;
      float x=ax*ir, y=ay*ir, z=az*ir;
      float f = r * 614.0f;                     // (T_TAB-1)/2.5
      int i0 = (int)f; if (i0 > T_TAB-2) i0 = T_TAB-2;
      float al = f - (float)i0;

      const float s3=1.73205081f, s5=2.23606798f, s15=3.87298335f;
      const float c33=2.09165007f, c32=10.2469508f, c31=1.62018517f, c30=1.32287566f, cp2=5.12347538f;
      float Y[16];
      Y[0]=1.0f;
      Y[1]=s3*y; Y[2]=s3*z; Y[3]=s3*x;
      Y[4]=s15*x*y; Y[5]=s15*y*z; Y[6]=0.5f*s5*(3.0f*z*z-1.0f); Y[7]=s15*x*z; Y[8]=0.5f*s15*(x*x-y*y);
      Y[9]=c33*y*(3.0f*x*x-y*y); Y[10]=c32*x*y*z; Y[11]=c31*y*(5.0f*z*z-1.0f);
      Y[12]=c30*(5.0f*z*z*z-3.0f*z); Y[13]=c31*x*(5.0f*z*z-1.0f); Y[14]=cp2*z*(x*x-y*y);
      Y[15]=c33*x*(x*x-3.0f*y*y);
      float X[16];
      {
        const float inv = 0.5129891760f;           // 1/sqrt(3.8)
        const float4* q4 = (const float4*)(xacc + (size_t)s*16);
        float4 a=q4[0],b=q4[1],cc4=q4[2],d4=q4[3];
        X[0]=a.x*inv;X[1]=a.y*inv;X[2]=a.z*inv;X[3]=a.w*inv;
        X[4]=b.x*inv;X[5]=b.y*inv;X[6]=b.z*inv;X[7]=b.w*inv;
        X[8]=cc4.x*inv;X[9]=cc4.y*inv;X[10]=cc4.z*inv;X[11]=cc4.w*inv;
        X[12]=d4.x*inv;X[13]=d4.y*inv;X[14]=d4.z*inv;X[15]=d4.w*inv;
      }
      float* SS = SI[lane];

      // t-block (scalar outputs)
      {
        float t0v = CG000.v[0]*X[0]*Y[0];
        float t1v=0.f, t2v=0.f, t3v=0.f;
#pragma unroll
        for (int i=0;i<3;++i)
#pragma unroll
          for (int j=0;j<3;++j) TERM(CG110, i*3+j, X[1+i]*Y[1+j], t1v)
#pragma unroll
        for (int i=0;i<5;++i)
#pragma unroll
          for (int j=0;j<5;++j) TERM(CG220, i*5+j, X[4+i]*Y[4+j], t2v)
#pragma unroll
        for (int i=0;i<7;++i)
#pragma unroll
          for (int j=0;j<7;++j) TERM(CG330, i*7+j, X[9+i]*Y[9+j], t3v)
        SS[0]=t0v; SS[1]=t1v; SS[2]=t2v; SS[3]=t3v;
      }
      // vector outputs
      {
        float v01[3]={0,0,0}, v10[3]={0,0,0}, v11[3]={0,0,0}, v12[3]={0,0,0},
              v21[3]={0,0,0}, v22[3]={0,0,0}, v23[3]={0,0,0}, v32[3]={0,0,0}, v33[3]={0,0,0};
#pragma unroll
        for (int j=0;j<3;++j){ float tt=X[0]*Y[1+j];
#pragma unroll
          for (int k=0;k<3;++k) TERM(CG011, j*3+k, tt, v01[k]) }
#pragma unroll
        for (int i=0;i<3;++i){ float tt=X[1+i]*Y[0];
#pragma unroll
          for (int k=0;k<3;++k) TERM(CG101, i*3+k, tt, v10[k]) }
#pragma unroll
        for (int i=0;i<3;++i)
#pragma unroll
          for (int j=0;j<3;++j){ float tt=X[1+i]*Y[1+j];
#pragma unroll
            for (int k=0;k<3;++k) TERM(CG111, (i*3+j)*3+k, tt, v11[k]) }
#pragma unroll
        for (int i=0;i<3;++i)
#pragma unroll
          for (int j=0;j<5;++j){ float tt=X[1+i]*Y[4+j];
#pragma unroll
            for (int k=0;k<3;++k) TERM(CG121, (i*5+j)*3+k, tt, v12[k]) }
#pragma unroll
        for (int i=0;i<5;++i)
#pragma unroll
          for (int j=0;j<3;++j){ float tt=X[4+i]*Y[1+j];
#pragma unroll
            for (int k=0;k<3;++k) TERM(CG211, (i*3+j)*3+k, tt, v21[k]) }
#pragma unroll
        for (int i=0;i<5;++i)
#pragma unroll
          for (int j=0;j<5;++j){ float tt=X[4+i]*Y[4+j];
#pragma unroll
            for (int k=0;k<3;++k) TERM(CG221, (i*5+j)*3+k, tt, v22[k]) }
#pragma unroll
        for (int i=0;i<5;++i)
#pragma unroll
          for (int j=0;j<7;++j){ float tt=X[4+i]*Y[9+j];
#pragma unroll
            for (int k=0;k<3;++k) TERM(CG231, (i*7+j)*3+k, tt, v23[k]) }
#pragma unroll
        for (int i=0;i<7;++i)
#pragma unroll
          for (int j=0;j<5;++j){ float tt=X[9+i]*Y[4+j];
#pragma unroll
            for (int k=0;k<3;++k) TERM(CG321, (i*5+j)*3+k, tt, v32[k]) }
#pragma unroll
        for (int i=0;i<7;++i)
#pragma unroll
          for (int j=0;j<7;++j){ float tt=X[9+i]*Y[9+j];
#pragma unroll
            for (int k=0;k<3;++k) TERM(CG331, (i*7+j)*3+k, tt, v33[k]) }
#pragma unroll
        for (int k=0;k<3;++k){
          SS[4+k]=v01[k]; SS[7+k]=v10[k]; SS[10+k]=v12[k]; SS[13+k]=v21[k];
          SS[16+k]=v23[k]; SS[19+k]=v32[k]; SS[22+k]=v11[k]; SS[25+k]=v22[k]; SS[28+k]=v33[k];
        }
      }
      SS[31]=0.0f; SS[32]=al;
      SiT[lane]=i0;
    }
    __syncthreads();                 // RAW: phase-1 SI/SiT visible
    // ---- phase 2: packed coalesced loads + lerp, static slots ----
#pragma unroll 4
    for (int j=0; j<CH; ++j){
      if (j < cnt){
        const float* __restrict__ I = SI[j];
        const float alj = I[32];
        const float* __restrict__ wp = tabP + ((size_t)SiT[j]*512) + 8*lane;
        float4 wa = *(const float4*)wp;        // row i0,   p=0..3
        float4 wb = *(const float4*)(wp+4);    // row i0,   p=4..7
        float4 wc = *(const float4*)(wp+512);  // row i0+1, p=0..3
        float4 wd = *(const float4*)(wp+516);  // row i0+1, p=4..7
        if (j & 1){
          acc0b = fmaf(fmaf(alj, wc.x-wa.x, wa.x), I[ioS[0]], acc0b);
          acc0b = fmaf(fmaf(alj, wc.y-wa.y, wa.y), I[ioS[1]], acc0b);
          acc0b = fmaf(fmaf(alj, wc.z-wa.z, wa.z), I[ioS[2]], acc0b);
          acc0b = fmaf(fmaf(alj, wc.w-wa.w, wa.w), I[ioS[3]], acc0b);
          acc1b = fmaf(fmaf(alj, wd.x-wb.x, wb.x), I[ioS[4]], acc1b);
          acc1b = fmaf(fmaf(alj, wd.y-wb.y, wb.y), I[ioS[5]], acc1b);
          acc1b = fmaf(fmaf(alj, wd.z-wb.z, wb.z), I[ioS[6]], acc1b);
          acc1b = fmaf(fmaf(alj, wd.w-wb.w, wb.w), I[ioS[7]], acc1b);
        } else {
          acc0a = fmaf(fmaf(alj, wc.x-wa.x, wa.x), I[ioS[0]], acc0a);
          acc0a = fmaf(fmaf(alj, wc.y-wa.y, wa.y), I[ioS[1]], acc0a);
          acc0a = fmaf(fmaf(alj, wc.z-wa.z, wa.z), I[ioS[2]], acc0a);
          acc0a = fmaf(fmaf(alj, wc.w-wa.w, wa.w), I[ioS[3]], acc0a);
          acc1a = fmaf(fmaf(alj, wd.x-wb.x, wb.x), I[ioS[4]], acc1a);
          acc1a = fmaf(fmaf(alj, wd.y-wb.y, wb.y), I[ioS[5]], acc1a);
          acc1a = fmaf(fmaf(alj, wd.z-wb.z, wb.z), I[ioS[6]], acc1a);
          acc1a = fmaf(fmaf(alj, wd.w-wb.w, wb.w), I[ioS[7]], acc1a);
        }
      }
    }
  }
  const float acc0 = acc0a + acc0b;
  const float acc1 = acc1a + acc1b;

  // ---- fused gate epilogue ----
  const float inv = 0.5129891760f;
  if (lane < 16){
    SG[2*lane]   = acc0*0.5f*inv;
    SG[2*lane+1] = acc1*0.5f*inv;
  }
  __syncthreads();
  float* __restrict__ o = xg + (size_t)node*64;
  if (lane < 16){
    o[lane] = fmaxf(SG[lane], 0.0f);                       // se
  } else if (lane < 40){
    int idx = lane-16;
    float vv = (acc0+acc1)*0.4082482905f*inv;
    o[16+idx] = vv * fmaxf(SG[gu0], 0.0f);                 // v1o (u<8)
  } else if (lane < 52){
    int m = lane-40;
    float vv0 = acc0*0.5773502692f*inv;
    float vv1 = acc1*0.5773502692f*inv;
    o[40+2*m]   = vv0 * fmaxf(SG[gu0], 0.0f);              // v1e (u<8)
    o[40+2*m+1] = vv1 * fmaxf(SG[gu1], 0.0f);
  }
}

// ---------------- fctp2 per edge -> e2buf[E][4] (pruned, compile-time CG) ----------
__global__ __launch_bounds__(256) void k_tp2(
    const float* __restrict__ pos, const int* __restrict__ src, const int* __restrict__ dst, int E,
    const float* __restrict__ xg, const float* __restrict__ tab2,
    float* __restrict__ e2buf)
{
  const int e = blockIdx.x*256 + threadIdx.x;
  if (e>=E) return;
  const int s = src[e], d = dst[e];
  float ax=pos[3*s]-pos[3*d], ay=pos[3*s+1]-pos[3*d+1], az=pos[3*s+2]-pos[3*d+2];
  float r = sqrtf(ax*ax+ay*ay+az*az);
  float ir = 1.0f/r;
  float x=ax*ir, y=ay*ir, z=az*ir;
  float f = r * 614.0f;                        // (T_TAB-1)/2.5
  int i0 = (int)f; if (i0 > T_TAB-2) i0 = T_TAB-2;
  const float al = f - (float)i0;
  const float* __restrict__ w0 = tab2 + (size_t)i0*64;
  const float* __restrict__ w1 = w0 + 64;
  float wse[16], wA[8], wB[8], wC[8];
#pragma unroll
  for (int j=0;j<16;j+=4){
    float4 p = *(const float4*)(w0+j);
    float4 q = *(const float4*)(w1+j);
    wse[j+0]=fmaf(al,q.x-p.x,p.x); wse[j+1]=fmaf(al,q.y-p.y,p.y);
    wse[j+2]=fmaf(al,q.z-p.z,p.z); wse[j+3]=fmaf(al,q.w-p.w,p.w);
  }
#pragma unroll
  for (int j=0;j<8;j+=4){
    float4 p = *(const float4*)(w0+16+j); float4 q = *(const float4*)(w1+16+j);
    wA[j+0]=fmaf(al,q.x-p.x,p.x); wA[j+1]=fmaf(al,q.y-p.y,p.y);
    wA[j+2]=fmaf(al,q.z-p.z,p.z); wA[j+3]=fmaf(al,q.w-p.w,p.w);
    p = *(const float4*)(w0+32+j); q = *(const float4*)(w1+32+j);
    wB[j+0]=fmaf(al,q.x-p.x,p.x); wB[j+1]=fmaf(al,q.y-p.y,p.y);
    wB[j+2]=fmaf(al,q.z-p.z,p.z); wB[j+3]=fmaf(al,q.w-p.w,p.w);
    p = *(const float4*)(w0+48+j); q = *(const float4*)(w1+48+j);
    wC[j+0]=fmaf(al,q.x-p.x,p.x); wC[j+1]=fmaf(al,q.y-p.y,p.y);
    wC[j+2]=fmaf(al,q.z-p.z,p.z); wC[j+3]=fmaf(al,q.w-p.w,p.w);
  }
  const float s3=1.73205081f, s5=2.23606798f, s15=3.87298335f;
  float Y[9];
  Y[0]=1.0f;
  Y[1]=s3*y; Y[2]=s3*z; Y[3]=s3*x;
  Y[4]=s15*x*y; Y[5]=s15*y*z; Y[6]=0.5f*s5*(3.0f*z*z-1.0f); Y[7]=s15*x*z; Y[8]=0.5f*s15*(x*x-y*y);
  const float* __restrict__ g = xg + (size_t)s*64;
  float se[16], vo[24], ve[24];
#pragma unroll
  for (int jj=0;jj<4;++jj){ float4 t=((const float4*)g)[jj];
    se[4*jj]=t.x; se[4*jj+1]=t.y; se[4*jj+2]=t.z; se[4*jj+3]=t.w; }
#pragma unroll
  for (int jj=0;jj<6;++jj){ float4 t=((const float4*)(g+16))[jj];
    vo[4*jj]=t.x; vo[4*jj+1]=t.y; vo[4*jj+2]=t.z; vo[4*jj+3]=t.w; }
#pragma unroll
  for (int jj=0;jj<6;++jj){ float4 t=((const float4*)(g+40))[jj];
    ve[4*jj]=t.x; ve[4*jj+1]=t.y; ve[4*jj+2]=t.z; ve[4*jj+3]=t.w; }

  float SA=0.0f;
#pragma unroll
  for (int u=0;u<16;++u) SA = fmaf(wse[u], se[u], SA);
  float AB[3]={0,0,0}, AC[3]={0,0,0}, AD[3]={0,0,0};
#pragma unroll
  for (int u=0;u<8;++u)
#pragma unroll
    for (int i=0;i<3;++i){
      AB[i]=fmaf(wA[u], vo[u*3+i], AB[i]);
      AC[i]=fmaf(wB[u], vo[u*3+i], AC[i]);
      AD[i]=fmaf(wC[u], ve[u*3+i], AD[i]);
    }
  float e2[3]={0,0,0};
#pragma unroll
  for (int j=0;j<3;++j){ float t=SA*Y[1+j];
#pragma unroll
    for (int k=0;k<3;++k) TERM(CG011, j*3+k, t, e2[k]) }
#pragma unroll
  for (int i=0;i<3;++i){ float t=AB[i]*Y[0];
#pragma unroll
    for (int k=0;k<3;++k) TERM(CG101, i*3+k, t, e2[k]) }
#pragma unroll
  for (int i=0;i<3;++i)
#pragma unroll
    for (int j=0;j<5;++j){ float t=AC[i]*Y[4+j];
#pragma unroll
      for (int k=0;k<3;++k) TERM(CG121, (i*5+j)*3+k, t, e2[k]) }
#pragma unroll
  for (int i=0;i<3;++i)
#pragma unroll
    for (int j=0;j<3;++j){ float t=AD[i]*Y[1+j];
#pragma unroll
      for (int k=0;k<3;++k) TERM(CG111, (i*3+j)*3+k, t, e2[k]) }

  *(float4*)(e2buf + (size_t)e*4) = make_float4(e2[0], e2[1], e2[2], 0.0f);
}

// ---------------- final gather ----------------
__global__ __launch_bounds__(256) void k_out(
    const float* __restrict__ e2buf, const int* __restrict__ rowptr,
    float* __restrict__ out)
{
  const int t = blockIdx.x*256 + threadIdx.x;
  const int n = t>>2, k = t&3;
  if (n>=NN) return;
  const int r0=rowptr[n], r1=rowptr[n+1];
  float a=0.f;
  for (int e=r0;e<r1;++e) a += e2buf[(size_t)e*4 + k];
  const float sc = 0.0641236437f;  // (1/sqrt(64)) * 1/sqrt(3.8)
  if (k<3) out[(size_t)n*3 + k] = a*sc;
}

// ---------------- host launcher ----------------
extern "C" void kernel_launch(void* const* d_in, const int* in_sizes, int n_in,
                              void* d_out, int out_size, void* d_ws, size_t ws_size,
                              hipStream_t stream)
{
  (void)n_in; (void)ws_size; (void)out_size;
  const float* pos = (const float*)d_in[0];
  const int*   src = (const int*)d_in[1];
  const int*   dst = (const int*)d_in[2];
  const float* W1  = (const float*)d_in[3];
  const float* W2  = (const float*)d_in[4];
  const float* W1f = (const float*)d_in[5];
  const float* W2f = (const float*)d_in[6];
  const int E = in_sizes[1];

  char* ws = (char*)d_ws;
  float* xacc  = (float*)ws;                     // NN*16
  float* xg    = xacc + (size_t)NN*16;           // NN*64
  float* tab1  = xg + (size_t)NN*64;             // T_TAB*272
  float* tab2  = tab1 + (size_t)T_TAB*272;       // T_TAB*64
  float* tabP  = tab2 + (size_t)T_TAB*64;        // T_TAB*512
  float* e2buf = tabP + (size_t)T_TAB*512;       // E*4
  int*   rowptr= (int*)(e2buf + (size_t)E*4);    // NN+1

  k_table<<<84*6, 256, 0, stream>>>(W1, W2, W1f, W2f, tab1, tab2);
  k_perm<<<(T_TAB*512)/256, 256, 0, stream>>>(tab1, tabP);
  k_rowptr<<<(NN+1+255)/256, 256, 0, stream>>>(dst, E, rowptr);
  k_x<<<(NN*4)/256, 256, 0, stream>>>(pos, src, rowptr, xacc);
  k_tp1<<<NN, 64, 0, stream>>>(pos, src, rowptr, xacc, tabP, xg);
  k_tp2<<<(E + 255) / 256, 256, 0, stream>>>(pos, src, dst, E, xg, tab2, e2buf);
  k_out<<<(NN*4)/256, 256, 0, stream>>>(e2buf, rowptr, (float*)d_out);
}

// Round 13
// 119.708 us; speedup vs baseline: 2.2436x; 1.0334x over previous
//
#include <hip/hip_runtime.h>
#include <cmath>

#define T_TAB 1536
#define NN 16384
#define CH 32

// ================= compile-time CG tables (constexpr port of the reference) ========
struct CD { double re, im; };
constexpr CD cmul(CD a, CD b){ return {a.re*b.re - a.im*b.im, a.re*b.im + a.im*b.re}; }
constexpr CD cadd(CD a, CD b){ return {a.re+b.re, a.im+b.im}; }
constexpr CD conj_(CD a){ return {a.re, -a.im}; }
constexpr CD cscale(CD a, double s){ return {a.re*s, a.im*s}; }
constexpr double cfabs_(double x){ return x<0.0 ? -x : x; }
constexpr double csqrt_(double x){
  double g = x > 1.0 ? x : 1.0;
  for (int i=0;i<80;++i) g = 0.5*(g + x/g);
  return g;
}
constexpr double factd(int n){ double r=1.0; for(int i=2;i<=n;++i) r*=(double)i; return r; }

constexpr double cg_coef(int j1,int m1,int j2,int m2,int j3,int m3){
  double pref = csqrt_((2.0*j3+1.0)*factd(j3+j1-j2)*factd(j3-j1+j2)*factd(j1+j2-j3)/factd(j1+j2+j3+1));
  pref *= csqrt_(factd(j3+m3)*factd(j3-m3)*factd(j1-m1)*factd(j1+m1)*factd(j2-m2)*factd(j2+m2));
  double s=0.0;
  for(int k=0;k<=j1+j2-j3;++k){
    int a0=k,a1=j1+j2-j3-k,a2=j1-m1-k,a3=j2+m2-k,a4=j3-j2+m1+k,a5=j3-j1-m2+k;
    if(a0<0||a1<0||a2<0||a3<0||a4<0||a5<0) continue;
    double d=factd(a0)*factd(a1)*factd(a2)*factd(a3)*factd(a4)*factd(a5);
    s += ((k&1)?-1.0:1.0)/d;
  }
  return pref*s;
}

struct UMat { CD u[7][7]; };
constexpr UMat u_fill(int l){
  UMat M{};
  const double is2 = csqrt_(0.5);
  M.u[l][l] = CD{1.0, 0.0};
  for(int m=1;m<=l;++m){
    double sgn = (m&1)?-1.0:1.0;
    M.u[l+m][l+m] = CD{sgn*is2, 0.0};
    M.u[l+m][l-m] = CD{is2, 0.0};
    M.u[l-m][l-m] = CD{0.0, is2};
    M.u[l-m][l+m] = CD{0.0, -sgn*is2};
  }
  return M;
}

template<int L1,int L2,int L3>
struct FT { float v[(2*L1+1)*(2*L2+1)*(2*L3+1)]; };

template<int L1,int L2,int L3>
constexpr FT<L1,L2,L3> cg_real_ct(){
  constexpr int n1=2*L1+1, n2=2*L2+1, n3=2*L3+1;
  double Cc[7][7][7] = {};
  for(int m1=-L1;m1<=L1;++m1)
    for(int m2=-L2;m2<=L2;++m2){
      int m3=m1+m2;
      if(m3>=-L3&&m3<=L3) Cc[m1+L1][m2+L2][m3+L3]=cg_coef(L1,m1,L2,m2,L3,m3);
    }
  UMat U1 = u_fill(L1), U2 = u_fill(L2), U3 = u_fill(L3);
  CD Cr[7][7][7] = {};
  double sre=0.0, sim=0.0;
  for(int a=0;a<n1;++a)for(int b=0;b<n2;++b)for(int c=0;c<n3;++c){
    CD acc{0.0,0.0};
    for(int u=0;u<n1;++u)for(int v=0;v<n2;++v){
      int w = (u-L1)+(v-L2)+L3;           // only m3=m1+m2 can be nonzero in Cc
      if (w < 0 || w >= n3) continue;
      double cc = Cc[u][v][w];
      if (cc == 0.0) continue;
      acc = cadd(acc, cscale(cmul(cmul(U1.u[a][u],U2.u[b][v]),conj_(U3.u[c][w])), cc));
    }
    Cr[a][b][c] = acc;
    sre += cfabs_(acc.re); sim += cfabs_(acc.im);
  }
  FT<L1,L2,L3> out{};
  bool useim = sim > sre;
  for(int a=0;a<n1;++a)for(int b=0;b<n2;++b)for(int c=0;c<n3;++c)
    out.v[(a*n2+b)*n3+c] = (float)(useim ? Cr[a][b][c].im : Cr[a][b][c].re);
  return out;
}

constexpr auto CG000 = cg_real_ct<0,0,0>();
constexpr auto CG110 = cg_real_ct<1,1,0>();
constexpr auto CG220 = cg_real_ct<2,2,0>();
constexpr auto CG330 = cg_real_ct<3,3,0>();
constexpr auto CG011 = cg_real_ct<0,1,1>();
constexpr auto CG101 = cg_real_ct<1,0,1>();
constexpr auto CG111 = cg_real_ct<1,1,1>();
constexpr auto CG121 = cg_real_ct<1,2,1>();
constexpr auto CG211 = cg_real_ct<2,1,1>();
constexpr auto CG221 = cg_real_ct<2,2,1>();
constexpr auto CG231 = cg_real_ct<2,3,1>();
constexpr auto CG321 = cg_real_ct<3,2,1>();
constexpr auto CG331 = cg_real_ct<3,3,1>();

// zero-pruned FMA term: coefficient folds to a literal; zero terms are deleted.
#define TERM(TBL, IDX, PROD, ACC) { float c_ = TBL.v[IDX]; if (c_ != 0.0f) ACC = fmaf((PROD), c_, ACC); }

// ---------------- device helpers ----------------
__device__ __forceinline__ float soh(float r, float c){
  float d = (r - c) * 2.0f;
  float d2 = d*d;
  return (d2 < 1.0f) ? 1.14136f * expf(2.0f + 1.0f/(d2-1.0f)) : 0.0f;
}

__device__ __forceinline__ float bf_lo(unsigned u){ return __uint_as_float(u << 16); }
__device__ __forceinline__ float bf_hi(unsigned u){ return __uint_as_float(u & 0xFFFF0000u); }

// Per-lane weight schedule: lane ℓ, sub-index q (0..7) -> (column in [0,272) or -1, LDS slot).
// Slot 31 is a guaranteed-zero slot.
__device__ __forceinline__ void lane_sched(int lane, int q, int& col, int& slot){
  col = -1; slot = 31;
  if (lane < 16){
    int s = q >> 2, qq = q & 3;
    int a = 2*lane + s;                 // scalar output index 0..31
    const int base0[4] = {0, 64, 144, 224};
    col = base0[qq] + a; slot = qq;
  } else if (lane < 40){
    int idx = lane-16, u = idx/3, k = idx-3*u;
    const int wb[6] = {32,48,112,128,192,208};
    const int sb[6] = {4,7,10,13,16,19};
    if (q < 6){ col = wb[q]+u; slot = sb[q]+k; }
  } else if (lane < 52){
    int m = lane-40;
    int c0 = (q < 4) ? 2*m : 2*m+1;
    int u = c0/3, k = c0-3*u;
    int qq = (q < 4) ? q : q-4;
    if (qq < 3){
      const int wb[3] = {96,176,256};
      const int sb[3] = {22,25,28};
      col = wb[qq]+u; slot = sb[qq]+k;
    }
  }
}

// ---------------- radial MLP tables: tab1[T_TAB][272] (fctp1), tab2[T_TAB][64] (fctp2)
__global__ __launch_bounds__(256) void k_table(
    const float* __restrict__ W1, const float* __restrict__ W2,
    const float* __restrict__ W1f, const float* __restrict__ W2f,
    float* __restrict__ tab1, float* __restrict__ tab2)
{
  const int bid = blockIdx.x;                 // 84*6 = 504
  const int jq  = bid / 6;                    // 0..83
  const int t   = (bid % 6)*256 + threadIdx.x;
  const int j0  = jq*4;
  const float dr = 2.5f / (float)(T_TAB-1);
  const float r = (float)t * dr;
  const float e0 = soh(r,1.0f), e1 = soh(r,1.5f), e2 = soh(r,2.0f);
  float ax=0.f, ay=0.f, az=0.f, aw=0.f;
  if (j0 < 272){
    for (int cc=0; cc<256; ++cc){
      float h = fmaxf(fmaf(e0,W1[cc], fmaf(e1,W1[256+cc], e2*W1[512+cc])), 0.0f);
      float4 w = *(const float4*)(W2 + cc*272 + j0);
      ax = fmaf(h,w.x,ax); ay = fmaf(h,w.y,ay);
      az = fmaf(h,w.z,az); aw = fmaf(h,w.w,aw);
    }
    *(float4*)(tab1 + (size_t)t*272 + j0) = make_float4(ax*0.0625f, ay*0.0625f, az*0.0625f, aw*0.0625f);
  } else {
    const int jj = j0 - 272;
    for (int cc=0; cc<256; ++cc){
      float h = fmaxf(fmaf(e0,W1f[cc], fmaf(e1,W1f[256+cc], e2*W1f[512+cc])), 0.0f);
      float4 w = *(const float4*)(W2f + cc*64 + jj);
      ax = fmaf(h,w.x,ax); ay = fmaf(h,w.y,ay);
      az = fmaf(h,w.z,az); aw = fmaf(h,w.w,aw);
    }
    *(float4*)(tab2 + (size_t)t*64 + jj) = make_float4(ax*0.0625f, ay*0.0625f, az*0.0625f, aw*0.0625f);
  }
}

// ---------------- per-lane packed table (bf16): tabP[T_TAB][512] ushort -------------
// lane l's 8 weights at 8l. Footprint 1.57 MB (L2-resident); halves k_tp1's per-edge
// weight traffic (2 KB -> 1 KB per row pair per wave).
__global__ __launch_bounds__(256) void k_perm(
    const float* __restrict__ tab1, unsigned short* __restrict__ tabP)
{
  const int gid = blockIdx.x*256 + threadIdx.x;     // [0, T_TAB*512)
  const int t = gid >> 9, p = gid & 511;
  int col, slot;
  lane_sched(p>>3, p&7, col, slot);
  float v = (col >= 0) ? tab1[(size_t)t*272 + col] : 0.0f;
  unsigned b = __float_as_uint(v);
  unsigned r = (b + 0x7FFFu + ((b >> 16) & 1u)) >> 16;   // RTNE bf16
  tabP[gid] = (unsigned short)r;
}

// ---------------- rowptr: dst is globally non-decreasing -> CSR via binary search ----
__global__ __launch_bounds__(256) void k_rowptr(
    const int* __restrict__ dst, int E, int* __restrict__ rowptr)
{
  const int n = blockIdx.x*256 + threadIdx.x;
  if (n > NN) return;
  int lo=0, hi=E;
  while (lo < hi){ int mid=(lo+hi)>>1; if (dst[mid] < n) lo=mid+1; else hi=mid; }
  rowptr[n]=lo;
}

// ---------------- x = segsum(sph_harm): 4 lanes/node, each edge touched once -------
__global__ __launch_bounds__(256) void k_x(
    const float* __restrict__ pos, const int* __restrict__ src,
    const int* __restrict__ rowptr, float* __restrict__ xacc)
{
  const int t = blockIdx.x*256 + threadIdx.x;
  const int n = t>>2, q = t&3;
  if (n>=NN) return;
  const int r0=rowptr[n], r1=rowptr[n+1];
  const float pdx=pos[3*n], pdy=pos[3*n+1], pdz=pos[3*n+2];
  const float s3=1.73205081f, s5=2.23606798f, s15=3.87298335f;
  const float c33=2.09165007f, c32=10.2469508f, c31=1.62018517f, c30=1.32287566f, cp2=5.12347538f;
  float a0=0,a1=0,a2=0,a3=0,a4=0,a5=0,a6=0,a7=0,a8=0,a9=0,a10=0,a11=0,a12=0,a13=0,a14=0,a15=0;
  for (int e=r0+q; e<r1; e+=4){
    const int s=src[e];
    float ax=pos[3*s]-pdx, ay=pos[3*s+1]-pdy, az=pos[3*s+2]-pdz;
    float ir = 1.0f/sqrtf(ax*ax+ay*ay+az*az);
    float x=ax*ir, y=ay*ir, z=az*ir;
    a0+=1.0f; a1+=s3*y; a2+=s3*z; a3+=s3*x;
    a4+=s15*x*y; a5+=s15*y*z; a6+=0.5f*s5*(3.0f*z*z-1.0f); a7+=s15*x*z;
    a8+=0.5f*s15*(x*x-y*y); a9+=c33*y*(3.0f*x*x-y*y); a10+=c32*x*y*z; a11+=c31*y*(5.0f*z*z-1.0f);
    a12+=c30*(5.0f*z*z*z-3.0f*z); a13+=c31*x*(5.0f*z*z-1.0f); a14+=cp2*z*(x*x-y*y);
    a15+=c33*x*(x*x-3.0f*y*y);
  }
#define RED(v) v += __shfl_xor(v,1); v += __shfl_xor(v,2);
  RED(a0) RED(a1) RED(a2) RED(a3) RED(a4) RED(a5) RED(a6) RED(a7)
  RED(a8) RED(a9) RED(a10) RED(a11) RED(a12) RED(a13) RED(a14) RED(a15)
#undef RED
  float o0,o1,o2,o3;
  if (q==0){ o0=a0; o1=a1; o2=a2; o3=a3; }
  else if (q==1){ o0=a4; o1=a5; o2=a6; o3=a7; }
  else if (q==2){ o0=a8; o1=a9; o2=a10; o3=a11; }
  else { o0=a12; o1=a13; o2=a14; o3=a15; }
  *(float4*)(xacc + (size_t)n*16 + q*4) = make_float4(o0,o1,o2,o3);
}

// ---------------- fctp1 + gate fused: ONE WAVE PER NODE --------------
// Phase 1: lane = edge, zero-pruned compile-time CG, single code path.
// Phase 2: 2 coalesced 16B loads/edge from bf16 packed tabP (L2-resident),
//          unpack + lerp + 8 FMA; alternating accumulator pairs.
__global__ __launch_bounds__(64) void k_tp1(
    const float* __restrict__ pos, const int* __restrict__ src,
    const int* __restrict__ rowptr, const float* __restrict__ xacc,
    const unsigned short* __restrict__ tabP, float* __restrict__ xg)
{
  const int lane = threadIdx.x;
  const int node = blockIdx.x;
  __shared__ float SI[CH][33];   // 0..30 intermediates, 31 zero, 32 al
  __shared__ int   SiT[CH];
  __shared__ float SG[32];
  const int r0 = rowptr[node], r1 = rowptr[node+1];
  const int nch = (r1 - r0 + CH - 1) / CH;

  // ---- static LDS-slot schedule + gate indices ----
  int ioS[8];
#pragma unroll
  for (int p=0;p<8;++p){ int c_, s_; lane_sched(lane, p, c_, s_); ioS[p] = s_; }
  int gu0=16, gu1=16;
  if (lane >= 16 && lane < 40){ gu0 = 16 + (lane-16)/3; }
  else if (lane >= 40 && lane < 52){
    int m=lane-40; gu0 = 24 + (2*m)/3; gu1 = 24 + (2*m+1)/3;
  }

  const float pdx=pos[3*node], pdy=pos[3*node+1], pdz=pos[3*node+2];
  float acc0a=0.f, acc0b=0.f, acc1a=0.f, acc1b=0.f;

  for (int t=0; t<nch; ++t){
    const int e0 = r0 + t*CH;
    const int cnt = min(CH, r1-e0);
    __syncthreads();                 // WAR: prev chunk phase-2 reads done
    if (lane < cnt){
      const int e = e0 + lane;
      const int s = src[e];
      float ax=pos[3*s]-pdx, ay=pos[3*s+1]-pdy, az=pos[3*s+2]-pdz;
      float r = sqrtf(ax*ax+ay*ay+az*az);
      float ir = 1.0f/r;
      float x=ax*ir, y=ay*ir, z=az*ir;
      float f = r * 614.0f;                     // (T_TAB-1)/2.5
      int i0 = (int)f; if (i0 > T_TAB-2) i0 = T_TAB-2;
      float al = f - (float)i0;

      const float s3=1.73205081f, s5=2.23606798f, s15=3.87298335f;
      const float c33=2.09165007f, c32=10.2469508f, c31=1.62018517f, c30=1.32287566f, cp2=5.12347538f;
      float Y[16];
      Y[0]=1.0f;
      Y[1]=s3*y; Y[2]=s3*z; Y[3]=s3*x;
      Y[4]=s15*x*y; Y[5]=s15*y*z; Y[6]=0.5f*s5*(3.0f*z*z-1.0f); Y[7]=s15*x*z; Y[8]=0.5f*s15*(x*x-y*y);
      Y[9]=c33*y*(3.0f*x*x-y*y); Y[10]=c32*x*y*z; Y[11]=c31*y*(5.0f*z*z-1.0f);
      Y[12]=c30*(5.0f*z*z*z-3.0f*z); Y[13]=c31*x*(5.0f*z*z-1.0f); Y[14]=cp2*z*(x*x-y*y);
      Y[15]=c33*x*(x*x-3.0f*y*y);
      float X[16];
      {
        const float inv = 0.5129891760f;           // 1/sqrt(3.8)
        const float4* q4 = (const float4*)(xacc + (size_t)s*16);
        float4 a=q4[0],b=q4[1],cc4=q4[2],d4=q4[3];
        X[0]=a.x*inv;X[1]=a.y*inv;X[2]=a.z*inv;X[3]=a.w*inv;
        X[4]=b.x*inv;X[5]=b.y*inv;X[6]=b.z*inv;X[7]=b.w*inv;
        X[8]=cc4.x*inv;X[9]=cc4.y*inv;X[10]=cc4.z*inv;X[11]=cc4.w*inv;
        X[12]=d4.x*inv;X[13]=d4.y*inv;X[14]=d4.z*inv;X[15]=d4.w*inv;
      }
      float* SS = SI[lane];

      // t-block (scalar outputs)
      {
        float t0v = CG000.v[0]*X[0]*Y[0];
        float t1v=0.f, t2v=0.f, t3v=0.f;
#pragma unroll
        for (int i=0;i<3;++i)
#pragma unroll
          for (int j=0;j<3;++j) TERM(CG110, i*3+j, X[1+i]*Y[1+j], t1v)
#pragma unroll
        for (int i=0;i<5;++i)
#pragma unroll
          for (int j=0;j<5;++j) TERM(CG220, i*5+j, X[4+i]*Y[4+j], t2v)
#pragma unroll
        for (int i=0;i<7;++i)
#pragma unroll
          for (int j=0;j<7;++j) TERM(CG330, i*7+j, X[9+i]*Y[9+j], t3v)
        SS[0]=t0v; SS[1]=t1v; SS[2]=t2v; SS[3]=t3v;
      }
      // vector outputs
      {
        float v01[3]={0,0,0}, v10[3]={0,0,0}, v11[3]={0,0,0}, v12[3]={0,0,0},
              v21[3]={0,0,0}, v22[3]={0,0,0}, v23[3]={0,0,0}, v32[3]={0,0,0}, v33[3]={0,0,0};
#pragma unroll
        for (int j=0;j<3;++j){ float tt=X[0]*Y[1+j];
#pragma unroll
          for (int k=0;k<3;++k) TERM(CG011, j*3+k, tt, v01[k]) }
#pragma unroll
        for (int i=0;i<3;++i){ float tt=X[1+i]*Y[0];
#pragma unroll
          for (int k=0;k<3;++k) TERM(CG101, i*3+k, tt, v10[k]) }
#pragma unroll
        for (int i=0;i<3;++i)
#pragma unroll
          for (int j=0;j<3;++j){ float tt=X[1+i]*Y[1+j];
#pragma unroll
            for (int k=0;k<3;++k) TERM(CG111, (i*3+j)*3+k, tt, v11[k]) }
#pragma unroll
        for (int i=0;i<3;++i)
#pragma unroll
          for (int j=0;j<5;++j){ float tt=X[1+i]*Y[4+j];
#pragma unroll
            for (int k=0;k<3;++k) TERM(CG121, (i*5+j)*3+k, tt, v12[k]) }
#pragma unroll
        for (int i=0;i<5;++i)
#pragma unroll
          for (int j=0;j<3;++j){ float tt=X[4+i]*Y[1+j];
#pragma unroll
            for (int k=0;k<3;++k) TERM(CG211, (i*3+j)*3+k, tt, v21[k]) }
#pragma unroll
        for (int i=0;i<5;++i)
#pragma unroll
          for (int j=0;j<5;++j){ float tt=X[4+i]*Y[4+j];
#pragma unroll
            for (int k=0;k<3;++k) TERM(CG221, (i*5+j)*3+k, tt, v22[k]) }
#pragma unroll
        for (int i=0;i<5;++i)
#pragma unroll
          for (int j=0;j<7;++j){ float tt=X[4+i]*Y[9+j];
#pragma unroll
            for (int k=0;k<3;++k) TERM(CG231, (i*7+j)*3+k, tt, v23[k]) }
#pragma unroll
        for (int i=0;i<7;++i)
#pragma unroll
          for (int j=0;j<5;++j){ float tt=X[9+i]*Y[4+j];
#pragma unroll
            for (int k=0;k<3;++k) TERM(CG321, (i*5+j)*3+k, tt, v32[k]) }
#pragma unroll
        for (int i=0;i<7;++i)
#pragma unroll
          for (int j=0;j<7;++j){ float tt=X[9+i]*Y[9+j];
#pragma unroll
            for (int k=0;k<3;++k) TERM(CG331, (i*7+j)*3+k, tt, v33[k]) }
#pragma unroll
        for (int k=0;k<3;++k){
          SS[4+k]=v01[k]; SS[7+k]=v10[k]; SS[10+k]=v12[k]; SS[13+k]=v21[k];
          SS[16+k]=v23[k]; SS[19+k]=v32[k]; SS[22+k]=v11[k]; SS[25+k]=v22[k]; SS[28+k]=v33[k];
        }
      }
      SS[31]=0.0f; SS[32]=al;
      SiT[lane]=i0;
    }
    __syncthreads();                 // RAW: phase-1 SI/SiT visible
    // ---- phase 2: bf16 packed coalesced loads + unpack + lerp, static slots ----
#pragma unroll 4
    for (int j=0; j<CH; ++j){
      if (j < cnt){
        const float* __restrict__ I = SI[j];
        const float alj = I[32];
        const unsigned short* __restrict__ wp = tabP + ((size_t)SiT[j]*512) + 8*lane;
        uint4 ra = *(const uint4*)wp;          // row i0:   8 bf16 (q0..q7)
        uint4 rb = *(const uint4*)(wp + 512);  // row i0+1: 8 bf16
        float a0w=bf_lo(ra.x), a1w=bf_hi(ra.x), a2w=bf_lo(ra.y), a3w=bf_hi(ra.y);
        float a4w=bf_lo(ra.z), a5w=bf_hi(ra.z), a6w=bf_lo(ra.w), a7w=bf_hi(ra.w);
        float b0w=bf_lo(rb.x), b1w=bf_hi(rb.x), b2w=bf_lo(rb.y), b3w=bf_hi(rb.y);
        float b4w=bf_lo(rb.z), b5w=bf_hi(rb.z), b6w=bf_lo(rb.w), b7w=bf_hi(rb.w);
        if (j & 1){
          acc0b = fmaf(fmaf(alj, b0w-a0w, a0w), I[ioS[0]], acc0b);
          acc0b = fmaf(fmaf(alj, b1w-a1w, a1w), I[ioS[1]], acc0b);
          acc0b = fmaf(fmaf(alj, b2w-a2w, a2w), I[ioS[2]], acc0b);
          acc0b = fmaf(fmaf(alj, b3w-a3w, a3w), I[ioS[3]], acc0b);
          acc1b = fmaf(fmaf(alj, b4w-a4w, a4w), I[ioS[4]], acc1b);
          acc1b = fmaf(fmaf(alj, b5w-a5w, a5w), I[ioS[5]], acc1b);
          acc1b = fmaf(fmaf(alj, b6w-a6w, a6w), I[ioS[6]], acc1b);
          acc1b = fmaf(fmaf(alj, b7w-a7w, a7w), I[ioS[7]], acc1b);
        } else {
          acc0a = fmaf(fmaf(alj, b0w-a0w, a0w), I[ioS[0]], acc0a);
          acc0a = fmaf(fmaf(alj, b1w-a1w, a1w), I[ioS[1]], acc0a);
          acc0a = fmaf(fmaf(alj, b2w-a2w, a2w), I[ioS[2]], acc0a);
          acc0a = fmaf(fmaf(alj, b3w-a3w, a3w), I[ioS[3]], acc0a);
          acc1a = fmaf(fmaf(alj, b4w-a4w, a4w), I[ioS[4]], acc1a);
          acc1a = fmaf(fmaf(alj, b5w-a5w, a5w), I[ioS[5]], acc1a);
          acc1a = fmaf(fmaf(alj, b6w-a6w, a6w), I[ioS[6]], acc1a);
          acc1a = fmaf(fmaf(alj, b7w-a7w, a7w), I[ioS[7]], acc1a);
        }
      }
    }
  }
  const float acc0 = acc0a + acc0b;
  const float acc1 = acc1a + acc1b;

  // ---- fused gate epilogue ----
  const float inv = 0.5129891760f;
  if (lane < 16){
    SG[2*lane]   = acc0*0.5f*inv;
    SG[2*lane+1] = acc1*0.5f*inv;
  }
  __syncthreads();
  float* __restrict__ o = xg + (size_t)node*64;
  if (lane < 16){
    o[lane] = fmaxf(SG[lane], 0.0f);                       // se
  } else if (lane < 40){
    int idx = lane-16;
    float vv = (acc0+acc1)*0.4082482905f*inv;
    o[16+idx] = vv * fmaxf(SG[gu0], 0.0f);                 // v1o (u<8)
  } else if (lane < 52){
    int m = lane-40;
    float vv0 = acc0*0.5773502692f*inv;
    float vv1 = acc1*0.5773502692f*inv;
    o[40+2*m]   = vv0 * fmaxf(SG[gu0], 0.0f);              // v1e (u<8)
    o[40+2*m+1] = vv1 * fmaxf(SG[gu1], 0.0f);
  }
}

// ---------------- fctp2 per edge -> e2buf[E][4] (pruned, compile-time CG) ----------
__global__ __launch_bounds__(256) void k_tp2(
    const float* __restrict__ pos, const int* __restrict__ src, const int* __restrict__ dst, int E,
    const float* __restrict__ xg, const float* __restrict__ tab2,
    float* __restrict__ e2buf)
{
  const int e = blockIdx.x*256 + threadIdx.x;
  if (e>=E) return;
  const int s = src[e], d = dst[e];
  float ax=pos[3*s]-pos[3*d], ay=pos[3*s+1]-pos[3*d+1], az=pos[3*s+2]-pos[3*d+2];
  float r = sqrtf(ax*ax+ay*ay+az*az);
  float ir = 1.0f/r;
  float x=ax*ir, y=ay*ir, z=az*ir;
  float f = r * 614.0f;                        // (T_TAB-1)/2.5
  int i0 = (int)f; if (i0 > T_TAB-2) i0 = T_TAB-2;
  const float al = f - (float)i0;
  const float* __restrict__ w0 = tab2 + (size_t)i0*64;
  const float* __restrict__ w1 = w0 + 64;
  float wse[16], wA[8], wB[8], wC[8];
#pragma unroll
  for (int j=0;j<16;j+=4){
    float4 p = *(const float4*)(w0+j);
    float4 q = *(const float4*)(w1+j);
    wse[j+0]=fmaf(al,q.x-p.x,p.x); wse[j+1]=fmaf(al,q.y-p.y,p.y);
    wse[j+2]=fmaf(al,q.z-p.z,p.z); wse[j+3]=fmaf(al,q.w-p.w,p.w);
  }
#pragma unroll
  for (int j=0;j<8;j+=4){
    float4 p = *(const float4*)(w0+16+j); float4 q = *(const float4*)(w1+16+j);
    wA[j+0]=fmaf(al,q.x-p.x,p.x); wA[j+1]=fmaf(al,q.y-p.y,p.y);
    wA[j+2]=fmaf(al,q.z-p.z,p.z); wA[j+3]=fmaf(al,q.w-p.w,p.w);
    p = *(const float4*)(w0+32+j); q = *(const float4*)(w1+32+j);
    wB[j+0]=fmaf(al,q.x-p.x,p.x); wB[j+1]=fmaf(al,q.y-p.y,p.y);
    wB[j+2]=fmaf(al,q.z-p.z,p.z); wB[j+3]=fmaf(al,q.w-p.w,p.w);
    p = *(const float4*)(w0+48+j); q = *(const float4*)(w1+48+j);
    wC[j+0]=fmaf(al,q.x-p.x,p.x); wC[j+1]=fmaf(al,q.y-p.y,p.y);
    wC[j+2]=fmaf(al,q.z-p.z,p.z); wC[j+3]=fmaf(al,q.w-p.w,p.w);
  }
  const float s3=1.73205081f, s5=2.23606798f, s15=3.87298335f;
  float Y[9];
  Y[0]=1.0f;
  Y[1]=s3*y; Y[2]=s3*z; Y[3]=s3*x;
  Y[4]=s15*x*y; Y[5]=s15*y*z; Y[6]=0.5f*s5*(3.0f*z*z-1.0f); Y[7]=s15*x*z; Y[8]=0.5f*s15*(x*x-y*y);
  const float* __restrict__ g = xg + (size_t)s*64;
  float se[16], vo[24], ve[24];
#pragma unroll
  for (int jj=0;jj<4;++jj){ float4 t=((const float4*)g)[jj];
    se[4*jj]=t.x; se[4*jj+1]=t.y; se[4*jj+2]=t.z; se[4*jj+3]=t.w; }
#pragma unroll
  for (int jj=0;jj<6;++jj){ float4 t=((const float4*)(g+16))[jj];
    vo[4*jj]=t.x; vo[4*jj+1]=t.y; vo[4*jj+2]=t.z; vo[4*jj+3]=t.w; }
#pragma unroll
  for (int jj=0;jj<6;++jj){ float4 t=((const float4*)(g+40))[jj];
    ve[4*jj]=t.x; ve[4*jj+1]=t.y; ve[4*jj+2]=t.z; ve[4*jj+3]=t.w; }

  float SA=0.0f;
#pragma unroll
  for (int u=0;u<16;++u) SA = fmaf(wse[u], se[u], SA);
  float AB[3]={0,0,0}, AC[3]={0,0,0}, AD[3]={0,0,0};
#pragma unroll
  for (int u=0;u<8;++u)
#pragma unroll
    for (int i=0;i<3;++i){
      AB[i]=fmaf(wA[u], vo[u*3+i], AB[i]);
      AC[i]=fmaf(wB[u], vo[u*3+i], AC[i]);
      AD[i]=fmaf(wC[u], ve[u*3+i], AD[i]);
    }
  float e2[3]={0,0,0};
#pragma unroll
  for (int j=0;j<3;++j){ float t=SA*Y[1+j];
#pragma unroll
    for (int k=0;k<3;++k) TERM(CG011, j*3+k, t, e2[k]) }
#pragma unroll
  for (int i=0;i<3;++i){ float t=AB[i]*Y[0];
#pragma unroll
    for (int k=0;k<3;++k) TERM(CG101, i*3+k, t, e2[k]) }
#pragma unroll
  for (int i=0;i<3;++i)
#pragma unroll
    for (int j=0;j<5;++j){ float t=AC[i]*Y[4+j];
#pragma unroll
      for (int k=0;k<3;++k) TERM(CG121, (i*5+j)*3+k, t, e2[k]) }
#pragma unroll
  for (int i=0;i<3;++i)
#pragma unroll
    for (int j=0;j<3;++j){ float t=AD[i]*Y[1+j];
#pragma unroll
      for (int k=0;k<3;++k) TERM(CG111, (i*3+j)*3+k, t, e2[k]) }

  *(float4*)(e2buf + (size_t)e*4) = make_float4(e2[0], e2[1], e2[2], 0.0f);
}

// ---------------- final gather ----------------
__global__ __launch_bounds__(256) void k_out(
    const float* __restrict__ e2buf, const int* __restrict__ rowptr,
    float* __restrict__ out)
{
  const int t = blockIdx.x*256 + threadIdx.x;
  const int n = t>>2, k = t&3;
  if (n>=NN) return;
  const int r0=rowptr[n], r1=rowptr[n+1];
  float a=0.f;
  for (int e=r0;e<r1;++e) a += e2buf[(size_t)e*4 + k];
  const float sc = 0.0641236437f;  // (1/sqrt(64)) * 1/sqrt(3.8)
  if (k<3) out[(size_t)n*3 + k] = a*sc;
}

// ---------------- host launcher ----------------
extern "C" void kernel_launch(void* const* d_in, const int* in_sizes, int n_in,
                              void* d_out, int out_size, void* d_ws, size_t ws_size,
                              hipStream_t stream)
{
  (void)n_in; (void)ws_size; (void)out_size;
  const float* pos = (const float*)d_in[0];
  const int*   src = (const int*)d_in[1];
  const int*   dst = (const int*)d_in[2];
  const float* W1  = (const float*)d_in[3];
  const float* W2  = (const float*)d_in[4];
  const float* W1f = (const float*)d_in[5];
  const float* W2f = (const float*)d_in[6];
  const int E = in_sizes[1];

  char* ws = (char*)d_ws;
  float* xacc  = (float*)ws;                     // NN*16
  float* xg    = xacc + (size_t)NN*16;           // NN*64
  float* tab1  = xg + (size_t)NN*64;             // T_TAB*272
  float* tab2  = tab1 + (size_t)T_TAB*272;       // T_TAB*64
  unsigned short* tabP = (unsigned short*)(tab2 + (size_t)T_TAB*64);  // T_TAB*512 ushort
  float* e2buf = (float*)(tabP + (size_t)T_TAB*512);                  // E*4
  int*   rowptr= (int*)(e2buf + (size_t)E*4);    // NN+1

  k_table<<<84*6, 256, 0, stream>>>(W1, W2, W1f, W2f, tab1, tab2);
  k_perm<<<(T_TAB*512)/256, 256, 0, stream>>>(tab1, tabP);
  k_rowptr<<<(NN+1+255)/256, 256, 0, stream>>>(dst, E, rowptr);
  k_x<<<(NN*4)/256, 256, 0, stream>>>(pos, src, rowptr, xacc);
  k_tp1<<<NN, 64, 0, stream>>>(pos, src, rowptr, xacc, tabP, xg);
  k_tp2<<<(E + 255) / 256, 256, 0, stream>>>(pos, src, dst, E, xg, tab2, e2buf);
  k_out<<<(NN*4)/256, 256, 0, stream>>>(e2buf, rowptr, (float*)d_out);
}

// Round 14
// 108.738 us; speedup vs baseline: 2.4700x; 1.1009x over previous
//
#include <hip/hip_runtime.h>
#include <cmath>

#define T_TAB 1536
#define NN 16384
#define NG 4
#define CH2 16

// ================= compile-time CG tables (constexpr port of the reference) ========
struct CD { double re, im; };
constexpr CD cmul(CD a, CD b){ return {a.re*b.re - a.im*b.im, a.re*b.im + a.im*b.re}; }
constexpr CD cadd(CD a, CD b){ return {a.re+b.re, a.im+b.im}; }
constexpr CD conj_(CD a){ return {a.re, -a.im}; }
constexpr CD cscale(CD a, double s){ return {a.re*s, a.im*s}; }
constexpr double cfabs_(double x){ return x<0.0 ? -x : x; }
constexpr double csqrt_(double x){
  double g = x > 1.0 ? x : 1.0;
  for (int i=0;i<80;++i) g = 0.5*(g + x/g);
  return g;
}
constexpr double factd(int n){ double r=1.0; for(int i=2;i<=n;++i) r*=(double)i; return r; }

constexpr double cg_coef(int j1,int m1,int j2,int m2,int j3,int m3){
  double pref = csqrt_((2.0*j3+1.0)*factd(j3+j1-j2)*factd(j3-j1+j2)*factd(j1+j2-j3)/factd(j1+j2+j3+1));
  pref *= csqrt_(factd(j3+m3)*factd(j3-m3)*factd(j1-m1)*factd(j1+m1)*factd(j2-m2)*factd(j2+m2));
  double s=0.0;
  for(int k=0;k<=j1+j2-j3;++k){
    int a0=k,a1=j1+j2-j3-k,a2=j1-m1-k,a3=j2+m2-k,a4=j3-j2+m1+k,a5=j3-j1-m2+k;
    if(a0<0||a1<0||a2<0||a3<0||a4<0||a5<0) continue;
    double d=factd(a0)*factd(a1)*factd(a2)*factd(a3)*factd(a4)*factd(a5);
    s += ((k&1)?-1.0:1.0)/d;
  }
  return pref*s;
}

struct UMat { CD u[7][7]; };
constexpr UMat u_fill(int l){
  UMat M{};
  const double is2 = csqrt_(0.5);
  M.u[l][l] = CD{1.0, 0.0};
  for(int m=1;m<=l;++m){
    double sgn = (m&1)?-1.0:1.0;
    M.u[l+m][l+m] = CD{sgn*is2, 0.0};
    M.u[l+m][l-m] = CD{is2, 0.0};
    M.u[l-m][l-m] = CD{0.0, is2};
    M.u[l-m][l+m] = CD{0.0, -sgn*is2};
  }
  return M;
}

template<int L1,int L2,int L3>
struct FT { float v[(2*L1+1)*(2*L2+1)*(2*L3+1)]; };

template<int L1,int L2,int L3>
constexpr FT<L1,L2,L3> cg_real_ct(){
  constexpr int n1=2*L1+1, n2=2*L2+1, n3=2*L3+1;
  double Cc[7][7][7] = {};
  for(int m1=-L1;m1<=L1;++m1)
    for(int m2=-L2;m2<=L2;++m2){
      int m3=m1+m2;
      if(m3>=-L3&&m3<=L3) Cc[m1+L1][m2+L2][m3+L3]=cg_coef(L1,m1,L2,m2,L3,m3);
    }
  UMat U1 = u_fill(L1), U2 = u_fill(L2), U3 = u_fill(L3);
  CD Cr[7][7][7] = {};
  double sre=0.0, sim=0.0;
  for(int a=0;a<n1;++a)for(int b=0;b<n2;++b)for(int c=0;c<n3;++c){
    CD acc{0.0,0.0};
    for(int u=0;u<n1;++u)for(int v=0;v<n2;++v){
      int w = (u-L1)+(v-L2)+L3;           // only m3=m1+m2 can be nonzero in Cc
      if (w < 0 || w >= n3) continue;
      double cc = Cc[u][v][w];
      if (cc == 0.0) continue;
      acc = cadd(acc, cscale(cmul(cmul(U1.u[a][u],U2.u[b][v]),conj_(U3.u[c][w])), cc));
    }
    Cr[a][b][c] = acc;
    sre += cfabs_(acc.re); sim += cfabs_(acc.im);
  }
  FT<L1,L2,L3> out{};
  bool useim = sim > sre;
  for(int a=0;a<n1;++a)for(int b=0;b<n2;++b)for(int c=0;c<n3;++c)
    out.v[(a*n2+b)*n3+c] = (float)(useim ? Cr[a][b][c].im : Cr[a][b][c].re);
  return out;
}

constexpr auto CG000 = cg_real_ct<0,0,0>();
constexpr auto CG110 = cg_real_ct<1,1,0>();
constexpr auto CG220 = cg_real_ct<2,2,0>();
constexpr auto CG330 = cg_real_ct<3,3,0>();
constexpr auto CG011 = cg_real_ct<0,1,1>();
constexpr auto CG101 = cg_real_ct<1,0,1>();
constexpr auto CG111 = cg_real_ct<1,1,1>();
constexpr auto CG121 = cg_real_ct<1,2,1>();
constexpr auto CG211 = cg_real_ct<2,1,1>();
constexpr auto CG221 = cg_real_ct<2,2,1>();
constexpr auto CG231 = cg_real_ct<2,3,1>();
constexpr auto CG321 = cg_real_ct<3,2,1>();
constexpr auto CG331 = cg_real_ct<3,3,1>();

// zero-pruned FMA term: coefficient folds to a literal; zero terms are deleted.
#define TERM(TBL, IDX, PROD, ACC) { float c_ = TBL.v[IDX]; if (c_ != 0.0f) ACC = fmaf((PROD), c_, ACC); }

// ---------------- device helpers ----------------
__device__ __forceinline__ float soh(float r, float c){
  float d = (r - c) * 2.0f;
  float d2 = d*d;
  return (d2 < 1.0f) ? 1.14136f * expf(2.0f + 1.0f/(d2-1.0f)) : 0.0f;
}

__device__ __forceinline__ float bf_lo(unsigned u){ return __uint_as_float(u << 16); }
__device__ __forceinline__ float bf_hi(unsigned u){ return __uint_as_float(u & 0xFFFF0000u); }
__device__ __forceinline__ unsigned short bfpack(float v){
  unsigned b = __float_as_uint(v);
  return (unsigned short)((b + 0x7FFFu + ((b >> 16) & 1u)) >> 16);   // RTNE
}
__device__ __forceinline__ void unp8(uint4 u, float* o){
  o[0]=bf_lo(u.x); o[1]=bf_hi(u.x); o[2]=bf_lo(u.y); o[3]=bf_hi(u.y);
  o[4]=bf_lo(u.z); o[5]=bf_hi(u.z); o[6]=bf_lo(u.w); o[7]=bf_hi(u.w);
}

// Per-lane weight schedule: lane ℓ, sub-index q (0..7) -> (column in [0,272) or -1, LDS slot).
// Slot 31 is a guaranteed-zero slot.
__device__ __forceinline__ void lane_sched(int lane, int q, int& col, int& slot){
  col = -1; slot = 31;
  if (lane < 16){
    int s = q >> 2, qq = q & 3;
    int a = 2*lane + s;                 // scalar output index 0..31
    const int base0[4] = {0, 64, 144, 224};
    col = base0[qq] + a; slot = qq;
  } else if (lane < 40){
    int idx = lane-16, u = idx/3, k = idx-3*u;
    const int wb[6] = {32,48,112,128,192,208};
    const int sb[6] = {4,7,10,13,16,19};
    if (q < 6){ col = wb[q]+u; slot = sb[q]+k; }
  } else if (lane < 52){
    int m = lane-40;
    int c0 = (q < 4) ? 2*m : 2*m+1;
    int u = c0/3, k = c0-3*u;
    int qq = (q < 4) ? q : q-4;
    if (qq < 3){
      const int wb[3] = {96,176,256};
      const int sb[3] = {22,25,28};
      col = wb[qq]+u; slot = sb[qq]+k;
    }
  }
}

// ---------------- radial MLP tables: tab1[T_TAB][272] fp32, tab2b[T_TAB][64] bf16 ---
__global__ __launch_bounds__(256) void k_table(
    const float* __restrict__ W1, const float* __restrict__ W2,
    const float* __restrict__ W1f, const float* __restrict__ W2f,
    float* __restrict__ tab1, unsigned short* __restrict__ tab2b)
{
  const int bid = blockIdx.x;                 // 84*6 = 504
  const int jq  = bid / 6;                    // 0..83
  const int t   = (bid % 6)*256 + threadIdx.x;
  const int j0  = jq*4;
  const float dr = 2.5f / (float)(T_TAB-1);
  const float r = (float)t * dr;
  const float e0 = soh(r,1.0f), e1 = soh(r,1.5f), e2 = soh(r,2.0f);
  float ax=0.f, ay=0.f, az=0.f, aw=0.f;
  if (j0 < 272){
    for (int cc=0; cc<256; ++cc){
      float h = fmaxf(fmaf(e0,W1[cc], fmaf(e1,W1[256+cc], e2*W1[512+cc])), 0.0f);
      float4 w = *(const float4*)(W2 + cc*272 + j0);
      ax = fmaf(h,w.x,ax); ay = fmaf(h,w.y,ay);
      az = fmaf(h,w.z,az); aw = fmaf(h,w.w,aw);
    }
    *(float4*)(tab1 + (size_t)t*272 + j0) = make_float4(ax*0.0625f, ay*0.0625f, az*0.0625f, aw*0.0625f);
  } else {
    const int jj = j0 - 272;
    for (int cc=0; cc<256; ++cc){
      float h = fmaxf(fmaf(e0,W1f[cc], fmaf(e1,W1f[256+cc], e2*W1f[512+cc])), 0.0f);
      float4 w = *(const float4*)(W2f + cc*64 + jj);
      ax = fmaf(h,w.x,ax); ay = fmaf(h,w.y,ay);
      az = fmaf(h,w.z,az); aw = fmaf(h,w.w,aw);
    }
    ushort4 o;
    o.x = bfpack(ax*0.0625f); o.y = bfpack(ay*0.0625f);
    o.z = bfpack(az*0.0625f); o.w = bfpack(aw*0.0625f);
    *(ushort4*)(tab2b + (size_t)t*64 + jj) = o;
  }
}

// ---------------- per-lane packed table (bf16): tabP[T_TAB][512] ushort -------------
__global__ __launch_bounds__(256) void k_perm(
    const float* __restrict__ tab1, unsigned short* __restrict__ tabP)
{
  const int gid = blockIdx.x*256 + threadIdx.x;     // [0, T_TAB*512)
  const int t = gid >> 9, p = gid & 511;
  int col, slot;
  lane_sched(p>>3, p&7, col, slot);
  float v = (col >= 0) ? tab1[(size_t)t*272 + col] : 0.0f;
  tabP[gid] = bfpack(v);
}

// ---------------- rowptr: dst is globally non-decreasing -> CSR via binary search ----
__global__ __launch_bounds__(256) void k_rowptr(
    const int* __restrict__ dst, int E, int* __restrict__ rowptr)
{
  const int n = blockIdx.x*256 + threadIdx.x;
  if (n > NN) return;
  int lo=0, hi=E;
  while (lo < hi){ int mid=(lo+hi)>>1; if (dst[mid] < n) lo=mid+1; else hi=mid; }
  rowptr[n]=lo;
}

// ---------------- x = segsum(sph_harm): 4 lanes/node, each edge touched once -------
__global__ __launch_bounds__(256) void k_x(
    const float* __restrict__ pos, const int* __restrict__ src,
    const int* __restrict__ rowptr, float* __restrict__ xacc)
{
  const int t = blockIdx.x*256 + threadIdx.x;
  const int n = t>>2, q = t&3;
  if (n>=NN) return;
  const int r0=rowptr[n], r1=rowptr[n+1];
  const float pdx=pos[3*n], pdy=pos[3*n+1], pdz=pos[3*n+2];
  const float s3=1.73205081f, s5=2.23606798f, s15=3.87298335f;
  const float c33=2.09165007f, c32=10.2469508f, c31=1.62018517f, c30=1.32287566f, cp2=5.12347538f;
  float a0=0,a1=0,a2=0,a3=0,a4=0,a5=0,a6=0,a7=0,a8=0,a9=0,a10=0,a11=0,a12=0,a13=0,a14=0,a15=0;
  for (int e=r0+q; e<r1; e+=4){
    const int s=src[e];
    float ax=pos[3*s]-pdx, ay=pos[3*s+1]-pdy, az=pos[3*s+2]-pdz;
    float ir = 1.0f/sqrtf(ax*ax+ay*ay+az*az);
    float x=ax*ir, y=ay*ir, z=az*ir;
    a0+=1.0f; a1+=s3*y; a2+=s3*z; a3+=s3*x;
    a4+=s15*x*y; a5+=s15*y*z; a6+=0.5f*s5*(3.0f*z*z-1.0f); a7+=s15*x*z;
    a8+=0.5f*s15*(x*x-y*y); a9+=c33*y*(3.0f*x*x-y*y); a10+=c32*x*y*z; a11+=c31*y*(5.0f*z*z-1.0f);
    a12+=c30*(5.0f*z*z*z-3.0f*z); a13+=c31*x*(5.0f*z*z-1.0f); a14+=cp2*z*(x*x-y*y);
    a15+=c33*x*(x*x-3.0f*y*y);
  }
#define RED(v) v += __shfl_xor(v,1); v += __shfl_xor(v,2);
  RED(a0) RED(a1) RED(a2) RED(a3) RED(a4) RED(a5) RED(a6) RED(a7)
  RED(a8) RED(a9) RED(a10) RED(a11) RED(a12) RED(a13) RED(a14) RED(a15)
#undef RED
  float o0,o1,o2,o3;
  if (q==0){ o0=a0; o1=a1; o2=a2; o3=a3; }
  else if (q==1){ o0=a4; o1=a5; o2=a6; o3=a7; }
  else if (q==2){ o0=a8; o1=a9; o2=a10; o3=a11; }
  else { o0=a12; o1=a13; o2=a14; o3=a15; }
  *(float4*)(xacc + (size_t)n*16 + q*4) = make_float4(o0,o1,o2,o3);
}

// ---------------- fctp1 + gate fused: ONE WAVE covers FOUR nodes --------------
// lane = (g = lane>>4, je = lane&15). Phase 1: 16-lane group g computes CG for node
// nb+g's <=16-edge chunk (single code path; fixes the 19% phase-1 lane utilization of
// the 1-node/wave version). Phase 2: all 64 lanes accumulate each node in turn
// (per-node accumulators, fully unrolled). Barriers are intra-wave (1 wave/block).
__global__ __launch_bounds__(64) void k_tp1(
    const float* __restrict__ pos, const int* __restrict__ src,
    const int* __restrict__ rowptr, const float* __restrict__ xacc,
    const unsigned short* __restrict__ tabP, float* __restrict__ xg)
{
  const int lane = threadIdx.x;
  const int nb   = blockIdx.x*NG;
  const int g    = lane >> 4, je = lane & 15;
  __shared__ float SI[NG][CH2][33];   // 0..30 intermediates, 31 zero, 32 al
  __shared__ int   SiT[NG][CH2];
  __shared__ float SG[NG][32];

  int rp[NG+1];
#pragma unroll
  for (int q=0;q<=NG;++q) rp[q] = rowptr[nb+q];
  int deg[NG];
#pragma unroll
  for (int q=0;q<NG;++q) deg[q] = rp[q+1]-rp[q];
  const int dmax = max(max(deg[0],deg[1]), max(deg[2],deg[3]));
  const int nch = (dmax + CH2 - 1) / CH2;

  // ---- static LDS-slot schedule + gate indices ----
  int ioS[8];
#pragma unroll
  for (int p=0;p<8;++p){ int c_, s_; lane_sched(lane, p, c_, s_); ioS[p] = s_; }
  int gu0=16, gu1=16;
  if (lane >= 16 && lane < 40){ gu0 = 16 + (lane-16)/3; }
  else if (lane >= 40 && lane < 52){
    int m=lane-40; gu0 = 24 + (2*m)/3; gu1 = 24 + (2*m+1)/3;
  }

  const int mynode = nb + g;
  const float pdx=pos[3*mynode], pdy=pos[3*mynode+1], pdz=pos[3*mynode+2];
  float acc0[NG]={0,0,0,0}, acc1[NG]={0,0,0,0};

  for (int t=0; t<nch; ++t){
    __syncthreads();                 // WAR: prev chunk phase-2 reads done
    const int cg_ = deg[g] - t*CH2;  // my group's remaining edges
    if (je < cg_){
      const int e = rp[g] + t*CH2 + je;
      const int s = src[e];
      float ax=pos[3*s]-pdx, ay=pos[3*s+1]-pdy, az=pos[3*s+2]-pdz;
      float r = sqrtf(ax*ax+ay*ay+az*az);
      float ir = 1.0f/r;
      float x=ax*ir, y=ay*ir, z=az*ir;
      float f = r * 614.0f;                     // (T_TAB-1)/2.5
      int i0 = (int)f; if (i0 > T_TAB-2) i0 = T_TAB-2;
      float al = f - (float)i0;

      const float s3=1.73205081f, s5=2.23606798f, s15=3.87298335f;
      const float c33=2.09165007f, c32=10.2469508f, c31=1.62018517f, c30=1.32287566f, cp2=5.12347538f;
      float Y[16];
      Y[0]=1.0f;
      Y[1]=s3*y; Y[2]=s3*z; Y[3]=s3*x;
      Y[4]=s15*x*y; Y[5]=s15*y*z; Y[6]=0.5f*s5*(3.0f*z*z-1.0f); Y[7]=s15*x*z; Y[8]=0.5f*s15*(x*x-y*y);
      Y[9]=c33*y*(3.0f*x*x-y*y); Y[10]=c32*x*y*z; Y[11]=c31*y*(5.0f*z*z-1.0f);
      Y[12]=c30*(5.0f*z*z*z-3.0f*z); Y[13]=c31*x*(5.0f*z*z-1.0f); Y[14]=cp2*z*(x*x-y*y);
      Y[15]=c33*x*(x*x-3.0f*y*y);
      float X[16];
      {
        const float inv = 0.5129891760f;           // 1/sqrt(3.8)
        const float4* q4 = (const float4*)(xacc + (size_t)s*16);
        float4 a=q4[0],b=q4[1],cc4=q4[2],d4=q4[3];
        X[0]=a.x*inv;X[1]=a.y*inv;X[2]=a.z*inv;X[3]=a.w*inv;
        X[4]=b.x*inv;X[5]=b.y*inv;X[6]=b.z*inv;X[7]=b.w*inv;
        X[8]=cc4.x*inv;X[9]=cc4.y*inv;X[10]=cc4.z*inv;X[11]=cc4.w*inv;
        X[12]=d4.x*inv;X[13]=d4.y*inv;X[14]=d4.z*inv;X[15]=d4.w*inv;
      }
      float* SS = SI[g][je];

      // t-block (scalar outputs)
      {
        float t0v = CG000.v[0]*X[0]*Y[0];
        float t1v=0.f, t2v=0.f, t3v=0.f;
#pragma unroll
        for (int i=0;i<3;++i)
#pragma unroll
          for (int j=0;j<3;++j) TERM(CG110, i*3+j, X[1+i]*Y[1+j], t1v)
#pragma unroll
        for (int i=0;i<5;++i)
#pragma unroll
          for (int j=0;j<5;++j) TERM(CG220, i*5+j, X[4+i]*Y[4+j], t2v)
#pragma unroll
        for (int i=0;i<7;++i)
#pragma unroll
          for (int j=0;j<7;++j) TERM(CG330, i*7+j, X[9+i]*Y[9+j], t3v)
        SS[0]=t0v; SS[1]=t1v; SS[2]=t2v; SS[3]=t3v;
      }
      // vector outputs
      {
        float v01[3]={0,0,0}, v10[3]={0,0,0}, v11[3]={0,0,0}, v12[3]={0,0,0},
              v21[3]={0,0,0}, v22[3]={0,0,0}, v23[3]={0,0,0}, v32[3]={0,0,0}, v33[3]={0,0,0};
#pragma unroll
        for (int j=0;j<3;++j){ float tt=X[0]*Y[1+j];
#pragma unroll
          for (int k=0;k<3;++k) TERM(CG011, j*3+k, tt, v01[k]) }
#pragma unroll
        for (int i=0;i<3;++i){ float tt=X[1+i]*Y[0];
#pragma unroll
          for (int k=0;k<3;++k) TERM(CG101, i*3+k, tt, v10[k]) }
#pragma unroll
        for (int i=0;i<3;++i)
#pragma unroll
          for (int j=0;j<3;++j){ float tt=X[1+i]*Y[1+j];
#pragma unroll
            for (int k=0;k<3;++k) TERM(CG111, (i*3+j)*3+k, tt, v11[k]) }
#pragma unroll
        for (int i=0;i<3;++i)
#pragma unroll
          for (int j=0;j<5;++j){ float tt=X[1+i]*Y[4+j];
#pragma unroll
            for (int k=0;k<3;++k) TERM(CG121, (i*5+j)*3+k, tt, v12[k]) }
#pragma unroll
        for (int i=0;i<5;++i)
#pragma unroll
          for (int j=0;j<3;++j){ float tt=X[4+i]*Y[1+j];
#pragma unroll
            for (int k=0;k<3;++k) TERM(CG211, (i*3+j)*3+k, tt, v21[k]) }
#pragma unroll
        for (int i=0;i<5;++i)
#pragma unroll
          for (int j=0;j<5;++j){ float tt=X[4+i]*Y[4+j];
#pragma unroll
            for (int k=0;k<3;++k) TERM(CG221, (i*5+j)*3+k, tt, v22[k]) }
#pragma unroll
        for (int i=0;i<5;++i)
#pragma unroll
          for (int j=0;j<7;++j){ float tt=X[4+i]*Y[9+j];
#pragma unroll
            for (int k=0;k<3;++k) TERM(CG231, (i*7+j)*3+k, tt, v23[k]) }
#pragma unroll
        for (int i=0;i<7;++i)
#pragma unroll
          for (int j=0;j<5;++j){ float tt=X[9+i]*Y[4+j];
#pragma unroll
            for (int k=0;k<3;++k) TERM(CG321, (i*5+j)*3+k, tt, v32[k]) }
#pragma unroll
        for (int i=0;i<7;++i)
#pragma unroll
          for (int j=0;j<7;++j){ float tt=X[9+i]*Y[9+j];
#pragma unroll
            for (int k=0;k<3;++k) TERM(CG331, (i*7+j)*3+k, tt, v33[k]) }
#pragma unroll
        for (int k=0;k<3;++k){
          SS[4+k]=v01[k]; SS[7+k]=v10[k]; SS[10+k]=v12[k]; SS[13+k]=v21[k];
          SS[16+k]=v23[k]; SS[19+k]=v32[k]; SS[22+k]=v11[k]; SS[25+k]=v22[k]; SS[28+k]=v33[k];
        }
      }
      SS[31]=0.0f; SS[32]=al;
      SiT[g][je]=i0;
    }
    __syncthreads();                 // RAW: phase-1 SI/SiT visible
    // ---- phase 2: per-node accumulation, bf16 packed coalesced loads ----
#pragma unroll
    for (int q=0;q<NG;++q){
      const int cq = deg[q] - t*CH2;
#pragma unroll 4
      for (int j=0; j<CH2; ++j){
        if (j < cq){
          const float* __restrict__ I = SI[q][j];
          const float alj = I[32];
          const unsigned short* __restrict__ wp = tabP + ((size_t)SiT[q][j]*512) + 8*lane;
          uint4 ra = *(const uint4*)wp;          // row i0:   8 bf16
          uint4 rb = *(const uint4*)(wp + 512);  // row i0+1: 8 bf16
          float a8[8], b8[8];
          unp8(ra, a8); unp8(rb, b8);
          acc0[q] = fmaf(fmaf(alj, b8[0]-a8[0], a8[0]), I[ioS[0]], acc0[q]);
          acc0[q] = fmaf(fmaf(alj, b8[1]-a8[1], a8[1]), I[ioS[1]], acc0[q]);
          acc0[q] = fmaf(fmaf(alj, b8[2]-a8[2], a8[2]), I[ioS[2]], acc0[q]);
          acc0[q] = fmaf(fmaf(alj, b8[3]-a8[3], a8[3]), I[ioS[3]], acc0[q]);
          acc1[q] = fmaf(fmaf(alj, b8[4]-a8[4], a8[4]), I[ioS[4]], acc1[q]);
          acc1[q] = fmaf(fmaf(alj, b8[5]-a8[5], a8[5]), I[ioS[5]], acc1[q]);
          acc1[q] = fmaf(fmaf(alj, b8[6]-a8[6], a8[6]), I[ioS[6]], acc1[q]);
          acc1[q] = fmaf(fmaf(alj, b8[7]-a8[7], a8[7]), I[ioS[7]], acc1[q]);
        }
      }
    }
  }

  // ---- fused gate epilogue (per node) ----
  const float inv = 0.5129891760f;
  if (lane < 16){
#pragma unroll
    for (int q=0;q<NG;++q){
      SG[q][2*lane]   = acc0[q]*0.5f*inv;
      SG[q][2*lane+1] = acc1[q]*0.5f*inv;
    }
  }
  __syncthreads();
#pragma unroll
  for (int q=0;q<NG;++q){
    float* __restrict__ o = xg + (size_t)(nb+q)*64;
    if (lane < 16){
      o[lane] = fmaxf(SG[q][lane], 0.0f);                    // se
    } else if (lane < 40){
      int idx = lane-16;
      float vv = (acc0[q]+acc1[q])*0.4082482905f*inv;
      o[16+idx] = vv * fmaxf(SG[q][gu0], 0.0f);              // v1o (u<8)
    } else if (lane < 52){
      int m = lane-40;
      float vv0 = acc0[q]*0.5773502692f*inv;
      float vv1 = acc1[q]*0.5773502692f*inv;
      o[40+2*m]   = vv0 * fmaxf(SG[q][gu0], 0.0f);           // v1e (u<8)
      o[40+2*m+1] = vv1 * fmaxf(SG[q][gu1], 0.0f);
    }
  }
}

// ---------------- fctp2 per edge -> e2buf[E][4] (bf16 table, compile-time CG) ------
__global__ __launch_bounds__(256) void k_tp2(
    const float* __restrict__ pos, const int* __restrict__ src, const int* __restrict__ dst, int E,
    const float* __restrict__ xg, const unsigned short* __restrict__ tab2b,
    float* __restrict__ e2buf)
{
  const int e = blockIdx.x*256 + threadIdx.x;
  if (e>=E) return;
  const int s = src[e], d = dst[e];
  float ax=pos[3*s]-pos[3*d], ay=pos[3*s+1]-pos[3*d+1], az=pos[3*s+2]-pos[3*d+2];
  float r = sqrtf(ax*ax+ay*ay+az*az);
  float ir = 1.0f/r;
  float x=ax*ir, y=ay*ir, z=az*ir;
  float f = r * 614.0f;                        // (T_TAB-1)/2.5
  int i0 = (int)f; if (i0 > T_TAB-2) i0 = T_TAB-2;
  const float al = f - (float)i0;
  const unsigned short* __restrict__ w0 = tab2b + (size_t)i0*64;
  const unsigned short* __restrict__ w1 = w0 + 64;
  float wse[16], wA[8], wB[8], wC[8];
  {
    float a8[8], b8[8];
    unp8(*(const uint4*)(w0+0), a8); unp8(*(const uint4*)(w1+0), b8);
#pragma unroll
    for (int k=0;k<8;++k) wse[k]   = fmaf(al, b8[k]-a8[k], a8[k]);
    unp8(*(const uint4*)(w0+8), a8); unp8(*(const uint4*)(w1+8), b8);
#pragma unroll
    for (int k=0;k<8;++k) wse[8+k] = fmaf(al, b8[k]-a8[k], a8[k]);
    unp8(*(const uint4*)(w0+16), a8); unp8(*(const uint4*)(w1+16), b8);
#pragma unroll
    for (int k=0;k<8;++k) wA[k]    = fmaf(al, b8[k]-a8[k], a8[k]);
    unp8(*(const uint4*)(w0+32), a8); unp8(*(const uint4*)(w1+32), b8);
#pragma unroll
    for (int k=0;k<8;++k) wB[k]    = fmaf(al, b8[k]-a8[k], a8[k]);
    unp8(*(const uint4*)(w0+48), a8); unp8(*(const uint4*)(w1+48), b8);
#pragma unroll
    for (int k=0;k<8;++k) wC[k]    = fmaf(al, b8[k]-a8[k], a8[k]);
  }
  const float s3=1.73205081f, s5=2.23606798f, s15=3.87298335f;
  float Y[9];
  Y[0]=1.0f;
  Y[1]=s3*y; Y[2]=s3*z; Y[3]=s3*x;
  Y[4]=s15*x*y; Y[5]=s15*y*z; Y[6]=0.5f*s5*(3.0f*z*z-1.0f); Y[7]=s15*x*z; Y[8]=0.5f*s15*(x*x-y*y);
  const float* __restrict__ g = xg + (size_t)s*64;
  float se[16], vo[24], ve[24];
#pragma unroll
  for (int jj=0;jj<4;++jj){ float4 t=((const float4*)g)[jj];
    se[4*jj]=t.x; se[4*jj+1]=t.y; se[4*jj+2]=t.z; se[4*jj+3]=t.w; }
#pragma unroll
  for (int jj=0;jj<6;++jj){ float4 t=((const float4*)(g+16))[jj];
    vo[4*jj]=t.x; vo[4*jj+1]=t.y; vo[4*jj+2]=t.z; vo[4*jj+3]=t.w; }
#pragma unroll
  for (int jj=0;jj<6;++jj){ float4 t=((const float4*)(g+40))[jj];
    ve[4*jj]=t.x; ve[4*jj+1]=t.y; ve[4*jj+2]=t.z; ve[4*jj+3]=t.w; }

  float SA=0.0f;
#pragma unroll
  for (int u=0;u<16;++u) SA = fmaf(wse[u], se[u], SA);
  float AB[3]={0,0,0}, AC[3]={0,0,0}, AD[3]={0,0,0};
#pragma unroll
  for (int u=0;u<8;++u)
#pragma unroll
    for (int i=0;i<3;++i){
      AB[i]=fmaf(wA[u], vo[u*3+i], AB[i]);
      AC[i]=fmaf(wB[u], vo[u*3+i], AC[i]);
      AD[i]=fmaf(wC[u], ve[u*3+i], AD[i]);
    }
  float e2[3]={0,0,0};
#pragma unroll
  for (int j=0;j<3;++j){ float t=SA*Y[1+j];
#pragma unroll
    for (int k=0;k<3;++k) TERM(CG011, j*3+k, t, e2[k]) }
#pragma unroll
  for (int i=0;i<3;++i){ float t=AB[i]*Y[0];
#pragma unroll
    for (int k=0;k<3;++k) TERM(CG101, i*3+k, t, e2[k]) }
#pragma unroll
  for (int i=0;i<3;++i)
#pragma unroll
    for (int j=0;j<5;++j){ float t=AC[i]*Y[4+j];
#pragma unroll
      for (int k=0;k<3;++k) TERM(CG121, (i*5+j)*3+k, t, e2[k]) }
#pragma unroll
  for (int i=0;i<3;++i)
#pragma unroll
    for (int j=0;j<3;++j){ float t=AD[i]*Y[1+j];
#pragma unroll
      for (int k=0;k<3;++k) TERM(CG111, (i*3+j)*3+k, t, e2[k]) }

  *(float4*)(e2buf + (size_t)e*4) = make_float4(e2[0], e2[1], e2[2], 0.0f);
}

// ---------------- final gather ----------------
__global__ __launch_bounds__(256) void k_out(
    const float* __restrict__ e2buf, const int* __restrict__ rowptr,
    float* __restrict__ out)
{
  const int t = blockIdx.x*256 + threadIdx.x;
  const int n = t>>2, k = t&3;
  if (n>=NN) return;
  const int r0=rowptr[n], r1=rowptr[n+1];
  float a=0.f;
  for (int e=r0;e<r1;++e) a += e2buf[(size_t)e*4 + k];
  const float sc = 0.0641236437f;  // (1/sqrt(64)) * 1/sqrt(3.8)
  if (k<3) out[(size_t)n*3 + k] = a*sc;
}

// ---------------- host launcher ----------------
extern "C" void kernel_launch(void* const* d_in, const int* in_sizes, int n_in,
                              void* d_out, int out_size, void* d_ws, size_t ws_size,
                              hipStream_t stream)
{
  (void)n_in; (void)ws_size; (void)out_size;
  const float* pos = (const float*)d_in[0];
  const int*   src = (const int*)d_in[1];
  const int*   dst = (const int*)d_in[2];
  const float* W1  = (const float*)d_in[3];
  const float* W2  = (const float*)d_in[4];
  const float* W1f = (const float*)d_in[5];
  const float* W2f = (const float*)d_in[6];
  const int E = in_sizes[1];

  char* ws = (char*)d_ws;
  float* xacc  = (float*)ws;                     // NN*16
  float* xg    = xacc + (size_t)NN*16;           // NN*64
  float* tab1  = xg + (size_t)NN*64;             // T_TAB*272
  unsigned short* tab2b = (unsigned short*)(tab1 + (size_t)T_TAB*272);  // T_TAB*64 ushort
  unsigned short* tabP  = tab2b + (size_t)T_TAB*64;                     // T_TAB*512 ushort
  float* e2buf = (float*)(tabP + (size_t)T_TAB*512);                    // E*4
  int*   rowptr= (int*)(e2buf + (size_t)E*4);    // NN+1

  k_table<<<84*6, 256, 0, stream>>>(W1, W2, W1f, W2f, tab1, tab2b);
  k_perm<<<(T_TAB*512)/256, 256, 0, stream>>>(tab1, tabP);
  k_rowptr<<<(NN+1+255)/256, 256, 0, stream>>>(dst, E, rowptr);
  k_x<<<(NN*4)/256, 256, 0, stream>>>(pos, src, rowptr, xacc);
  k_tp1<<<NN/NG, 64, 0, stream>>>(pos, src, rowptr, xacc, tabP, xg);
  k_tp2<<<(E + 255) / 256, 256, 0, stream>>>(pos, src, dst, E, xg, tab2b, e2buf);
  k_out<<<(NN*4)/256, 256, 0, stream>>>(e2buf, rowptr, (float*)d_out);
}

// Round 15
// 99.266 us; speedup vs baseline: 2.7057x; 1.0954x over previous
//
#include <hip/hip_runtime.h>
#include <cmath>

#define T_TAB 1536
#define NN 16384
#define NG 4
#define CH2 16

// ================= compile-time CG tables (constexpr port of the reference) ========
struct CD { double re, im; };
constexpr CD cmul(CD a, CD b){ return {a.re*b.re - a.im*b.im, a.re*b.im + a.im*b.re}; }
constexpr CD cadd(CD a, CD b){ return {a.re+b.re, a.im+b.im}; }
constexpr CD conj_(CD a){ return {a.re, -a.im}; }
constexpr CD cscale(CD a, double s){ return {a.re*s, a.im*s}; }
constexpr double cfabs_(double x){ return x<0.0 ? -x : x; }
constexpr double csqrt_(double x){
  double g = x > 1.0 ? x : 1.0;
  for (int i=0;i<80;++i) g = 0.5*(g + x/g);
  return g;
}
constexpr double factd(int n){ double r=1.0; for(int i=2;i<=n;++i) r*=(double)i; return r; }

constexpr double cg_coef(int j1,int m1,int j2,int m2,int j3,int m3){
  double pref = csqrt_((2.0*j3+1.0)*factd(j3+j1-j2)*factd(j3-j1+j2)*factd(j1+j2-j3)/factd(j1+j2+j3+1));
  pref *= csqrt_(factd(j3+m3)*factd(j3-m3)*factd(j1-m1)*factd(j1+m1)*factd(j2-m2)*factd(j2+m2));
  double s=0.0;
  for(int k=0;k<=j1+j2-j3;++k){
    int a0=k,a1=j1+j2-j3-k,a2=j1-m1-k,a3=j2+m2-k,a4=j3-j2+m1+k,a5=j3-j1-m2+k;
    if(a0<0||a1<0||a2<0||a3<0||a4<0||a5<0) continue;
    double d=factd(a0)*factd(a1)*factd(a2)*factd(a3)*factd(a4)*factd(a5);
    s += ((k&1)?-1.0:1.0)/d;
  }
  return pref*s;
}

struct UMat { CD u[7][7]; };
constexpr UMat u_fill(int l){
  UMat M{};
  const double is2 = csqrt_(0.5);
  M.u[l][l] = CD{1.0, 0.0};
  for(int m=1;m<=l;++m){
    double sgn = (m&1)?-1.0:1.0;
    M.u[l+m][l+m] = CD{sgn*is2, 0.0};
    M.u[l+m][l-m] = CD{is2, 0.0};
    M.u[l-m][l-m] = CD{0.0, is2};
    M.u[l-m][l+m] = CD{0.0, -sgn*is2};
  }
  return M;
}

template<int L1,int L2,int L3>
struct FT { float v[(2*L1+1)*(2*L2+1)*(2*L3+1)]; };

template<int L1,int L2,int L3>
constexpr FT<L1,L2,L3> cg_real_ct(){
  constexpr int n1=2*L1+1, n2=2*L2+1, n3=2*L3+1;
  double Cc[7][7][7] = {};
  for(int m1=-L1;m1<=L1;++m1)
    for(int m2=-L2;m2<=L2;++m2){
      int m3=m1+m2;
      if(m3>=-L3&&m3<=L3) Cc[m1+L1][m2+L2][m3+L3]=cg_coef(L1,m1,L2,m2,L3,m3);
    }
  UMat U1 = u_fill(L1), U2 = u_fill(L2), U3 = u_fill(L3);
  CD Cr[7][7][7] = {};
  double sre=0.0, sim=0.0;
  for(int a=0;a<n1;++a)for(int b=0;b<n2;++b)for(int c=0;c<n3;++c){
    CD acc{0.0,0.0};
    for(int u=0;u<n1;++u)for(int v=0;v<n2;++v){
      int w = (u-L1)+(v-L2)+L3;           // only m3=m1+m2 can be nonzero in Cc
      if (w < 0 || w >= n3) continue;
      double cc = Cc[u][v][w];
      if (cc == 0.0) continue;
      acc = cadd(acc, cscale(cmul(cmul(U1.u[a][u],U2.u[b][v]),conj_(U3.u[c][w])), cc));
    }
    Cr[a][b][c] = acc;
    sre += cfabs_(acc.re); sim += cfabs_(acc.im);
  }
  FT<L1,L2,L3> out{};
  bool useim = sim > sre;
  for(int a=0;a<n1;++a)for(int b=0;b<n2;++b)for(int c=0;c<n3;++c)
    out.v[(a*n2+b)*n3+c] = (float)(useim ? Cr[a][b][c].im : Cr[a][b][c].re);
  return out;
}

constexpr auto CG000 = cg_real_ct<0,0,0>();
constexpr auto CG110 = cg_real_ct<1,1,0>();
constexpr auto CG220 = cg_real_ct<2,2,0>();
constexpr auto CG330 = cg_real_ct<3,3,0>();
constexpr auto CG011 = cg_real_ct<0,1,1>();
constexpr auto CG101 = cg_real_ct<1,0,1>();
constexpr auto CG111 = cg_real_ct<1,1,1>();
constexpr auto CG121 = cg_real_ct<1,2,1>();
constexpr auto CG211 = cg_real_ct<2,1,1>();
constexpr auto CG221 = cg_real_ct<2,2,1>();
constexpr auto CG231 = cg_real_ct<2,3,1>();
constexpr auto CG321 = cg_real_ct<3,2,1>();
constexpr auto CG331 = cg_real_ct<3,3,1>();

// zero-pruned FMA term: coefficient folds to a literal; zero terms are deleted.
#define TERM(TBL, IDX, PROD, ACC) { float c_ = TBL.v[IDX]; if (c_ != 0.0f) ACC = fmaf((PROD), c_, ACC); }

// ---------------- device helpers ----------------
__device__ __forceinline__ void afadd(float* p, float v){ unsafeAtomicAdd(p, v); }

__device__ __forceinline__ float soh(float r, float c){
  float d = (r - c) * 2.0f;
  float d2 = d*d;
  return (d2 < 1.0f) ? 1.14136f * expf(2.0f + 1.0f/(d2-1.0f)) : 0.0f;
}

__device__ __forceinline__ float bf_lo(unsigned u){ return __uint_as_float(u << 16); }
__device__ __forceinline__ float bf_hi(unsigned u){ return __uint_as_float(u & 0xFFFF0000u); }
__device__ __forceinline__ unsigned short bfpack(float v){
  unsigned b = __float_as_uint(v);
  return (unsigned short)((b + 0x7FFFu + ((b >> 16) & 1u)) >> 16);   // RTNE
}
__device__ __forceinline__ void unp8(uint4 u, float* o){
  o[0]=bf_lo(u.x); o[1]=bf_hi(u.x); o[2]=bf_lo(u.y); o[3]=bf_hi(u.y);
  o[4]=bf_lo(u.z); o[5]=bf_hi(u.z); o[6]=bf_lo(u.w); o[7]=bf_hi(u.w);
}

// Per-lane weight schedule: lane ℓ, sub-index q (0..7) -> (column in [0,272) or -1, LDS slot).
// Slot 31 is a guaranteed-zero slot.
__device__ __forceinline__ void lane_sched(int lane, int q, int& col, int& slot){
  col = -1; slot = 31;
  if (lane < 16){
    int s = q >> 2, qq = q & 3;
    int a = 2*lane + s;                 // scalar output index 0..31
    const int base0[4] = {0, 64, 144, 224};
    col = base0[qq] + a; slot = qq;
  } else if (lane < 40){
    int idx = lane-16, u = idx/3, k = idx-3*u;
    const int wb[6] = {32,48,112,128,192,208};
    const int sb[6] = {4,7,10,13,16,19};
    if (q < 6){ col = wb[q]+u; slot = sb[q]+k; }
  } else if (lane < 52){
    int m = lane-40;
    int c0 = (q < 4) ? 2*m : 2*m+1;
    int u = c0/3, k = c0-3*u;
    int qq = (q < 4) ? q : q-4;
    if (qq < 3){
      const int wb[3] = {96,176,256};
      const int sb[3] = {22,25,28};
      col = wb[qq]+u; slot = sb[qq]+k;
    }
  }
}

// ---------------- radial MLP tables: tab1[T_TAB][272] fp32, tab2b[T_TAB][64] bf16 ---
__global__ __launch_bounds__(256) void k_table(
    const float* __restrict__ W1, const float* __restrict__ W2,
    const float* __restrict__ W1f, const float* __restrict__ W2f,
    float* __restrict__ tab1, unsigned short* __restrict__ tab2b)
{
  const int bid = blockIdx.x;                 // 84*6 = 504
  const int jq  = bid / 6;                    // 0..83
  const int t   = (bid % 6)*256 + threadIdx.x;
  const int j0  = jq*4;
  const float dr = 2.5f / (float)(T_TAB-1);
  const float r = (float)t * dr;
  const float e0 = soh(r,1.0f), e1 = soh(r,1.5f), e2 = soh(r,2.0f);
  float ax=0.f, ay=0.f, az=0.f, aw=0.f;
  if (j0 < 272){
    for (int cc=0; cc<256; ++cc){
      float h = fmaxf(fmaf(e0,W1[cc], fmaf(e1,W1[256+cc], e2*W1[512+cc])), 0.0f);
      float4 w = *(const float4*)(W2 + cc*272 + j0);
      ax = fmaf(h,w.x,ax); ay = fmaf(h,w.y,ay);
      az = fmaf(h,w.z,az); aw = fmaf(h,w.w,aw);
    }
    *(float4*)(tab1 + (size_t)t*272 + j0) = make_float4(ax*0.0625f, ay*0.0625f, az*0.0625f, aw*0.0625f);
  } else {
    const int jj = j0 - 272;
    for (int cc=0; cc<256; ++cc){
      float h = fmaxf(fmaf(e0,W1f[cc], fmaf(e1,W1f[256+cc], e2*W1f[512+cc])), 0.0f);
      float4 w = *(const float4*)(W2f + cc*64 + jj);
      ax = fmaf(h,w.x,ax); ay = fmaf(h,w.y,ay);
      az = fmaf(h,w.z,az); aw = fmaf(h,w.w,aw);
    }
    ushort4 o;
    o.x = bfpack(ax*0.0625f); o.y = bfpack(ay*0.0625f);
    o.z = bfpack(az*0.0625f); o.w = bfpack(aw*0.0625f);
    *(ushort4*)(tab2b + (size_t)t*64 + jj) = o;
  }
}

// ---------------- per-lane packed table (bf16): tabP[T_TAB][512] ushort -------------
__global__ __launch_bounds__(256) void k_perm(
    const float* __restrict__ tab1, unsigned short* __restrict__ tabP)
{
  const int gid = blockIdx.x*256 + threadIdx.x;     // [0, T_TAB*512)
  const int t = gid >> 9, p = gid & 511;
  int col, slot;
  lane_sched(p>>3, p&7, col, slot);
  float v = (col >= 0) ? tab1[(size_t)t*272 + col] : 0.0f;
  tabP[gid] = bfpack(v);
}

// ---------------- rowptr: dst is globally non-decreasing -> CSR via binary search ----
__global__ __launch_bounds__(256) void k_rowptr(
    const int* __restrict__ dst, int E, int* __restrict__ rowptr)
{
  const int n = blockIdx.x*256 + threadIdx.x;
  if (n > NN) return;
  int lo=0, hi=E;
  while (lo < hi){ int mid=(lo+hi)>>1; if (dst[mid] < n) lo=mid+1; else hi=mid; }
  rowptr[n]=lo;
}

// ---------------- x = segsum(sph_harm): 4 lanes/node, each edge touched once -------
__global__ __launch_bounds__(256) void k_x(
    const float* __restrict__ pos, const int* __restrict__ src,
    const int* __restrict__ rowptr, float* __restrict__ xacc)
{
  const int t = blockIdx.x*256 + threadIdx.x;
  const int n = t>>2, q = t&3;
  if (n>=NN) return;
  const int r0=rowptr[n], r1=rowptr[n+1];
  const float pdx=pos[3*n], pdy=pos[3*n+1], pdz=pos[3*n+2];
  const float s3=1.73205081f, s5=2.23606798f, s15=3.87298335f;
  const float c33=2.09165007f, c32=10.2469508f, c31=1.62018517f, c30=1.32287566f, cp2=5.12347538f;
  float a0=0,a1=0,a2=0,a3=0,a4=0,a5=0,a6=0,a7=0,a8=0,a9=0,a10=0,a11=0,a12=0,a13=0,a14=0,a15=0;
  for (int e=r0+q; e<r1; e+=4){
    const int s=src[e];
    float ax=pos[3*s]-pdx, ay=pos[3*s+1]-pdy, az=pos[3*s+2]-pdz;
    float ir = 1.0f/sqrtf(ax*ax+ay*ay+az*az);
    float x=ax*ir, y=ay*ir, z=az*ir;
    a0+=1.0f; a1+=s3*y; a2+=s3*z; a3+=s3*x;
    a4+=s15*x*y; a5+=s15*y*z; a6+=0.5f*s5*(3.0f*z*z-1.0f); a7+=s15*x*z;
    a8+=0.5f*s15*(x*x-y*y); a9+=c33*y*(3.0f*x*x-y*y); a10+=c32*x*y*z; a11+=c31*y*(5.0f*z*z-1.0f);
    a12+=c30*(5.0f*z*z*z-3.0f*z); a13+=c31*x*(5.0f*z*z-1.0f); a14+=cp2*z*(x*x-y*y);
    a15+=c33*x*(x*x-3.0f*y*y);
  }
#define RED(v) v += __shfl_xor(v,1); v += __shfl_xor(v,2);
  RED(a0) RED(a1) RED(a2) RED(a3) RED(a4) RED(a5) RED(a6) RED(a7)
  RED(a8) RED(a9) RED(a10) RED(a11) RED(a12) RED(a13) RED(a14) RED(a15)
#undef RED
  float o0,o1,o2,o3;
  if (q==0){ o0=a0; o1=a1; o2=a2; o3=a3; }
  else if (q==1){ o0=a4; o1=a5; o2=a6; o3=a7; }
  else if (q==2){ o0=a8; o1=a9; o2=a10; o3=a11; }
  else { o0=a12; o1=a13; o2=a14; o3=a15; }
  *(float4*)(xacc + (size_t)n*16 + q*4) = make_float4(o0,o1,o2,o3);
}

// ---------------- fctp1 + gate fused: ONE WAVE covers FOUR nodes --------------
// lane = (g = lane>>4, je = lane&15). Phase 1: 16-lane group g computes CG for node
// nb+g's <=16-edge chunk. Phase 2: all 64 lanes accumulate each node in turn.
// Epilogue writes bf16 xg (2.1 MB total -> L2-resident for k_tp2's random reads).
__global__ __launch_bounds__(64) void k_tp1(
    const float* __restrict__ pos, const int* __restrict__ src,
    const int* __restrict__ rowptr, const float* __restrict__ xacc,
    const unsigned short* __restrict__ tabP, unsigned short* __restrict__ xgb)
{
  const int lane = threadIdx.x;
  const int nb   = blockIdx.x*NG;
  const int g    = lane >> 4, je = lane & 15;
  __shared__ float SI[NG][CH2][33];   // 0..30 intermediates, 31 zero, 32 al
  __shared__ int   SiT[NG][CH2];
  __shared__ float SG[NG][32];

  int rp[NG+1];
#pragma unroll
  for (int q=0;q<=NG;++q) rp[q] = rowptr[nb+q];
  int deg[NG];
#pragma unroll
  for (int q=0;q<NG;++q) deg[q] = rp[q+1]-rp[q];
  const int dmax = max(max(deg[0],deg[1]), max(deg[2],deg[3]));
  const int nch = (dmax + CH2 - 1) / CH2;

  // ---- static LDS-slot schedule + gate indices ----
  int ioS[8];
#pragma unroll
  for (int p=0;p<8;++p){ int c_, s_; lane_sched(lane, p, c_, s_); ioS[p] = s_; }
  int gu0=16, gu1=16;
  if (lane >= 16 && lane < 40){ gu0 = 16 + (lane-16)/3; }
  else if (lane >= 40 && lane < 52){
    int m=lane-40; gu0 = 24 + (2*m)/3; gu1 = 24 + (2*m+1)/3;
  }

  const int mynode = nb + g;
  const float pdx=pos[3*mynode], pdy=pos[3*mynode+1], pdz=pos[3*mynode+2];
  float acc0[NG]={0,0,0,0}, acc1[NG]={0,0,0,0};

  for (int t=0; t<nch; ++t){
    __syncthreads();                 // WAR: prev chunk phase-2 reads done
    const int cg_ = deg[g] - t*CH2;  // my group's remaining edges
    if (je < cg_){
      const int e = rp[g] + t*CH2 + je;
      const int s = src[e];
      float ax=pos[3*s]-pdx, ay=pos[3*s+1]-pdy, az=pos[3*s+2]-pdz;
      float r = sqrtf(ax*ax+ay*ay+az*az);
      float ir = 1.0f/r;
      float x=ax*ir, y=ay*ir, z=az*ir;
      float f = r * 614.0f;                     // (T_TAB-1)/2.5
      int i0 = (int)f; if (i0 > T_TAB-2) i0 = T_TAB-2;
      float al = f - (float)i0;

      const float s3=1.73205081f, s5=2.23606798f, s15=3.87298335f;
      const float c33=2.09165007f, c32=10.2469508f, c31=1.62018517f, c30=1.32287566f, cp2=5.12347538f;
      float Y[16];
      Y[0]=1.0f;
      Y[1]=s3*y; Y[2]=s3*z; Y[3]=s3*x;
      Y[4]=s15*x*y; Y[5]=s15*y*z; Y[6]=0.5f*s5*(3.0f*z*z-1.0f); Y[7]=s15*x*z; Y[8]=0.5f*s15*(x*x-y*y);
      Y[9]=c33*y*(3.0f*x*x-y*y); Y[10]=c32*x*y*z; Y[11]=c31*y*(5.0f*z*z-1.0f);
      Y[12]=c30*(5.0f*z*z*z-3.0f*z); Y[13]=c31*x*(5.0f*z*z-1.0f); Y[14]=cp2*z*(x*x-y*y);
      Y[15]=c33*x*(x*x-3.0f*y*y);
      float X[16];
      {
        const float inv = 0.5129891760f;           // 1/sqrt(3.8)
        const float4* q4 = (const float4*)(xacc + (size_t)s*16);
        float4 a=q4[0],b=q4[1],cc4=q4[2],d4=q4[3];
        X[0]=a.x*inv;X[1]=a.y*inv;X[2]=a.z*inv;X[3]=a.w*inv;
        X[4]=b.x*inv;X[5]=b.y*inv;X[6]=b.z*inv;X[7]=b.w*inv;
        X[8]=cc4.x*inv;X[9]=cc4.y*inv;X[10]=cc4.z*inv;X[11]=cc4.w*inv;
        X[12]=d4.x*inv;X[13]=d4.y*inv;X[14]=d4.z*inv;X[15]=d4.w*inv;
      }
      float* SS = SI[g][je];

      // t-block (scalar outputs)
      {
        float t0v = CG000.v[0]*X[0]*Y[0];
        float t1v=0.f, t2v=0.f, t3v=0.f;
#pragma unroll
        for (int i=0;i<3;++i)
#pragma unroll
          for (int j=0;j<3;++j) TERM(CG110, i*3+j, X[1+i]*Y[1+j], t1v)
#pragma unroll
        for (int i=0;i<5;++i)
#pragma unroll
          for (int j=0;j<5;++j) TERM(CG220, i*5+j, X[4+i]*Y[4+j], t2v)
#pragma unroll
        for (int i=0;i<7;++i)
#pragma unroll
          for (int j=0;j<7;++j) TERM(CG330, i*7+j, X[9+i]*Y[9+j], t3v)
        SS[0]=t0v; SS[1]=t1v; SS[2]=t2v; SS[3]=t3v;
      }
      // vector outputs
      {
        float v01[3]={0,0,0}, v10[3]={0,0,0}, v11[3]={0,0,0}, v12[3]={0,0,0},
              v21[3]={0,0,0}, v22[3]={0,0,0}, v23[3]={0,0,0}, v32[3]={0,0,0}, v33[3]={0,0,0};
#pragma unroll
        for (int j=0;j<3;++j){ float tt=X[0]*Y[1+j];
#pragma unroll
          for (int k=0;k<3;++k) TERM(CG011, j*3+k, tt, v01[k]) }
#pragma unroll
        for (int i=0;i<3;++i){ float tt=X[1+i]*Y[0];
#pragma unroll
          for (int k=0;k<3;++k) TERM(CG101, i*3+k, tt, v10[k]) }
#pragma unroll
        for (int i=0;i<3;++i)
#pragma unroll
          for (int j=0;j<3;++j){ float tt=X[1+i]*Y[1+j];
#pragma unroll
            for (int k=0;k<3;++k) TERM(CG111, (i*3+j)*3+k, tt, v11[k]) }
#pragma unroll
        for (int i=0;i<3;++i)
#pragma unroll
          for (int j=0;j<5;++j){ float tt=X[1+i]*Y[4+j];
#pragma unroll
            for (int k=0;k<3;++k) TERM(CG121, (i*5+j)*3+k, tt, v12[k]) }
#pragma unroll
        for (int i=0;i<5;++i)
#pragma unroll
          for (int j=0;j<3;++j){ float tt=X[4+i]*Y[1+j];
#pragma unroll
            for (int k=0;k<3;++k) TERM(CG211, (i*3+j)*3+k, tt, v21[k]) }
#pragma unroll
        for (int i=0;i<5;++i)
#pragma unroll
          for (int j=0;j<5;++j){ float tt=X[4+i]*Y[4+j];
#pragma unroll
            for (int k=0;k<3;++k) TERM(CG221, (i*5+j)*3+k, tt, v22[k]) }
#pragma unroll
        for (int i=0;i<5;++i)
#pragma unroll
          for (int j=0;j<7;++j){ float tt=X[4+i]*Y[9+j];
#pragma unroll
            for (int k=0;k<3;++k) TERM(CG231, (i*7+j)*3+k, tt, v23[k]) }
#pragma unroll
        for (int i=0;i<7;++i)
#pragma unroll
          for (int j=0;j<5;++j){ float tt=X[9+i]*Y[4+j];
#pragma unroll
            for (int k=0;k<3;++k) TERM(CG321, (i*5+j)*3+k, tt, v32[k]) }
#pragma unroll
        for (int i=0;i<7;++i)
#pragma unroll
          for (int j=0;j<7;++j){ float tt=X[9+i]*Y[9+j];
#pragma unroll
            for (int k=0;k<3;++k) TERM(CG331, (i*7+j)*3+k, tt, v33[k]) }
#pragma unroll
        for (int k=0;k<3;++k){
          SS[4+k]=v01[k]; SS[7+k]=v10[k]; SS[10+k]=v12[k]; SS[13+k]=v21[k];
          SS[16+k]=v23[k]; SS[19+k]=v32[k]; SS[22+k]=v11[k]; SS[25+k]=v22[k]; SS[28+k]=v33[k];
        }
      }
      SS[31]=0.0f; SS[32]=al;
      SiT[g][je]=i0;
    }
    __syncthreads();                 // RAW: phase-1 SI/SiT visible
    // ---- phase 2: per-node accumulation, bf16 packed coalesced loads ----
#pragma unroll
    for (int q=0;q<NG;++q){
      const int cq = deg[q] - t*CH2;
#pragma unroll 4
      for (int j=0; j<CH2; ++j){
        if (j < cq){
          const float* __restrict__ I = SI[q][j];
          const float alj = I[32];
          const unsigned short* __restrict__ wp = tabP + ((size_t)SiT[q][j]*512) + 8*lane;
          uint4 ra = *(const uint4*)wp;          // row i0:   8 bf16
          uint4 rb = *(const uint4*)(wp + 512);  // row i0+1: 8 bf16
          float a8[8], b8[8];
          unp8(ra, a8); unp8(rb, b8);
          acc0[q] = fmaf(fmaf(alj, b8[0]-a8[0], a8[0]), I[ioS[0]], acc0[q]);
          acc0[q] = fmaf(fmaf(alj, b8[1]-a8[1], a8[1]), I[ioS[1]], acc0[q]);
          acc0[q] = fmaf(fmaf(alj, b8[2]-a8[2], a8[2]), I[ioS[2]], acc0[q]);
          acc0[q] = fmaf(fmaf(alj, b8[3]-a8[3], a8[3]), I[ioS[3]], acc0[q]);
          acc1[q] = fmaf(fmaf(alj, b8[4]-a8[4], a8[4]), I[ioS[4]], acc1[q]);
          acc1[q] = fmaf(fmaf(alj, b8[5]-a8[5], a8[5]), I[ioS[5]], acc1[q]);
          acc1[q] = fmaf(fmaf(alj, b8[6]-a8[6], a8[6]), I[ioS[6]], acc1[q]);
          acc1[q] = fmaf(fmaf(alj, b8[7]-a8[7], a8[7]), I[ioS[7]], acc1[q]);
        }
      }
    }
  }

  // ---- fused gate epilogue (per node), bf16 output ----
  const float inv = 0.5129891760f;
  if (lane < 16){
#pragma unroll
    for (int q=0;q<NG;++q){
      SG[q][2*lane]   = acc0[q]*0.5f*inv;
      SG[q][2*lane+1] = acc1[q]*0.5f*inv;
    }
  }
  __syncthreads();
#pragma unroll
  for (int q=0;q<NG;++q){
    unsigned short* __restrict__ o = xgb + (size_t)(nb+q)*64;
    if (lane < 16){
      o[lane] = bfpack(fmaxf(SG[q][lane], 0.0f));            // se
    } else if (lane < 40){
      int idx = lane-16;
      float vv = (acc0[q]+acc1[q])*0.4082482905f*inv;
      o[16+idx] = bfpack(vv * fmaxf(SG[q][gu0], 0.0f));      // v1o (u<8)
    } else if (lane < 52){
      int m = lane-40;
      float vv0 = acc0[q]*0.5773502692f*inv;
      float vv1 = acc1[q]*0.5773502692f*inv;
      o[40+2*m]   = bfpack(vv0 * fmaxf(SG[q][gu0], 0.0f));   // v1e (u<8)
      o[40+2*m+1] = bfpack(vv1 * fmaxf(SG[q][gu1], 0.0f));
    }
  }
}

// ---------------- fctp2 + fused dst-segmented reduction -> out ----------------
// Edges are dst-sorted; each 256-edge block reduces its dst-segments in LDS and
// issues 3 unsafeAtomicAdds per segment (~21/block) -- replaces e2buf + k_out.
__global__ __launch_bounds__(256) void k_tp2(
    const float* __restrict__ pos, const int* __restrict__ src, const int* __restrict__ dst, int E,
    const unsigned short* __restrict__ xgb, const unsigned short* __restrict__ tab2b,
    float* __restrict__ out)
{
  const int tid = threadIdx.x;
  const int e = blockIdx.x*256 + tid;
  __shared__ float S0[256], S1[256], S2[256];
  __shared__ int   D[256];
  float e2[3]={0,0,0};
  int dd = -1;
  if (e < E){
    const int s = src[e];
    dd = dst[e];
    float ax=pos[3*s]-pos[3*dd], ay=pos[3*s+1]-pos[3*dd+1], az=pos[3*s+2]-pos[3*dd+2];
    float r = sqrtf(ax*ax+ay*ay+az*az);
    float ir = 1.0f/r;
    float x=ax*ir, y=ay*ir, z=az*ir;
    float f = r * 614.0f;                      // (T_TAB-1)/2.5
    int i0 = (int)f; if (i0 > T_TAB-2) i0 = T_TAB-2;
    const float al = f - (float)i0;
    const unsigned short* __restrict__ w0 = tab2b + (size_t)i0*64;
    const unsigned short* __restrict__ w1 = w0 + 64;
    float wse[16], wA[8], wB[8], wC[8];
    {
      float a8[8], b8[8];
      unp8(*(const uint4*)(w0+0), a8); unp8(*(const uint4*)(w1+0), b8);
#pragma unroll
      for (int k=0;k<8;++k) wse[k]   = fmaf(al, b8[k]-a8[k], a8[k]);
      unp8(*(const uint4*)(w0+8), a8); unp8(*(const uint4*)(w1+8), b8);
#pragma unroll
      for (int k=0;k<8;++k) wse[8+k] = fmaf(al, b8[k]-a8[k], a8[k]);
      unp8(*(const uint4*)(w0+16), a8); unp8(*(const uint4*)(w1+16), b8);
#pragma unroll
      for (int k=0;k<8;++k) wA[k]    = fmaf(al, b8[k]-a8[k], a8[k]);
      unp8(*(const uint4*)(w0+32), a8); unp8(*(const uint4*)(w1+32), b8);
#pragma unroll
      for (int k=0;k<8;++k) wB[k]    = fmaf(al, b8[k]-a8[k], a8[k]);
      unp8(*(const uint4*)(w0+48), a8); unp8(*(const uint4*)(w1+48), b8);
#pragma unroll
      for (int k=0;k<8;++k) wC[k]    = fmaf(al, b8[k]-a8[k], a8[k]);
    }
    const float s3=1.73205081f, s5=2.23606798f, s15=3.87298335f;
    float Y[9];
    Y[0]=1.0f;
    Y[1]=s3*y; Y[2]=s3*z; Y[3]=s3*x;
    Y[4]=s15*x*y; Y[5]=s15*y*z; Y[6]=0.5f*s5*(3.0f*z*z-1.0f); Y[7]=s15*x*z; Y[8]=0.5f*s15*(x*x-y*y);
    const unsigned short* __restrict__ g = xgb + (size_t)s*64;
    float se[16], vo[24], ve[24];
    unp8(*(const uint4*)(g+0),  se);  unp8(*(const uint4*)(g+8),  se+8);
    unp8(*(const uint4*)(g+16), vo);  unp8(*(const uint4*)(g+24), vo+8); unp8(*(const uint4*)(g+32), vo+16);
    unp8(*(const uint4*)(g+40), ve);  unp8(*(const uint4*)(g+48), ve+8); unp8(*(const uint4*)(g+56), ve+16);

    float SA=0.0f;
#pragma unroll
    for (int u=0;u<16;++u) SA = fmaf(wse[u], se[u], SA);
    float AB[3]={0,0,0}, AC[3]={0,0,0}, AD[3]={0,0,0};
#pragma unroll
    for (int u=0;u<8;++u)
#pragma unroll
      for (int i=0;i<3;++i){
        AB[i]=fmaf(wA[u], vo[u*3+i], AB[i]);
        AC[i]=fmaf(wB[u], vo[u*3+i], AC[i]);
        AD[i]=fmaf(wC[u], ve[u*3+i], AD[i]);
      }
#pragma unroll
    for (int j=0;j<3;++j){ float t=SA*Y[1+j];
#pragma unroll
      for (int k=0;k<3;++k) TERM(CG011, j*3+k, t, e2[k]) }
#pragma unroll
    for (int i=0;i<3;++i){ float t=AB[i]*Y[0];
#pragma unroll
      for (int k=0;k<3;++k) TERM(CG101, i*3+k, t, e2[k]) }
#pragma unroll
    for (int i=0;i<3;++i)
#pragma unroll
      for (int j=0;j<5;++j){ float t=AC[i]*Y[4+j];
#pragma unroll
        for (int k=0;k<3;++k) TERM(CG121, (i*5+j)*3+k, t, e2[k]) }
#pragma unroll
    for (int i=0;i<3;++i)
#pragma unroll
      for (int j=0;j<3;++j){ float t=AD[i]*Y[1+j];
#pragma unroll
        for (int k=0;k<3;++k) TERM(CG111, (i*3+j)*3+k, t, e2[k]) }
  }
  S0[tid]=e2[0]; S1[tid]=e2[1]; S2[tid]=e2[2]; D[tid]=dd;
  __syncthreads();
  if (e < E && (tid==0 || D[tid-1] != dd)){
    float a0=0.f, a1=0.f, a2=0.f;
    int j = tid;
    while (j < 256 && D[j] == dd){ a0+=S0[j]; a1+=S1[j]; a2+=S2[j]; ++j; }
    const float sc = 0.0641236437f;  // (1/sqrt(64)) * 1/sqrt(3.8)
    afadd(out + (size_t)dd*3 + 0, a0*sc);
    afadd(out + (size_t)dd*3 + 1, a1*sc);
    afadd(out + (size_t)dd*3 + 2, a2*sc);
  }
}

// ---------------- host launcher ----------------
extern "C" void kernel_launch(void* const* d_in, const int* in_sizes, int n_in,
                              void* d_out, int out_size, void* d_ws, size_t ws_size,
                              hipStream_t stream)
{
  (void)n_in; (void)ws_size;
  const float* pos = (const float*)d_in[0];
  const int*   src = (const int*)d_in[1];
  const int*   dst = (const int*)d_in[2];
  const float* W1  = (const float*)d_in[3];
  const float* W2  = (const float*)d_in[4];
  const float* W1f = (const float*)d_in[5];
  const float* W2f = (const float*)d_in[6];
  const int E = in_sizes[1];

  char* ws = (char*)d_ws;
  float* xacc  = (float*)ws;                     // NN*16
  unsigned short* xgb = (unsigned short*)(xacc + (size_t)NN*16);        // NN*64 ushort
  float* tab1  = (float*)(xgb + (size_t)NN*64);  // T_TAB*272
  unsigned short* tab2b = (unsigned short*)(tab1 + (size_t)T_TAB*272);  // T_TAB*64 ushort
  unsigned short* tabP  = tab2b + (size_t)T_TAB*64;                     // T_TAB*512 ushort
  int*   rowptr= (int*)(tabP + (size_t)T_TAB*512);                      // NN+1

  hipMemsetAsync(d_out, 0, (size_t)out_size*sizeof(float), stream);

  k_table<<<84*6, 256, 0, stream>>>(W1, W2, W1f, W2f, tab1, tab2b);
  k_perm<<<(T_TAB*512)/256, 256, 0, stream>>>(tab1, tabP);
  k_rowptr<<<(NN+1+255)/256, 256, 0, stream>>>(dst, E, rowptr);
  k_x<<<(NN*4)/256, 256, 0, stream>>>(pos, src, rowptr, xacc);
  k_tp1<<<NN/NG, 64, 0, stream>>>(pos, src, rowptr, xacc, tabP, xgb);
  k_tp2<<<(E + 255) / 256, 256, 0, stream>>>(pos, src, dst, E, xgb, tab2b, (float*)d_out);
}

// Round 16
// 96.618 us; speedup vs baseline: 2.7798x; 1.0274x over previous
//
#include <hip/hip_runtime.h>
#include <cmath>

#define T_TAB 3072
#define NN 16384
#define NG 4
#define CH2 16

// ================= compile-time CG tables (constexpr port of the reference) ========
struct CD { double re, im; };
constexpr CD cmul(CD a, CD b){ return {a.re*b.re - a.im*b.im, a.re*b.im + a.im*b.re}; }
constexpr CD cadd(CD a, CD b){ return {a.re+b.re, a.im+b.im}; }
constexpr CD conj_(CD a){ return {a.re, -a.im}; }
constexpr CD cscale(CD a, double s){ return {a.re*s, a.im*s}; }
constexpr double cfabs_(double x){ return x<0.0 ? -x : x; }
constexpr double csqrt_(double x){
  double g = x > 1.0 ? x : 1.0;
  for (int i=0;i<80;++i) g = 0.5*(g + x/g);
  return g;
}
constexpr double factd(int n){ double r=1.0; for(int i=2;i<=n;++i) r*=(double)i; return r; }

constexpr double cg_coef(int j1,int m1,int j2,int m2,int j3,int m3){
  double pref = csqrt_((2.0*j3+1.0)*factd(j3+j1-j2)*factd(j3-j1+j2)*factd(j1+j2-j3)/factd(j1+j2+j3+1));
  pref *= csqrt_(factd(j3+m3)*factd(j3-m3)*factd(j1-m1)*factd(j1+m1)*factd(j2-m2)*factd(j2+m2));
  double s=0.0;
  for(int k=0;k<=j1+j2-j3;++k){
    int a0=k,a1=j1+j2-j3-k,a2=j1-m1-k,a3=j2+m2-k,a4=j3-j2+m1+k,a5=j3-j1-m2+k;
    if(a0<0||a1<0||a2<0||a3<0||a4<0||a5<0) continue;
    double d=factd(a0)*factd(a1)*factd(a2)*factd(a3)*factd(a4)*factd(a5);
    s += ((k&1)?-1.0:1.0)/d;
  }
  return pref*s;
}

struct UMat { CD u[7][7]; };
constexpr UMat u_fill(int l){
  UMat M{};
  const double is2 = csqrt_(0.5);
  M.u[l][l] = CD{1.0, 0.0};
  for(int m=1;m<=l;++m){
    double sgn = (m&1)?-1.0:1.0;
    M.u[l+m][l+m] = CD{sgn*is2, 0.0};
    M.u[l+m][l-m] = CD{is2, 0.0};
    M.u[l-m][l-m] = CD{0.0, is2};
    M.u[l-m][l+m] = CD{0.0, -sgn*is2};
  }
  return M;
}

template<int L1,int L2,int L3>
struct FT { float v[(2*L1+1)*(2*L2+1)*(2*L3+1)]; };

template<int L1,int L2,int L3>
constexpr FT<L1,L2,L3> cg_real_ct(){
  constexpr int n1=2*L1+1, n2=2*L2+1, n3=2*L3+1;
  double Cc[7][7][7] = {};
  for(int m1=-L1;m1<=L1;++m1)
    for(int m2=-L2;m2<=L2;++m2){
      int m3=m1+m2;
      if(m3>=-L3&&m3<=L3) Cc[m1+L1][m2+L2][m3+L3]=cg_coef(L1,m1,L2,m2,L3,m3);
    }
  UMat U1 = u_fill(L1), U2 = u_fill(L2), U3 = u_fill(L3);
  CD Cr[7][7][7] = {};
  double sre=0.0, sim=0.0;
  for(int a=0;a<n1;++a)for(int b=0;b<n2;++b)for(int c=0;c<n3;++c){
    CD acc{0.0,0.0};
    for(int u=0;u<n1;++u)for(int v=0;v<n2;++v){
      int w = (u-L1)+(v-L2)+L3;           // only m3=m1+m2 can be nonzero in Cc
      if (w < 0 || w >= n3) continue;
      double cc = Cc[u][v][w];
      if (cc == 0.0) continue;
      acc = cadd(acc, cscale(cmul(cmul(U1.u[a][u],U2.u[b][v]),conj_(U3.u[c][w])), cc));
    }
    Cr[a][b][c] = acc;
    sre += cfabs_(acc.re); sim += cfabs_(acc.im);
  }
  FT<L1,L2,L3> out{};
  bool useim = sim > sre;
  for(int a=0;a<n1;++a)for(int b=0;b<n2;++b)for(int c=0;c<n3;++c)
    out.v[(a*n2+b)*n3+c] = (float)(useim ? Cr[a][b][c].im : Cr[a][b][c].re);
  return out;
}

constexpr auto CG000 = cg_real_ct<0,0,0>();
constexpr auto CG110 = cg_real_ct<1,1,0>();
constexpr auto CG220 = cg_real_ct<2,2,0>();
constexpr auto CG330 = cg_real_ct<3,3,0>();
constexpr auto CG011 = cg_real_ct<0,1,1>();
constexpr auto CG101 = cg_real_ct<1,0,1>();
constexpr auto CG111 = cg_real_ct<1,1,1>();
constexpr auto CG121 = cg_real_ct<1,2,1>();
constexpr auto CG211 = cg_real_ct<2,1,1>();
constexpr auto CG221 = cg_real_ct<2,2,1>();
constexpr auto CG231 = cg_real_ct<2,3,1>();
constexpr auto CG321 = cg_real_ct<3,2,1>();
constexpr auto CG331 = cg_real_ct<3,3,1>();

// zero-pruned FMA term: coefficient folds to a literal; zero terms are deleted.
#define TERM(TBL, IDX, PROD, ACC) { float c_ = TBL.v[IDX]; if (c_ != 0.0f) ACC = fmaf((PROD), c_, ACC); }

// ---------------- device helpers ----------------
__device__ __forceinline__ void afadd(float* p, float v){ unsafeAtomicAdd(p, v); }

__device__ __forceinline__ float soh(float r, float c){
  float d = (r - c) * 2.0f;
  float d2 = d*d;
  return (d2 < 1.0f) ? 1.14136f * expf(2.0f + 1.0f/(d2-1.0f)) : 0.0f;
}

__device__ __forceinline__ float bf_lo(unsigned u){ return __uint_as_float(u << 16); }
__device__ __forceinline__ float bf_hi(unsigned u){ return __uint_as_float(u & 0xFFFF0000u); }
__device__ __forceinline__ unsigned short bfpack(float v){
  unsigned b = __float_as_uint(v);
  return (unsigned short)((b + 0x7FFFu + ((b >> 16) & 1u)) >> 16);   // RTNE
}
__device__ __forceinline__ void unp8(uint4 u, float* o){
  o[0]=bf_lo(u.x); o[1]=bf_hi(u.x); o[2]=bf_lo(u.y); o[3]=bf_hi(u.y);
  o[4]=bf_lo(u.z); o[5]=bf_hi(u.z); o[6]=bf_lo(u.w); o[7]=bf_hi(u.w);
}

// Per-lane weight schedule: lane ℓ, sub-index q (0..7) -> (column in [0,272) or -1, LDS slot).
// Slot 31 is a guaranteed-zero slot.
__device__ __forceinline__ void lane_sched(int lane, int q, int& col, int& slot){
  col = -1; slot = 31;
  if (lane < 16){
    int s = q >> 2, qq = q & 3;
    int a = 2*lane + s;                 // scalar output index 0..31
    const int base0[4] = {0, 64, 144, 224};
    col = base0[qq] + a; slot = qq;
  } else if (lane < 40){
    int idx = lane-16, u = idx/3, k = idx-3*u;
    const int wb[6] = {32,48,112,128,192,208};
    const int sb[6] = {4,7,10,13,16,19};
    if (q < 6){ col = wb[q]+u; slot = sb[q]+k; }
  } else if (lane < 52){
    int m = lane-40;
    int c0 = (q < 4) ? 2*m : 2*m+1;
    int u = c0/3, k = c0-3*u;
    int qq = (q < 4) ? q : q-4;
    if (qq < 3){
      const int wb[3] = {96,176,256};
      const int sb[3] = {22,25,28};
      col = wb[qq]+u; slot = sb[qq]+k;
    }
  }
}

// ---------------- radial MLP tables: tab1[T_TAB][272] fp32, tab2b[T_TAB][64] bf16 ---
__global__ __launch_bounds__(256) void k_table(
    const float* __restrict__ W1, const float* __restrict__ W2,
    const float* __restrict__ W1f, const float* __restrict__ W2f,
    float* __restrict__ tab1, unsigned short* __restrict__ tab2b)
{
  const int bid = blockIdx.x;                 // 84*12 = 1008
  const int jq  = bid / 12;                   // 0..83
  const int t   = (bid % 12)*256 + threadIdx.x;
  const int j0  = jq*4;
  const float dr = 2.5f / (float)(T_TAB-1);
  const float r = (float)t * dr;
  const float e0 = soh(r,1.0f), e1 = soh(r,1.5f), e2 = soh(r,2.0f);
  float ax=0.f, ay=0.f, az=0.f, aw=0.f;
  if (j0 < 272){
    for (int cc=0; cc<256; ++cc){
      float h = fmaxf(fmaf(e0,W1[cc], fmaf(e1,W1[256+cc], e2*W1[512+cc])), 0.0f);
      float4 w = *(const float4*)(W2 + cc*272 + j0);
      ax = fmaf(h,w.x,ax); ay = fmaf(h,w.y,ay);
      az = fmaf(h,w.z,az); aw = fmaf(h,w.w,aw);
    }
    *(float4*)(tab1 + (size_t)t*272 + j0) = make_float4(ax*0.0625f, ay*0.0625f, az*0.0625f, aw*0.0625f);
  } else {
    const int jj = j0 - 272;
    for (int cc=0; cc<256; ++cc){
      float h = fmaxf(fmaf(e0,W1f[cc], fmaf(e1,W1f[256+cc], e2*W1f[512+cc])), 0.0f);
      float4 w = *(const float4*)(W2f + cc*64 + jj);
      ax = fmaf(h,w.x,ax); ay = fmaf(h,w.y,ay);
      az = fmaf(h,w.z,az); aw = fmaf(h,w.w,aw);
    }
    ushort4 o;
    o.x = bfpack(ax*0.0625f); o.y = bfpack(ay*0.0625f);
    o.z = bfpack(az*0.0625f); o.w = bfpack(aw*0.0625f);
    *(ushort4*)(tab2b + (size_t)t*64 + jj) = o;
  }
}

// ---------------- per-lane packed table (bf16): tabP[T_TAB][512] ushort -------------
// Footprint 3072*512*2B = 3.15 MB < 4 MB per-XCD L2.
__global__ __launch_bounds__(256) void k_perm(
    const float* __restrict__ tab1, unsigned short* __restrict__ tabP)
{
  const int gid = blockIdx.x*256 + threadIdx.x;     // [0, T_TAB*512)
  const int t = gid >> 9, p = gid & 511;
  int col, slot;
  lane_sched(p>>3, p&7, col, slot);
  float v = (col >= 0) ? tab1[(size_t)t*272 + col] : 0.0f;
  tabP[gid] = bfpack(v);
}

// ---------------- rowptr: dst is globally non-decreasing -> CSR via binary search ----
__global__ __launch_bounds__(256) void k_rowptr(
    const int* __restrict__ dst, int E, int* __restrict__ rowptr)
{
  const int n = blockIdx.x*256 + threadIdx.x;
  if (n > NN) return;
  int lo=0, hi=E;
  while (lo < hi){ int mid=(lo+hi)>>1; if (dst[mid] < n) lo=mid+1; else hi=mid; }
  rowptr[n]=lo;
}

// ---------------- x = segsum(sph_harm): 4 lanes/node, each edge touched once -------
__global__ __launch_bounds__(256) void k_x(
    const float* __restrict__ pos, const int* __restrict__ src,
    const int* __restrict__ rowptr, float* __restrict__ xacc)
{
  const int t = blockIdx.x*256 + threadIdx.x;
  const int n = t>>2, q = t&3;
  if (n>=NN) return;
  const int r0=rowptr[n], r1=rowptr[n+1];
  const float pdx=pos[3*n], pdy=pos[3*n+1], pdz=pos[3*n+2];
  const float s3=1.73205081f, s5=2.23606798f, s15=3.87298335f;
  const float c33=2.09165007f, c32=10.2469508f, c31=1.62018517f, c30=1.32287566f, cp2=5.12347538f;
  float a0=0,a1=0,a2=0,a3=0,a4=0,a5=0,a6=0,a7=0,a8=0,a9=0,a10=0,a11=0,a12=0,a13=0,a14=0,a15=0;
  for (int e=r0+q; e<r1; e+=4){
    const int s=src[e];
    float ax=pos[3*s]-pdx, ay=pos[3*s+1]-pdy, az=pos[3*s+2]-pdz;
    float ir = 1.0f/sqrtf(ax*ax+ay*ay+az*az);
    float x=ax*ir, y=ay*ir, z=az*ir;
    a0+=1.0f; a1+=s3*y; a2+=s3*z; a3+=s3*x;
    a4+=s15*x*y; a5+=s15*y*z; a6+=0.5f*s5*(3.0f*z*z-1.0f); a7+=s15*x*z;
    a8+=0.5f*s15*(x*x-y*y); a9+=c33*y*(3.0f*x*x-y*y); a10+=c32*x*y*z; a11+=c31*y*(5.0f*z*z-1.0f);
    a12+=c30*(5.0f*z*z*z-3.0f*z); a13+=c31*x*(5.0f*z*z-1.0f); a14+=cp2*z*(x*x-y*y);
    a15+=c33*x*(x*x-3.0f*y*y);
  }
#define RED(v) v += __shfl_xor(v,1); v += __shfl_xor(v,2);
  RED(a0) RED(a1) RED(a2) RED(a3) RED(a4) RED(a5) RED(a6) RED(a7)
  RED(a8) RED(a9) RED(a10) RED(a11) RED(a12) RED(a13) RED(a14) RED(a15)
#undef RED
  float o0,o1,o2,o3;
  if (q==0){ o0=a0; o1=a1; o2=a2; o3=a3; }
  else if (q==1){ o0=a4; o1=a5; o2=a6; o3=a7; }
  else if (q==2){ o0=a8; o1=a9; o2=a10; o3=a11; }
  else { o0=a12; o1=a13; o2=a14; o3=a15; }
  *(float4*)(xacc + (size_t)n*16 + q*4) = make_float4(o0,o1,o2,o3);
}

// ---------------- fctp1 + gate fused: ONE WAVE covers FOUR nodes --------------
// lane = (g = lane>>4, je = lane&15). Phase 1: 16-lane group g computes CG for node
// nb+g's <=16-edge chunk. Phase 2: all 64 lanes accumulate each node in turn,
// NEAREST-NEIGHBOR table row (T=3072): ONE uint4 load + 8 FMA per edge per lane
// (bf16 quantization already dominates the error budget; lerp row-pair removed).
// Epilogue writes bf16 xg (2.1 MB total -> L2-resident for k_tp2's random reads).
__global__ __launch_bounds__(64) void k_tp1(
    const float* __restrict__ pos, const int* __restrict__ src,
    const int* __restrict__ rowptr, const float* __restrict__ xacc,
    const unsigned short* __restrict__ tabP, unsigned short* __restrict__ xgb)
{
  const int lane = threadIdx.x;
  const int nb   = blockIdx.x*NG;
  const int g    = lane >> 4, je = lane & 15;
  __shared__ float SI[NG][CH2][33];   // 0..30 intermediates, 31 zero
  __shared__ int   SiT[NG][CH2];
  __shared__ float SG[NG][32];

  int rp[NG+1];
#pragma unroll
  for (int q=0;q<=NG;++q) rp[q] = rowptr[nb+q];
  int deg[NG];
#pragma unroll
  for (int q=0;q<NG;++q) deg[q] = rp[q+1]-rp[q];
  const int dmax = max(max(deg[0],deg[1]), max(deg[2],deg[3]));
  const int nch = (dmax + CH2 - 1) / CH2;

  // ---- static LDS-slot schedule + gate indices ----
  int ioS[8];
#pragma unroll
  for (int p=0;p<8;++p){ int c_, s_; lane_sched(lane, p, c_, s_); ioS[p] = s_; }
  int gu0=16, gu1=16;
  if (lane >= 16 && lane < 40){ gu0 = 16 + (lane-16)/3; }
  else if (lane >= 40 && lane < 52){
    int m=lane-40; gu0 = 24 + (2*m)/3; gu1 = 24 + (2*m+1)/3;
  }

  const int mynode = nb + g;
  const float pdx=pos[3*mynode], pdy=pos[3*mynode+1], pdz=pos[3*mynode+2];
  float acc0[NG]={0,0,0,0}, acc1[NG]={0,0,0,0};

  for (int t=0; t<nch; ++t){
    __syncthreads();                 // WAR: prev chunk phase-2 reads done
    const int cg_ = deg[g] - t*CH2;  // my group's remaining edges
    if (je < cg_){
      const int e = rp[g] + t*CH2 + je;
      const int s = src[e];
      float ax=pos[3*s]-pdx, ay=pos[3*s+1]-pdy, az=pos[3*s+2]-pdz;
      float r = sqrtf(ax*ax+ay*ay+az*az);
      float ir = 1.0f/r;
      float x=ax*ir, y=ay*ir, z=az*ir;
      float f = r * 1228.4f;                    // (T_TAB-1)/2.5
      int i0 = (int)(f + 0.5f);                 // nearest row
      if (i0 > T_TAB-1) i0 = T_TAB-1;

      const float s3=1.73205081f, s5=2.23606798f, s15=3.87298335f;
      const float c33=2.09165007f, c32=10.2469508f, c31=1.62018517f, c30=1.32287566f, cp2=5.12347538f;
      float Y[16];
      Y[0]=1.0f;
      Y[1]=s3*y; Y[2]=s3*z; Y[3]=s3*x;
      Y[4]=s15*x*y; Y[5]=s15*y*z; Y[6]=0.5f*s5*(3.0f*z*z-1.0f); Y[7]=s15*x*z; Y[8]=0.5f*s15*(x*x-y*y);
      Y[9]=c33*y*(3.0f*x*x-y*y); Y[10]=c32*x*y*z; Y[11]=c31*y*(5.0f*z*z-1.0f);
      Y[12]=c30*(5.0f*z*z*z-3.0f*z); Y[13]=c31*x*(5.0f*z*z-1.0f); Y[14]=cp2*z*(x*x-y*y);
      Y[15]=c33*x*(x*x-3.0f*y*y);
      float X[16];
      {
        const float inv = 0.5129891760f;           // 1/sqrt(3.8)
        const float4* q4 = (const float4*)(xacc + (size_t)s*16);
        float4 a=q4[0],b=q4[1],cc4=q4[2],d4=q4[3];
        X[0]=a.x*inv;X[1]=a.y*inv;X[2]=a.z*inv;X[3]=a.w*inv;
        X[4]=b.x*inv;X[5]=b.y*inv;X[6]=b.z*inv;X[7]=b.w*inv;
        X[8]=cc4.x*inv;X[9]=cc4.y*inv;X[10]=cc4.z*inv;X[11]=cc4.w*inv;
        X[12]=d4.x*inv;X[13]=d4.y*inv;X[14]=d4.z*inv;X[15]=d4.w*inv;
      }
      float* SS = SI[g][je];

      // t-block (scalar outputs)
      {
        float t0v = CG000.v[0]*X[0]*Y[0];
        float t1v=0.f, t2v=0.f, t3v=0.f;
#pragma unroll
        for (int i=0;i<3;++i)
#pragma unroll
          for (int j=0;j<3;++j) TERM(CG110, i*3+j, X[1+i]*Y[1+j], t1v)
#pragma unroll
        for (int i=0;i<5;++i)
#pragma unroll
          for (int j=0;j<5;++j) TERM(CG220, i*5+j, X[4+i]*Y[4+j], t2v)
#pragma unroll
        for (int i=0;i<7;++i)
#pragma unroll
          for (int j=0;j<7;++j) TERM(CG330, i*7+j, X[9+i]*Y[9+j], t3v)
        SS[0]=t0v; SS[1]=t1v; SS[2]=t2v; SS[3]=t3v;
      }
      // vector outputs
      {
        float v01[3]={0,0,0}, v10[3]={0,0,0}, v11[3]={0,0,0}, v12[3]={0,0,0},
              v21[3]={0,0,0}, v22[3]={0,0,0}, v23[3]={0,0,0}, v32[3]={0,0,0}, v33[3]={0,0,0};
#pragma unroll
        for (int j=0;j<3;++j){ float tt=X[0]*Y[1+j];
#pragma unroll
          for (int k=0;k<3;++k) TERM(CG011, j*3+k, tt, v01[k]) }
#pragma unroll
        for (int i=0;i<3;++i){ float tt=X[1+i]*Y[0];
#pragma unroll
          for (int k=0;k<3;++k) TERM(CG101, i*3+k, tt, v10[k]) }
#pragma unroll
        for (int i=0;i<3;++i)
#pragma unroll
          for (int j=0;j<3;++j){ float tt=X[1+i]*Y[1+j];
#pragma unroll
            for (int k=0;k<3;++k) TERM(CG111, (i*3+j)*3+k, tt, v11[k]) }
#pragma unroll
        for (int i=0;i<3;++i)
#pragma unroll
          for (int j=0;j<5;++j){ float tt=X[1+i]*Y[4+j];
#pragma unroll
            for (int k=0;k<3;++k) TERM(CG121, (i*5+j)*3+k, tt, v12[k]) }
#pragma unroll
        for (int i=0;i<5;++i)
#pragma unroll
          for (int j=0;j<3;++j){ float tt=X[4+i]*Y[1+j];
#pragma unroll
            for (int k=0;k<3;++k) TERM(CG211, (i*3+j)*3+k, tt, v21[k]) }
#pragma unroll
        for (int i=0;i<5;++i)
#pragma unroll
          for (int j=0;j<5;++j){ float tt=X[4+i]*Y[4+j];
#pragma unroll
            for (int k=0;k<3;++k) TERM(CG221, (i*5+j)*3+k, tt, v22[k]) }
#pragma unroll
        for (int i=0;i<5;++i)
#pragma unroll
          for (int j=0;j<7;++j){ float tt=X[4+i]*Y[9+j];
#pragma unroll
            for (int k=0;k<3;++k) TERM(CG231, (i*7+j)*3+k, tt, v23[k]) }
#pragma unroll
        for (int i=0;i<7;++i)
#pragma unroll
          for (int j=0;j<5;++j){ float tt=X[9+i]*Y[4+j];
#pragma unroll
            for (int k=0;k<3;++k) TERM(CG321, (i*5+j)*3+k, tt, v32[k]) }
#pragma unroll
        for (int i=0;i<7;++i)
#pragma unroll
          for (int j=0;j<7;++j){ float tt=X[9+i]*Y[9+j];
#pragma unroll
            for (int k=0;k<3;++k) TERM(CG331, (i*7+j)*3+k, tt, v33[k]) }
#pragma unroll
        for (int k=0;k<3;++k){
          SS[4+k]=v01[k]; SS[7+k]=v10[k]; SS[10+k]=v12[k]; SS[13+k]=v21[k];
          SS[16+k]=v23[k]; SS[19+k]=v32[k]; SS[22+k]=v11[k]; SS[25+k]=v22[k]; SS[28+k]=v33[k];
        }
      }
      SS[31]=0.0f;
      SiT[g][je]=i0;
    }
    __syncthreads();                 // RAW: phase-1 SI/SiT visible
    // ---- phase 2: per-node accumulation, single nearest bf16 row ----
#pragma unroll
    for (int q=0;q<NG;++q){
      const int cq = deg[q] - t*CH2;
#pragma unroll 4
      for (int j=0; j<CH2; ++j){
        if (j < cq){
          const float* __restrict__ I = SI[q][j];
          const unsigned short* __restrict__ wp = tabP + ((size_t)SiT[q][j]*512) + 8*lane;
          uint4 ra = *(const uint4*)wp;          // 8 bf16 weights
          float a8[8];
          unp8(ra, a8);
          acc0[q] = fmaf(a8[0], I[ioS[0]], acc0[q]);
          acc0[q] = fmaf(a8[1], I[ioS[1]], acc0[q]);
          acc0[q] = fmaf(a8[2], I[ioS[2]], acc0[q]);
          acc0[q] = fmaf(a8[3], I[ioS[3]], acc0[q]);
          acc1[q] = fmaf(a8[4], I[ioS[4]], acc1[q]);
          acc1[q] = fmaf(a8[5], I[ioS[5]], acc1[q]);
          acc1[q] = fmaf(a8[6], I[ioS[6]], acc1[q]);
          acc1[q] = fmaf(a8[7], I[ioS[7]], acc1[q]);
        }
      }
    }
  }

  // ---- fused gate epilogue (per node), bf16 output ----
  const float inv = 0.5129891760f;
  if (lane < 16){
#pragma unroll
    for (int q=0;q<NG;++q){
      SG[q][2*lane]   = acc0[q]*0.5f*inv;
      SG[q][2*lane+1] = acc1[q]*0.5f*inv;
    }
  }
  __syncthreads();
#pragma unroll
  for (int q=0;q<NG;++q){
    unsigned short* __restrict__ o = xgb + (size_t)(nb+q)*64;
    if (lane < 16){
      o[lane] = bfpack(fmaxf(SG[q][lane], 0.0f));            // se
    } else if (lane < 40){
      int idx = lane-16;
      float vv = (acc0[q]+acc1[q])*0.4082482905f*inv;
      o[16+idx] = bfpack(vv * fmaxf(SG[q][gu0], 0.0f));      // v1o (u<8)
    } else if (lane < 52){
      int m = lane-40;
      float vv0 = acc0[q]*0.5773502692f*inv;
      float vv1 = acc1[q]*0.5773502692f*inv;
      o[40+2*m]   = bfpack(vv0 * fmaxf(SG[q][gu0], 0.0f));   // v1e (u<8)
      o[40+2*m+1] = bfpack(vv1 * fmaxf(SG[q][gu1], 0.0f));
    }
  }
}

// ---------------- fctp2 + fused dst-segmented reduction -> out ----------------
// Edges are dst-sorted; each 256-edge block reduces its dst-segments in LDS and
// issues 3 unsafeAtomicAdds per segment (~21/block). Nearest bf16 weight row.
__global__ __launch_bounds__(256) void k_tp2(
    const float* __restrict__ pos, const int* __restrict__ src, const int* __restrict__ dst, int E,
    const unsigned short* __restrict__ xgb, const unsigned short* __restrict__ tab2b,
    float* __restrict__ out)
{
  const int tid = threadIdx.x;
  const int e = blockIdx.x*256 + tid;
  __shared__ float S0[256], S1[256], S2[256];
  __shared__ int   D[256];
  float e2[3]={0,0,0};
  int dd = -1;
  if (e < E){
    const int s = src[e];
    dd = dst[e];
    float ax=pos[3*s]-pos[3*dd], ay=pos[3*s+1]-pos[3*dd+1], az=pos[3*s+2]-pos[3*dd+2];
    float r = sqrtf(ax*ax+ay*ay+az*az);
    float ir = 1.0f/r;
    float x=ax*ir, y=ay*ir, z=az*ir;
    float f = r * 1228.4f;                     // (T_TAB-1)/2.5
    int i0 = (int)(f + 0.5f);                  // nearest row
    if (i0 > T_TAB-1) i0 = T_TAB-1;
    const unsigned short* __restrict__ w0 = tab2b + (size_t)i0*64;
    float wse[16], wA[8], wB[8], wC[8];
    unp8(*(const uint4*)(w0+0),  wse);
    unp8(*(const uint4*)(w0+8),  wse+8);
    unp8(*(const uint4*)(w0+16), wA);
    unp8(*(const uint4*)(w0+32), wB);
    unp8(*(const uint4*)(w0+48), wC);
    const float s3=1.73205081f, s5=2.23606798f, s15=3.87298335f;
    float Y[9];
    Y[0]=1.0f;
    Y[1]=s3*y; Y[2]=s3*z; Y[3]=s3*x;
    Y[4]=s15*x*y; Y[5]=s15*y*z; Y[6]=0.5f*s5*(3.0f*z*z-1.0f); Y[7]=s15*x*z; Y[8]=0.5f*s15*(x*x-y*y);
    const unsigned short* __restrict__ g = xgb + (size_t)s*64;
    float se[16], vo[24], ve[24];
    unp8(*(const uint4*)(g+0),  se);  unp8(*(const uint4*)(g+8),  se+8);
    unp8(*(const uint4*)(g+16), vo);  unp8(*(const uint4*)(g+24), vo+8); unp8(*(const uint4*)(g+32), vo+16);
    unp8(*(const uint4*)(g+40), ve);  unp8(*(const uint4*)(g+48), ve+8); unp8(*(const uint4*)(g+56), ve+16);

    float SA=0.0f;
#pragma unroll
    for (int u=0;u<16;++u) SA = fmaf(wse[u], se[u], SA);
    float AB[3]={0,0,0}, AC[3]={0,0,0}, AD[3]={0,0,0};
#pragma unroll
    for (int u=0;u<8;++u)
#pragma unroll
      for (int i=0;i<3;++i){
        AB[i]=fmaf(wA[u], vo[u*3+i], AB[i]);
        AC[i]=fmaf(wB[u], vo[u*3+i], AC[i]);
        AD[i]=fmaf(wC[u], ve[u*3+i], AD[i]);
      }
#pragma unroll
    for (int j=0;j<3;++j){ float t=SA*Y[1+j];
#pragma unroll
      for (int k=0;k<3;++k) TERM(CG011, j*3+k, t, e2[k]) }
#pragma unroll
    for (int i=0;i<3;++i){ float t=AB[i]*Y[0];
#pragma unroll
      for (int k=0;k<3;++k) TERM(CG101, i*3+k, t, e2[k]) }
#pragma unroll
    for (int i=0;i<3;++i)
#pragma unroll
      for (int j=0;j<5;++j){ float t=AC[i]*Y[4+j];
#pragma unroll
        for (int k=0;k<3;++k) TERM(CG121, (i*5+j)*3+k, t, e2[k]) }
#pragma unroll
    for (int i=0;i<3;++i)
#pragma unroll
      for (int j=0;j<3;++j){ float t=AD[i]*Y[1+j];
#pragma unroll
        for (int k=0;k<3;++k) TERM(CG111, (i*3+j)*3+k, t, e2[k]) }
  }
  S0[tid]=e2[0]; S1[tid]=e2[1]; S2[tid]=e2[2]; D[tid]=dd;
  __syncthreads();
  if (e < E && (tid==0 || D[tid-1] != dd)){
    float a0=0.f, a1=0.f, a2=0.f;
    int j = tid;
    while (j < 256 && D[j] == dd){ a0+=S0[j]; a1+=S1[j]; a2+=S2[j]; ++j; }
    const float sc = 0.0641236437f;  // (1/sqrt(64)) * 1/sqrt(3.8)
    afadd(out + (size_t)dd*3 + 0, a0*sc);
    afadd(out + (size_t)dd*3 + 1, a1*sc);
    afadd(out + (size_t)dd*3 + 2, a2*sc);
  }
}

// ---------------- host launcher ----------------
extern "C" void kernel_launch(void* const* d_in, const int* in_sizes, int n_in,
                              void* d_out, int out_size, void* d_ws, size_t ws_size,
                              hipStream_t stream)
{
  (void)n_in; (void)ws_size;
  const float* pos = (const float*)d_in[0];
  const int*   src = (const int*)d_in[1];
  const int*   dst = (const int*)d_in[2];
  const float* W1  = (const float*)d_in[3];
  const float* W2  = (const float*)d_in[4];
  const float* W1f = (const float*)d_in[5];
  const float* W2f = (const float*)d_in[6];
  const int E = in_sizes[1];

  char* ws = (char*)d_ws;
  float* xacc  = (float*)ws;                     // NN*16
  unsigned short* xgb = (unsigned short*)(xacc + (size_t)NN*16);        // NN*64 ushort
  float* tab1  = (float*)(xgb + (size_t)NN*64);  // T_TAB*272
  unsigned short* tab2b = (unsigned short*)(tab1 + (size_t)T_TAB*272);  // T_TAB*64 ushort
  unsigned short* tabP  = tab2b + (size_t)T_TAB*64;                     // T_TAB*512 ushort
  int*   rowptr= (int*)(tabP + (size_t)T_TAB*512);                      // NN+1

  hipMemsetAsync(d_out, 0, (size_t)out_size*sizeof(float), stream);

  k_table<<<84*12, 256, 0, stream>>>(W1, W2, W1f, W2f, tab1, tab2b);
  k_perm<<<(T_TAB*512)/256, 256, 0, stream>>>(tab1, tabP);
  k_rowptr<<<(NN+1+255)/256, 256, 0, stream>>>(dst, E, rowptr);
  k_x<<<(NN*4)/256, 256, 0, stream>>>(pos, src, rowptr, xacc);
  k_tp1<<<NN/NG, 64, 0, stream>>>(pos, src, rowptr, xacc, tabP, xgb);
  k_tp2<<<(E + 255) / 256, 256, 0, stream>>>(pos, src, dst, E, xgb, tab2b, (float*)d_out);
}

// Round 17
// 91.756 us; speedup vs baseline: 2.9271x; 1.0530x over previous
//
#include <hip/hip_runtime.h>
#include <cmath>

#define T_TAB 3072
#define NN 16384
#define NG 4
#define CH2 16

// ================= compile-time CG tables (constexpr port of the reference) ========
struct CD { double re, im; };
constexpr CD cmul(CD a, CD b){ return {a.re*b.re - a.im*b.im, a.re*b.im + a.im*b.re}; }
constexpr CD cadd(CD a, CD b){ return {a.re+b.re, a.im+b.im}; }
constexpr CD conj_(CD a){ return {a.re, -a.im}; }
constexpr CD cscale(CD a, double s){ return {a.re*s, a.im*s}; }
constexpr double cfabs_(double x){ return x<0.0 ? -x : x; }
constexpr double csqrt_(double x){
  double g = x > 1.0 ? x : 1.0;
  for (int i=0;i<80;++i) g = 0.5*(g + x/g);
  return g;
}
constexpr double factd(int n){ double r=1.0; for(int i=2;i<=n;++i) r*=(double)i; return r; }

constexpr double cg_coef(int j1,int m1,int j2,int m2,int j3,int m3){
  double pref = csqrt_((2.0*j3+1.0)*factd(j3+j1-j2)*factd(j3-j1+j2)*factd(j1+j2-j3)/factd(j1+j2+j3+1));
  pref *= csqrt_(factd(j3+m3)*factd(j3-m3)*factd(j1-m1)*factd(j1+m1)*factd(j2-m2)*factd(j2+m2));
  double s=0.0;
  for(int k=0;k<=j1+j2-j3;++k){
    int a0=k,a1=j1+j2-j3-k,a2=j1-m1-k,a3=j2+m2-k,a4=j3-j2+m1+k,a5=j3-j1-m2+k;
    if(a0<0||a1<0||a2<0||a3<0||a4<0||a5<0) continue;
    double d=factd(a0)*factd(a1)*factd(a2)*factd(a3)*factd(a4)*factd(a5);
    s += ((k&1)?-1.0:1.0)/d;
  }
  return pref*s;
}

struct UMat { CD u[7][7]; };
constexpr UMat u_fill(int l){
  UMat M{};
  const double is2 = csqrt_(0.5);
  M.u[l][l] = CD{1.0, 0.0};
  for(int m=1;m<=l;++m){
    double sgn = (m&1)?-1.0:1.0;
    M.u[l+m][l+m] = CD{sgn*is2, 0.0};
    M.u[l+m][l-m] = CD{is2, 0.0};
    M.u[l-m][l-m] = CD{0.0, is2};
    M.u[l-m][l+m] = CD{0.0, -sgn*is2};
  }
  return M;
}

template<int L1,int L2,int L3>
struct FT { float v[(2*L1+1)*(2*L2+1)*(2*L3+1)]; };

template<int L1,int L2,int L3>
constexpr FT<L1,L2,L3> cg_real_ct(){
  constexpr int n1=2*L1+1, n2=2*L2+1, n3=2*L3+1;
  double Cc[7][7][7] = {};
  for(int m1=-L1;m1<=L1;++m1)
    for(int m2=-L2;m2<=L2;++m2){
      int m3=m1+m2;
      if(m3>=-L3&&m3<=L3) Cc[m1+L1][m2+L2][m3+L3]=cg_coef(L1,m1,L2,m2,L3,m3);
    }
  UMat U1 = u_fill(L1), U2 = u_fill(L2), U3 = u_fill(L3);
  CD Cr[7][7][7] = {};
  double sre=0.0, sim=0.0;
  for(int a=0;a<n1;++a)for(int b=0;b<n2;++b)for(int c=0;c<n3;++c){
    CD acc{0.0,0.0};
    for(int u=0;u<n1;++u)for(int v=0;v<n2;++v){
      int w = (u-L1)+(v-L2)+L3;           // only m3=m1+m2 can be nonzero in Cc
      if (w < 0 || w >= n3) continue;
      double cc = Cc[u][v][w];
      if (cc == 0.0) continue;
      acc = cadd(acc, cscale(cmul(cmul(U1.u[a][u],U2.u[b][v]),conj_(U3.u[c][w])), cc));
    }
    Cr[a][b][c] = acc;
    sre += cfabs_(acc.re); sim += cfabs_(acc.im);
  }
  FT<L1,L2,L3> out{};
  bool useim = sim > sre;
  for(int a=0;a<n1;++a)for(int b=0;b<n2;++b)for(int c=0;c<n3;++c)
    out.v[(a*n2+b)*n3+c] = (float)(useim ? Cr[a][b][c].im : Cr[a][b][c].re);
  return out;
}

constexpr auto CG000 = cg_real_ct<0,0,0>();
constexpr auto CG110 = cg_real_ct<1,1,0>();
constexpr auto CG220 = cg_real_ct<2,2,0>();
constexpr auto CG330 = cg_real_ct<3,3,0>();
constexpr auto CG011 = cg_real_ct<0,1,1>();
constexpr auto CG101 = cg_real_ct<1,0,1>();
constexpr auto CG111 = cg_real_ct<1,1,1>();
constexpr auto CG121 = cg_real_ct<1,2,1>();
constexpr auto CG211 = cg_real_ct<2,1,1>();
constexpr auto CG221 = cg_real_ct<2,2,1>();
constexpr auto CG231 = cg_real_ct<2,3,1>();
constexpr auto CG321 = cg_real_ct<3,2,1>();
constexpr auto CG331 = cg_real_ct<3,3,1>();

// zero-pruned FMA term: coefficient folds to a literal; zero terms are deleted.
#define TERM(TBL, IDX, PROD, ACC) { float c_ = TBL.v[IDX]; if (c_ != 0.0f) ACC = fmaf((PROD), c_, ACC); }

// ---------------- device helpers ----------------
__device__ __forceinline__ void afadd(float* p, float v){ unsafeAtomicAdd(p, v); }

__device__ __forceinline__ float soh(float r, float c){
  float d = (r - c) * 2.0f;
  float d2 = d*d;
  return (d2 < 1.0f) ? 1.14136f * expf(2.0f + 1.0f/(d2-1.0f)) : 0.0f;
}

__device__ __forceinline__ float bf_lo(unsigned u){ return __uint_as_float(u << 16); }
__device__ __forceinline__ float bf_hi(unsigned u){ return __uint_as_float(u & 0xFFFF0000u); }
__device__ __forceinline__ unsigned short bfpack(float v){
  unsigned b = __float_as_uint(v);
  return (unsigned short)((b + 0x7FFFu + ((b >> 16) & 1u)) >> 16);   // RTNE
}
__device__ __forceinline__ void unp8(uint4 u, float* o){
  o[0]=bf_lo(u.x); o[1]=bf_hi(u.x); o[2]=bf_lo(u.y); o[3]=bf_hi(u.y);
  o[4]=bf_lo(u.z); o[5]=bf_hi(u.z); o[6]=bf_lo(u.w); o[7]=bf_hi(u.w);
}

// Per-lane weight schedule: lane ℓ, sub-index q (0..7) -> (column in [0,272) or -1, LDS slot).
// Slot 31 is a guaranteed-zero slot.
__device__ __forceinline__ void lane_sched(int lane, int q, int& col, int& slot){
  col = -1; slot = 31;
  if (lane < 16){
    int s = q >> 2, qq = q & 3;
    int a = 2*lane + s;                 // scalar output index 0..31
    const int base0[4] = {0, 64, 144, 224};
    col = base0[qq] + a; slot = qq;
  } else if (lane < 40){
    int idx = lane-16, u = idx/3, k = idx-3*u;
    const int wb[6] = {32,48,112,128,192,208};
    const int sb[6] = {4,7,10,13,16,19};
    if (q < 6){ col = wb[q]+u; slot = sb[q]+k; }
  } else if (lane < 52){
    int m = lane-40;
    int c0 = (q < 4) ? 2*m : 2*m+1;
    int u = c0/3, k = c0-3*u;
    int qq = (q < 4) ? q : q-4;
    if (qq < 3){
      const int wb[3] = {96,176,256};
      const int sb[3] = {22,25,28};
      col = wb[qq]+u; slot = sb[qq]+k;
    }
  }
}

// ---------------- stage A (fused): radial tables + rowptr + out-zero ----------------
// blocks [0,252): table, 16 columns (4 j-quads) per block -> h computed ONCE per cc
//                 and applied to 16 FMAs (was recomputed per quad = ~half the VALU).
// blocks [252,317): rowptr binary search (dst is globally non-decreasing).
// blocks [317, ...): zero out[].
#define TBLK 252
#define RPB  65
__global__ __launch_bounds__(256) void k_stageA(
    const float* __restrict__ W1, const float* __restrict__ W2,
    const float* __restrict__ W1f, const float* __restrict__ W2f,
    float* __restrict__ tab1, unsigned short* __restrict__ tab2b,
    const int* __restrict__ dst, int E, int* __restrict__ rowptr,
    float* __restrict__ out, int outN)
{
  const int bid = blockIdx.x;
  if (bid < TBLK){
    const int grp = bid / 12;                 // 0..20
    const int t   = (bid % 12)*256 + threadIdx.x;
    const float dr = 2.5f / (float)(T_TAB-1);
    const float r = (float)t * dr;
    float acc[16];
#pragma unroll
    for (int k=0;k<16;++k) acc[k]=0.f;
    if (grp < 17){
      const int j0 = grp*16;
      const float e0 = soh(r,1.0f), e1 = soh(r,1.5f), e2 = soh(r,2.0f);
      for (int cc=0; cc<256; ++cc){
        float h = fmaxf(fmaf(e0,W1[cc], fmaf(e1,W1[256+cc], e2*W1[512+cc])), 0.0f);
        const float* __restrict__ wrow = W2 + cc*272 + j0;
#pragma unroll
        for (int k=0;k<16;k+=4){
          float4 w = *(const float4*)(wrow+k);
          acc[k]  =fmaf(h,w.x,acc[k]);   acc[k+1]=fmaf(h,w.y,acc[k+1]);
          acc[k+2]=fmaf(h,w.z,acc[k+2]); acc[k+3]=fmaf(h,w.w,acc[k+3]);
        }
      }
      float* __restrict__ o = tab1 + (size_t)t*272 + j0;
#pragma unroll
      for (int k=0;k<16;k+=4)
        *(float4*)(o+k) = make_float4(acc[k]*0.0625f, acc[k+1]*0.0625f,
                                      acc[k+2]*0.0625f, acc[k+3]*0.0625f);
    } else {
      const int j0 = (grp-17)*16;
      const float e0 = soh(r,1.0f), e1 = soh(r,1.5f), e2 = soh(r,2.0f);
      for (int cc=0; cc<256; ++cc){
        float h = fmaxf(fmaf(e0,W1f[cc], fmaf(e1,W1f[256+cc], e2*W1f[512+cc])), 0.0f);
        const float* __restrict__ wrow = W2f + cc*64 + j0;
#pragma unroll
        for (int k=0;k<16;k+=4){
          float4 w = *(const float4*)(wrow+k);
          acc[k]  =fmaf(h,w.x,acc[k]);   acc[k+1]=fmaf(h,w.y,acc[k+1]);
          acc[k+2]=fmaf(h,w.z,acc[k+2]); acc[k+3]=fmaf(h,w.w,acc[k+3]);
        }
      }
      unsigned short* __restrict__ o = tab2b + (size_t)t*64 + j0;
#pragma unroll
      for (int k=0;k<16;k+=4){
        ushort4 u;
        u.x = bfpack(acc[k]*0.0625f);   u.y = bfpack(acc[k+1]*0.0625f);
        u.z = bfpack(acc[k+2]*0.0625f); u.w = bfpack(acc[k+3]*0.0625f);
        *(ushort4*)(o+k) = u;
      }
    }
  } else if (bid < TBLK + RPB){
    const int n = (bid-TBLK)*256 + threadIdx.x;
    if (n > NN) return;
    int lo=0, hi=E;
    while (lo < hi){ int mid=(lo+hi)>>1; if (dst[mid] < n) lo=mid+1; else hi=mid; }
    rowptr[n]=lo;
  } else {
    const int idx = (bid - TBLK - RPB)*256 + threadIdx.x;
    if (idx < outN) out[idx] = 0.0f;
  }
}

// ---------------- stage B (fused): per-lane packed table + x = segsum(sph_harm) -----
// blocks [0,6144): tabP perm (bf16, 3.15 MB -> L2-resident).
// blocks [6144,6400): k_x, 4 lanes/node.
#define PERB 6144
__global__ __launch_bounds__(256) void k_stageB(
    const float* __restrict__ tab1, unsigned short* __restrict__ tabP,
    const float* __restrict__ pos, const int* __restrict__ src,
    const int* __restrict__ rowptr, float* __restrict__ xacc)
{
  const int bid = blockIdx.x;
  if (bid < PERB){
    const int gid = bid*256 + threadIdx.x;     // [0, T_TAB*512)
    const int t = gid >> 9, p = gid & 511;
    int col, slot;
    lane_sched(p>>3, p&7, col, slot);
    float v = (col >= 0) ? tab1[(size_t)t*272 + col] : 0.0f;
    tabP[gid] = bfpack(v);
    return;
  }
  const int tt = (bid-PERB)*256 + threadIdx.x;
  const int n = tt>>2, q = tt&3;
  if (n>=NN) return;
  const int r0=rowptr[n], r1=rowptr[n+1];
  const float pdx=pos[3*n], pdy=pos[3*n+1], pdz=pos[3*n+2];
  const float s3=1.73205081f, s5=2.23606798f, s15=3.87298335f;
  const float c33=2.09165007f, c32=10.2469508f, c31=1.62018517f, c30=1.32287566f, cp2=5.12347538f;
  float a0=0,a1=0,a2=0,a3=0,a4=0,a5=0,a6=0,a7=0,a8=0,a9=0,a10=0,a11=0,a12=0,a13=0,a14=0,a15=0;
  for (int e=r0+q; e<r1; e+=4){
    const int s=src[e];
    float ax=pos[3*s]-pdx, ay=pos[3*s+1]-pdy, az=pos[3*s+2]-pdz;
    float ir = 1.0f/sqrtf(ax*ax+ay*ay+az*az);
    float x=ax*ir, y=ay*ir, z=az*ir;
    a0+=1.0f; a1+=s3*y; a2+=s3*z; a3+=s3*x;
    a4+=s15*x*y; a5+=s15*y*z; a6+=0.5f*s5*(3.0f*z*z-1.0f); a7+=s15*x*z;
    a8+=0.5f*s15*(x*x-y*y); a9+=c33*y*(3.0f*x*x-y*y); a10+=c32*x*y*z; a11+=c31*y*(5.0f*z*z-1.0f);
    a12+=c30*(5.0f*z*z*z-3.0f*z); a13+=c31*x*(5.0f*z*z-1.0f); a14+=cp2*z*(x*x-y*y);
    a15+=c33*x*(x*x-3.0f*y*y);
  }
#define RED(v) v += __shfl_xor(v,1); v += __shfl_xor(v,2);
  RED(a0) RED(a1) RED(a2) RED(a3) RED(a4) RED(a5) RED(a6) RED(a7)
  RED(a8) RED(a9) RED(a10) RED(a11) RED(a12) RED(a13) RED(a14) RED(a15)
#undef RED
  float o0,o1,o2,o3;
  if (q==0){ o0=a0; o1=a1; o2=a2; o3=a3; }
  else if (q==1){ o0=a4; o1=a5; o2=a6; o3=a7; }
  else if (q==2){ o0=a8; o1=a9; o2=a10; o3=a11; }
  else { o0=a12; o1=a13; o2=a14; o3=a15; }
  *(float4*)(xacc + (size_t)n*16 + q*4) = make_float4(o0,o1,o2,o3);
}

// ---------------- fctp1 + gate fused: ONE WAVE covers FOUR nodes --------------
__global__ __launch_bounds__(64) void k_tp1(
    const float* __restrict__ pos, const int* __restrict__ src,
    const int* __restrict__ rowptr, const float* __restrict__ xacc,
    const unsigned short* __restrict__ tabP, unsigned short* __restrict__ xgb)
{
  const int lane = threadIdx.x;
  const int nb   = blockIdx.x*NG;
  const int g    = lane >> 4, je = lane & 15;
  __shared__ float SI[NG][CH2][33];   // 0..30 intermediates, 31 zero
  __shared__ int   SiT[NG][CH2];
  __shared__ float SG[NG][32];

  int rp[NG+1];
#pragma unroll
  for (int q=0;q<=NG;++q) rp[q] = rowptr[nb+q];
  int deg[NG];
#pragma unroll
  for (int q=0;q<NG;++q) deg[q] = rp[q+1]-rp[q];
  const int dmax = max(max(deg[0],deg[1]), max(deg[2],deg[3]));
  const int nch = (dmax + CH2 - 1) / CH2;

  // ---- static LDS-slot schedule + gate indices ----
  int ioS[8];
#pragma unroll
  for (int p=0;p<8;++p){ int c_, s_; lane_sched(lane, p, c_, s_); ioS[p] = s_; }
  int gu0=16, gu1=16;
  if (lane >= 16 && lane < 40){ gu0 = 16 + (lane-16)/3; }
  else if (lane >= 40 && lane < 52){
    int m=lane-40; gu0 = 24 + (2*m)/3; gu1 = 24 + (2*m+1)/3;
  }

  const int mynode = nb + g;
  const float pdx=pos[3*mynode], pdy=pos[3*mynode+1], pdz=pos[3*mynode+2];
  float acc0[NG]={0,0,0,0}, acc1[NG]={0,0,0,0};

  for (int t=0; t<nch; ++t){
    __syncthreads();                 // WAR: prev chunk phase-2 reads done
    const int cg_ = deg[g] - t*CH2;  // my group's remaining edges
    if (je < cg_){
      const int e = rp[g] + t*CH2 + je;
      const int s = src[e];
      float ax=pos[3*s]-pdx, ay=pos[3*s+1]-pdy, az=pos[3*s+2]-pdz;
      float r = sqrtf(ax*ax+ay*ay+az*az);
      float ir = 1.0f/r;
      float x=ax*ir, y=ay*ir, z=az*ir;
      float f = r * 1228.4f;                    // (T_TAB-1)/2.5
      int i0 = (int)(f + 0.5f);                 // nearest row
      if (i0 > T_TAB-1) i0 = T_TAB-1;

      const float s3=1.73205081f, s5=2.23606798f, s15=3.87298335f;
      const float c33=2.09165007f, c32=10.2469508f, c31=1.62018517f, c30=1.32287566f, cp2=5.12347538f;
      float Y[16];
      Y[0]=1.0f;
      Y[1]=s3*y; Y[2]=s3*z; Y[3]=s3*x;
      Y[4]=s15*x*y; Y[5]=s15*y*z; Y[6]=0.5f*s5*(3.0f*z*z-1.0f); Y[7]=s15*x*z; Y[8]=0.5f*s15*(x*x-y*y);
      Y[9]=c33*y*(3.0f*x*x-y*y); Y[10]=c32*x*y*z; Y[11]=c31*y*(5.0f*z*z-1.0f);
      Y[12]=c30*(5.0f*z*z*z-3.0f*z); Y[13]=c31*x*(5.0f*z*z-1.0f); Y[14]=cp2*z*(x*x-y*y);
      Y[15]=c33*x*(x*x-3.0f*y*y);
      float X[16];
      {
        const float inv = 0.5129891760f;           // 1/sqrt(3.8)
        const float4* q4 = (const float4*)(xacc + (size_t)s*16);
        float4 a=q4[0],b=q4[1],cc4=q4[2],d4=q4[3];
        X[0]=a.x*inv;X[1]=a.y*inv;X[2]=a.z*inv;X[3]=a.w*inv;
        X[4]=b.x*inv;X[5]=b.y*inv;X[6]=b.z*inv;X[7]=b.w*inv;
        X[8]=cc4.x*inv;X[9]=cc4.y*inv;X[10]=cc4.z*inv;X[11]=cc4.w*inv;
        X[12]=d4.x*inv;X[13]=d4.y*inv;X[14]=d4.z*inv;X[15]=d4.w*inv;
      }
      float* SS = SI[g][je];

      // t-block (scalar outputs)
      {
        float t0v = CG000.v[0]*X[0]*Y[0];
        float t1v=0.f, t2v=0.f, t3v=0.f;
#pragma unroll
        for (int i=0;i<3;++i)
#pragma unroll
          for (int j=0;j<3;++j) TERM(CG110, i*3+j, X[1+i]*Y[1+j], t1v)
#pragma unroll
        for (int i=0;i<5;++i)
#pragma unroll
          for (int j=0;j<5;++j) TERM(CG220, i*5+j, X[4+i]*Y[4+j], t2v)
#pragma unroll
        for (int i=0;i<7;++i)
#pragma unroll
          for (int j=0;j<7;++j) TERM(CG330, i*7+j, X[9+i]*Y[9+j], t3v)
        SS[0]=t0v; SS[1]=t1v; SS[2]=t2v; SS[3]=t3v;
      }
      // vector outputs
      {
        float v01[3]={0,0,0}, v10[3]={0,0,0}, v11[3]={0,0,0}, v12[3]={0,0,0},
              v21[3]={0,0,0}, v22[3]={0,0,0}, v23[3]={0,0,0}, v32[3]={0,0,0}, v33[3]={0,0,0};
#pragma unroll
        for (int j=0;j<3;++j){ float tt=X[0]*Y[1+j];
#pragma unroll
          for (int k=0;k<3;++k) TERM(CG011, j*3+k, tt, v01[k]) }
#pragma unroll
        for (int i=0;i<3;++i){ float tt=X[1+i]*Y[0];
#pragma unroll
          for (int k=0;k<3;++k) TERM(CG101, i*3+k, tt, v10[k]) }
#pragma unroll
        for (int i=0;i<3;++i)
#pragma unroll
          for (int j=0;j<3;++j){ float tt=X[1+i]*Y[1+j];
#pragma unroll
            for (int k=0;k<3;++k) TERM(CG111, (i*3+j)*3+k, tt, v11[k]) }
#pragma unroll
        for (int i=0;i<3;++i)
#pragma unroll
          for (int j=0;j<5;++j){ float tt=X[1+i]*Y[4+j];
#pragma unroll
            for (int k=0;k<3;++k) TERM(CG121, (i*5+j)*3+k, tt, v12[k]) }
#pragma unroll
        for (int i=0;i<5;++i)
#pragma unroll
          for (int j=0;j<3;++j){ float tt=X[4+i]*Y[1+j];
#pragma unroll
            for (int k=0;k<3;++k) TERM(CG211, (i*3+j)*3+k, tt, v21[k]) }
#pragma unroll
        for (int i=0;i<5;++i)
#pragma unroll
          for (int j=0;j<5;++j){ float tt=X[4+i]*Y[4+j];
#pragma unroll
            for (int k=0;k<3;++k) TERM(CG221, (i*5+j)*3+k, tt, v22[k]) }
#pragma unroll
        for (int i=0;i<5;++i)
#pragma unroll
          for (int j=0;j<7;++j){ float tt=X[4+i]*Y[9+j];
#pragma unroll
            for (int k=0;k<3;++k) TERM(CG231, (i*7+j)*3+k, tt, v23[k]) }
#pragma unroll
        for (int i=0;i<7;++i)
#pragma unroll
          for (int j=0;j<5;++j){ float tt=X[9+i]*Y[4+j];
#pragma unroll
            for (int k=0;k<3;++k) TERM(CG321, (i*5+j)*3+k, tt, v32[k]) }
#pragma unroll
        for (int i=0;i<7;++i)
#pragma unroll
          for (int j=0;j<7;++j){ float tt=X[9+i]*Y[9+j];
#pragma unroll
            for (int k=0;k<3;++k) TERM(CG331, (i*7+j)*3+k, tt, v33[k]) }
#pragma unroll
        for (int k=0;k<3;++k){
          SS[4+k]=v01[k]; SS[7+k]=v10[k]; SS[10+k]=v12[k]; SS[13+k]=v21[k];
          SS[16+k]=v23[k]; SS[19+k]=v32[k]; SS[22+k]=v11[k]; SS[25+k]=v22[k]; SS[28+k]=v33[k];
        }
      }
      SS[31]=0.0f;
      SiT[g][je]=i0;
    }
    __syncthreads();                 // RAW: phase-1 SI/SiT visible
    // ---- phase 2: per-node accumulation, single nearest bf16 row ----
#pragma unroll
    for (int q=0;q<NG;++q){
      const int cq = deg[q] - t*CH2;
#pragma unroll 4
      for (int j=0; j<CH2; ++j){
        if (j < cq){
          const float* __restrict__ I = SI[q][j];
          const unsigned short* __restrict__ wp = tabP + ((size_t)SiT[q][j]*512) + 8*lane;
          uint4 ra = *(const uint4*)wp;          // 8 bf16 weights
          float a8[8];
          unp8(ra, a8);
          acc0[q] = fmaf(a8[0], I[ioS[0]], acc0[q]);
          acc0[q] = fmaf(a8[1], I[ioS[1]], acc0[q]);
          acc0[q] = fmaf(a8[2], I[ioS[2]], acc0[q]);
          acc0[q] = fmaf(a8[3], I[ioS[3]], acc0[q]);
          acc1[q] = fmaf(a8[4], I[ioS[4]], acc1[q]);
          acc1[q] = fmaf(a8[5], I[ioS[5]], acc1[q]);
          acc1[q] = fmaf(a8[6], I[ioS[6]], acc1[q]);
          acc1[q] = fmaf(a8[7], I[ioS[7]], acc1[q]);
        }
      }
    }
  }

  // ---- fused gate epilogue (per node), bf16 output ----
  const float inv = 0.5129891760f;
  if (lane < 16){
#pragma unroll
    for (int q=0;q<NG;++q){
      SG[q][2*lane]   = acc0[q]*0.5f*inv;
      SG[q][2*lane+1] = acc1[q]*0.5f*inv;
    }
  }
  __syncthreads();
#pragma unroll
  for (int q=0;q<NG;++q){
    unsigned short* __restrict__ o = xgb + (size_t)(nb+q)*64;
    if (lane < 16){
      o[lane] = bfpack(fmaxf(SG[q][lane], 0.0f));            // se
    } else if (lane < 40){
      int idx = lane-16;
      float vv = (acc0[q]+acc1[q])*0.4082482905f*inv;
      o[16+idx] = bfpack(vv * fmaxf(SG[q][gu0], 0.0f));      // v1o (u<8)
    } else if (lane < 52){
      int m = lane-40;
      float vv0 = acc0[q]*0.5773502692f*inv;
      float vv1 = acc1[q]*0.5773502692f*inv;
      o[40+2*m]   = bfpack(vv0 * fmaxf(SG[q][gu0], 0.0f));   // v1e (u<8)
      o[40+2*m+1] = bfpack(vv1 * fmaxf(SG[q][gu1], 0.0f));
    }
  }
}

// ---------------- fctp2 + fused dst-segmented reduction -> out ----------------
__global__ __launch_bounds__(256) void k_tp2(
    const float* __restrict__ pos, const int* __restrict__ src, const int* __restrict__ dst, int E,
    const unsigned short* __restrict__ xgb, const unsigned short* __restrict__ tab2b,
    float* __restrict__ out)
{
  const int tid = threadIdx.x;
  const int e = blockIdx.x*256 + tid;
  __shared__ float S0[256], S1[256], S2[256];
  __shared__ int   D[256];
  float e2[3]={0,0,0};
  int dd = -1;
  if (e < E){
    const int s = src[e];
    dd = dst[e];
    float ax=pos[3*s]-pos[3*dd], ay=pos[3*s+1]-pos[3*dd+1], az=pos[3*s+2]-pos[3*dd+2];
    float r = sqrtf(ax*ax+ay*ay+az*az);
    float ir = 1.0f/r;
    float x=ax*ir, y=ay*ir, z=az*ir;
    float f = r * 1228.4f;                     // (T_TAB-1)/2.5
    int i0 = (int)(f + 0.5f);                  // nearest row
    if (i0 > T_TAB-1) i0 = T_TAB-1;
    const unsigned short* __restrict__ w0 = tab2b + (size_t)i0*64;
    float wse[16], wA[8], wB[8], wC[8];
    unp8(*(const uint4*)(w0+0),  wse);
    unp8(*(const uint4*)(w0+8),  wse+8);
    unp8(*(const uint4*)(w0+16), wA);
    unp8(*(const uint4*)(w0+32), wB);
    unp8(*(const uint4*)(w0+48), wC);
    const float s3=1.73205081f, s5=2.23606798f, s15=3.87298335f;
    float Y[9];
    Y[0]=1.0f;
    Y[1]=s3*y; Y[2]=s3*z; Y[3]=s3*x;
    Y[4]=s15*x*y; Y[5]=s15*y*z; Y[6]=0.5f*s5*(3.0f*z*z-1.0f); Y[7]=s15*x*z; Y[8]=0.5f*s15*(x*x-y*y);
    const unsigned short* __restrict__ g = xgb + (size_t)s*64;
    float se[16], vo[24], ve[24];
    unp8(*(const uint4*)(g+0),  se);  unp8(*(const uint4*)(g+8),  se+8);
    unp8(*(const uint4*)(g+16), vo);  unp8(*(const uint4*)(g+24), vo+8); unp8(*(const uint4*)(g+32), vo+16);
    unp8(*(const uint4*)(g+40), ve);  unp8(*(const uint4*)(g+48), ve+8); unp8(*(const uint4*)(g+56), ve+16);

    float SA=0.0f;
#pragma unroll
    for (int u=0;u<16;++u) SA = fmaf(wse[u], se[u], SA);
    float AB[3]={0,0,0}, AC[3]={0,0,0}, AD[3]={0,0,0};
#pragma unroll
    for (int u=0;u<8;++u)
#pragma unroll
      for (int i=0;i<3;++i){
        AB[i]=fmaf(wA[u], vo[u*3+i], AB[i]);
        AC[i]=fmaf(wB[u], vo[u*3+i], AC[i]);
        AD[i]=fmaf(wC[u], ve[u*3+i], AD[i]);
      }
#pragma unroll
    for (int j=0;j<3;++j){ float t=SA*Y[1+j];
#pragma unroll
      for (int k=0;k<3;++k) TERM(CG011, j*3+k, t, e2[k]) }
#pragma unroll
    for (int i=0;i<3;++i){ float t=AB[i]*Y[0];
#pragma unroll
      for (int k=0;k<3;++k) TERM(CG101, i*3+k, t, e2[k]) }
#pragma unroll
    for (int i=0;i<3;++i)
#pragma unroll
      for (int j=0;j<5;++j){ float t=AC[i]*Y[4+j];
#pragma unroll
        for (int k=0;k<3;++k) TERM(CG121, (i*5+j)*3+k, t, e2[k]) }
#pragma unroll
    for (int i=0;i<3;++i)
#pragma unroll
      for (int j=0;j<3;++j){ float t=AD[i]*Y[1+j];
#pragma unroll
        for (int k=0;k<3;++k) TERM(CG111, (i*3+j)*3+k, t, e2[k]) }
  }
  S0[tid]=e2[0]; S1[tid]=e2[1]; S2[tid]=e2[2]; D[tid]=dd;
  __syncthreads();
  if (e < E && (tid==0 || D[tid-1] != dd)){
    float a0=0.f, a1=0.f, a2=0.f;
    int j = tid;
    while (j < 256 && D[j] == dd){ a0+=S0[j]; a1+=S1[j]; a2+=S2[j]; ++j; }
    const float sc = 0.0641236437f;  // (1/sqrt(64)) * 1/sqrt(3.8)
    afadd(out + (size_t)dd*3 + 0, a0*sc);
    afadd(out + (size_t)dd*3 + 1, a1*sc);
    afadd(out + (size_t)dd*3 + 2, a2*sc);
  }
}

// ---------------- host launcher ----------------
extern "C" void kernel_launch(void* const* d_in, const int* in_sizes, int n_in,
                              void* d_out, int out_size, void* d_ws, size_t ws_size,
                              hipStream_t stream)
{
  (void)n_in; (void)ws_size;
  const float* pos = (const float*)d_in[0];
  const int*   src = (const int*)d_in[1];
  const int*   dst = (const int*)d_in[2];
  const float* W1  = (const float*)d_in[3];
  const float* W2  = (const float*)d_in[4];
  const float* W1f = (const float*)d_in[5];
  const float* W2f = (const float*)d_in[6];
  const int E = in_sizes[1];

  char* ws = (char*)d_ws;
  float* xacc  = (float*)ws;                     // NN*16
  unsigned short* xgb = (unsigned short*)(xacc + (size_t)NN*16);        // NN*64 ushort
  float* tab1  = (float*)(xgb + (size_t)NN*64);  // T_TAB*272
  unsigned short* tab2b = (unsigned short*)(tab1 + (size_t)T_TAB*272);  // T_TAB*64 ushort
  unsigned short* tabP  = tab2b + (size_t)T_TAB*64;                     // T_TAB*512 ushort
  int*   rowptr= (int*)(tabP + (size_t)T_TAB*512);                      // NN+1

  const int ozb = (out_size + 255) / 256;
  k_stageA<<<TBLK + RPB + ozb, 256, 0, stream>>>(W1, W2, W1f, W2f, tab1, tab2b,
                                                 dst, E, rowptr, (float*)d_out, out_size);
  k_stageB<<<PERB + (NN*4)/256, 256, 0, stream>>>(tab1, tabP, pos, src, rowptr, xacc);
  k_tp1<<<NN/NG, 64, 0, stream>>>(pos, src, rowptr, xacc, tabP, xgb);
  k_tp2<<<(E + 255) / 256, 256, 0, stream>>>(pos, src, dst, E, xgb, tab2b, (float*)d_out);
}

// Round 18
// 83.981 us; speedup vs baseline: 3.1981x; 1.0926x over previous
//
#include <hip/hip_runtime.h>
#include <cmath>

#define T_TAB 3072
#define NN 16384
#define NG 4
#define CH2 16

// ================= compile-time CG tables (constexpr port of the reference) ========
struct CD { double re, im; };
constexpr CD cmul(CD a, CD b){ return {a.re*b.re - a.im*b.im, a.re*b.im + a.im*b.re}; }
constexpr CD cadd(CD a, CD b){ return {a.re+b.re, a.im+b.im}; }
constexpr CD conj_(CD a){ return {a.re, -a.im}; }
constexpr CD cscale(CD a, double s){ return {a.re*s, a.im*s}; }
constexpr double cfabs_(double x){ return x<0.0 ? -x : x; }
constexpr double csqrt_(double x){
  double g = x > 1.0 ? x : 1.0;
  for (int i=0;i<80;++i) g = 0.5*(g + x/g);
  return g;
}
constexpr double factd(int n){ double r=1.0; for(int i=2;i<=n;++i) r*=(double)i; return r; }

constexpr double cg_coef(int j1,int m1,int j2,int m2,int j3,int m3){
  double pref = csqrt_((2.0*j3+1.0)*factd(j3+j1-j2)*factd(j3-j1+j2)*factd(j1+j2-j3)/factd(j1+j2+j3+1));
  pref *= csqrt_(factd(j3+m3)*factd(j3-m3)*factd(j1-m1)*factd(j1+m1)*factd(j2-m2)*factd(j2+m2));
  double s=0.0;
  for(int k=0;k<=j1+j2-j3;++k){
    int a0=k,a1=j1+j2-j3-k,a2=j1-m1-k,a3=j2+m2-k,a4=j3-j2+m1+k,a5=j3-j1-m2+k;
    if(a0<0||a1<0||a2<0||a3<0||a4<0||a5<0) continue;
    double d=factd(a0)*factd(a1)*factd(a2)*factd(a3)*factd(a4)*factd(a5);
    s += ((k&1)?-1.0:1.0)/d;
  }
  return pref*s;
}

struct UMat { CD u[7][7]; };
constexpr UMat u_fill(int l){
  UMat M{};
  const double is2 = csqrt_(0.5);
  M.u[l][l] = CD{1.0, 0.0};
  for(int m=1;m<=l;++m){
    double sgn = (m&1)?-1.0:1.0;
    M.u[l+m][l+m] = CD{sgn*is2, 0.0};
    M.u[l+m][l-m] = CD{is2, 0.0};
    M.u[l-m][l-m] = CD{0.0, is2};
    M.u[l-m][l+m] = CD{0.0, -sgn*is2};
  }
  return M;
}

template<int L1,int L2,int L3>
struct FT { float v[(2*L1+1)*(2*L2+1)*(2*L3+1)]; };

template<int L1,int L2,int L3>
constexpr FT<L1,L2,L3> cg_real_ct(){
  constexpr int n1=2*L1+1, n2=2*L2+1, n3=2*L3+1;
  double Cc[7][7][7] = {};
  for(int m1=-L1;m1<=L1;++m1)
    for(int m2=-L2;m2<=L2;++m2){
      int m3=m1+m2;
      if(m3>=-L3&&m3<=L3) Cc[m1+L1][m2+L2][m3+L3]=cg_coef(L1,m1,L2,m2,L3,m3);
    }
  UMat U1 = u_fill(L1), U2 = u_fill(L2), U3 = u_fill(L3);
  CD Cr[7][7][7] = {};
  double sre=0.0, sim=0.0;
  for(int a=0;a<n1;++a)for(int b=0;b<n2;++b)for(int c=0;c<n3;++c){
    CD acc{0.0,0.0};
    for(int u=0;u<n1;++u)for(int v=0;v<n2;++v){
      int w = (u-L1)+(v-L2)+L3;           // only m3=m1+m2 can be nonzero in Cc
      if (w < 0 || w >= n3) continue;
      double cc = Cc[u][v][w];
      if (cc == 0.0) continue;
      acc = cadd(acc, cscale(cmul(cmul(U1.u[a][u],U2.u[b][v]),conj_(U3.u[c][w])), cc));
    }
    Cr[a][b][c] = acc;
    sre += cfabs_(acc.re); sim += cfabs_(acc.im);
  }
  FT<L1,L2,L3> out{};
  bool useim = sim > sre;
  for(int a=0;a<n1;++a)for(int b=0;b<n2;++b)for(int c=0;c<n3;++c)
    out.v[(a*n2+b)*n3+c] = (float)(useim ? Cr[a][b][c].im : Cr[a][b][c].re);
  return out;
}

constexpr auto CG000 = cg_real_ct<0,0,0>();
constexpr auto CG110 = cg_real_ct<1,1,0>();
constexpr auto CG220 = cg_real_ct<2,2,0>();
constexpr auto CG330 = cg_real_ct<3,3,0>();
constexpr auto CG011 = cg_real_ct<0,1,1>();
constexpr auto CG101 = cg_real_ct<1,0,1>();
constexpr auto CG111 = cg_real_ct<1,1,1>();
constexpr auto CG121 = cg_real_ct<1,2,1>();
constexpr auto CG211 = cg_real_ct<2,1,1>();
constexpr auto CG221 = cg_real_ct<2,2,1>();
constexpr auto CG231 = cg_real_ct<2,3,1>();
constexpr auto CG321 = cg_real_ct<3,2,1>();
constexpr auto CG331 = cg_real_ct<3,3,1>();

// zero-pruned FMA term: coefficient folds to a literal; zero terms are deleted.
#define TERM(TBL, IDX, PROD, ACC) { float c_ = TBL.v[IDX]; if (c_ != 0.0f) ACC = fmaf((PROD), c_, ACC); }

// ---------------- device helpers ----------------
__device__ __forceinline__ void afadd(float* p, float v){ unsafeAtomicAdd(p, v); }

__device__ __forceinline__ float soh(float r, float c){
  float d = (r - c) * 2.0f;
  float d2 = d*d;
  return (d2 < 1.0f) ? 1.14136f * expf(2.0f + 1.0f/(d2-1.0f)) : 0.0f;
}

__device__ __forceinline__ float bf_lo(unsigned u){ return __uint_as_float(u << 16); }
__device__ __forceinline__ float bf_hi(unsigned u){ return __uint_as_float(u & 0xFFFF0000u); }
__device__ __forceinline__ unsigned short bfpack(float v){
  unsigned b = __float_as_uint(v);
  return (unsigned short)((b + 0x7FFFu + ((b >> 16) & 1u)) >> 16);   // RTNE
}
__device__ __forceinline__ void unp8(uint4 u, float* o){
  o[0]=bf_lo(u.x); o[1]=bf_hi(u.x); o[2]=bf_lo(u.y); o[3]=bf_hi(u.y);
  o[4]=bf_lo(u.z); o[5]=bf_hi(u.z); o[6]=bf_lo(u.w); o[7]=bf_hi(u.w);
}

// Per-lane weight schedule: lane ℓ, sub-index q (0..7) -> (column in [0,272) or -1, LDS slot).
// Slot 31 is a guaranteed-zero slot.
__device__ __forceinline__ void lane_sched(int lane, int q, int& col, int& slot){
  col = -1; slot = 31;
  if (lane < 16){
    int s = q >> 2, qq = q & 3;
    int a = 2*lane + s;                 // scalar output index 0..31
    const int base0[4] = {0, 64, 144, 224};
    col = base0[qq] + a; slot = qq;
  } else if (lane < 40){
    int idx = lane-16, u = idx/3, k = idx-3*u;
    const int wb[6] = {32,48,112,128,192,208};
    const int sb[6] = {4,7,10,13,16,19};
    if (q < 6){ col = wb[q]+u; slot = sb[q]+k; }
  } else if (lane < 52){
    int m = lane-40;
    int c0 = (q < 4) ? 2*m : 2*m+1;
    int u = c0/3, k = c0-3*u;
    int qq = (q < 4) ? q : q-4;
    if (qq < 3){
      const int wb[3] = {96,176,256};
      const int sb[3] = {22,25,28};
      col = wb[qq]+u; slot = sb[qq]+k;
    }
  }
}

// ---------------- stage A (fused): radial tables + rowptr + out-zero ----------------
// blocks [0,1008): table, jq-major (R16's proven form: 4 fp32 acc/thread, no spill).
// blocks [1008,1073): rowptr binary search (dst is globally non-decreasing).
// blocks [1073, ...): zero out[].
#define TBLK 1008
#define RPB  65
__global__ __launch_bounds__(256) void k_stageA(
    const float* __restrict__ W1, const float* __restrict__ W2,
    const float* __restrict__ W1f, const float* __restrict__ W2f,
    float* __restrict__ tab1, unsigned short* __restrict__ tab2b,
    const int* __restrict__ dst, int E, int* __restrict__ rowptr,
    float* __restrict__ out, int outN)
{
  const int bid = blockIdx.x;
  if (bid < TBLK){
    const int jq  = bid / 12;                   // 0..83
    const int t   = (bid % 12)*256 + threadIdx.x;
    const int j0  = jq*4;
    const float dr = 2.5f / (float)(T_TAB-1);
    const float r = (float)t * dr;
    const float e0 = soh(r,1.0f), e1 = soh(r,1.5f), e2 = soh(r,2.0f);
    float ax=0.f, ay=0.f, az=0.f, aw=0.f;
    if (j0 < 272){
      for (int cc=0; cc<256; ++cc){
        float h = fmaxf(fmaf(e0,W1[cc], fmaf(e1,W1[256+cc], e2*W1[512+cc])), 0.0f);
        float4 w = *(const float4*)(W2 + cc*272 + j0);
        ax = fmaf(h,w.x,ax); ay = fmaf(h,w.y,ay);
        az = fmaf(h,w.z,az); aw = fmaf(h,w.w,aw);
      }
      *(float4*)(tab1 + (size_t)t*272 + j0) = make_float4(ax*0.0625f, ay*0.0625f, az*0.0625f, aw*0.0625f);
    } else {
      const int jj = j0 - 272;
      for (int cc=0; cc<256; ++cc){
        float h = fmaxf(fmaf(e0,W1f[cc], fmaf(e1,W1f[256+cc], e2*W1f[512+cc])), 0.0f);
        float4 w = *(const float4*)(W2f + cc*64 + jj);
        ax = fmaf(h,w.x,ax); ay = fmaf(h,w.y,ay);
        az = fmaf(h,w.z,az); aw = fmaf(h,w.w,aw);
      }
      ushort4 o;
      o.x = bfpack(ax*0.0625f); o.y = bfpack(ay*0.0625f);
      o.z = bfpack(az*0.0625f); o.w = bfpack(aw*0.0625f);
      *(ushort4*)(tab2b + (size_t)t*64 + jj) = o;
    }
  } else if (bid < TBLK + RPB){
    const int n = (bid-TBLK)*256 + threadIdx.x;
    if (n > NN) return;
    int lo=0, hi=E;
    while (lo < hi){ int mid=(lo+hi)>>1; if (dst[mid] < n) lo=mid+1; else hi=mid; }
    rowptr[n]=lo;
  } else {
    const int idx = (bid - TBLK - RPB)*256 + threadIdx.x;
    if (idx < outN) out[idx] = 0.0f;
  }
}

// ---------------- stage B (fused): per-lane packed table + x = segsum(sph_harm) -----
// blocks [0,6144): tabP perm (bf16, 3.15 MB -> L2-resident).
// blocks [6144,6400): k_x, 4 lanes/node.
#define PERB 6144
__global__ __launch_bounds__(256) void k_stageB(
    const float* __restrict__ tab1, unsigned short* __restrict__ tabP,
    const float* __restrict__ pos, const int* __restrict__ src,
    const int* __restrict__ rowptr, float* __restrict__ xacc)
{
  const int bid = blockIdx.x;
  if (bid < PERB){
    const int gid = bid*256 + threadIdx.x;     // [0, T_TAB*512)
    const int t = gid >> 9, p = gid & 511;
    int col, slot;
    lane_sched(p>>3, p&7, col, slot);
    float v = (col >= 0) ? tab1[(size_t)t*272 + col] : 0.0f;
    tabP[gid] = bfpack(v);
    return;
  }
  const int tt = (bid-PERB)*256 + threadIdx.x;
  const int n = tt>>2, q = tt&3;
  if (n>=NN) return;
  const int r0=rowptr[n], r1=rowptr[n+1];
  const float pdx=pos[3*n], pdy=pos[3*n+1], pdz=pos[3*n+2];
  const float s3=1.73205081f, s5=2.23606798f, s15=3.87298335f;
  const float c33=2.09165007f, c32=10.2469508f, c31=1.62018517f, c30=1.32287566f, cp2=5.12347538f;
  float a0=0,a1=0,a2=0,a3=0,a4=0,a5=0,a6=0,a7=0,a8=0,a9=0,a10=0,a11=0,a12=0,a13=0,a14=0,a15=0;
  for (int e=r0+q; e<r1; e+=4){
    const int s=src[e];
    float ax=pos[3*s]-pdx, ay=pos[3*s+1]-pdy, az=pos[3*s+2]-pdz;
    float ir = 1.0f/sqrtf(ax*ax+ay*ay+az*az);
    float x=ax*ir, y=ay*ir, z=az*ir;
    a0+=1.0f; a1+=s3*y; a2+=s3*z; a3+=s3*x;
    a4+=s15*x*y; a5+=s15*y*z; a6+=0.5f*s5*(3.0f*z*z-1.0f); a7+=s15*x*z;
    a8+=0.5f*s15*(x*x-y*y); a9+=c33*y*(3.0f*x*x-y*y); a10+=c32*x*y*z; a11+=c31*y*(5.0f*z*z-1.0f);
    a12+=c30*(5.0f*z*z*z-3.0f*z); a13+=c31*x*(5.0f*z*z-1.0f); a14+=cp2*z*(x*x-y*y);
    a15+=c33*x*(x*x-3.0f*y*y);
  }
#define RED(v) v += __shfl_xor(v,1); v += __shfl_xor(v,2);
  RED(a0) RED(a1) RED(a2) RED(a3) RED(a4) RED(a5) RED(a6) RED(a7)
  RED(a8) RED(a9) RED(a10) RED(a11) RED(a12) RED(a13) RED(a14) RED(a15)
#undef RED
  float o0,o1,o2,o3;
  if (q==0){ o0=a0; o1=a1; o2=a2; o3=a3; }
  else if (q==1){ o0=a4; o1=a5; o2=a6; o3=a7; }
  else if (q==2){ o0=a8; o1=a9; o2=a10; o3=a11; }
  else { o0=a12; o1=a13; o2=a14; o3=a15; }
  *(float4*)(xacc + (size_t)n*16 + q*4) = make_float4(o0,o1,o2,o3);
}

// ---------------- fctp1 + gate fused: ONE WAVE covers FOUR nodes --------------
__global__ __launch_bounds__(64) void k_tp1(
    const float* __restrict__ pos, const int* __restrict__ src,
    const int* __restrict__ rowptr, const float* __restrict__ xacc,
    const unsigned short* __restrict__ tabP, unsigned short* __restrict__ xgb)
{
  const int lane = threadIdx.x;
  const int nb   = blockIdx.x*NG;
  const int g    = lane >> 4, je = lane & 15;
  __shared__ float SI[NG][CH2][33];   // 0..30 intermediates, 31 zero
  __shared__ int   SiT[NG][CH2];
  __shared__ float SG[NG][32];

  int rp[NG+1];
#pragma unroll
  for (int q=0;q<=NG;++q) rp[q] = rowptr[nb+q];
  int deg[NG];
#pragma unroll
  for (int q=0;q<NG;++q) deg[q] = rp[q+1]-rp[q];
  const int dmax = max(max(deg[0],deg[1]), max(deg[2],deg[3]));
  const int nch = (dmax + CH2 - 1) / CH2;

  // ---- static LDS-slot schedule + gate indices ----
  int ioS[8];
#pragma unroll
  for (int p=0;p<8;++p){ int c_, s_; lane_sched(lane, p, c_, s_); ioS[p] = s_; }
  int gu0=16, gu1=16;
  if (lane >= 16 && lane < 40){ gu0 = 16 + (lane-16)/3; }
  else if (lane >= 40 && lane < 52){
    int m=lane-40; gu0 = 24 + (2*m)/3; gu1 = 24 + (2*m+1)/3;
  }

  const int mynode = nb + g;
  const float pdx=pos[3*mynode], pdy=pos[3*mynode+1], pdz=pos[3*mynode+2];
  float acc0[NG]={0,0,0,0}, acc1[NG]={0,0,0,0};

  for (int t=0; t<nch; ++t){
    __syncthreads();                 // WAR: prev chunk phase-2 reads done
    const int cg_ = deg[g] - t*CH2;  // my group's remaining edges
    if (je < cg_){
      const int e = rp[g] + t*CH2 + je;
      const int s = src[e];
      float ax=pos[3*s]-pdx, ay=pos[3*s+1]-pdy, az=pos[3*s+2]-pdz;
      float r = sqrtf(ax*ax+ay*ay+az*az);
      float ir = 1.0f/r;
      float x=ax*ir, y=ay*ir, z=az*ir;
      float f = r * 1228.4f;                    // (T_TAB-1)/2.5
      int i0 = (int)(f + 0.5f);                 // nearest row
      if (i0 > T_TAB-1) i0 = T_TAB-1;

      const float s3=1.73205081f, s5=2.23606798f, s15=3.87298335f;
      const float c33=2.09165007f, c32=10.2469508f, c31=1.62018517f, c30=1.32287566f, cp2=5.12347538f;
      float Y[16];
      Y[0]=1.0f;
      Y[1]=s3*y; Y[2]=s3*z; Y[3]=s3*x;
      Y[4]=s15*x*y; Y[5]=s15*y*z; Y[6]=0.5f*s5*(3.0f*z*z-1.0f); Y[7]=s15*x*z; Y[8]=0.5f*s15*(x*x-y*y);
      Y[9]=c33*y*(3.0f*x*x-y*y); Y[10]=c32*x*y*z; Y[11]=c31*y*(5.0f*z*z-1.0f);
      Y[12]=c30*(5.0f*z*z*z-3.0f*z); Y[13]=c31*x*(5.0f*z*z-1.0f); Y[14]=cp2*z*(x*x-y*y);
      Y[15]=c33*x*(x*x-3.0f*y*y);
      float X[16];
      {
        const float inv = 0.5129891760f;           // 1/sqrt(3.8)
        const float4* q4 = (const float4*)(xacc + (size_t)s*16);
        float4 a=q4[0],b=q4[1],cc4=q4[2],d4=q4[3];
        X[0]=a.x*inv;X[1]=a.y*inv;X[2]=a.z*inv;X[3]=a.w*inv;
        X[4]=b.x*inv;X[5]=b.y*inv;X[6]=b.z*inv;X[7]=b.w*inv;
        X[8]=cc4.x*inv;X[9]=cc4.y*inv;X[10]=cc4.z*inv;X[11]=cc4.w*inv;
        X[12]=d4.x*inv;X[13]=d4.y*inv;X[14]=d4.z*inv;X[15]=d4.w*inv;
      }
      float* SS = SI[g][je];

      // t-block (scalar outputs)
      {
        float t0v = CG000.v[0]*X[0]*Y[0];
        float t1v=0.f, t2v=0.f, t3v=0.f;
#pragma unroll
        for (int i=0;i<3;++i)
#pragma unroll
          for (int j=0;j<3;++j) TERM(CG110, i*3+j, X[1+i]*Y[1+j], t1v)
#pragma unroll
        for (int i=0;i<5;++i)
#pragma unroll
          for (int j=0;j<5;++j) TERM(CG220, i*5+j, X[4+i]*Y[4+j], t2v)
#pragma unroll
        for (int i=0;i<7;++i)
#pragma unroll
          for (int j=0;j<7;++j) TERM(CG330, i*7+j, X[9+i]*Y[9+j], t3v)
        SS[0]=t0v; SS[1]=t1v; SS[2]=t2v; SS[3]=t3v;
      }
      // vector outputs
      {
        float v01[3]={0,0,0}, v10[3]={0,0,0}, v11[3]={0,0,0}, v12[3]={0,0,0},
              v21[3]={0,0,0}, v22[3]={0,0,0}, v23[3]={0,0,0}, v32[3]={0,0,0}, v33[3]={0,0,0};
#pragma unroll
        for (int j=0;j<3;++j){ float tt=X[0]*Y[1+j];
#pragma unroll
          for (int k=0;k<3;++k) TERM(CG011, j*3+k, tt, v01[k]) }
#pragma unroll
        for (int i=0;i<3;++i){ float tt=X[1+i]*Y[0];
#pragma unroll
          for (int k=0;k<3;++k) TERM(CG101, i*3+k, tt, v10[k]) }
#pragma unroll
        for (int i=0;i<3;++i)
#pragma unroll
          for (int j=0;j<3;++j){ float tt=X[1+i]*Y[1+j];
#pragma unroll
            for (int k=0;k<3;++k) TERM(CG111, (i*3+j)*3+k, tt, v11[k]) }
#pragma unroll
        for (int i=0;i<3;++i)
#pragma unroll
          for (int j=0;j<5;++j){ float tt=X[1+i]*Y[4+j];
#pragma unroll
            for (int k=0;k<3;++k) TERM(CG121, (i*5+j)*3+k, tt, v12[k]) }
#pragma unroll
        for (int i=0;i<5;++i)
#pragma unroll
          for (int j=0;j<3;++j){ float tt=X[4+i]*Y[1+j];
#pragma unroll
            for (int k=0;k<3;++k) TERM(CG211, (i*3+j)*3+k, tt, v21[k]) }
#pragma unroll
        for (int i=0;i<5;++i)
#pragma unroll
          for (int j=0;j<5;++j){ float tt=X[4+i]*Y[4+j];
#pragma unroll
            for (int k=0;k<3;++k) TERM(CG221, (i*5+j)*3+k, tt, v22[k]) }
#pragma unroll
        for (int i=0;i<5;++i)
#pragma unroll
          for (int j=0;j<7;++j){ float tt=X[4+i]*Y[9+j];
#pragma unroll
            for (int k=0;k<3;++k) TERM(CG231, (i*7+j)*3+k, tt, v23[k]) }
#pragma unroll
        for (int i=0;i<7;++i)
#pragma unroll
          for (int j=0;j<5;++j){ float tt=X[9+i]*Y[4+j];
#pragma unroll
            for (int k=0;k<3;++k) TERM(CG321, (i*5+j)*3+k, tt, v32[k]) }
#pragma unroll
        for (int i=0;i<7;++i)
#pragma unroll
          for (int j=0;j<7;++j){ float tt=X[9+i]*Y[9+j];
#pragma unroll
            for (int k=0;k<3;++k) TERM(CG331, (i*7+j)*3+k, tt, v33[k]) }
#pragma unroll
        for (int k=0;k<3;++k){
          SS[4+k]=v01[k]; SS[7+k]=v10[k]; SS[10+k]=v12[k]; SS[13+k]=v21[k];
          SS[16+k]=v23[k]; SS[19+k]=v32[k]; SS[22+k]=v11[k]; SS[25+k]=v22[k]; SS[28+k]=v33[k];
        }
      }
      SS[31]=0.0f;
      SiT[g][je]=i0;
    }
    __syncthreads();                 // RAW: phase-1 SI/SiT visible
    // ---- phase 2: per-node accumulation, single nearest bf16 row ----
#pragma unroll
    for (int q=0;q<NG;++q){
      const int cq = deg[q] - t*CH2;
#pragma unroll 4
      for (int j=0; j<CH2; ++j){
        if (j < cq){
          const float* __restrict__ I = SI[q][j];
          const unsigned short* __restrict__ wp = tabP + ((size_t)SiT[q][j]*512) + 8*lane;
          uint4 ra = *(const uint4*)wp;          // 8 bf16 weights
          float a8[8];
          unp8(ra, a8);
          acc0[q] = fmaf(a8[0], I[ioS[0]], acc0[q]);
          acc0[q] = fmaf(a8[1], I[ioS[1]], acc0[q]);
          acc0[q] = fmaf(a8[2], I[ioS[2]], acc0[q]);
          acc0[q] = fmaf(a8[3], I[ioS[3]], acc0[q]);
          acc1[q] = fmaf(a8[4], I[ioS[4]], acc1[q]);
          acc1[q] = fmaf(a8[5], I[ioS[5]], acc1[q]);
          acc1[q] = fmaf(a8[6], I[ioS[6]], acc1[q]);
          acc1[q] = fmaf(a8[7], I[ioS[7]], acc1[q]);
        }
      }
    }
  }

  // ---- fused gate epilogue (per node), bf16 output ----
  const float inv = 0.5129891760f;
  if (lane < 16){
#pragma unroll
    for (int q=0;q<NG;++q){
      SG[q][2*lane]   = acc0[q]*0.5f*inv;
      SG[q][2*lane+1] = acc1[q]*0.5f*inv;
    }
  }
  __syncthreads();
#pragma unroll
  for (int q=0;q<NG;++q){
    unsigned short* __restrict__ o = xgb + (size_t)(nb+q)*64;
    if (lane < 16){
      o[lane] = bfpack(fmaxf(SG[q][lane], 0.0f));            // se
    } else if (lane < 40){
      int idx = lane-16;
      float vv = (acc0[q]+acc1[q])*0.4082482905f*inv;
      o[16+idx] = bfpack(vv * fmaxf(SG[q][gu0], 0.0f));      // v1o (u<8)
    } else if (lane < 52){
      int m = lane-40;
      float vv0 = acc0[q]*0.5773502692f*inv;
      float vv1 = acc1[q]*0.5773502692f*inv;
      o[40+2*m]   = bfpack(vv0 * fmaxf(SG[q][gu0], 0.0f));   // v1e (u<8)
      o[40+2*m+1] = bfpack(vv1 * fmaxf(SG[q][gu1], 0.0f));
    }
  }
}

// ---------------- fctp2 + fused dst-segmented reduction -> out ----------------
__global__ __launch_bounds__(256) void k_tp2(
    const float* __restrict__ pos, const int* __restrict__ src, const int* __restrict__ dst, int E,
    const unsigned short* __restrict__ xgb, const unsigned short* __restrict__ tab2b,
    float* __restrict__ out)
{
  const int tid = threadIdx.x;
  const int e = blockIdx.x*256 + tid;
  __shared__ float S0[256], S1[256], S2[256];
  __shared__ int   D[256];
  float e2[3]={0,0,0};
  int dd = -1;
  if (e < E){
    const int s = src[e];
    dd = dst[e];
    float ax=pos[3*s]-pos[3*dd], ay=pos[3*s+1]-pos[3*dd+1], az=pos[3*s+2]-pos[3*dd+2];
    float r = sqrtf(ax*ax+ay*ay+az*az);
    float ir = 1.0f/r;
    float x=ax*ir, y=ay*ir, z=az*ir;
    float f = r * 1228.4f;                     // (T_TAB-1)/2.5
    int i0 = (int)(f + 0.5f);                  // nearest row
    if (i0 > T_TAB-1) i0 = T_TAB-1;
    const unsigned short* __restrict__ w0 = tab2b + (size_t)i0*64;
    float wse[16], wA[8], wB[8], wC[8];
    unp8(*(const uint4*)(w0+0),  wse);
    unp8(*(const uint4*)(w0+8),  wse+8);
    unp8(*(const uint4*)(w0+16), wA);
    unp8(*(const uint4*)(w0+32), wB);
    unp8(*(const uint4*)(w0+48), wC);
    const float s3=1.73205081f, s5=2.23606798f, s15=3.87298335f;
    float Y[9];
    Y[0]=1.0f;
    Y[1]=s3*y; Y[2]=s3*z; Y[3]=s3*x;
    Y[4]=s15*x*y; Y[5]=s15*y*z; Y[6]=0.5f*s5*(3.0f*z*z-1.0f); Y[7]=s15*x*z; Y[8]=0.5f*s15*(x*x-y*y);
    const unsigned short* __restrict__ g = xgb + (size_t)s*64;
    float se[16], vo[24], ve[24];
    unp8(*(const uint4*)(g+0),  se);  unp8(*(const uint4*)(g+8),  se+8);
    unp8(*(const uint4*)(g+16), vo);  unp8(*(const uint4*)(g+24), vo+8); unp8(*(const uint4*)(g+32), vo+16);
    unp8(*(const uint4*)(g+40), ve);  unp8(*(const uint4*)(g+48), ve+8); unp8(*(const uint4*)(g+56), ve+16);

    float SA=0.0f;
#pragma unroll
    for (int u=0;u<16;++u) SA = fmaf(wse[u], se[u], SA);
    float AB[3]={0,0,0}, AC[3]={0,0,0}, AD[3]={0,0,0};
#pragma unroll
    for (int u=0;u<8;++u)
#pragma unroll
      for (int i=0;i<3;++i){
        AB[i]=fmaf(wA[u], vo[u*3+i], AB[i]);
        AC[i]=fmaf(wB[u], vo[u*3+i], AC[i]);
        AD[i]=fmaf(wC[u], ve[u*3+i], AD[i]);
      }
#pragma unroll
    for (int j=0;j<3;++j){ float t=SA*Y[1+j];
#pragma unroll
      for (int k=0;k<3;++k) TERM(CG011, j*3+k, t, e2[k]) }
#pragma unroll
    for (int i=0;i<3;++i){ float t=AB[i]*Y[0];
#pragma unroll
      for (int k=0;k<3;++k) TERM(CG101, i*3+k, t, e2[k]) }
#pragma unroll
    for (int i=0;i<3;++i)
#pragma unroll
      for (int j=0;j<5;++j){ float t=AC[i]*Y[4+j];
#pragma unroll
        for (int k=0;k<3;++k) TERM(CG121, (i*5+j)*3+k, t, e2[k]) }
#pragma unroll
    for (int i=0;i<3;++i)
#pragma unroll
      for (int j=0;j<3;++j){ float t=AD[i]*Y[1+j];
#pragma unroll
        for (int k=0;k<3;++k) TERM(CG111, (i*3+j)*3+k, t, e2[k]) }
  }
  S0[tid]=e2[0]; S1[tid]=e2[1]; S2[tid]=e2[2]; D[tid]=dd;
  __syncthreads();
  if (e < E && (tid==0 || D[tid-1] != dd)){
    float a0=0.f, a1=0.f, a2=0.f;
    int j = tid;
    while (j < 256 && D[j] == dd){ a0+=S0[j]; a1+=S1[j]; a2+=S2[j]; ++j; }
    const float sc = 0.0641236437f;  // (1/sqrt(64)) * 1/sqrt(3.8)
    afadd(out + (size_t)dd*3 + 0, a0*sc);
    afadd(out + (size_t)dd*3 + 1, a1*sc);
    afadd(out + (size_t)dd*3 + 2, a2*sc);
  }
}

// ---------------- host launcher ----------------
extern "C" void kernel_launch(void* const* d_in, const int* in_sizes, int n_in,
                              void* d_out, int out_size, void* d_ws, size_t ws_size,
                              hipStream_t stream)
{
  (void)n_in; (void)ws_size;
  const float* pos = (const float*)d_in[0];
  const int*   src = (const int*)d_in[1];
  const int*   dst = (const int*)d_in[2];
  const float* W1  = (const float*)d_in[3];
  const float* W2  = (const float*)d_in[4];
  const float* W1f = (const float*)d_in[5];
  const float* W2f = (const float*)d_in[6];
  const int E = in_sizes[1];

  char* ws = (char*)d_ws;
  float* xacc  = (float*)ws;                     // NN*16
  unsigned short* xgb = (unsigned short*)(xacc + (size_t)NN*16);        // NN*64 ushort
  float* tab1  = (float*)(xgb + (size_t)NN*64);  // T_TAB*272
  unsigned short* tab2b = (unsigned short*)(tab1 + (size_t)T_TAB*272);  // T_TAB*64 ushort
  unsigned short* tabP  = tab2b + (size_t)T_TAB*64;                     // T_TAB*512 ushort
  int*   rowptr= (int*)(tabP + (size_t)T_TAB*512);                      // NN+1

  const int ozb = (out_size + 255) / 256;
  k_stageA<<<TBLK + RPB + ozb, 256, 0, stream>>>(W1, W2, W1f, W2f, tab1, tab2b,
                                                 dst, E, rowptr, (float*)d_out, out_size);
  k_stageB<<<PERB + (NN*4)/256, 256, 0, stream>>>(tab1, tabP, pos, src, rowptr, xacc);
  k_tp1<<<NN/NG, 64, 0, stream>>>(pos, src, rowptr, xacc, tabP, xgb);
  k_tp2<<<(E + 255) / 256, 256, 0, stream>>>(pos, src, dst, E, xgb, tab2b, (float*)d_out);
}

// Round 19
// 77.024 us; speedup vs baseline: 3.4870x; 1.0903x over previous
//
#include <hip/hip_runtime.h>
#include <cmath>

#define T_TAB 3072
#define NN 16384
#define NG 4
#define CH2 16

// ================= compile-time CG tables (constexpr port of the reference) ========
struct CD { double re, im; };
constexpr CD cmul(CD a, CD b){ return {a.re*b.re - a.im*b.im, a.re*b.im + a.im*b.re}; }
constexpr CD cadd(CD a, CD b){ return {a.re+b.re, a.im+b.im}; }
constexpr CD conj_(CD a){ return {a.re, -a.im}; }
constexpr CD cscale(CD a, double s){ return {a.re*s, a.im*s}; }
constexpr double cfabs_(double x){ return x<0.0 ? -x : x; }
constexpr double csqrt_(double x){
  double g = x > 1.0 ? x : 1.0;
  for (int i=0;i<80;++i) g = 0.5*(g + x/g);
  return g;
}
constexpr double factd(int n){ double r=1.0; for(int i=2;i<=n;++i) r*=(double)i; return r; }

constexpr double cg_coef(int j1,int m1,int j2,int m2,int j3,int m3){
  double pref = csqrt_((2.0*j3+1.0)*factd(j3+j1-j2)*factd(j3-j1+j2)*factd(j1+j2-j3)/factd(j1+j2+j3+1));
  pref *= csqrt_(factd(j3+m3)*factd(j3-m3)*factd(j1-m1)*factd(j1+m1)*factd(j2-m2)*factd(j2+m2));
  double s=0.0;
  for(int k=0;k<=j1+j2-j3;++k){
    int a0=k,a1=j1+j2-j3-k,a2=j1-m1-k,a3=j2+m2-k,a4=j3-j2+m1+k,a5=j3-j1-m2+k;
    if(a0<0||a1<0||a2<0||a3<0||a4<0||a5<0) continue;
    double d=factd(a0)*factd(a1)*factd(a2)*factd(a3)*factd(a4)*factd(a5);
    s += ((k&1)?-1.0:1.0)/d;
  }
  return pref*s;
}

struct UMat { CD u[7][7]; };
constexpr UMat u_fill(int l){
  UMat M{};
  const double is2 = csqrt_(0.5);
  M.u[l][l] = CD{1.0, 0.0};
  for(int m=1;m<=l;++m){
    double sgn = (m&1)?-1.0:1.0;
    M.u[l+m][l+m] = CD{sgn*is2, 0.0};
    M.u[l+m][l-m] = CD{is2, 0.0};
    M.u[l-m][l-m] = CD{0.0, is2};
    M.u[l-m][l+m] = CD{0.0, -sgn*is2};
  }
  return M;
}

template<int L1,int L2,int L3>
struct FT { float v[(2*L1+1)*(2*L2+1)*(2*L3+1)]; };

template<int L1,int L2,int L3>
constexpr FT<L1,L2,L3> cg_real_ct(){
  constexpr int n1=2*L1+1, n2=2*L2+1, n3=2*L3+1;
  double Cc[7][7][7] = {};
  for(int m1=-L1;m1<=L1;++m1)
    for(int m2=-L2;m2<=L2;++m2){
      int m3=m1+m2;
      if(m3>=-L3&&m3<=L3) Cc[m1+L1][m2+L2][m3+L3]=cg_coef(L1,m1,L2,m2,L3,m3);
    }
  UMat U1 = u_fill(L1), U2 = u_fill(L2), U3 = u_fill(L3);
  CD Cr[7][7][7] = {};
  double sre=0.0, sim=0.0;
  for(int a=0;a<n1;++a)for(int b=0;b<n2;++b)for(int c=0;c<n3;++c){
    CD acc{0.0,0.0};
    for(int u=0;u<n1;++u)for(int v=0;v<n2;++v){
      int w = (u-L1)+(v-L2)+L3;           // only m3=m1+m2 can be nonzero in Cc
      if (w < 0 || w >= n3) continue;
      double cc = Cc[u][v][w];
      if (cc == 0.0) continue;
      acc = cadd(acc, cscale(cmul(cmul(U1.u[a][u],U2.u[b][v]),conj_(U3.u[c][w])), cc));
    }
    Cr[a][b][c] = acc;
    sre += cfabs_(acc.re); sim += cfabs_(acc.im);
  }
  FT<L1,L2,L3> out{};
  bool useim = sim > sre;
  for(int a=0;a<n1;++a)for(int b=0;b<n2;++b)for(int c=0;c<n3;++c)
    out.v[(a*n2+b)*n3+c] = (float)(useim ? Cr[a][b][c].im : Cr[a][b][c].re);
  return out;
}

constexpr auto CG000 = cg_real_ct<0,0,0>();
constexpr auto CG110 = cg_real_ct<1,1,0>();
constexpr auto CG220 = cg_real_ct<2,2,0>();
constexpr auto CG330 = cg_real_ct<3,3,0>();
constexpr auto CG011 = cg_real_ct<0,1,1>();
constexpr auto CG101 = cg_real_ct<1,0,1>();
constexpr auto CG111 = cg_real_ct<1,1,1>();
constexpr auto CG121 = cg_real_ct<1,2,1>();
constexpr auto CG211 = cg_real_ct<2,1,1>();
constexpr auto CG221 = cg_real_ct<2,2,1>();
constexpr auto CG231 = cg_real_ct<2,3,1>();
constexpr auto CG321 = cg_real_ct<3,2,1>();
constexpr auto CG331 = cg_real_ct<3,3,1>();

// zero-pruned FMA term: coefficient folds to a literal; zero terms are deleted.
#define TERM(TBL, IDX, PROD, ACC) { float c_ = TBL.v[IDX]; if (c_ != 0.0f) ACC = fmaf((PROD), c_, ACC); }

// Per-lane weight schedule: lane ℓ, sub-index q (0..7) -> (column in [0,272) or -1, LDS slot).
// Slot 31 is a guaranteed-zero slot. constexpr: usable on host (INV build) and device.
__host__ __device__ constexpr void lane_sched(int lane, int q, int& col, int& slot){
  col = -1; slot = 31;
  if (lane < 16){
    int s = q >> 2, qq = q & 3;
    int a = 2*lane + s;                 // scalar output index 0..31
    const int base0[4] = {0, 64, 144, 224};
    col = base0[qq] + a; slot = qq;
  } else if (lane < 40){
    int idx = lane-16, u = idx/3, k = idx-3*u;
    const int wb[6] = {32,48,112,128,192,208};
    const int sb[6] = {4,7,10,13,16,19};
    if (q < 6){ col = wb[q]+u; slot = sb[q]+k; }
  } else if (lane < 52){
    int m = lane-40;
    int c0 = (q < 4) ? 2*m : 2*m+1;
    int u = c0/3, k = c0-3*u;
    int qq = (q < 4) ? q : q-4;
    if (qq < 3){
      const int wb[3] = {96,176,256};
      const int sb[3] = {22,25,28};
      col = wb[qq]+u; slot = sb[qq]+k;
    }
  }
}

// Compile-time inverse map: column -> packed tabP positions (<=3, shared weights dup'd).
struct InvMap { short cnt[272]; short pos[272][3]; };
constexpr InvMap build_inv(){
  InvMap v{};
  for (int c=0;c<272;++c) v.cnt[c]=0;
  for (int p=0;p<512;++p){
    int col=-1, slot=31;
    lane_sched(p>>3, p&7, col, slot);
    if (col>=0){ v.pos[col][v.cnt[col]] = (short)p; v.cnt[col] = (short)(v.cnt[col]+1); }
  }
  return v;
}
constexpr auto INV = build_inv();

// ---------------- device helpers ----------------
__device__ __forceinline__ void afadd(float* p, float v){ unsafeAtomicAdd(p, v); }

__device__ __forceinline__ float soh(float r, float c){
  float d = (r - c) * 2.0f;
  float d2 = d*d;
  return (d2 < 1.0f) ? 1.14136f * expf(2.0f + 1.0f/(d2-1.0f)) : 0.0f;
}

__device__ __forceinline__ float bf_lo(unsigned u){ return __uint_as_float(u << 16); }
__device__ __forceinline__ float bf_hi(unsigned u){ return __uint_as_float(u & 0xFFFF0000u); }
__device__ __forceinline__ unsigned short bfpack(float v){
  unsigned b = __float_as_uint(v);
  return (unsigned short)((b + 0x7FFFu + ((b >> 16) & 1u)) >> 16);   // RTNE
}
__device__ __forceinline__ void unp8(uint4 u, float* o){
  o[0]=bf_lo(u.x); o[1]=bf_hi(u.x); o[2]=bf_lo(u.y); o[3]=bf_hi(u.y);
  o[4]=bf_lo(u.z); o[5]=bf_hi(u.z); o[6]=bf_lo(u.w); o[7]=bf_hi(u.w);
}

// ---------------- stage A (fused): tabP/tab2b build + k_x(+rowptr) + out-zero -------
// blocks [0,1008):   radial MLP, jq-major; tab1 columns scatter-written DIRECTLY into
//                    bf16 tabP via the constexpr inverse map (k_perm deleted).
//                    Dummy tabP slots are never read with nonzero I (I[31]=0), and
//                    0xAA poison is a finite bf16, so they need no init.
// blocks [1008,1264): k_x, 4 lanes/node; each group does its own rowptr binary search
//                    (lanes search n+(q&1), shfl-exchange; q==0 writes rowptr[n]).
// blocks [1264, ...): zero out[].
#define TBLK 1008
#define XB   256
__global__ __launch_bounds__(256) void k_stageA(
    const float* __restrict__ W1, const float* __restrict__ W2,
    const float* __restrict__ W1f, const float* __restrict__ W2f,
    unsigned short* __restrict__ tabP, unsigned short* __restrict__ tab2b,
    const float* __restrict__ pos, const int* __restrict__ src,
    const int* __restrict__ dst, int E, int* __restrict__ rowptr,
    float* __restrict__ xacc, float* __restrict__ out, int outN)
{
  const int bid = blockIdx.x;
  if (bid < TBLK){
    const int jq  = bid / 12;                   // 0..83
    const int t   = (bid % 12)*256 + threadIdx.x;
    const int j0  = jq*4;
    const float dr = 2.5f / (float)(T_TAB-1);
    const float r = (float)t * dr;
    const float e0 = soh(r,1.0f), e1 = soh(r,1.5f), e2 = soh(r,2.0f);
    float ax=0.f, ay=0.f, az=0.f, aw=0.f;
    if (j0 < 272){
      for (int cc=0; cc<256; ++cc){
        float h = fmaxf(fmaf(e0,W1[cc], fmaf(e1,W1[256+cc], e2*W1[512+cc])), 0.0f);
        float4 w = *(const float4*)(W2 + cc*272 + j0);
        ax = fmaf(h,w.x,ax); ay = fmaf(h,w.y,ay);
        az = fmaf(h,w.z,az); aw = fmaf(h,w.w,aw);
      }
      float val[4] = {ax*0.0625f, ay*0.0625f, az*0.0625f, aw*0.0625f};
      unsigned short* __restrict__ rowp = tabP + (size_t)t*512;
#pragma unroll
      for (int k2=0;k2<4;++k2){
        const int c = j0 + k2;
        const unsigned short bv = bfpack(val[k2]);
        const int cn = INV.cnt[c];
        for (int i=0;i<cn;++i) rowp[INV.pos[c][i]] = bv;
      }
    } else {
      const int jj = j0 - 272;
      for (int cc=0; cc<256; ++cc){
        float h = fmaxf(fmaf(e0,W1f[cc], fmaf(e1,W1f[256+cc], e2*W1f[512+cc])), 0.0f);
        float4 w = *(const float4*)(W2f + cc*64 + jj);
        ax = fmaf(h,w.x,ax); ay = fmaf(h,w.y,ay);
        az = fmaf(h,w.z,az); aw = fmaf(h,w.w,aw);
      }
      ushort4 o;
      o.x = bfpack(ax*0.0625f); o.y = bfpack(ay*0.0625f);
      o.z = bfpack(az*0.0625f); o.w = bfpack(aw*0.0625f);
      *(ushort4*)(tab2b + (size_t)t*64 + jj) = o;
    }
  } else if (bid < TBLK + XB){
    const int tt = (bid-TBLK)*256 + threadIdx.x;
    const int n = tt>>2, q = tt&3;
    // own rowptr binary search (dst globally non-decreasing): target n + (q&1)
    const int tgt = n + (q&1);
    int lo=0, hi=E;
    while (lo<hi){ int mid=(lo+hi)>>1; if (dst[mid] < tgt) lo=mid+1; else hi=mid; }
    if (q==0) rowptr[n] = lo;
    if (q==1 && n==NN-1) rowptr[NN] = lo;
    const int l = threadIdx.x & 63;
    const int base = l & ~3;
    const int r0 = __shfl(lo, base);
    const int r1 = __shfl(lo, base+1);
    const float pdx=pos[3*n], pdy=pos[3*n+1], pdz=pos[3*n+2];
    const float s3=1.73205081f, s5=2.23606798f, s15=3.87298335f;
    const float c33=2.09165007f, c32=10.2469508f, c31=1.62018517f, c30=1.32287566f, cp2=5.12347538f;
    float a0=0,a1=0,a2=0,a3=0,a4=0,a5=0,a6=0,a7=0,a8=0,a9=0,a10=0,a11=0,a12=0,a13=0,a14=0,a15=0;
    for (int e=r0+q; e<r1; e+=4){
      const int s=src[e];
      float ax=pos[3*s]-pdx, ay=pos[3*s+1]-pdy, az=pos[3*s+2]-pdz;
      float ir = 1.0f/sqrtf(ax*ax+ay*ay+az*az);
      float x=ax*ir, y=ay*ir, z=az*ir;
      a0+=1.0f; a1+=s3*y; a2+=s3*z; a3+=s3*x;
      a4+=s15*x*y; a5+=s15*y*z; a6+=0.5f*s5*(3.0f*z*z-1.0f); a7+=s15*x*z;
      a8+=0.5f*s15*(x*x-y*y); a9+=c33*y*(3.0f*x*x-y*y); a10+=c32*x*y*z; a11+=c31*y*(5.0f*z*z-1.0f);
      a12+=c30*(5.0f*z*z*z-3.0f*z); a13+=c31*x*(5.0f*z*z-1.0f); a14+=cp2*z*(x*x-y*y);
      a15+=c33*x*(x*x-3.0f*y*y);
    }
#define RED(v) v += __shfl_xor(v,1); v += __shfl_xor(v,2);
    RED(a0) RED(a1) RED(a2) RED(a3) RED(a4) RED(a5) RED(a6) RED(a7)
    RED(a8) RED(a9) RED(a10) RED(a11) RED(a12) RED(a13) RED(a14) RED(a15)
#undef RED
    float o0,o1,o2,o3;
    if (q==0){ o0=a0; o1=a1; o2=a2; o3=a3; }
    else if (q==1){ o0=a4; o1=a5; o2=a6; o3=a7; }
    else if (q==2){ o0=a8; o1=a9; o2=a10; o3=a11; }
    else { o0=a12; o1=a13; o2=a14; o3=a15; }
    *(float4*)(xacc + (size_t)n*16 + q*4) = make_float4(o0,o1,o2,o3);
  } else {
    const int idx = (bid - TBLK - XB)*256 + threadIdx.x;
    if (idx < outN) out[idx] = 0.0f;
  }
}

// ---------------- fctp1 + gate fused: ONE WAVE covers FOUR nodes --------------
__global__ __launch_bounds__(64) void k_tp1(
    const float* __restrict__ pos, const int* __restrict__ src,
    const int* __restrict__ rowptr, const float* __restrict__ xacc,
    const unsigned short* __restrict__ tabP, unsigned short* __restrict__ xgb)
{
  const int lane = threadIdx.x;
  const int nb   = blockIdx.x*NG;
  const int g    = lane >> 4, je = lane & 15;
  __shared__ float SI[NG][CH2][33];   // 0..30 intermediates, 31 zero
  __shared__ int   SiT[NG][CH2];
  __shared__ float SG[NG][32];

  int rp[NG+1];
#pragma unroll
  for (int q=0;q<=NG;++q) rp[q] = rowptr[nb+q];
  int deg[NG];
#pragma unroll
  for (int q=0;q<NG;++q) deg[q] = rp[q+1]-rp[q];
  const int dmax = max(max(deg[0],deg[1]), max(deg[2],deg[3]));
  const int nch = (dmax + CH2 - 1) / CH2;

  // ---- static LDS-slot schedule + gate indices ----
  int ioS[8];
#pragma unroll
  for (int p=0;p<8;++p){ int c_=-1, s_=31; lane_sched(lane, p, c_, s_); ioS[p] = s_; }
  int gu0=16, gu1=16;
  if (lane >= 16 && lane < 40){ gu0 = 16 + (lane-16)/3; }
  else if (lane >= 40 && lane < 52){
    int m=lane-40; gu0 = 24 + (2*m)/3; gu1 = 24 + (2*m+1)/3;
  }

  const int mynode = nb + g;
  const float pdx=pos[3*mynode], pdy=pos[3*mynode+1], pdz=pos[3*mynode+2];
  float acc0[NG]={0,0,0,0}, acc1[NG]={0,0,0,0};

  for (int t=0; t<nch; ++t){
    __syncthreads();                 // WAR: prev chunk phase-2 reads done
    const int cg_ = deg[g] - t*CH2;  // my group's remaining edges
    if (je < cg_){
      const int e = rp[g] + t*CH2 + je;
      const int s = src[e];
      float ax=pos[3*s]-pdx, ay=pos[3*s+1]-pdy, az=pos[3*s+2]-pdz;
      float r = sqrtf(ax*ax+ay*ay+az*az);
      float ir = 1.0f/r;
      float x=ax*ir, y=ay*ir, z=az*ir;
      float f = r * 1228.4f;                    // (T_TAB-1)/2.5
      int i0 = (int)(f + 0.5f);                 // nearest row
      if (i0 > T_TAB-1) i0 = T_TAB-1;

      const float s3=1.73205081f, s5=2.23606798f, s15=3.87298335f;
      const float c33=2.09165007f, c32=10.2469508f, c31=1.62018517f, c30=1.32287566f, cp2=5.12347538f;
      float Y[16];
      Y[0]=1.0f;
      Y[1]=s3*y; Y[2]=s3*z; Y[3]=s3*x;
      Y[4]=s15*x*y; Y[5]=s15*y*z; Y[6]=0.5f*s5*(3.0f*z*z-1.0f); Y[7]=s15*x*z; Y[8]=0.5f*s15*(x*x-y*y);
      Y[9]=c33*y*(3.0f*x*x-y*y); Y[10]=c32*x*y*z; Y[11]=c31*y*(5.0f*z*z-1.0f);
      Y[12]=c30*(5.0f*z*z*z-3.0f*z); Y[13]=c31*x*(5.0f*z*z-1.0f); Y[14]=cp2*z*(x*x-y*y);
      Y[15]=c33*x*(x*x-3.0f*y*y);
      float X[16];
      {
        const float inv = 0.5129891760f;           // 1/sqrt(3.8)
        const float4* q4 = (const float4*)(xacc + (size_t)s*16);
        float4 a=q4[0],b=q4[1],cc4=q4[2],d4=q4[3];
        X[0]=a.x*inv;X[1]=a.y*inv;X[2]=a.z*inv;X[3]=a.w*inv;
        X[4]=b.x*inv;X[5]=b.y*inv;X[6]=b.z*inv;X[7]=b.w*inv;
        X[8]=cc4.x*inv;X[9]=cc4.y*inv;X[10]=cc4.z*inv;X[11]=cc4.w*inv;
        X[12]=d4.x*inv;X[13]=d4.y*inv;X[14]=d4.z*inv;X[15]=d4.w*inv;
      }
      float* SS = SI[g][je];

      // t-block (scalar outputs)
      {
        float t0v = CG000.v[0]*X[0]*Y[0];
        float t1v=0.f, t2v=0.f, t3v=0.f;
#pragma unroll
        for (int i=0;i<3;++i)
#pragma unroll
          for (int j=0;j<3;++j) TERM(CG110, i*3+j, X[1+i]*Y[1+j], t1v)
#pragma unroll
        for (int i=0;i<5;++i)
#pragma unroll
          for (int j=0;j<5;++j) TERM(CG220, i*5+j, X[4+i]*Y[4+j], t2v)
#pragma unroll
        for (int i=0;i<7;++i)
#pragma unroll
          for (int j=0;j<7;++j) TERM(CG330, i*7+j, X[9+i]*Y[9+j], t3v)
        SS[0]=t0v; SS[1]=t1v; SS[2]=t2v; SS[3]=t3v;
      }
      // vector outputs
      {
        float v01[3]={0,0,0}, v10[3]={0,0,0}, v11[3]={0,0,0}, v12[3]={0,0,0},
              v21[3]={0,0,0}, v22[3]={0,0,0}, v23[3]={0,0,0}, v32[3]={0,0,0}, v33[3]={0,0,0};
#pragma unroll
        for (int j=0;j<3;++j){ float tt=X[0]*Y[1+j];
#pragma unroll
          for (int k=0;k<3;++k) TERM(CG011, j*3+k, tt, v01[k]) }
#pragma unroll
        for (int i=0;i<3;++i){ float tt=X[1+i]*Y[0];
#pragma unroll
          for (int k=0;k<3;++k) TERM(CG101, i*3+k, tt, v10[k]) }
#pragma unroll
        for (int i=0;i<3;++i)
#pragma unroll
          for (int j=0;j<3;++j){ float tt=X[1+i]*Y[1+j];
#pragma unroll
            for (int k=0;k<3;++k) TERM(CG111, (i*3+j)*3+k, tt, v11[k]) }
#pragma unroll
        for (int i=0;i<3;++i)
#pragma unroll
          for (int j=0;j<5;++j){ float tt=X[1+i]*Y[4+j];
#pragma unroll
            for (int k=0;k<3;++k) TERM(CG121, (i*5+j)*3+k, tt, v12[k]) }
#pragma unroll
        for (int i=0;i<5;++i)
#pragma unroll
          for (int j=0;j<3;++j){ float tt=X[4+i]*Y[1+j];
#pragma unroll
            for (int k=0;k<3;++k) TERM(CG211, (i*3+j)*3+k, tt, v21[k]) }
#pragma unroll
        for (int i=0;i<5;++i)
#pragma unroll
          for (int j=0;j<5;++j){ float tt=X[4+i]*Y[4+j];
#pragma unroll
            for (int k=0;k<3;++k) TERM(CG221, (i*5+j)*3+k, tt, v22[k]) }
#pragma unroll
        for (int i=0;i<5;++i)
#pragma unroll
          for (int j=0;j<7;++j){ float tt=X[4+i]*Y[9+j];
#pragma unroll
            for (int k=0;k<3;++k) TERM(CG231, (i*7+j)*3+k, tt, v23[k]) }
#pragma unroll
        for (int i=0;i<7;++i)
#pragma unroll
          for (int j=0;j<5;++j){ float tt=X[9+i]*Y[4+j];
#pragma unroll
            for (int k=0;k<3;++k) TERM(CG321, (i*5+j)*3+k, tt, v32[k]) }
#pragma unroll
        for (int i=0;i<7;++i)
#pragma unroll
          for (int j=0;j<7;++j){ float tt=X[9+i]*Y[9+j];
#pragma unroll
            for (int k=0;k<3;++k) TERM(CG331, (i*7+j)*3+k, tt, v33[k]) }
#pragma unroll
        for (int k=0;k<3;++k){
          SS[4+k]=v01[k]; SS[7+k]=v10[k]; SS[10+k]=v12[k]; SS[13+k]=v21[k];
          SS[16+k]=v23[k]; SS[19+k]=v32[k]; SS[22+k]=v11[k]; SS[25+k]=v22[k]; SS[28+k]=v33[k];
        }
      }
      SS[31]=0.0f;
      SiT[g][je]=i0;
    }
    __syncthreads();                 // RAW: phase-1 SI/SiT visible
    // ---- phase 2: per-node accumulation, single nearest bf16 row ----
#pragma unroll
    for (int q=0;q<NG;++q){
      const int cq = deg[q] - t*CH2;
#pragma unroll 4
      for (int j=0; j<CH2; ++j){
        if (j < cq){
          const float* __restrict__ I = SI[q][j];
          const unsigned short* __restrict__ wp = tabP + ((size_t)SiT[q][j]*512) + 8*lane;
          uint4 ra = *(const uint4*)wp;          // 8 bf16 weights
          float a8[8];
          unp8(ra, a8);
          acc0[q] = fmaf(a8[0], I[ioS[0]], acc0[q]);
          acc0[q] = fmaf(a8[1], I[ioS[1]], acc0[q]);
          acc0[q] = fmaf(a8[2], I[ioS[2]], acc0[q]);
          acc0[q] = fmaf(a8[3], I[ioS[3]], acc0[q]);
          acc1[q] = fmaf(a8[4], I[ioS[4]], acc1[q]);
          acc1[q] = fmaf(a8[5], I[ioS[5]], acc1[q]);
          acc1[q] = fmaf(a8[6], I[ioS[6]], acc1[q]);
          acc1[q] = fmaf(a8[7], I[ioS[7]], acc1[q]);
        }
      }
    }
  }

  // ---- fused gate epilogue (per node), bf16 output ----
  const float inv = 0.5129891760f;
  if (lane < 16){
#pragma unroll
    for (int q=0;q<NG;++q){
      SG[q][2*lane]   = acc0[q]*0.5f*inv;
      SG[q][2*lane+1] = acc1[q]*0.5f*inv;
    }
  }
  __syncthreads();
#pragma unroll
  for (int q=0;q<NG;++q){
    unsigned short* __restrict__ o = xgb + (size_t)(nb+q)*64;
    if (lane < 16){
      o[lane] = bfpack(fmaxf(SG[q][lane], 0.0f));            // se
    } else if (lane < 40){
      int idx = lane-16;
      float vv = (acc0[q]+acc1[q])*0.4082482905f*inv;
      o[16+idx] = bfpack(vv * fmaxf(SG[q][gu0], 0.0f));      // v1o (u<8)
    } else if (lane < 52){
      int m = lane-40;
      float vv0 = acc0[q]*0.5773502692f*inv;
      float vv1 = acc1[q]*0.5773502692f*inv;
      o[40+2*m]   = bfpack(vv0 * fmaxf(SG[q][gu0], 0.0f));   // v1e (u<8)
      o[40+2*m+1] = bfpack(vv1 * fmaxf(SG[q][gu1], 0.0f));
    }
  }
}

// ---------------- fctp2 + fused dst-segmented reduction -> out ----------------
__global__ __launch_bounds__(256) void k_tp2(
    const float* __restrict__ pos, const int* __restrict__ src, const int* __restrict__ dst, int E,
    const unsigned short* __restrict__ xgb, const unsigned short* __restrict__ tab2b,
    float* __restrict__ out)
{
  const int tid = threadIdx.x;
  const int e = blockIdx.x*256 + tid;
  __shared__ float S0[256], S1[256], S2[256];
  __shared__ int   D[256];
  float e2[3]={0,0,0};
  int dd = -1;
  if (e < E){
    const int s = src[e];
    dd = dst[e];
    float ax=pos[3*s]-pos[3*dd], ay=pos[3*s+1]-pos[3*dd+1], az=pos[3*s+2]-pos[3*dd+2];
    float r = sqrtf(ax*ax+ay*ay+az*az);
    float ir = 1.0f/r;
    float x=ax*ir, y=ay*ir, z=az*ir;
    float f = r * 1228.4f;                     // (T_TAB-1)/2.5
    int i0 = (int)(f + 0.5f);                  // nearest row
    if (i0 > T_TAB-1) i0 = T_TAB-1;
    const unsigned short* __restrict__ w0 = tab2b + (size_t)i0*64;
    float wse[16], wA[8], wB[8], wC[8];
    unp8(*(const uint4*)(w0+0),  wse);
    unp8(*(const uint4*)(w0+8),  wse+8);
    unp8(*(const uint4*)(w0+16), wA);
    unp8(*(const uint4*)(w0+32), wB);
    unp8(*(const uint4*)(w0+48), wC);
    const float s3=1.73205081f, s5=2.23606798f, s15=3.87298335f;
    float Y[9];
    Y[0]=1.0f;
    Y[1]=s3*y; Y[2]=s3*z; Y[3]=s3*x;
    Y[4]=s15*x*y; Y[5]=s15*y*z; Y[6]=0.5f*s5*(3.0f*z*z-1.0f); Y[7]=s15*x*z; Y[8]=0.5f*s15*(x*x-y*y);
    const unsigned short* __restrict__ g = xgb + (size_t)s*64;
    float se[16], vo[24], ve[24];
    unp8(*(const uint4*)(g+0),  se);  unp8(*(const uint4*)(g+8),  se+8);
    unp8(*(const uint4*)(g+16), vo);  unp8(*(const uint4*)(g+24), vo+8); unp8(*(const uint4*)(g+32), vo+16);
    unp8(*(const uint4*)(g+40), ve);  unp8(*(const uint4*)(g+48), ve+8); unp8(*(const uint4*)(g+56), ve+16);

    float SA=0.0f;
#pragma unroll
    for (int u=0;u<16;++u) SA = fmaf(wse[u], se[u], SA);
    float AB[3]={0,0,0}, AC[3]={0,0,0}, AD[3]={0,0,0};
#pragma unroll
    for (int u=0;u<8;++u)
#pragma unroll
      for (int i=0;i<3;++i){
        AB[i]=fmaf(wA[u], vo[u*3+i], AB[i]);
        AC[i]=fmaf(wB[u], vo[u*3+i], AC[i]);
        AD[i]=fmaf(wC[u], ve[u*3+i], AD[i]);
      }
#pragma unroll
    for (int j=0;j<3;++j){ float t=SA*Y[1+j];
#pragma unroll
      for (int k=0;k<3;++k) TERM(CG011, j*3+k, t, e2[k]) }
#pragma unroll
    for (int i=0;i<3;++i){ float t=AB[i]*Y[0];
#pragma unroll
      for (int k=0;k<3;++k) TERM(CG101, i*3+k, t, e2[k]) }
#pragma unroll
    for (int i=0;i<3;++i)
#pragma unroll
      for (int j=0;j<5;++j){ float t=AC[i]*Y[4+j];
#pragma unroll
        for (int k=0;k<3;++k) TERM(CG121, (i*5+j)*3+k, t, e2[k]) }
#pragma unroll
    for (int i=0;i<3;++i)
#pragma unroll
      for (int j=0;j<3;++j){ float t=AD[i]*Y[1+j];
#pragma unroll
        for (int k=0;k<3;++k) TERM(CG111, (i*3+j)*3+k, t, e2[k]) }
  }
  S0[tid]=e2[0]; S1[tid]=e2[1]; S2[tid]=e2[2]; D[tid]=dd;
  __syncthreads();
  if (e < E && (tid==0 || D[tid-1] != dd)){
    float a0=0.f, a1=0.f, a2=0.f;
    int j = tid;
    while (j < 256 && D[j] == dd){ a0+=S0[j]; a1+=S1[j]; a2+=S2[j]; ++j; }
    const float sc = 0.0641236437f;  // (1/sqrt(64)) * 1/sqrt(3.8)
    afadd(out + (size_t)dd*3 + 0, a0*sc);
    afadd(out + (size_t)dd*3 + 1, a1*sc);
    afadd(out + (size_t)dd*3 + 2, a2*sc);
  }
}

// ---------------- host launcher ----------------
extern "C" void kernel_launch(void* const* d_in, const int* in_sizes, int n_in,
                              void* d_out, int out_size, void* d_ws, size_t ws_size,
                              hipStream_t stream)
{
  (void)n_in; (void)ws_size;
  const float* pos = (const float*)d_in[0];
  const int*   src = (const int*)d_in[1];
  const int*   dst = (const int*)d_in[2];
  const float* W1  = (const float*)d_in[3];
  const float* W2  = (const float*)d_in[4];
  const float* W1f = (const float*)d_in[5];
  const float* W2f = (const float*)d_in[6];
  const int E = in_sizes[1];

  char* ws = (char*)d_ws;
  float* xacc  = (float*)ws;                     // NN*16
  unsigned short* xgb = (unsigned short*)(xacc + (size_t)NN*16);        // NN*64 ushort
  unsigned short* tab2b = xgb + (size_t)NN*64;   // T_TAB*64 ushort
  unsigned short* tabP  = tab2b + (size_t)T_TAB*64;                     // T_TAB*512 ushort
  int*   rowptr= (int*)(tabP + (size_t)T_TAB*512);                      // NN+1

  const int ozb = (out_size + 255) / 256;
  k_stageA<<<TBLK + XB + ozb, 256, 0, stream>>>(W1, W2, W1f, W2f, tabP, tab2b,
                                                pos, src, dst, E, rowptr, xacc,
                                                (float*)d_out, out_size);
  k_tp1<<<NN/NG, 64, 0, stream>>>(pos, src, rowptr, xacc, tabP, xgb);
  k_tp2<<<(E + 255) / 256, 256, 0, stream>>>(pos, src, dst, E, xgb, tab2b, (float*)d_out);
}

// Round 20
// 76.844 us; speedup vs baseline: 3.4952x; 1.0023x over previous
//
#include <hip/hip_runtime.h>
#include <cmath>

#define T_TAB 3072
#define NN 16384
#define NG 2
#define CH2 32

// ================= compile-time CG tables (constexpr port of the reference) ========
struct CD { double re, im; };
constexpr CD cmul(CD a, CD b){ return {a.re*b.re - a.im*b.im, a.re*b.im + a.im*b.re}; }
constexpr CD cadd(CD a, CD b){ return {a.re+b.re, a.im+b.im}; }
constexpr CD conj_(CD a){ return {a.re, -a.im}; }
constexpr CD cscale(CD a, double s){ return {a.re*s, a.im*s}; }
constexpr double cfabs_(double x){ return x<0.0 ? -x : x; }
constexpr double csqrt_(double x){
  double g = x > 1.0 ? x : 1.0;
  for (int i=0;i<80;++i) g = 0.5*(g + x/g);
  return g;
}
constexpr double factd(int n){ double r=1.0; for(int i=2;i<=n;++i) r*=(double)i; return r; }

constexpr double cg_coef(int j1,int m1,int j2,int m2,int j3,int m3){
  double pref = csqrt_((2.0*j3+1.0)*factd(j3+j1-j2)*factd(j3-j1+j2)*factd(j1+j2-j3)/factd(j1+j2+j3+1));
  pref *= csqrt_(factd(j3+m3)*factd(j3-m3)*factd(j1-m1)*factd(j1+m1)*factd(j2-m2)*factd(j2+m2));
  double s=0.0;
  for(int k=0;k<=j1+j2-j3;++k){
    int a0=k,a1=j1+j2-j3-k,a2=j1-m1-k,a3=j2+m2-k,a4=j3-j2+m1+k,a5=j3-j1-m2+k;
    if(a0<0||a1<0||a2<0||a3<0||a4<0||a5<0) continue;
    double d=factd(a0)*factd(a1)*factd(a2)*factd(a3)*factd(a4)*factd(a5);
    s += ((k&1)?-1.0:1.0)/d;
  }
  return pref*s;
}

struct UMat { CD u[7][7]; };
constexpr UMat u_fill(int l){
  UMat M{};
  const double is2 = csqrt_(0.5);
  M.u[l][l] = CD{1.0, 0.0};
  for(int m=1;m<=l;++m){
    double sgn = (m&1)?-1.0:1.0;
    M.u[l+m][l+m] = CD{sgn*is2, 0.0};
    M.u[l+m][l-m] = CD{is2, 0.0};
    M.u[l-m][l-m] = CD{0.0, is2};
    M.u[l-m][l+m] = CD{0.0, -sgn*is2};
  }
  return M;
}

template<int L1,int L2,int L3>
struct FT { float v[(2*L1+1)*(2*L2+1)*(2*L3+1)]; };

template<int L1,int L2,int L3>
constexpr FT<L1,L2,L3> cg_real_ct(){
  constexpr int n1=2*L1+1, n2=2*L2+1, n3=2*L3+1;
  double Cc[7][7][7] = {};
  for(int m1=-L1;m1<=L1;++m1)
    for(int m2=-L2;m2<=L2;++m2){
      int m3=m1+m2;
      if(m3>=-L3&&m3<=L3) Cc[m1+L1][m2+L2][m3+L3]=cg_coef(L1,m1,L2,m2,L3,m3);
    }
  UMat U1 = u_fill(L1), U2 = u_fill(L2), U3 = u_fill(L3);
  CD Cr[7][7][7] = {};
  double sre=0.0, sim=0.0;
  for(int a=0;a<n1;++a)for(int b=0;b<n2;++b)for(int c=0;c<n3;++c){
    CD acc{0.0,0.0};
    for(int u=0;u<n1;++u)for(int v=0;v<n2;++v){
      int w = (u-L1)+(v-L2)+L3;           // only m3=m1+m2 can be nonzero in Cc
      if (w < 0 || w >= n3) continue;
      double cc = Cc[u][v][w];
      if (cc == 0.0) continue;
      acc = cadd(acc, cscale(cmul(cmul(U1.u[a][u],U2.u[b][v]),conj_(U3.u[c][w])), cc));
    }
    Cr[a][b][c] = acc;
    sre += cfabs_(acc.re); sim += cfabs_(acc.im);
  }
  FT<L1,L2,L3> out{};
  bool useim = sim > sre;
  for(int a=0;a<n1;++a)for(int b=0;b<n2;++b)for(int c=0;c<n3;++c)
    out.v[(a*n2+b)*n3+c] = (float)(useim ? Cr[a][b][c].im : Cr[a][b][c].re);
  return out;
}

constexpr auto CG000 = cg_real_ct<0,0,0>();
constexpr auto CG110 = cg_real_ct<1,1,0>();
constexpr auto CG220 = cg_real_ct<2,2,0>();
constexpr auto CG330 = cg_real_ct<3,3,0>();
constexpr auto CG011 = cg_real_ct<0,1,1>();
constexpr auto CG101 = cg_real_ct<1,0,1>();
constexpr auto CG111 = cg_real_ct<1,1,1>();
constexpr auto CG121 = cg_real_ct<1,2,1>();
constexpr auto CG211 = cg_real_ct<2,1,1>();
constexpr auto CG221 = cg_real_ct<2,2,1>();
constexpr auto CG231 = cg_real_ct<2,3,1>();
constexpr auto CG321 = cg_real_ct<3,2,1>();
constexpr auto CG331 = cg_real_ct<3,3,1>();

// zero-pruned FMA term: coefficient folds to a literal; zero terms are deleted.
#define TERM(TBL, IDX, PROD, ACC) { float c_ = TBL.v[IDX]; if (c_ != 0.0f) ACC = fmaf((PROD), c_, ACC); }

// Per-lane weight schedule: lane ℓ, sub-index q (0..7) -> (column in [0,272) or -1, LDS slot).
// Slot 31 is a guaranteed-zero slot. constexpr: usable on host (INV build) and device.
__host__ __device__ constexpr void lane_sched(int lane, int q, int& col, int& slot){
  col = -1; slot = 31;
  if (lane < 16){
    int s = q >> 2, qq = q & 3;
    int a = 2*lane + s;                 // scalar output index 0..31
    const int base0[4] = {0, 64, 144, 224};
    col = base0[qq] + a; slot = qq;
  } else if (lane < 40){
    int idx = lane-16, u = idx/3, k = idx-3*u;
    const int wb[6] = {32,48,112,128,192,208};
    const int sb[6] = {4,7,10,13,16,19};
    if (q < 6){ col = wb[q]+u; slot = sb[q]+k; }
  } else if (lane < 52){
    int m = lane-40;
    int c0 = (q < 4) ? 2*m : 2*m+1;
    int u = c0/3, k = c0-3*u;
    int qq = (q < 4) ? q : q-4;
    if (qq < 3){
      const int wb[3] = {96,176,256};
      const int sb[3] = {22,25,28};
      col = wb[qq]+u; slot = sb[qq]+k;
    }
  }
}

// Compile-time inverse map: column -> packed tabP positions (<=3, shared weights dup'd).
struct InvMap { short cnt[272]; short pos[272][3]; };
constexpr InvMap build_inv(){
  InvMap v{};
  for (int c=0;c<272;++c) v.cnt[c]=0;
  for (int p=0;p<512;++p){
    int col=-1, slot=31;
    lane_sched(p>>3, p&7, col, slot);
    if (col>=0){ v.pos[col][v.cnt[col]] = (short)p; v.cnt[col] = (short)(v.cnt[col]+1); }
  }
  return v;
}
constexpr auto INV = build_inv();

// ---------------- device helpers ----------------
__device__ __forceinline__ void afadd(float* p, float v){ unsafeAtomicAdd(p, v); }

__device__ __forceinline__ float soh(float r, float c){
  float d = (r - c) * 2.0f;
  float d2 = d*d;
  return (d2 < 1.0f) ? 1.14136f * expf(2.0f + 1.0f/(d2-1.0f)) : 0.0f;
}

__device__ __forceinline__ float bf_lo(unsigned u){ return __uint_as_float(u << 16); }
__device__ __forceinline__ float bf_hi(unsigned u){ return __uint_as_float(u & 0xFFFF0000u); }
__device__ __forceinline__ unsigned short bfpack(float v){
  unsigned b = __float_as_uint(v);
  return (unsigned short)((b + 0x7FFFu + ((b >> 16) & 1u)) >> 16);   // RTNE
}
__device__ __forceinline__ void unp8(uint4 u, float* o){
  o[0]=bf_lo(u.x); o[1]=bf_hi(u.x); o[2]=bf_lo(u.y); o[3]=bf_hi(u.y);
  o[4]=bf_lo(u.z); o[5]=bf_hi(u.z); o[6]=bf_lo(u.w); o[7]=bf_hi(u.w);
}

// ---------------- stage A (fused): tabP/tab2b build + k_x(+rowptr) + out-zero -------
#define TBLK 1008
#define XB   256
__global__ __launch_bounds__(256) void k_stageA(
    const float* __restrict__ W1, const float* __restrict__ W2,
    const float* __restrict__ W1f, const float* __restrict__ W2f,
    unsigned short* __restrict__ tabP, unsigned short* __restrict__ tab2b,
    const float* __restrict__ pos, const int* __restrict__ src,
    const int* __restrict__ dst, int E, int* __restrict__ rowptr,
    float* __restrict__ xacc, float* __restrict__ out, int outN)
{
  const int bid = blockIdx.x;
  if (bid < TBLK){
    const int jq  = bid / 12;                   // 0..83
    const int t   = (bid % 12)*256 + threadIdx.x;
    const int j0  = jq*4;
    const float dr = 2.5f / (float)(T_TAB-1);
    const float r = (float)t * dr;
    const float e0 = soh(r,1.0f), e1 = soh(r,1.5f), e2 = soh(r,2.0f);
    float ax=0.f, ay=0.f, az=0.f, aw=0.f;
    if (j0 < 272){
      for (int cc=0; cc<256; ++cc){
        float h = fmaxf(fmaf(e0,W1[cc], fmaf(e1,W1[256+cc], e2*W1[512+cc])), 0.0f);
        float4 w = *(const float4*)(W2 + cc*272 + j0);
        ax = fmaf(h,w.x,ax); ay = fmaf(h,w.y,ay);
        az = fmaf(h,w.z,az); aw = fmaf(h,w.w,aw);
      }
      float val[4] = {ax*0.0625f, ay*0.0625f, az*0.0625f, aw*0.0625f};
      unsigned short* __restrict__ rowp = tabP + (size_t)t*512;
#pragma unroll
      for (int k2=0;k2<4;++k2){
        const int c = j0 + k2;
        const unsigned short bv = bfpack(val[k2]);
        const int cn = INV.cnt[c];
        for (int i=0;i<cn;++i) rowp[INV.pos[c][i]] = bv;
      }
    } else {
      const int jj = j0 - 272;
      for (int cc=0; cc<256; ++cc){
        float h = fmaxf(fmaf(e0,W1f[cc], fmaf(e1,W1f[256+cc], e2*W1f[512+cc])), 0.0f);
        float4 w = *(const float4*)(W2f + cc*64 + jj);
        ax = fmaf(h,w.x,ax); ay = fmaf(h,w.y,ay);
        az = fmaf(h,w.z,az); aw = fmaf(h,w.w,aw);
      }
      ushort4 o;
      o.x = bfpack(ax*0.0625f); o.y = bfpack(ay*0.0625f);
      o.z = bfpack(az*0.0625f); o.w = bfpack(aw*0.0625f);
      *(ushort4*)(tab2b + (size_t)t*64 + jj) = o;
    }
  } else if (bid < TBLK + XB){
    const int tt = (bid-TBLK)*256 + threadIdx.x;
    const int n = tt>>2, q = tt&3;
    // own rowptr binary search (dst globally non-decreasing): target n + (q&1)
    const int tgt = n + (q&1);
    int lo=0, hi=E;
    while (lo<hi){ int mid=(lo+hi)>>1; if (dst[mid] < tgt) lo=mid+1; else hi=mid; }
    if (q==0) rowptr[n] = lo;
    if (q==1 && n==NN-1) rowptr[NN] = lo;
    const int l = threadIdx.x & 63;
    const int base = l & ~3;
    const int r0 = __shfl(lo, base);
    const int r1 = __shfl(lo, base+1);
    const float pdx=pos[3*n], pdy=pos[3*n+1], pdz=pos[3*n+2];
    const float s3=1.73205081f, s5=2.23606798f, s15=3.87298335f;
    const float c33=2.09165007f, c32=10.2469508f, c31=1.62018517f, c30=1.32287566f, cp2=5.12347538f;
    float a0=0,a1=0,a2=0,a3=0,a4=0,a5=0,a6=0,a7=0,a8=0,a9=0,a10=0,a11=0,a12=0,a13=0,a14=0,a15=0;
    for (int e=r0+q; e<r1; e+=4){
      const int s=src[e];
      float ax=pos[3*s]-pdx, ay=pos[3*s+1]-pdy, az=pos[3*s+2]-pdz;
      float ir = 1.0f/sqrtf(ax*ax+ay*ay+az*az);
      float x=ax*ir, y=ay*ir, z=az*ir;
      a0+=1.0f; a1+=s3*y; a2+=s3*z; a3+=s3*x;
      a4+=s15*x*y; a5+=s15*y*z; a6+=0.5f*s5*(3.0f*z*z-1.0f); a7+=s15*x*z;
      a8+=0.5f*s15*(x*x-y*y); a9+=c33*y*(3.0f*x*x-y*y); a10+=c32*x*y*z; a11+=c31*y*(5.0f*z*z-1.0f);
      a12+=c30*(5.0f*z*z*z-3.0f*z); a13+=c31*x*(5.0f*z*z-1.0f); a14+=cp2*z*(x*x-y*y);
      a15+=c33*x*(x*x-3.0f*y*y);
    }
#define RED(v) v += __shfl_xor(v,1); v += __shfl_xor(v,2);
    RED(a0) RED(a1) RED(a2) RED(a3) RED(a4) RED(a5) RED(a6) RED(a7)
    RED(a8) RED(a9) RED(a10) RED(a11) RED(a12) RED(a13) RED(a14) RED(a15)
#undef RED
    float o0,o1,o2,o3;
    if (q==0){ o0=a0; o1=a1; o2=a2; o3=a3; }
    else if (q==1){ o0=a4; o1=a5; o2=a6; o3=a7; }
    else if (q==2){ o0=a8; o1=a9; o2=a10; o3=a11; }
    else { o0=a12; o1=a13; o2=a14; o3=a15; }
    *(float4*)(xacc + (size_t)n*16 + q*4) = make_float4(o0,o1,o2,o3);
  } else {
    const int idx = (bid - TBLK - XB)*256 + threadIdx.x;
    if (idx < outN) out[idx] = 0.0f;
  }
}

// ---------------- fctp1 + gate fused: ONE WAVE covers TWO nodes (NG=2, CH2=32) ------
// 8192 one-wave blocks = 32/CU resident (was 4096 = 16/CU, entire grid co-resident at
// 31% occupancy -- tp1 was latency-bound on the phase-2 L2 row loads with too few
// waves to hide them). Per-node edge accumulation order unchanged -> bit-identical.
__global__ __launch_bounds__(64) void k_tp1(
    const float* __restrict__ pos, const int* __restrict__ src,
    const int* __restrict__ rowptr, const float* __restrict__ xacc,
    const unsigned short* __restrict__ tabP, unsigned short* __restrict__ xgb)
{
  const int lane = threadIdx.x;
  const int nb   = blockIdx.x*NG;
  const int g    = lane >> 5, je = lane & 31;
  __shared__ float SI[NG][CH2][33];   // 0..30 intermediates, 31 zero
  __shared__ int   SiT[NG][CH2];
  __shared__ float SG[NG][32];

  int rp[NG+1];
#pragma unroll
  for (int q=0;q<=NG;++q) rp[q] = rowptr[nb+q];
  int deg[NG];
#pragma unroll
  for (int q=0;q<NG;++q) deg[q] = rp[q+1]-rp[q];
  const int dmax = max(deg[0],deg[1]);
  const int nch = (dmax + CH2 - 1) / CH2;

  // ---- static LDS-slot schedule + gate indices ----
  int ioS[8];
#pragma unroll
  for (int p=0;p<8;++p){ int c_=-1, s_=31; lane_sched(lane, p, c_, s_); ioS[p] = s_; }
  int gu0=16, gu1=16;
  if (lane >= 16 && lane < 40){ gu0 = 16 + (lane-16)/3; }
  else if (lane >= 40 && lane < 52){
    int m=lane-40; gu0 = 24 + (2*m)/3; gu1 = 24 + (2*m+1)/3;
  }

  const int mynode = nb + g;
  const float pdx=pos[3*mynode], pdy=pos[3*mynode+1], pdz=pos[3*mynode+2];
  float acc0[NG]={0,0}, acc1[NG]={0,0};

  for (int t=0; t<nch; ++t){
    __syncthreads();                 // WAR: prev chunk phase-2 reads done
    const int cg_ = deg[g] - t*CH2;  // my group's remaining edges
    if (je < cg_){
      const int e = rp[g] + t*CH2 + je;
      const int s = src[e];
      float ax=pos[3*s]-pdx, ay=pos[3*s+1]-pdy, az=pos[3*s+2]-pdz;
      float r = sqrtf(ax*ax+ay*ay+az*az);
      float ir = 1.0f/r;
      float x=ax*ir, y=ay*ir, z=az*ir;
      float f = r * 1228.4f;                    // (T_TAB-1)/2.5
      int i0 = (int)(f + 0.5f);                 // nearest row
      if (i0 > T_TAB-1) i0 = T_TAB-1;

      const float s3=1.73205081f, s5=2.23606798f, s15=3.87298335f;
      const float c33=2.09165007f, c32=10.2469508f, c31=1.62018517f, c30=1.32287566f, cp2=5.12347538f;
      float Y[16];
      Y[0]=1.0f;
      Y[1]=s3*y; Y[2]=s3*z; Y[3]=s3*x;
      Y[4]=s15*x*y; Y[5]=s15*y*z; Y[6]=0.5f*s5*(3.0f*z*z-1.0f); Y[7]=s15*x*z; Y[8]=0.5f*s15*(x*x-y*y);
      Y[9]=c33*y*(3.0f*x*x-y*y); Y[10]=c32*x*y*z; Y[11]=c31*y*(5.0f*z*z-1.0f);
      Y[12]=c30*(5.0f*z*z*z-3.0f*z); Y[13]=c31*x*(5.0f*z*z-1.0f); Y[14]=cp2*z*(x*x-y*y);
      Y[15]=c33*x*(x*x-3.0f*y*y);
      float X[16];
      {
        const float inv = 0.5129891760f;           // 1/sqrt(3.8)
        const float4* q4 = (const float4*)(xacc + (size_t)s*16);
        float4 a=q4[0],b=q4[1],cc4=q4[2],d4=q4[3];
        X[0]=a.x*inv;X[1]=a.y*inv;X[2]=a.z*inv;X[3]=a.w*inv;
        X[4]=b.x*inv;X[5]=b.y*inv;X[6]=b.z*inv;X[7]=b.w*inv;
        X[8]=cc4.x*inv;X[9]=cc4.y*inv;X[10]=cc4.z*inv;X[11]=cc4.w*inv;
        X[12]=d4.x*inv;X[13]=d4.y*inv;X[14]=d4.z*inv;X[15]=d4.w*inv;
      }
      float* SS = SI[g][je];

      // t-block (scalar outputs)
      {
        float t0v = CG000.v[0]*X[0]*Y[0];
        float t1v=0.f, t2v=0.f, t3v=0.f;
#pragma unroll
        for (int i=0;i<3;++i)
#pragma unroll
          for (int j=0;j<3;++j) TERM(CG110, i*3+j, X[1+i]*Y[1+j], t1v)
#pragma unroll
        for (int i=0;i<5;++i)
#pragma unroll
          for (int j=0;j<5;++j) TERM(CG220, i*5+j, X[4+i]*Y[4+j], t2v)
#pragma unroll
        for (int i=0;i<7;++i)
#pragma unroll
          for (int j=0;j<7;++j) TERM(CG330, i*7+j, X[9+i]*Y[9+j], t3v)
        SS[0]=t0v; SS[1]=t1v; SS[2]=t2v; SS[3]=t3v;
      }
      // vector outputs
      {
        float v01[3]={0,0,0}, v10[3]={0,0,0}, v11[3]={0,0,0}, v12[3]={0,0,0},
              v21[3]={0,0,0}, v22[3]={0,0,0}, v23[3]={0,0,0}, v32[3]={0,0,0}, v33[3]={0,0,0};
#pragma unroll
        for (int j=0;j<3;++j){ float tt=X[0]*Y[1+j];
#pragma unroll
          for (int k=0;k<3;++k) TERM(CG011, j*3+k, tt, v01[k]) }
#pragma unroll
        for (int i=0;i<3;++i){ float tt=X[1+i]*Y[0];
#pragma unroll
          for (int k=0;k<3;++k) TERM(CG101, i*3+k, tt, v10[k]) }
#pragma unroll
        for (int i=0;i<3;++i)
#pragma unroll
          for (int j=0;j<3;++j){ float tt=X[1+i]*Y[1+j];
#pragma unroll
            for (int k=0;k<3;++k) TERM(CG111, (i*3+j)*3+k, tt, v11[k]) }
#pragma unroll
        for (int i=0;i<3;++i)
#pragma unroll
          for (int j=0;j<5;++j){ float tt=X[1+i]*Y[4+j];
#pragma unroll
            for (int k=0;k<3;++k) TERM(CG121, (i*5+j)*3+k, tt, v12[k]) }
#pragma unroll
        for (int i=0;i<5;++i)
#pragma unroll
          for (int j=0;j<3;++j){ float tt=X[4+i]*Y[1+j];
#pragma unroll
            for (int k=0;k<3;++k) TERM(CG211, (i*3+j)*3+k, tt, v21[k]) }
#pragma unroll
        for (int i=0;i<5;++i)
#pragma unroll
          for (int j=0;j<5;++j){ float tt=X[4+i]*Y[4+j];
#pragma unroll
            for (int k=0;k<3;++k) TERM(CG221, (i*5+j)*3+k, tt, v22[k]) }
#pragma unroll
        for (int i=0;i<5;++i)
#pragma unroll
          for (int j=0;j<7;++j){ float tt=X[4+i]*Y[9+j];
#pragma unroll
            for (int k=0;k<3;++k) TERM(CG231, (i*7+j)*3+k, tt, v23[k]) }
#pragma unroll
        for (int i=0;i<7;++i)
#pragma unroll
          for (int j=0;j<5;++j){ float tt=X[9+i]*Y[4+j];
#pragma unroll
            for (int k=0;k<3;++k) TERM(CG321, (i*5+j)*3+k, tt, v32[k]) }
#pragma unroll
        for (int i=0;i<7;++i)
#pragma unroll
          for (int j=0;j<7;++j){ float tt=X[9+i]*Y[9+j];
#pragma unroll
            for (int k=0;k<3;++k) TERM(CG331, (i*7+j)*3+k, tt, v33[k]) }
#pragma unroll
        for (int k=0;k<3;++k){
          SS[4+k]=v01[k]; SS[7+k]=v10[k]; SS[10+k]=v12[k]; SS[13+k]=v21[k];
          SS[16+k]=v23[k]; SS[19+k]=v32[k]; SS[22+k]=v11[k]; SS[25+k]=v22[k]; SS[28+k]=v33[k];
        }
      }
      SS[31]=0.0f;
      SiT[g][je]=i0;
    }
    __syncthreads();                 // RAW: phase-1 SI/SiT visible
    // ---- phase 2: per-node accumulation, single nearest bf16 row ----
#pragma unroll
    for (int q=0;q<NG;++q){
      const int cq = deg[q] - t*CH2;
#pragma unroll 4
      for (int j=0; j<CH2; ++j){
        if (j < cq){
          const float* __restrict__ I = SI[q][j];
          const unsigned short* __restrict__ wp = tabP + ((size_t)SiT[q][j]*512) + 8*lane;
          uint4 ra = *(const uint4*)wp;          // 8 bf16 weights
          float a8[8];
          unp8(ra, a8);
          acc0[q] = fmaf(a8[0], I[ioS[0]], acc0[q]);
          acc0[q] = fmaf(a8[1], I[ioS[1]], acc0[q]);
          acc0[q] = fmaf(a8[2], I[ioS[2]], acc0[q]);
          acc0[q] = fmaf(a8[3], I[ioS[3]], acc0[q]);
          acc1[q] = fmaf(a8[4], I[ioS[4]], acc1[q]);
          acc1[q] = fmaf(a8[5], I[ioS[5]], acc1[q]);
          acc1[q] = fmaf(a8[6], I[ioS[6]], acc1[q]);
          acc1[q] = fmaf(a8[7], I[ioS[7]], acc1[q]);
        }
      }
    }
  }

  // ---- fused gate epilogue (per node), bf16 output ----
  const float inv = 0.5129891760f;
  if (lane < 16){
#pragma unroll
    for (int q=0;q<NG;++q){
      SG[q][2*lane]   = acc0[q]*0.5f*inv;
      SG[q][2*lane+1] = acc1[q]*0.5f*inv;
    }
  }
  __syncthreads();
#pragma unroll
  for (int q=0;q<NG;++q){
    unsigned short* __restrict__ o = xgb + (size_t)(nb+q)*64;
    if (lane < 16){
      o[lane] = bfpack(fmaxf(SG[q][lane], 0.0f));            // se
    } else if (lane < 40){
      int idx = lane-16;
      float vv = (acc0[q]+acc1[q])*0.4082482905f*inv;
      o[16+idx] = bfpack(vv * fmaxf(SG[q][gu0], 0.0f));      // v1o (u<8)
    } else if (lane < 52){
      int m = lane-40;
      float vv0 = acc0[q]*0.5773502692f*inv;
      float vv1 = acc1[q]*0.5773502692f*inv;
      o[40+2*m]   = bfpack(vv0 * fmaxf(SG[q][gu0], 0.0f));   // v1e (u<8)
      o[40+2*m+1] = bfpack(vv1 * fmaxf(SG[q][gu1], 0.0f));
    }
  }
}

// ---------------- fctp2 + fused dst-segmented reduction -> out ----------------
__global__ __launch_bounds__(256) void k_tp2(
    const float* __restrict__ pos, const int* __restrict__ src, const int* __restrict__ dst, int E,
    const unsigned short* __restrict__ xgb, const unsigned short* __restrict__ tab2b,
    float* __restrict__ out)
{
  const int tid = threadIdx.x;
  const int e = blockIdx.x*256 + tid;
  __shared__ float S0[256], S1[256], S2[256];
  __shared__ int   D[256];
  float e2[3]={0,0,0};
  int dd = -1;
  if (e < E){
    const int s = src[e];
    dd = dst[e];
    float ax=pos[3*s]-pos[3*dd], ay=pos[3*s+1]-pos[3*dd+1], az=pos[3*s+2]-pos[3*dd+2];
    float r = sqrtf(ax*ax+ay*ay+az*az);
    float ir = 1.0f/r;
    float x=ax*ir, y=ay*ir, z=az*ir;
    float f = r * 1228.4f;                     // (T_TAB-1)/2.5
    int i0 = (int)(f + 0.5f);                  // nearest row
    if (i0 > T_TAB-1) i0 = T_TAB-1;
    const unsigned short* __restrict__ w0 = tab2b + (size_t)i0*64;
    float wse[16], wA[8], wB[8], wC[8];
    unp8(*(const uint4*)(w0+0),  wse);
    unp8(*(const uint4*)(w0+8),  wse+8);
    unp8(*(const uint4*)(w0+16), wA);
    unp8(*(const uint4*)(w0+32), wB);
    unp8(*(const uint4*)(w0+48), wC);
    const float s3=1.73205081f, s5=2.23606798f, s15=3.87298335f;
    float Y[9];
    Y[0]=1.0f;
    Y[1]=s3*y; Y[2]=s3*z; Y[3]=s3*x;
    Y[4]=s15*x*y; Y[5]=s15*y*z; Y[6]=0.5f*s5*(3.0f*z*z-1.0f); Y[7]=s15*x*z; Y[8]=0.5f*s15*(x*x-y*y);
    const unsigned short* __restrict__ g = xgb + (size_t)s*64;
    float se[16], vo[24], ve[24];
    unp8(*(const uint4*)(g+0),  se);  unp8(*(const uint4*)(g+8),  se+8);
    unp8(*(const uint4*)(g+16), vo);  unp8(*(const uint4*)(g+24), vo+8); unp8(*(const uint4*)(g+32), vo+16);
    unp8(*(const uint4*)(g+40), ve);  unp8(*(const uint4*)(g+48), ve+8); unp8(*(const uint4*)(g+56), ve+16);

    float SA=0.0f;
#pragma unroll
    for (int u=0;u<16;++u) SA = fmaf(wse[u], se[u], SA);
    float AB[3]={0,0,0}, AC[3]={0,0,0}, AD[3]={0,0,0};
#pragma unroll
    for (int u=0;u<8;++u)
#pragma unroll
      for (int i=0;i<3;++i){
        AB[i]=fmaf(wA[u], vo[u*3+i], AB[i]);
        AC[i]=fmaf(wB[u], vo[u*3+i], AC[i]);
        AD[i]=fmaf(wC[u], ve[u*3+i], AD[i]);
      }
#pragma unroll
    for (int j=0;j<3;++j){ float t=SA*Y[1+j];
#pragma unroll
      for (int k=0;k<3;++k) TERM(CG011, j*3+k, t, e2[k]) }
#pragma unroll
    for (int i=0;i<3;++i){ float t=AB[i]*Y[0];
#pragma unroll
      for (int k=0;k<3;++k) TERM(CG101, i*3+k, t, e2[k]) }
#pragma unroll
    for (int i=0;i<3;++i)
#pragma unroll
      for (int j=0;j<5;++j){ float t=AC[i]*Y[4+j];
#pragma unroll
        for (int k=0;k<3;++k) TERM(CG121, (i*5+j)*3+k, t, e2[k]) }
#pragma unroll
    for (int i=0;i<3;++i)
#pragma unroll
      for (int j=0;j<3;++j){ float t=AD[i]*Y[1+j];
#pragma unroll
        for (int k=0;k<3;++k) TERM(CG111, (i*3+j)*3+k, t, e2[k]) }
  }
  S0[tid]=e2[0]; S1[tid]=e2[1]; S2[tid]=e2[2]; D[tid]=dd;
  __syncthreads();
  if (e < E && (tid==0 || D[tid-1] != dd)){
    float a0=0.f, a1=0.f, a2=0.f;
    int j = tid;
    while (j < 256 && D[j] == dd){ a0+=S0[j]; a1+=S1[j]; a2+=S2[j]; ++j; }
    const float sc = 0.0641236437f;  // (1/sqrt(64)) * 1/sqrt(3.8)
    afadd(out + (size_t)dd*3 + 0, a0*sc);
    afadd(out + (size_t)dd*3 + 1, a1*sc);
    afadd(out + (size_t)dd*3 + 2, a2*sc);
  }
}

// ---------------- host launcher ----------------
extern "C" void kernel_launch(void* const* d_in, const int* in_sizes, int n_in,
                              void* d_out, int out_size, void* d_ws, size_t ws_size,
                              hipStream_t stream)
{
  (void)n_in; (void)ws_size;
  const float* pos = (const float*)d_in[0];
  const int*   src = (const int*)d_in[1];
  const int*   dst = (const int*)d_in[2];
  const float* W1  = (const float*)d_in[3];
  const float* W2  = (const float*)d_in[4];
  const float* W1f = (const float*)d_in[5];
  const float* W2f = (const float*)d_in[6];
  const int E = in_sizes[1];

  char* ws = (char*)d_ws;
  float* xacc  = (float*)ws;                     // NN*16
  unsigned short* xgb = (unsigned short*)(xacc + (size_t)NN*16);        // NN*64 ushort
  unsigned short* tab2b = xgb + (size_t)NN*64;   // T_TAB*64 ushort
  unsigned short* tabP  = tab2b + (size_t)T_TAB*64;                     // T_TAB*512 ushort
  int*   rowptr= (int*)(tabP + (size_t)T_TAB*512);                      // NN+1

  const int ozb = (out_size + 255) / 256;
  k_stageA<<<TBLK + XB + ozb, 256, 0, stream>>>(W1, W2, W1f, W2f, tabP, tab2b,
                                                pos, src, dst, E, rowptr, xacc,
                                                (float*)d_out, out_size);
  k_tp1<<<NN/NG, 64, 0, stream>>>(pos, src, rowptr, xacc, tabP, xgb);
  k_tp2<<<(E + 255) / 256, 256, 0, stream>>>(pos, src, dst, E, xgb, tab2b, (float*)d_out);
}